// Round 2
// baseline (1059.125 us; speedup 1.0000x reference)
//
#include <hip/hip_runtime.h>
#include <hip/hip_bf16.h>

#define NN 100000
#define EE 800000
#define ETOT 900000   // EE + NN self loops
#define HID 128
#define NH 4
#define CH 32
#define NL 3
#define NOUT 5
#define NEG_SLOPE 0.2f
#define LN_EPS 1e-5f

// ---------------------------------------------------------------------------
// CSR build: histogram (+ degree & edge-attr sums for self-loop fill), scan,
// scatter. Edge e<EE: src=ei[e], dst=ei[EE+e]. Edge e>=EE: self loop n=e-EE.
// ---------------------------------------------------------------------------
__global__ void hist_kernel(const int* __restrict__ ei, const float* __restrict__ ea,
                            int* __restrict__ rowcnt, float* __restrict__ degf,
                            float* __restrict__ easum) {
    int e = blockIdx.x * blockDim.x + threadIdx.x;
    if (e >= ETOT) return;
    if (e < EE) {
        int d = ei[EE + e];
        atomicAdd(&rowcnt[d + 1], 1);
        atomicAdd(&degf[d], 1.0f);
        atomicAdd(&easum[d], ea[e]);
    } else {
        int n = e - EE;
        atomicAdd(&rowcnt[n + 1], 1);
    }
}

// single-block inclusive scan over n ints (in place), 1024 threads
__global__ void scan_kernel(int* __restrict__ data, int n) {
    __shared__ int wsum[16];
    __shared__ int carry_s;
    if (threadIdx.x == 0) carry_s = 0;
    __syncthreads();
    int lane = threadIdx.x & 63, wid = threadIdx.x >> 6;
    for (int base = 0; base < n; base += 1024) {
        int i = base + threadIdx.x;
        int v = (i < n) ? data[i] : 0;
        int s = v;
        #pragma unroll
        for (int off = 1; off < 64; off <<= 1) {
            int t = __shfl_up(s, off, 64);
            if (lane >= off) s += t;
        }
        if (lane == 63) wsum[wid] = s;
        __syncthreads();
        int add = carry_s;
        for (int ww = 0; ww < wid; ww++) add += wsum[ww];
        int res = s + add;
        if (i < n) data[i] = res;
        __syncthreads();
        if (threadIdx.x == 1023) carry_s = res;  // tid 1023's res == chunk total prefix
        __syncthreads();
    }
}

__global__ void scatter_kernel(const int* __restrict__ ei, const float* __restrict__ ea,
                               const int* __restrict__ rowptr, int* __restrict__ fill,
                               const float* __restrict__ degf, const float* __restrict__ easum,
                               int* __restrict__ src_s, float* __restrict__ ea_s) {
    int e = blockIdx.x * blockDim.x + threadIdx.x;
    if (e >= ETOT) return;
    int s, d; float v;
    if (e < EE) {
        s = ei[e]; d = ei[EE + e]; v = ea[e];
    } else {
        int n = e - EE;
        s = n; d = n;
        v = easum[n] / fmaxf(degf[n], 1.0f);   // PyG fill_value='mean'
    }
    int pos = rowptr[d] + atomicAdd(&fill[d], 1);
    src_s[pos] = s;
    ea_s[pos] = v;
}

// ---------------------------------------------------------------------------
// h0 = x @ Win + b_in   (x:[N,32] fp32, Win:[32,128] fp32) -> h fp32 [N,128]
// one wave per node; each lane computes 2 output columns
// ---------------------------------------------------------------------------
__global__ __launch_bounds__(64) void input_proj_kernel(const float* __restrict__ x,
                                                        const float* __restrict__ Win,
                                                        const float* __restrict__ b_in,
                                                        float* __restrict__ h) {
    int n = blockIdx.x;
    int lane = threadIdx.x;
    float xr[32];
    #pragma unroll
    for (int k = 0; k < 32; k += 4) {
        float4 v = *(const float4*)&x[n * 32 + k];
        xr[k] = v.x; xr[k + 1] = v.y; xr[k + 2] = v.z; xr[k + 3] = v.w;
    }
    int c0 = lane * 2;
    float a0 = 0.f, a1 = 0.f;
    #pragma unroll
    for (int k = 0; k < 32; k++) {
        a0 += xr[k] * Win[k * HID + c0];
        a1 += xr[k] * Win[k * HID + c0 + 1];
    }
    h[(size_t)n * HID + c0]     = a0 + b_in[c0];
    h[(size_t)n * HID + c0 + 1] = a1 + b_in[c0 + 1];
}

// ---------------------------------------------------------------------------
// xh = h @ Wg[l]  (h fp32 [N,128], Wg fp32 [128,128]) -> xh fp32 [N,128]
// block=256, tile 64 rows x 128 cols, K slabs of 32 staged in LDS
// thread: 8 rows x 4 cols
// ---------------------------------------------------------------------------
__global__ __launch_bounds__(256) void gemm128_kernel(const float* __restrict__ h,
                                                      const float* __restrict__ W,
                                                      float* __restrict__ xh) {
    __shared__ float hs[64][33];
    __shared__ float ws[32][128];
    int n0 = blockIdx.x * 64;
    int t = threadIdx.x;
    int cg = t & 31, rg = t >> 5;
    int c0 = cg * 4, r0 = rg * 8;
    float acc[8][4] = {};
    for (int ksl = 0; ksl < HID; ksl += 32) {
        // stage h slab: 64 rows x 32 k (fp32) = 512 float4
        #pragma unroll
        for (int it = 0; it < 2; it++) {
            int idx = t + it * 256;          // 0..511
            int row = idx >> 3;
            int kk = (idx & 7) * 4;
            float4 v = make_float4(0.f, 0.f, 0.f, 0.f);
            if (n0 + row < NN) v = *(const float4*)&h[(size_t)(n0 + row) * HID + ksl + kk];
            hs[row][kk] = v.x; hs[row][kk + 1] = v.y; hs[row][kk + 2] = v.z; hs[row][kk + 3] = v.w;
        }
        // stage W slab: 32 k x 128 cols = 1024 float4
        #pragma unroll
        for (int it = 0; it < 4; it++) {
            int idx = t + it * 256;          // 0..1023
            int kr = idx >> 5;               // 32 float4 per k-row
            int f4 = (idx & 31) * 4;
            float4 v = *(const float4*)&W[(size_t)(ksl + kr) * HID + f4];
            ws[kr][f4] = v.x; ws[kr][f4 + 1] = v.y; ws[kr][f4 + 2] = v.z; ws[kr][f4 + 3] = v.w;
        }
        __syncthreads();
        #pragma unroll 8
        for (int k = 0; k < 32; k++) {
            float b0 = ws[k][c0], b1 = ws[k][c0 + 1], b2 = ws[k][c0 + 2], b3 = ws[k][c0 + 3];
            #pragma unroll
            for (int i = 0; i < 8; i++) {
                float a = hs[r0 + i][k];
                acc[i][0] += a * b0; acc[i][1] += a * b1;
                acc[i][2] += a * b2; acc[i][3] += a * b3;
            }
        }
        __syncthreads();
    }
    #pragma unroll
    for (int i = 0; i < 8; i++) {
        int row = n0 + r0 + i;
        if (row < NN) {
            float4 v = make_float4(acc[i][0], acc[i][1], acc[i][2], acc[i][3]);
            *(float4*)&xh[(size_t)row * HID + c0] = v;
        }
    }
}

// ---------------------------------------------------------------------------
// al_s[n,h] = sum_c xh[n,h,c]*a_src[h,c]  (and al_d)
// ---------------------------------------------------------------------------
__global__ void al_kernel(const float* __restrict__ xh,
                          const float* __restrict__ a_src,
                          const float* __restrict__ a_dst,
                          float* __restrict__ al_s, float* __restrict__ al_d) {
    int t = blockIdx.x * blockDim.x + threadIdx.x;
    if (t >= NN * NH) return;
    int n = t >> 2, hh = t & 3;
    const float* row = xh + (size_t)n * HID + hh * CH;
    float s = 0.f, d = 0.f;
    #pragma unroll
    for (int c = 0; c < CH; c++) {
        float v = row[c];
        s += v * a_src[hh * CH + c];
        d += v * a_dst[hh * CH + c];
    }
    al_s[t] = s;
    al_d[t] = d;
}

// we_dot[h] = sum_c We[h*32+c] * a_edge[h,c]
__global__ void wedot_kernel(const float* __restrict__ We,
                             const float* __restrict__ a_e,
                             float* __restrict__ wedot) {
    int hh = threadIdx.x;
    if (hh >= NH) return;
    float s = 0.f;
    #pragma unroll
    for (int c = 0; c < CH; c++) s += We[hh * CH + c] * a_e[hh * CH + c];
    wedot[hh] = s;
}

// ---------------------------------------------------------------------------
// GAT aggregation: one wave per destination node. Pass 1: per-head max of
// leaky_relu logits (lane-parallel over edges + shuffle-butterfly).
// Pass 2: serial over edges, all lanes; lane owns 2 channels.
//   out = (sum ex*xh[src]) / (den + 1e-16) + bg, stored fp32 to g.
// Also accumulates (sum, sumsq) for graph-LayerNorm into spread partials.
// ---------------------------------------------------------------------------
__global__ __launch_bounds__(64) void gat_agg_kernel(const int* __restrict__ rowptr,
                                                     const int* __restrict__ src_s,
                                                     const float* __restrict__ ea_s,
                                                     const float* __restrict__ xh,
                                                     const float* __restrict__ al_s,
                                                     const float* __restrict__ al_d,
                                                     const float* __restrict__ wedot,
                                                     const float* __restrict__ bg,
                                                     float* __restrict__ g,
                                                     float* __restrict__ partials) {
    int n = blockIdx.x;
    int lane = threadIdx.x;
    int head = lane >> 4;          // 2 channels/lane -> 16 lanes per head
    int rs = rowptr[n], re = rowptr[n + 1];
    float wd[4] = { wedot[0], wedot[1], wedot[2], wedot[3] };
    float4 aldv = *(const float4*)&al_d[n * 4];
    float ald[4] = { aldv.x, aldv.y, aldv.z, aldv.w };

    // pass 1: per-head max over incoming edges
    float mx[4] = { -1e30f, -1e30f, -1e30f, -1e30f };
    for (int i = rs + lane; i < re; i += 64) {
        int s = src_s[i];
        float eav = ea_s[i];
        float4 als = *(const float4*)&al_s[s * 4];
        float alsa[4] = { als.x, als.y, als.z, als.w };
        #pragma unroll
        for (int hh = 0; hh < 4; hh++) {
            float lg = alsa[hh] + ald[hh] + eav * wd[hh];
            lg = lg > 0.f ? lg : NEG_SLOPE * lg;
            mx[hh] = fmaxf(mx[hh], lg);
        }
    }
    #pragma unroll
    for (int off = 32; off; off >>= 1) {
        #pragma unroll
        for (int hh = 0; hh < 4; hh++) mx[hh] = fmaxf(mx[hh], __shfl_xor(mx[hh], off, 64));
    }
    float m = mx[head];            // every node has its self-loop -> finite

    // pass 2: fused exp / den / weighted aggregation
    float ald_h = ald[head], wd_h = wd[head];
    int c0 = lane * 2;
    float acc0 = 0.f, acc1 = 0.f, den = 0.f;
    for (int i = rs; i < re; i++) {
        int s = src_s[i];
        float eav = ea_s[i];
        float lg = al_s[s * 4 + head] + ald_h + eav * wd_h;
        lg = lg > 0.f ? lg : NEG_SLOPE * lg;
        float ex = __expf(lg - m);
        den += ex;
        float2 xv = *(const float2*)&xh[(size_t)s * HID + c0];
        acc0 += ex * xv.x;
        acc1 += ex * xv.y;
    }
    float inv = 1.0f / (den + 1e-16f);
    float o0 = acc0 * inv + bg[c0];
    float o1 = acc1 * inv + bg[c0 + 1];
    g[(size_t)n * HID + c0]     = o0;
    g[(size_t)n * HID + c0 + 1] = o1;

    // LayerNorm stats (graph mode: global mean/var)
    float ssum = o0 + o1;
    float ssq = o0 * o0 + o1 * o1;
    #pragma unroll
    for (int off = 32; off; off >>= 1) {
        ssum += __shfl_xor(ssum, off, 64);
        ssq  += __shfl_xor(ssq,  off, 64);
    }
    if (lane == 0) {
        int slot = (n & 1023) * 2;
        atomicAdd(&partials[slot], ssum);
        atomicAdd(&partials[slot + 1], ssq);
    }
}

// reduce 1024 partial (sum,sumsq) pairs -> stats {mean, rstd}
__global__ void stats_kernel(const float* __restrict__ partials, float* __restrict__ stats) {
    __shared__ float ls[16], lq[16];
    int tid = threadIdx.x;
    float s = partials[tid * 2], q = partials[tid * 2 + 1];
    #pragma unroll
    for (int off = 32; off; off >>= 1) {
        s += __shfl_xor(s, off, 64);
        q += __shfl_xor(q, off, 64);
    }
    int lane = tid & 63, wid = tid >> 6;
    if (lane == 0) { ls[wid] = s; lq[wid] = q; }
    __syncthreads();
    if (tid == 0) {
        float S = 0.f, Q = 0.f;
        for (int w = 0; w < 16; w++) { S += ls[w]; Q += lq[w]; }
        const float M = (float)NN * (float)HID;
        float mean = S / M;
        float var = Q / M - mean * mean;
        stats[0] = mean;
        stats[1] = rsqrtf(fmaxf(var, 0.f) + LN_EPS);
    }
}

// h = relu( (g - mean)*rstd*ln_w + ln_b + h )
__global__ void apply_ln_kernel(const float* __restrict__ g, float* __restrict__ h,
                                const float* __restrict__ lnw,
                                const float* __restrict__ lnb,
                                const float* __restrict__ stats) {
    int t = blockIdx.x * blockDim.x + threadIdx.x;
    if (t >= NN * HID / 4) return;
    float mean = stats[0], rstd = stats[1];
    float4 gv = ((const float4*)g)[t];
    float4 hv = ((const float4*)h)[t];
    int c = (t * 4) & (HID - 1);
    float o;
    o = (gv.x - mean) * rstd * lnw[c]     + lnb[c]     + hv.x; hv.x = fmaxf(o, 0.f);
    o = (gv.y - mean) * rstd * lnw[c + 1] + lnb[c + 1] + hv.y; hv.y = fmaxf(o, 0.f);
    o = (gv.z - mean) * rstd * lnw[c + 2] + lnb[c + 2] + hv.z; hv.z = fmaxf(o, 0.f);
    o = (gv.w - mean) * rstd * lnw[c + 3] + lnb[c + 3] + hv.w; hv.w = fmaxf(o, 0.f);
    ((float4*)h)[t] = hv;
}

// out = h @ Wout + bout  (one wave per node, 5 outputs via shuffle reduce)
__global__ __launch_bounds__(64) void out_proj_kernel(const float* __restrict__ h,
                                                      const float* __restrict__ Wout,
                                                      const float* __restrict__ bout,
                                                      float* __restrict__ out) {
    int n = blockIdx.x;
    int lane = threadIdx.x;
    float h0 = h[(size_t)n * HID + lane];
    float h1 = h[(size_t)n * HID + 64 + lane];
    float p[NOUT];
    #pragma unroll
    for (int j = 0; j < NOUT; j++) {
        p[j] = h0 * Wout[lane * NOUT + j] + h1 * Wout[(64 + lane) * NOUT + j];
    }
    #pragma unroll
    for (int off = 32; off; off >>= 1) {
        #pragma unroll
        for (int j = 0; j < NOUT; j++) p[j] += __shfl_xor(p[j], off, 64);
    }
    if (lane == 0) {
        #pragma unroll
        for (int j = 0; j < NOUT; j++)
            out[(size_t)n * NOUT + j] = p[j] + bout[j];
    }
}

// ---------------------------------------------------------------------------
extern "C" void kernel_launch(void* const* d_in, const int* in_sizes, int n_in,
                              void* d_out, int out_size, void* d_ws, size_t ws_size,
                              hipStream_t stream) {
    const float* x      = (const float*)d_in[0];
    const int*   ei     = (const int*)d_in[1];
    const float* ea     = (const float*)d_in[2];
    const float* Win    = (const float*)d_in[3];
    const float* b_in   = (const float*)d_in[4];
    const float* Wg     = (const float*)d_in[5];
    const float* bg     = (const float*)d_in[6];
    const float* a_src  = (const float*)d_in[7];
    const float* a_dst  = (const float*)d_in[8];
    const float* We     = (const float*)d_in[9];
    const float* a_edge = (const float*)d_in[10];
    const float* ln_w   = (const float*)d_in[11];
    const float* ln_b   = (const float*)d_in[12];
    const float* Wout   = (const float*)d_in[13];
    const float* bout   = (const float*)d_in[14];
    float* out = (float*)d_out;

    // workspace layout (256B aligned blocks)
    char* w = (char*)d_ws;
    size_t off = 0;
    auto alloc = [&](size_t bytes) -> void* {
        void* p = w + off;
        off = (off + bytes + 255) & ~(size_t)255;
        return p;
    };
    int*   rowptr  = (int*)alloc((NN + 1) * sizeof(int));
    int*   fill    = (int*)alloc(NN * sizeof(int));
    float* degf    = (float*)alloc(NN * sizeof(float));
    float* easum   = (float*)alloc(NN * sizeof(float));
    size_t zero_span = off;                       // zero everything above in one memset
    int*   src_s   = (int*)alloc(ETOT * sizeof(int));
    float* ea_s    = (float*)alloc(ETOT * sizeof(float));
    float* h       = (float*)alloc((size_t)NN * HID * sizeof(float));
    float* g       = (float*)alloc((size_t)NN * HID * sizeof(float));
    float* xh      = (float*)alloc((size_t)NN * HID * sizeof(float));
    float* al_s    = (float*)alloc((size_t)NN * NH * sizeof(float));
    float* al_d    = (float*)alloc((size_t)NN * NH * sizeof(float));
    float* wedot   = (float*)alloc(16 * sizeof(float));
    float* partials = (float*)alloc(2048 * sizeof(float));
    float* stats   = (float*)alloc(16 * sizeof(float));
    (void)ws_size; (void)n_in; (void)in_sizes; (void)out_size;

    // --- CSR build ---
    hipMemsetAsync(d_ws, 0, zero_span, stream);
    int egrid = (ETOT + 255) / 256;
    hist_kernel<<<egrid, 256, 0, stream>>>(ei, ea, rowptr, degf, easum);
    scan_kernel<<<1, 1024, 0, stream>>>(rowptr, NN + 1);
    scatter_kernel<<<egrid, 256, 0, stream>>>(ei, ea, rowptr, fill, degf, easum, src_s, ea_s);

    // --- input projection ---
    input_proj_kernel<<<NN, 64, 0, stream>>>(x, Win, b_in, h);

    // --- GAT layers ---
    for (int l = 0; l < NL; l++) {
        gemm128_kernel<<<(NN + 63) / 64, 256, 0, stream>>>(h, Wg + (size_t)l * HID * HID, xh);
        al_kernel<<<(NN * NH + 255) / 256, 256, 0, stream>>>(xh, a_src + l * HID, a_dst + l * HID, al_s, al_d);
        wedot_kernel<<<1, 64, 0, stream>>>(We + l * HID, a_edge + l * HID, wedot);
        hipMemsetAsync(partials, 0, 2048 * sizeof(float), stream);
        gat_agg_kernel<<<NN, 64, 0, stream>>>(rowptr, src_s, ea_s, xh, al_s, al_d, wedot,
                                              bg + l * HID, g, partials);
        stats_kernel<<<1, 1024, 0, stream>>>(partials, stats);
        apply_ln_kernel<<<(NN * HID / 4 + 255) / 256, 256, 0, stream>>>(g, h, ln_w + l * HID,
                                                                        ln_b + l * HID, stats);
    }

    // --- output projection ---
    out_proj_kernel<<<NN, 64, 0, stream>>>(h, Wout, bout, out);
}

// Round 3
// 744.001 us; speedup vs baseline: 1.4236x; 1.4236x over previous
//
#include <hip/hip_runtime.h>
#include <hip/hip_bf16.h>

#define NN 100000
#define EE 800000
#define HID 128
#define NH 4
#define CH 32
#define NL 3
#define NOUT 5
#define NEG_SLOPE 0.2f
#define LN_EPS 1e-5f
#define CAP 256            // LDS-cached edges per node row (deg > CAP falls to slow path)
#define NB_SCAN 98         // ceil((NN+1)/1024)

typedef unsigned int u32;

static __device__ __forceinline__ float bflo(u32 r) { return __uint_as_float(r << 16); }
static __device__ __forceinline__ float bfhi(u32 r) { return __uint_as_float(r & 0xffff0000u); }
static __device__ __forceinline__ unsigned short f2bf(float x) {
    union U { __hip_bfloat16 b; unsigned short s; } u;
    u.b = __float2bfloat16(x);
    return u.s;
}

// ---------------------------------------------------------------------------
// CSR build. cnt[n] starts at 1 (self-loop reserved at row slot 0); one atomic
// per real edge whose return value is the edge's slot -> scatter is atomic-free.
// ---------------------------------------------------------------------------
__global__ void init_cnt_kernel(int* __restrict__ cnt) {
    int n = blockIdx.x * blockDim.x + threadIdx.x;
    if (n < NN) cnt[n] = 1;
}

__global__ void hist_kernel(const int* __restrict__ ei, int* __restrict__ cnt,
                            int* __restrict__ slot) {
    int e = blockIdx.x * blockDim.x + threadIdx.x;
    if (e >= EE) return;
    int d = ei[EE + e];
    slot[e] = atomicAdd(&cnt[d], 1);
}

// hierarchical exclusive scan of cnt[0..NN] (element NN treated as 0) -> rowptr
__global__ __launch_bounds__(1024) void scan1_kernel(const int* __restrict__ cnt,
                                                     int* __restrict__ rowptr,
                                                     int* __restrict__ bsum) {
    __shared__ int ws[16];
    int gid = blockIdx.x * 1024 + threadIdx.x;
    int v = (gid < NN) ? cnt[gid] : 0;
    int lane = threadIdx.x & 63, wid = threadIdx.x >> 6;
    int s = v;
    #pragma unroll
    for (int off = 1; off < 64; off <<= 1) {
        int t = __shfl_up(s, off, 64);
        if (lane >= off) s += t;
    }
    if (lane == 63) ws[wid] = s;
    __syncthreads();
    int add = 0;
    for (int w2 = 0; w2 < wid; w2++) add += ws[w2];
    int incl = s + add;
    if (gid <= NN) rowptr[gid] = incl - v;   // exclusive
    if (threadIdx.x == 1023) bsum[blockIdx.x] = incl;
}

__global__ void scan2_kernel(int* __restrict__ bsum) {
    __shared__ int w0tot;
    int tid = threadIdx.x;                   // 128 threads
    int v = (tid < NB_SCAN) ? bsum[tid] : 0;
    int lane = tid & 63, wid = tid >> 6;
    int s = v;
    #pragma unroll
    for (int off = 1; off < 64; off <<= 1) {
        int t = __shfl_up(s, off, 64);
        if (lane >= off) s += t;
    }
    if (wid == 0 && lane == 63) w0tot = s;
    __syncthreads();
    int incl = s + (wid ? w0tot : 0);
    if (tid < NB_SCAN) bsum[tid] = incl - v; // exclusive
}

__global__ void scan3_kernel(int* __restrict__ rowptr, const int* __restrict__ bsum) {
    int gid = blockIdx.x * 1024 + threadIdx.x;
    if (gid <= NN) rowptr[gid] += bsum[blockIdx.x];
}

__global__ void scatter_kernel(const int* __restrict__ ei, const float* __restrict__ ea,
                               const int* __restrict__ rowptr, const int* __restrict__ slot,
                               int* __restrict__ src_s, float* __restrict__ ea_s) {
    int e = blockIdx.x * blockDim.x + threadIdx.x;
    if (e >= EE) return;
    int d = ei[EE + e];
    int pos = rowptr[d] + slot[e];           // slot >= 1; slot 0 is the self loop
    src_s[pos] = ei[e];
    ea_s[pos] = ea[e];
}

// self-loop attr = mean of the row's real-edge attrs (PyG fill_value='mean')
__global__ void selfloop_kernel(const int* __restrict__ rowptr, int* __restrict__ src_s,
                                float* __restrict__ ea_s) {
    int n = blockIdx.x * blockDim.x + threadIdx.x;
    if (n >= NN) return;
    int rs = rowptr[n], re = rowptr[n + 1];
    float s = 0.f;
    for (int i = rs + 1; i < re; i++) s += ea_s[i];
    ea_s[rs] = s / fmaxf((float)(re - rs - 1), 1.0f);
    src_s[rs] = n;
}

// ---------------------------------------------------------------------------
// h0 = x @ Win + b_in
// ---------------------------------------------------------------------------
__global__ __launch_bounds__(64) void input_proj_kernel(const float* __restrict__ x,
                                                        const float* __restrict__ Win,
                                                        const float* __restrict__ b_in,
                                                        float* __restrict__ h) {
    int n = blockIdx.x;
    int lane = threadIdx.x;
    float xr[32];
    #pragma unroll
    for (int k = 0; k < 32; k += 4) {
        float4 v = *(const float4*)&x[n * 32 + k];
        xr[k] = v.x; xr[k + 1] = v.y; xr[k + 2] = v.z; xr[k + 3] = v.w;
    }
    int c0 = lane * 2;
    float a0 = 0.f, a1 = 0.f;
    #pragma unroll
    for (int k = 0; k < 32; k++) {
        a0 += xr[k] * Win[k * HID + c0];
        a1 += xr[k] * Win[k * HID + c0 + 1];
    }
    h[(size_t)n * HID + c0]     = a0 + b_in[c0];
    h[(size_t)n * HID + c0 + 1] = a1 + b_in[c0 + 1];
}

// ---------------------------------------------------------------------------
// xh = hin @ Wg  (xh packed bf16 as u32 pairs). FUSE: hin is produced on the
// fly as relu(LN(g)+h) (prev layer's epilogue) and written back to h.
// ---------------------------------------------------------------------------
template <bool FUSE>
__global__ __launch_bounds__(256) void gemm_kernel(const float* h, const float* __restrict__ W,
                                                   u32* __restrict__ xh, const float* __restrict__ g,
                                                   const float* __restrict__ lnw,
                                                   const float* __restrict__ lnb,
                                                   const float* __restrict__ stats,
                                                   float* hout) {
    __shared__ float hs[64][33];
    __shared__ float ws[32][128];
    float mean = 0.f, rstd = 0.f;
    if (FUSE) { mean = stats[0]; rstd = stats[1]; }
    int n0 = blockIdx.x * 64;
    int t = threadIdx.x;
    int cg = t & 31, rg = t >> 5;
    int c0 = cg * 4, r0 = rg * 8;
    float acc[8][4] = {};
    for (int ksl = 0; ksl < HID; ksl += 32) {
        #pragma unroll
        for (int it = 0; it < 2; it++) {
            int idx = t + it * 256;          // 0..511
            int row = idx >> 3;
            int kk = (idx & 7) * 4;
            int gr = n0 + row;
            float4 v = make_float4(0.f, 0.f, 0.f, 0.f);
            if (gr < NN) {
                size_t base = (size_t)gr * HID + ksl + kk;
                if (FUSE) {
                    float4 gv = *(const float4*)&g[base];
                    float4 hv = *(const float4*)&h[base];
                    float4 w4 = *(const float4*)&lnw[ksl + kk];
                    float4 b4 = *(const float4*)&lnb[ksl + kk];
                    v.x = fmaxf((gv.x - mean) * rstd * w4.x + b4.x + hv.x, 0.f);
                    v.y = fmaxf((gv.y - mean) * rstd * w4.y + b4.y + hv.y, 0.f);
                    v.z = fmaxf((gv.z - mean) * rstd * w4.z + b4.z + hv.z, 0.f);
                    v.w = fmaxf((gv.w - mean) * rstd * w4.w + b4.w + hv.w, 0.f);
                    *(float4*)&hout[base] = v;
                } else {
                    v = *(const float4*)&h[base];
                }
            }
            hs[row][kk] = v.x; hs[row][kk + 1] = v.y; hs[row][kk + 2] = v.z; hs[row][kk + 3] = v.w;
        }
        #pragma unroll
        for (int it = 0; it < 4; it++) {
            int idx = t + it * 256;          // 0..1023
            int kr = idx >> 5;
            int f4 = (idx & 31) * 4;
            float4 v = *(const float4*)&W[(size_t)(ksl + kr) * HID + f4];
            ws[kr][f4] = v.x; ws[kr][f4 + 1] = v.y; ws[kr][f4 + 2] = v.z; ws[kr][f4 + 3] = v.w;
        }
        __syncthreads();
        #pragma unroll 8
        for (int k = 0; k < 32; k++) {
            float4 b4 = *(const float4*)&ws[k][c0];
            #pragma unroll
            for (int i = 0; i < 8; i++) {
                float a = hs[r0 + i][k];
                acc[i][0] += a * b4.x; acc[i][1] += a * b4.y;
                acc[i][2] += a * b4.z; acc[i][3] += a * b4.w;
            }
        }
        __syncthreads();
    }
    #pragma unroll
    for (int i = 0; i < 8; i++) {
        int row = n0 + r0 + i;
        if (row < NN) {
            u32 lo = (u32)f2bf(acc[i][0]) | ((u32)f2bf(acc[i][1]) << 16);
            u32 hi = (u32)f2bf(acc[i][2]) | ((u32)f2bf(acc[i][3]) << 16);
            *(uint2*)&xh[(size_t)row * (HID / 2) + (c0 >> 1)] = make_uint2(lo, hi);
        }
    }
}

// ---------------------------------------------------------------------------
// al_s/al_d dots from bf16 xh; block 0 also computes wedot[h]=sum We*a_edge
// ---------------------------------------------------------------------------
__global__ void al_kernel(const u32* __restrict__ xh,
                          const float* __restrict__ a_src, const float* __restrict__ a_dst,
                          const float* __restrict__ We, const float* __restrict__ a_e,
                          float* __restrict__ al_s, float* __restrict__ al_d,
                          float* __restrict__ wedot) {
    if (blockIdx.x == 0 && threadIdx.x < NH) {
        float s = 0.f;
        #pragma unroll
        for (int c = 0; c < CH; c++) s += We[threadIdx.x * CH + c] * a_e[threadIdx.x * CH + c];
        wedot[threadIdx.x] = s;
    }
    int t = blockIdx.x * blockDim.x + threadIdx.x;
    if (t >= NN * NH) return;
    int n = t >> 2, hh = t & 3;
    const u32* row = xh + (size_t)n * (HID / 2) + hh * (CH / 2);
    const float* as = a_src + hh * CH;
    const float* ad = a_dst + hh * CH;
    float s = 0.f, d = 0.f;
    #pragma unroll
    for (int q = 0; q < CH / 2; q++) {
        u32 r = row[q];
        float v0 = bflo(r), v1 = bfhi(r);
        s += v0 * as[2 * q] + v1 * as[2 * q + 1];
        d += v0 * ad[2 * q] + v1 * ad[2 * q + 1];
    }
    al_s[t] = s;
    al_d[t] = d;
}

// ---------------------------------------------------------------------------
// GAT aggregation: 4 waves/block, one node per wave (wave-private LDS, no
// barriers). Pass M: logits+max (cached in LDS). Then exp/den in LDS. Phase B:
// 2-edge-parallel gather of bf16 xh rows, 2x unrolled.
// ---------------------------------------------------------------------------
__global__ __launch_bounds__(256) void gat_agg_kernel(const int* __restrict__ rowptr,
        const int* __restrict__ src_s, const float* __restrict__ ea_s,
        const u32* __restrict__ xh, const float* __restrict__ al_s,
        const float* __restrict__ al_d, const float* __restrict__ wedot,
        const float* __restrict__ bg, float* __restrict__ g,
        float* __restrict__ partials) {
    __shared__ float lds_ex[4][CAP * 4];
    __shared__ int lds_src[4][CAP];
    int wv = threadIdx.x >> 6, lane = threadIdx.x & 63;
    int n = blockIdx.x * 4 + wv;
    if (n >= NN) return;
    float* ex_w = lds_ex[wv];
    int* src_w = lds_src[wv];
    int rs = rowptr[n], re = rowptr[n + 1];
    int deg = re - rs;
    float wd0 = wedot[0], wd1 = wedot[1], wd2 = wedot[2], wd3 = wedot[3];
    float4 aldv = *(const float4*)&al_d[n * 4];

    // Pass M: logits for all edges, cache first CAP, track per-head max
    float m0 = -1e30f, m1 = -1e30f, m2 = -1e30f, m3 = -1e30f;
    for (int i = rs + lane; i < re; i += 64) {
        int s = src_s[i];
        float eav = ea_s[i];
        float4 als = *(const float4*)&al_s[s * 4];
        float l0 = als.x + aldv.x + eav * wd0; l0 = l0 > 0.f ? l0 : NEG_SLOPE * l0;
        float l1 = als.y + aldv.y + eav * wd1; l1 = l1 > 0.f ? l1 : NEG_SLOPE * l1;
        float l2 = als.z + aldv.z + eav * wd2; l2 = l2 > 0.f ? l2 : NEG_SLOPE * l2;
        float l3 = als.w + aldv.w + eav * wd3; l3 = l3 > 0.f ? l3 : NEG_SLOPE * l3;
        int k = i - rs;
        if (k < CAP) {
            src_w[k] = s;
            *(float4*)&ex_w[k * 4] = make_float4(l0, l1, l2, l3);
        }
        m0 = fmaxf(m0, l0); m1 = fmaxf(m1, l1); m2 = fmaxf(m2, l2); m3 = fmaxf(m3, l3);
    }
    #pragma unroll
    for (int off = 32; off; off >>= 1) {
        m0 = fmaxf(m0, __shfl_xor(m0, off, 64));
        m1 = fmaxf(m1, __shfl_xor(m1, off, 64));
        m2 = fmaxf(m2, __shfl_xor(m2, off, 64));
        m3 = fmaxf(m3, __shfl_xor(m3, off, 64));
    }

    // exp in LDS + per-head denominator for cached edges
    int nc = deg < CAP ? deg : CAP;
    float d0 = 0.f, d1 = 0.f, d2 = 0.f, d3 = 0.f;
    for (int k = lane; k < nc; k += 64) {
        float4 lg = *(const float4*)&ex_w[k * 4];
        float e0 = __expf(lg.x - m0), e1 = __expf(lg.y - m1);
        float e2 = __expf(lg.z - m2), e3 = __expf(lg.w - m3);
        *(float4*)&ex_w[k * 4] = make_float4(e0, e1, e2, e3);
        d0 += e0; d1 += e1; d2 += e2; d3 += e3;
    }
    #pragma unroll
    for (int off = 32; off; off >>= 1) {
        d0 += __shfl_xor(d0, off, 64); d1 += __shfl_xor(d1, off, 64);
        d2 += __shfl_xor(d2, off, 64); d3 += __shfl_xor(d3, off, 64);
    }

    // Phase B: lanes = (epar in {0,1}) x (cgroup: 4 channels each)
    int epar = lane >> 5, cgroup = lane & 31;
    int c0 = cgroup * 4;
    int head = cgroup >> 3;
    float mh   = head == 0 ? m0 : head == 1 ? m1 : head == 2 ? m2 : m3;
    float aldh = head == 0 ? aldv.x : head == 1 ? aldv.y : head == 2 ? aldv.z : aldv.w;
    float wdh  = head == 0 ? wd0 : head == 1 ? wd1 : head == 2 ? wd2 : wd3;
    float dh   = head == 0 ? d0 : head == 1 ? d1 : head == 2 ? d2 : d3;

    float a0 = 0.f, a1 = 0.f, a2 = 0.f, a3 = 0.f, dent = 0.f;
    int j = epar;
    for (; j + 2 < nc; j += 4) {
        int s0 = src_w[j], s1 = src_w[j + 2];
        float e0 = ex_w[j * 4 + head], e1 = ex_w[(j + 2) * 4 + head];
        uint2 r0 = *(const uint2*)&xh[(size_t)s0 * (HID / 2) + (c0 >> 1)];
        uint2 r1 = *(const uint2*)&xh[(size_t)s1 * (HID / 2) + (c0 >> 1)];
        a0 += e0 * bflo(r0.x); a1 += e0 * bfhi(r0.x);
        a2 += e0 * bflo(r0.y); a3 += e0 * bfhi(r0.y);
        a0 += e1 * bflo(r1.x); a1 += e1 * bfhi(r1.x);
        a2 += e1 * bflo(r1.y); a3 += e1 * bfhi(r1.y);
    }
    for (; j < nc; j += 2) {
        int s0 = src_w[j];
        float e0 = ex_w[j * 4 + head];
        uint2 r0 = *(const uint2*)&xh[(size_t)s0 * (HID / 2) + (c0 >> 1)];
        a0 += e0 * bflo(r0.x); a1 += e0 * bfhi(r0.x);
        a2 += e0 * bflo(r0.y); a3 += e0 * bfhi(r0.y);
    }
    // rare tail: rows longer than CAP
    for (int jt = CAP + epar; jt < deg; jt += 2) {
        int i = rs + jt;
        int s = src_s[i];
        float eav = ea_s[i];
        float lg = al_s[s * 4 + head] + aldh + eav * wdh;
        lg = lg > 0.f ? lg : NEG_SLOPE * lg;
        float ex = __expf(lg - mh);
        dent += ex;
        uint2 r0 = *(const uint2*)&xh[(size_t)s * (HID / 2) + (c0 >> 1)];
        a0 += ex * bflo(r0.x); a1 += ex * bfhi(r0.x);
        a2 += ex * bflo(r0.y); a3 += ex * bfhi(r0.y);
    }
    a0 += __shfl_xor(a0, 32, 64); a1 += __shfl_xor(a1, 32, 64);
    a2 += __shfl_xor(a2, 32, 64); a3 += __shfl_xor(a3, 32, 64);
    dent += __shfl_xor(dent, 32, 64);

    float inv = 1.0f / (dh + dent + 1e-16f);
    float4 bgv = *(const float4*)&bg[c0];
    float o0 = a0 * inv + bgv.x, o1 = a1 * inv + bgv.y;
    float o2 = a2 * inv + bgv.z, o3 = a3 * inv + bgv.w;
    float ss = 0.f, sq = 0.f;
    if (epar == 0) {
        *(float4*)&g[(size_t)n * HID + c0] = make_float4(o0, o1, o2, o3);
        ss = o0 + o1 + o2 + o3;
        sq = o0 * o0 + o1 * o1 + o2 * o2 + o3 * o3;
    }
    #pragma unroll
    for (int off = 32; off; off >>= 1) {
        ss += __shfl_xor(ss, off, 64);
        sq += __shfl_xor(sq, off, 64);
    }
    if (lane == 0) {
        int sl = (n & 1023) * 2;
        atomicAdd(&partials[sl], ss);
        atomicAdd(&partials[sl + 1], sq);
    }
}

// reduce partials -> {mean, rstd}; re-zero partials for the next layer
__global__ void stats_kernel(float* __restrict__ partials, float* __restrict__ stats) {
    __shared__ float ls[16], lq[16];
    int tid = threadIdx.x;
    float s = partials[tid * 2], q = partials[tid * 2 + 1];
    partials[tid * 2] = 0.f;
    partials[tid * 2 + 1] = 0.f;
    #pragma unroll
    for (int off = 32; off; off >>= 1) {
        s += __shfl_xor(s, off, 64);
        q += __shfl_xor(q, off, 64);
    }
    int lane = tid & 63, wid = tid >> 6;
    if (lane == 0) { ls[wid] = s; lq[wid] = q; }
    __syncthreads();
    if (tid == 0) {
        float S = 0.f, Q = 0.f;
        for (int w2 = 0; w2 < 16; w2++) { S += ls[w2]; Q += lq[w2]; }
        const float M = (float)NN * (float)HID;
        float mean = S / M;
        float var = Q / M - mean * mean;
        stats[0] = mean;
        stats[1] = rsqrtf(fmaxf(var, 0.f) + LN_EPS);
    }
}

// final: out = relu(LN(g)+h) @ Wout + bout  (one wave per node)
__global__ __launch_bounds__(64) void ln_out_kernel(const float* __restrict__ g,
        const float* __restrict__ h, const float* __restrict__ lnw,
        const float* __restrict__ lnb, const float* __restrict__ stats,
        const float* __restrict__ Wout, const float* __restrict__ bout,
        float* __restrict__ out) {
    int n = blockIdx.x, lane = threadIdx.x;
    float mean = stats[0], rstd = stats[1];
    int c0 = lane * 2;
    float2 gv = *(const float2*)&g[(size_t)n * HID + c0];
    float2 hv = *(const float2*)&h[(size_t)n * HID + c0];
    float o0 = fmaxf((gv.x - mean) * rstd * lnw[c0]     + lnb[c0]     + hv.x, 0.f);
    float o1 = fmaxf((gv.y - mean) * rstd * lnw[c0 + 1] + lnb[c0 + 1] + hv.y, 0.f);
    float p[NOUT];
    #pragma unroll
    for (int jj = 0; jj < NOUT; jj++)
        p[jj] = o0 * Wout[c0 * NOUT + jj] + o1 * Wout[(c0 + 1) * NOUT + jj];
    #pragma unroll
    for (int off = 32; off; off >>= 1) {
        #pragma unroll
        for (int jj = 0; jj < NOUT; jj++) p[jj] += __shfl_xor(p[jj], off, 64);
    }
    if (lane == 0) {
        #pragma unroll
        for (int jj = 0; jj < NOUT; jj++)
            out[(size_t)n * NOUT + jj] = p[jj] + bout[jj];
    }
}

// ---------------------------------------------------------------------------
extern "C" void kernel_launch(void* const* d_in, const int* in_sizes, int n_in,
                              void* d_out, int out_size, void* d_ws, size_t ws_size,
                              hipStream_t stream) {
    const float* x      = (const float*)d_in[0];
    const int*   ei     = (const int*)d_in[1];
    const float* ea     = (const float*)d_in[2];
    const float* Win    = (const float*)d_in[3];
    const float* b_in   = (const float*)d_in[4];
    const float* Wg     = (const float*)d_in[5];
    const float* bg     = (const float*)d_in[6];
    const float* a_src  = (const float*)d_in[7];
    const float* a_dst  = (const float*)d_in[8];
    const float* We     = (const float*)d_in[9];
    const float* a_edge = (const float*)d_in[10];
    const float* ln_w   = (const float*)d_in[11];
    const float* ln_b   = (const float*)d_in[12];
    const float* Wout   = (const float*)d_in[13];
    const float* bout   = (const float*)d_in[14];
    float* out = (float*)d_out;

    char* w = (char*)d_ws;
    size_t off = 0;
    auto alloc = [&](size_t bytes) -> void* {
        void* p = w + off;
        off = (off + bytes + 255) & ~(size_t)255;
        return p;
    };
    int*   slot    = (int*)alloc((size_t)EE * sizeof(int));
    int*   cnt     = (int*)alloc(NN * sizeof(int));
    int*   rowptr  = (int*)alloc((NN + 1) * sizeof(int));
    int*   bsum    = (int*)alloc(NB_SCAN * sizeof(int));
    int*   src_s   = (int*)alloc((size_t)(EE + NN) * sizeof(int));
    float* ea_s    = (float*)alloc((size_t)(EE + NN) * sizeof(float));
    float* h       = (float*)alloc((size_t)NN * HID * sizeof(float));
    float* g       = (float*)alloc((size_t)NN * HID * sizeof(float));
    u32*   xh      = (u32*)alloc((size_t)NN * (HID / 2) * sizeof(u32));
    float* al_s    = (float*)alloc((size_t)NN * NH * sizeof(float));
    float* al_d    = (float*)alloc((size_t)NN * NH * sizeof(float));
    float* wedot   = (float*)alloc(16 * sizeof(float));
    float* partials = (float*)alloc(2048 * sizeof(float));
    float* stats   = (float*)alloc(16 * sizeof(float));
    (void)ws_size; (void)n_in; (void)in_sizes; (void)out_size;

    // --- CSR build ---
    hipMemsetAsync(partials, 0, 2048 * sizeof(float), stream);
    init_cnt_kernel<<<(NN + 255) / 256, 256, 0, stream>>>(cnt);
    hist_kernel<<<(EE + 255) / 256, 256, 0, stream>>>(ei, cnt, slot);
    scan1_kernel<<<NB_SCAN, 1024, 0, stream>>>(cnt, rowptr, bsum);
    scan2_kernel<<<1, 128, 0, stream>>>(bsum);
    scan3_kernel<<<NB_SCAN, 1024, 0, stream>>>(rowptr, bsum);
    scatter_kernel<<<(EE + 255) / 256, 256, 0, stream>>>(ei, ea, rowptr, slot, src_s, ea_s);
    selfloop_kernel<<<(NN + 255) / 256, 256, 0, stream>>>(rowptr, src_s, ea_s);

    // --- input projection ---
    input_proj_kernel<<<NN, 64, 0, stream>>>(x, Win, b_in, h);

    // --- GAT layers ---
    for (int l = 0; l < NL; l++) {
        if (l == 0) {
            gemm_kernel<false><<<(NN + 63) / 64, 256, 0, stream>>>(
                h, Wg, xh, nullptr, nullptr, nullptr, nullptr, nullptr);
        } else {
            // fused epilogue of layer l-1: h = relu(LN(g)+h), then xh = h @ Wg[l]
            gemm_kernel<true><<<(NN + 63) / 64, 256, 0, stream>>>(
                h, Wg + (size_t)l * HID * HID, xh, g,
                ln_w + (size_t)(l - 1) * HID, ln_b + (size_t)(l - 1) * HID, stats, h);
        }
        al_kernel<<<(NN * NH + 255) / 256, 256, 0, stream>>>(
            xh, a_src + l * HID, a_dst + l * HID, We + l * HID, a_edge + l * HID,
            al_s, al_d, wedot);
        gat_agg_kernel<<<(NN + 3) / 4, 256, 0, stream>>>(
            rowptr, src_s, ea_s, xh, al_s, al_d, wedot, bg + (size_t)l * HID, g, partials);
        stats_kernel<<<1, 1024, 0, stream>>>(partials, stats);
    }

    // --- final LN + residual + relu + output projection (fused) ---
    ln_out_kernel<<<NN, 64, 0, stream>>>(g, h, ln_w + (size_t)2 * HID, ln_b + (size_t)2 * HID,
                                         stats, Wout, bout, out);
}

// Round 4
// 642.234 us; speedup vs baseline: 1.6491x; 1.1585x over previous
//
#include <hip/hip_runtime.h>
#include <hip/hip_bf16.h>

#define NN 100000
#define EE 800000
#define HID 128
#define NH 4
#define CH 32
#define NL 3
#define NOUT 5
#define NEG_SLOPE 0.2f
#define LN_EPS 1e-5f
#define CAP 256            // LDS-cached edges per node row (deg > CAP falls to slow path)
#define NB_SCAN 98         // ceil((NN+1)/1024)

typedef unsigned int u32;

static __device__ __forceinline__ float bflo(u32 r) { return __uint_as_float(r << 16); }
static __device__ __forceinline__ float bfhi(u32 r) { return __uint_as_float(r & 0xffff0000u); }
static __device__ __forceinline__ unsigned short f2bf(float x) {
    union U { __hip_bfloat16 b; unsigned short s; } u;
    u.b = __float2bfloat16(x);
    return u.s;
}

// ---------------------------------------------------------------------------
// CSR build. cnt[n] starts at 1 (self-loop reserved at row slot 0); one atomic
// per real edge whose return value is the edge's slot -> scatter is atomic-free.
// ---------------------------------------------------------------------------
__global__ void init_cnt_kernel(int* __restrict__ cnt) {
    int n = blockIdx.x * blockDim.x + threadIdx.x;
    if (n < NN) cnt[n] = 1;
}

__global__ void hist_kernel(const int* __restrict__ ei, int* __restrict__ cnt,
                            int* __restrict__ slot) {
    int e = blockIdx.x * blockDim.x + threadIdx.x;
    if (e >= EE) return;
    int d = ei[EE + e];
    slot[e] = atomicAdd(&cnt[d], 1);
}

// hierarchical exclusive scan of cnt[0..NN] (element NN treated as 0) -> rowptr
__global__ __launch_bounds__(1024) void scan1_kernel(const int* __restrict__ cnt,
                                                     int* __restrict__ rowptr,
                                                     int* __restrict__ bsum) {
    __shared__ int ws[16];
    int gid = blockIdx.x * 1024 + threadIdx.x;
    int v = (gid < NN) ? cnt[gid] : 0;
    int lane = threadIdx.x & 63, wid = threadIdx.x >> 6;
    int s = v;
    #pragma unroll
    for (int off = 1; off < 64; off <<= 1) {
        int t = __shfl_up(s, off, 64);
        if (lane >= off) s += t;
    }
    if (lane == 63) ws[wid] = s;
    __syncthreads();
    int add = 0;
    for (int w2 = 0; w2 < wid; w2++) add += ws[w2];
    int incl = s + add;
    if (gid <= NN) rowptr[gid] = incl - v;   // exclusive
    if (threadIdx.x == 1023) bsum[blockIdx.x] = incl;
}

__global__ void scan2_kernel(int* __restrict__ bsum) {
    __shared__ int w0tot;
    int tid = threadIdx.x;                   // 128 threads
    int v = (tid < NB_SCAN) ? bsum[tid] : 0;
    int lane = tid & 63, wid = tid >> 6;
    int s = v;
    #pragma unroll
    for (int off = 1; off < 64; off <<= 1) {
        int t = __shfl_up(s, off, 64);
        if (lane >= off) s += t;
    }
    if (wid == 0 && lane == 63) w0tot = s;
    __syncthreads();
    int incl = s + (wid ? w0tot : 0);
    if (tid < NB_SCAN) bsum[tid] = incl - v; // exclusive
}

__global__ void scan3_kernel(int* __restrict__ rowptr, const int* __restrict__ bsum) {
    int gid = blockIdx.x * 1024 + threadIdx.x;
    if (gid <= NN) rowptr[gid] += bsum[blockIdx.x];
}

__global__ void scatter_kernel(const int* __restrict__ ei, const float* __restrict__ ea,
                               const int* __restrict__ rowptr, const int* __restrict__ slot,
                               int* __restrict__ src_s, float* __restrict__ ea_s) {
    int e = blockIdx.x * blockDim.x + threadIdx.x;
    if (e >= EE) return;
    int d = ei[EE + e];
    int pos = rowptr[d] + slot[e];           // slot >= 1; slot 0 is the self loop
    src_s[pos] = ei[e];
    ea_s[pos] = ea[e];
}

// self-loop attr = mean of the row's real-edge attrs (PyG fill_value='mean')
__global__ void selfloop_kernel(const int* __restrict__ rowptr, int* __restrict__ src_s,
                                float* __restrict__ ea_s) {
    int n = blockIdx.x * blockDim.x + threadIdx.x;
    if (n >= NN) return;
    int rs = rowptr[n], re = rowptr[n + 1];
    float s = 0.f;
    for (int i = rs + 1; i < re; i++) s += ea_s[i];
    ea_s[rs] = s / fmaxf((float)(re - rs - 1), 1.0f);
    src_s[rs] = n;
}

// wedot[l*4+h] = sum_c We[l][h*32+c] * a_edge[l][h*32+c]  (all layers at once)
__global__ void wedot_kernel(const float* __restrict__ We, const float* __restrict__ a_e,
                             float* __restrict__ wedot) {
    int t = threadIdx.x;
    if (t >= NL * NH) return;
    int l = t >> 2, hh = t & 3;
    float s = 0.f;
    #pragma unroll
    for (int c = 0; c < CH; c++)
        s += We[l * HID + hh * CH + c] * a_e[l * HID + hh * CH + c];
    wedot[t] = s;
}

// ---------------------------------------------------------------------------
// shared GEMM epilogue: pack xh to bf16 + compute al_s/al_d via 8-lane reduce
// ---------------------------------------------------------------------------
static __device__ __forceinline__ void store_xh_al(
        float acc[8][4], int n0, int r0, int c0, int cg,
        u32* __restrict__ xh, const float* __restrict__ asl, const float* __restrict__ adl,
        float* __restrict__ al_s, float* __restrict__ al_d) {
    float4 as4 = *(const float4*)&asl[c0];
    float4 ad4 = *(const float4*)&adl[c0];
    int hh = cg >> 3;
    #pragma unroll
    for (int i = 0; i < 8; i++) {
        int row = n0 + r0 + i;
        if (row < NN) {
            u32 lo = (u32)f2bf(acc[i][0]) | ((u32)f2bf(acc[i][1]) << 16);
            u32 hi = (u32)f2bf(acc[i][2]) | ((u32)f2bf(acc[i][3]) << 16);
            *(uint2*)&xh[(size_t)row * (HID / 2) + (c0 >> 1)] = make_uint2(lo, hi);
        }
        float ps = acc[i][0] * as4.x + acc[i][1] * as4.y + acc[i][2] * as4.z + acc[i][3] * as4.w;
        float pd = acc[i][0] * ad4.x + acc[i][1] * ad4.y + acc[i][2] * ad4.z + acc[i][3] * ad4.w;
        ps += __shfl_xor(ps, 1, 64); pd += __shfl_xor(pd, 1, 64);
        ps += __shfl_xor(ps, 2, 64); pd += __shfl_xor(pd, 2, 64);
        ps += __shfl_xor(ps, 4, 64); pd += __shfl_xor(pd, 4, 64);
        if ((cg & 7) == 0 && row < NN) {
            al_s[row * 4 + hh] = ps;
            al_d[row * 4 + hh] = pd;
        }
    }
}

// ---------------------------------------------------------------------------
// Layer 0 fused: h = x@Win + b_in (K=32), then xh = h@Wg0 (bf16), al dots.
// Tile 64 rows; h tile kept in LDS between the two GEMMs.
// ---------------------------------------------------------------------------
__global__ __launch_bounds__(256) void in_gemm_kernel(
        const float* __restrict__ x, const float* __restrict__ Win,
        const float* __restrict__ b_in, const float* __restrict__ Wg0,
        float* __restrict__ h, u32* __restrict__ xh,
        const float* __restrict__ a_src0, const float* __restrict__ a_dst0,
        float* __restrict__ al_s, float* __restrict__ al_d) {
    __shared__ float xs[64][36];
    __shared__ float ws[32][128];
    __shared__ float hs[64][128];
    int n0 = blockIdx.x * 64;
    int t = threadIdx.x;
    int cg = t & 31, rg = t >> 5;
    int c0 = cg * 4, r0 = rg * 8;
    // stage x (64 x 32)
    #pragma unroll
    for (int it = 0; it < 2; it++) {
        int idx = t + it * 256;
        int row = idx >> 3, kk = (idx & 7) * 4;
        float4 v = make_float4(0.f, 0.f, 0.f, 0.f);
        if (n0 + row < NN) v = *(const float4*)&x[(size_t)(n0 + row) * 32 + kk];
        *(float4*)&xs[row][kk] = v;
    }
    // stage Win (32 x 128)
    #pragma unroll
    for (int it = 0; it < 4; it++) {
        int idx = t + it * 256;
        int kr = idx >> 5, f4 = (idx & 31) * 4;
        *(float4*)&ws[kr][f4] = *(const float4*)&Win[kr * HID + f4];
    }
    __syncthreads();
    float acc[8][4] = {};
    #pragma unroll 8
    for (int k = 0; k < 32; k++) {
        float4 b4 = *(const float4*)&ws[k][c0];
        #pragma unroll
        for (int i = 0; i < 8; i++) {
            float a = xs[r0 + i][k];
            acc[i][0] += a * b4.x; acc[i][1] += a * b4.y;
            acc[i][2] += a * b4.z; acc[i][3] += a * b4.w;
        }
    }
    float4 bi = *(const float4*)&b_in[c0];
    #pragma unroll
    for (int i = 0; i < 8; i++) {
        acc[i][0] += bi.x; acc[i][1] += bi.y; acc[i][2] += bi.z; acc[i][3] += bi.w;
        int row = n0 + r0 + i;
        float4 v = make_float4(acc[i][0], acc[i][1], acc[i][2], acc[i][3]);
        *(float4*)&hs[r0 + i][c0] = v;
        if (row < NN) *(float4*)&h[(size_t)row * HID + c0] = v;
    }
    // second GEMM: xh = hs @ Wg0 (K=128, slabs of 32 overwrite ws)
    float acc2[8][4] = {};
    for (int ksl = 0; ksl < HID; ksl += 32) {
        __syncthreads();                     // prior ws readers done (+ hs visible, iter 0)
        #pragma unroll
        for (int it = 0; it < 4; it++) {
            int idx = t + it * 256;
            int kr = idx >> 5, f4 = (idx & 31) * 4;
            *(float4*)&ws[kr][f4] = *(const float4*)&Wg0[(size_t)(ksl + kr) * HID + f4];
        }
        __syncthreads();
        #pragma unroll 8
        for (int k = 0; k < 32; k++) {
            float4 b4 = *(const float4*)&ws[k][c0];
            #pragma unroll
            for (int i = 0; i < 8; i++) {
                float a = hs[r0 + i][ksl + k];
                acc2[i][0] += a * b4.x; acc2[i][1] += a * b4.y;
                acc2[i][2] += a * b4.z; acc2[i][3] += a * b4.w;
            }
        }
    }
    store_xh_al(acc2, n0, r0, c0, cg, xh, a_src0, a_dst0, al_s, al_d);
}

// ---------------------------------------------------------------------------
// Layers 1..2: hin = relu(LN(g)+h) computed on the fly (epilogue of prev
// layer), written back to h; xh = hin @ Wg (bf16); al dots in epilogue.
// ---------------------------------------------------------------------------
__global__ __launch_bounds__(256) void gemm_kernel(const float* __restrict__ h,
        const float* __restrict__ W, u32* __restrict__ xh, const float* __restrict__ g,
        const float* __restrict__ lnw, const float* __restrict__ lnb,
        const float* __restrict__ stats, float* __restrict__ hout,
        const float* __restrict__ asl, const float* __restrict__ adl,
        float* __restrict__ al_s, float* __restrict__ al_d) {
    __shared__ float hs[64][33];
    __shared__ float ws[32][128];
    float mean = stats[0], rstd = stats[1];
    int n0 = blockIdx.x * 64;
    int t = threadIdx.x;
    int cg = t & 31, rg = t >> 5;
    int c0 = cg * 4, r0 = rg * 8;
    float acc[8][4] = {};
    for (int ksl = 0; ksl < HID; ksl += 32) {
        #pragma unroll
        for (int it = 0; it < 2; it++) {
            int idx = t + it * 256;          // 0..511
            int row = idx >> 3;
            int kk = (idx & 7) * 4;
            int gr = n0 + row;
            float4 v = make_float4(0.f, 0.f, 0.f, 0.f);
            if (gr < NN) {
                size_t base = (size_t)gr * HID + ksl + kk;
                float4 gv = *(const float4*)&g[base];
                float4 hv = *(const float4*)&h[base];
                float4 w4 = *(const float4*)&lnw[ksl + kk];
                float4 b4 = *(const float4*)&lnb[ksl + kk];
                v.x = fmaxf((gv.x - mean) * rstd * w4.x + b4.x + hv.x, 0.f);
                v.y = fmaxf((gv.y - mean) * rstd * w4.y + b4.y + hv.y, 0.f);
                v.z = fmaxf((gv.z - mean) * rstd * w4.z + b4.z + hv.z, 0.f);
                v.w = fmaxf((gv.w - mean) * rstd * w4.w + b4.w + hv.w, 0.f);
                *(float4*)&hout[base] = v;
            }
            hs[row][kk] = v.x; hs[row][kk + 1] = v.y; hs[row][kk + 2] = v.z; hs[row][kk + 3] = v.w;
        }
        #pragma unroll
        for (int it = 0; it < 4; it++) {
            int idx = t + it * 256;          // 0..1023
            int kr = idx >> 5;
            int f4 = (idx & 31) * 4;
            *(float4*)&ws[kr][f4] = *(const float4*)&W[(size_t)(ksl + kr) * HID + f4];
        }
        __syncthreads();
        #pragma unroll 8
        for (int k = 0; k < 32; k++) {
            float4 b4 = *(const float4*)&ws[k][c0];
            #pragma unroll
            for (int i = 0; i < 8; i++) {
                float a = hs[r0 + i][k];
                acc[i][0] += a * b4.x; acc[i][1] += a * b4.y;
                acc[i][2] += a * b4.z; acc[i][3] += a * b4.w;
            }
        }
        __syncthreads();
    }
    store_xh_al(acc, n0, r0, c0, cg, xh, asl, adl, al_s, al_d);
}

// ---------------------------------------------------------------------------
// GAT aggregation: 4 waves/block, one node per wave (wave-private LDS, no
// barriers). Pass M: logits+max (cached in LDS). Then exp/den in LDS. Phase B:
// 2-edge-parallel gather of bf16 xh rows, 2x unrolled.
// ---------------------------------------------------------------------------
__global__ __launch_bounds__(256) void gat_agg_kernel(const int* __restrict__ rowptr,
        const int* __restrict__ src_s, const float* __restrict__ ea_s,
        const u32* __restrict__ xh, const float* __restrict__ al_s,
        const float* __restrict__ al_d, const float* __restrict__ wedot,
        const float* __restrict__ bg, float* __restrict__ g,
        float* __restrict__ partials) {
    __shared__ float lds_ex[4][CAP * 4];
    __shared__ int lds_src[4][CAP];
    int wv = threadIdx.x >> 6, lane = threadIdx.x & 63;
    int n = blockIdx.x * 4 + wv;
    if (n >= NN) return;
    float* ex_w = lds_ex[wv];
    int* src_w = lds_src[wv];
    int rs = rowptr[n], re = rowptr[n + 1];
    int deg = re - rs;
    float wd0 = wedot[0], wd1 = wedot[1], wd2 = wedot[2], wd3 = wedot[3];
    float4 aldv = *(const float4*)&al_d[n * 4];

    // Pass M: logits for all edges, cache first CAP, track per-head max
    float m0 = -1e30f, m1 = -1e30f, m2 = -1e30f, m3 = -1e30f;
    for (int i = rs + lane; i < re; i += 64) {
        int s = src_s[i];
        float eav = ea_s[i];
        float4 als = *(const float4*)&al_s[s * 4];
        float l0 = als.x + aldv.x + eav * wd0; l0 = l0 > 0.f ? l0 : NEG_SLOPE * l0;
        float l1 = als.y + aldv.y + eav * wd1; l1 = l1 > 0.f ? l1 : NEG_SLOPE * l1;
        float l2 = als.z + aldv.z + eav * wd2; l2 = l2 > 0.f ? l2 : NEG_SLOPE * l2;
        float l3 = als.w + aldv.w + eav * wd3; l3 = l3 > 0.f ? l3 : NEG_SLOPE * l3;
        int k = i - rs;
        if (k < CAP) {
            src_w[k] = s;
            *(float4*)&ex_w[k * 4] = make_float4(l0, l1, l2, l3);
        }
        m0 = fmaxf(m0, l0); m1 = fmaxf(m1, l1); m2 = fmaxf(m2, l2); m3 = fmaxf(m3, l3);
    }
    #pragma unroll
    for (int off = 32; off; off >>= 1) {
        m0 = fmaxf(m0, __shfl_xor(m0, off, 64));
        m1 = fmaxf(m1, __shfl_xor(m1, off, 64));
        m2 = fmaxf(m2, __shfl_xor(m2, off, 64));
        m3 = fmaxf(m3, __shfl_xor(m3, off, 64));
    }

    // exp in LDS + per-head denominator for cached edges
    int nc = deg < CAP ? deg : CAP;
    float d0 = 0.f, d1 = 0.f, d2 = 0.f, d3 = 0.f;
    for (int k = lane; k < nc; k += 64) {
        float4 lg = *(const float4*)&ex_w[k * 4];
        float e0 = __expf(lg.x - m0), e1 = __expf(lg.y - m1);
        float e2 = __expf(lg.z - m2), e3 = __expf(lg.w - m3);
        *(float4*)&ex_w[k * 4] = make_float4(e0, e1, e2, e3);
        d0 += e0; d1 += e1; d2 += e2; d3 += e3;
    }
    #pragma unroll
    for (int off = 32; off; off >>= 1) {
        d0 += __shfl_xor(d0, off, 64); d1 += __shfl_xor(d1, off, 64);
        d2 += __shfl_xor(d2, off, 64); d3 += __shfl_xor(d3, off, 64);
    }

    // Phase B: lanes = (epar in {0,1}) x (cgroup: 4 channels each)
    int epar = lane >> 5, cgroup = lane & 31;
    int c0 = cgroup * 4;
    int head = cgroup >> 3;
    float mh   = head == 0 ? m0 : head == 1 ? m1 : head == 2 ? m2 : m3;
    float aldh = head == 0 ? aldv.x : head == 1 ? aldv.y : head == 2 ? aldv.z : aldv.w;
    float wdh  = head == 0 ? wd0 : head == 1 ? wd1 : head == 2 ? wd2 : wd3;
    float dh   = head == 0 ? d0 : head == 1 ? d1 : head == 2 ? d2 : d3;

    float a0 = 0.f, a1 = 0.f, a2 = 0.f, a3 = 0.f, dent = 0.f;
    int j = epar;
    for (; j + 2 < nc; j += 4) {
        int s0 = src_w[j], s1 = src_w[j + 2];
        float e0 = ex_w[j * 4 + head], e1 = ex_w[(j + 2) * 4 + head];
        uint2 r0 = *(const uint2*)&xh[(size_t)s0 * (HID / 2) + (c0 >> 1)];
        uint2 r1 = *(const uint2*)&xh[(size_t)s1 * (HID / 2) + (c0 >> 1)];
        a0 += e0 * bflo(r0.x); a1 += e0 * bfhi(r0.x);
        a2 += e0 * bflo(r0.y); a3 += e0 * bfhi(r0.y);
        a0 += e1 * bflo(r1.x); a1 += e1 * bfhi(r1.x);
        a2 += e1 * bflo(r1.y); a3 += e1 * bfhi(r1.y);
    }
    for (; j < nc; j += 2) {
        int s0 = src_w[j];
        float e0 = ex_w[j * 4 + head];
        uint2 r0 = *(const uint2*)&xh[(size_t)s0 * (HID / 2) + (c0 >> 1)];
        a0 += e0 * bflo(r0.x); a1 += e0 * bfhi(r0.x);
        a2 += e0 * bflo(r0.y); a3 += e0 * bfhi(r0.y);
    }
    // rare tail: rows longer than CAP
    for (int jt = CAP + epar; jt < deg; jt += 2) {
        int i = rs + jt;
        int s = src_s[i];
        float eav = ea_s[i];
        float lg = al_s[s * 4 + head] + aldh + eav * wdh;
        lg = lg > 0.f ? lg : NEG_SLOPE * lg;
        float ex = __expf(lg - mh);
        dent += ex;
        uint2 r0 = *(const uint2*)&xh[(size_t)s * (HID / 2) + (c0 >> 1)];
        a0 += ex * bflo(r0.x); a1 += ex * bfhi(r0.x);
        a2 += ex * bflo(r0.y); a3 += ex * bfhi(r0.y);
    }
    a0 += __shfl_xor(a0, 32, 64); a1 += __shfl_xor(a1, 32, 64);
    a2 += __shfl_xor(a2, 32, 64); a3 += __shfl_xor(a3, 32, 64);
    dent += __shfl_xor(dent, 32, 64);

    float inv = 1.0f / (dh + dent + 1e-16f);
    float4 bgv = *(const float4*)&bg[c0];
    float o0 = a0 * inv + bgv.x, o1 = a1 * inv + bgv.y;
    float o2 = a2 * inv + bgv.z, o3 = a3 * inv + bgv.w;
    float ss = 0.f, sq = 0.f;
    if (epar == 0) {
        *(float4*)&g[(size_t)n * HID + c0] = make_float4(o0, o1, o2, o3);
        ss = o0 + o1 + o2 + o3;
        sq = o0 * o0 + o1 * o1 + o2 * o2 + o3 * o3;
    }
    #pragma unroll
    for (int off = 32; off; off >>= 1) {
        ss += __shfl_xor(ss, off, 64);
        sq += __shfl_xor(sq, off, 64);
    }
    if (lane == 0) {
        int sl = (n & 1023) * 2;
        atomicAdd(&partials[sl], ss);
        atomicAdd(&partials[sl + 1], sq);
    }
}

// reduce partials -> {mean, rstd}; re-zero partials for the next layer
__global__ void stats_kernel(float* __restrict__ partials, float* __restrict__ stats) {
    __shared__ float ls[16], lq[16];
    int tid = threadIdx.x;
    float s = partials[tid * 2], q = partials[tid * 2 + 1];
    partials[tid * 2] = 0.f;
    partials[tid * 2 + 1] = 0.f;
    #pragma unroll
    for (int off = 32; off; off >>= 1) {
        s += __shfl_xor(s, off, 64);
        q += __shfl_xor(q, off, 64);
    }
    int lane = tid & 63, wid = tid >> 6;
    if (lane == 0) { ls[wid] = s; lq[wid] = q; }
    __syncthreads();
    if (tid == 0) {
        float S = 0.f, Q = 0.f;
        for (int w2 = 0; w2 < 16; w2++) { S += ls[w2]; Q += lq[w2]; }
        const float M = (float)NN * (float)HID;
        float mean = S / M;
        float var = Q / M - mean * mean;
        stats[0] = mean;
        stats[1] = rsqrtf(fmaxf(var, 0.f) + LN_EPS);
    }
}

// final: out = relu(LN(g)+h) @ Wout + bout  (4 nodes/block, wave per node)
__global__ __launch_bounds__(256) void ln_out_kernel(const float* __restrict__ g,
        const float* __restrict__ h, const float* __restrict__ lnw,
        const float* __restrict__ lnb, const float* __restrict__ stats,
        const float* __restrict__ Wout, const float* __restrict__ bout,
        float* __restrict__ out) {
    __shared__ float wsh[HID * NOUT];
    int t = threadIdx.x;
    for (int i = t; i < HID * NOUT; i += 256) wsh[i] = Wout[i];
    __syncthreads();
    int wv = t >> 6, lane = t & 63;
    int n = blockIdx.x * 4 + wv;
    if (n >= NN) return;
    float mean = stats[0], rstd = stats[1];
    int c0 = lane * 2;
    float2 gv = *(const float2*)&g[(size_t)n * HID + c0];
    float2 hv = *(const float2*)&h[(size_t)n * HID + c0];
    float o0 = fmaxf((gv.x - mean) * rstd * lnw[c0]     + lnb[c0]     + hv.x, 0.f);
    float o1 = fmaxf((gv.y - mean) * rstd * lnw[c0 + 1] + lnb[c0 + 1] + hv.y, 0.f);
    float p[NOUT];
    #pragma unroll
    for (int jj = 0; jj < NOUT; jj++)
        p[jj] = o0 * wsh[c0 * NOUT + jj] + o1 * wsh[(c0 + 1) * NOUT + jj];
    #pragma unroll
    for (int off = 32; off; off >>= 1) {
        #pragma unroll
        for (int jj = 0; jj < NOUT; jj++) p[jj] += __shfl_xor(p[jj], off, 64);
    }
    if (lane == 0) {
        #pragma unroll
        for (int jj = 0; jj < NOUT; jj++)
            out[(size_t)n * NOUT + jj] = p[jj] + bout[jj];
    }
}

// ---------------------------------------------------------------------------
extern "C" void kernel_launch(void* const* d_in, const int* in_sizes, int n_in,
                              void* d_out, int out_size, void* d_ws, size_t ws_size,
                              hipStream_t stream) {
    const float* x      = (const float*)d_in[0];
    const int*   ei     = (const int*)d_in[1];
    const float* ea     = (const float*)d_in[2];
    const float* Win    = (const float*)d_in[3];
    const float* b_in   = (const float*)d_in[4];
    const float* Wg     = (const float*)d_in[5];
    const float* bg     = (const float*)d_in[6];
    const float* a_src  = (const float*)d_in[7];
    const float* a_dst  = (const float*)d_in[8];
    const float* We     = (const float*)d_in[9];
    const float* a_edge = (const float*)d_in[10];
    const float* ln_w   = (const float*)d_in[11];
    const float* ln_b   = (const float*)d_in[12];
    const float* Wout   = (const float*)d_in[13];
    const float* bout   = (const float*)d_in[14];
    float* out = (float*)d_out;

    char* w = (char*)d_ws;
    size_t off = 0;
    auto alloc = [&](size_t bytes) -> void* {
        void* p = w + off;
        off = (off + bytes + 255) & ~(size_t)255;
        return p;
    };
    int*   slot    = (int*)alloc((size_t)EE * sizeof(int));
    int*   cnt     = (int*)alloc(NN * sizeof(int));
    int*   rowptr  = (int*)alloc((NN + 1) * sizeof(int));
    int*   bsum    = (int*)alloc(NB_SCAN * sizeof(int));
    int*   src_s   = (int*)alloc((size_t)(EE + NN) * sizeof(int));
    float* ea_s    = (float*)alloc((size_t)(EE + NN) * sizeof(float));
    float* h       = (float*)alloc((size_t)NN * HID * sizeof(float));
    float* g       = (float*)alloc((size_t)NN * HID * sizeof(float));
    u32*   xh      = (u32*)alloc((size_t)NN * (HID / 2) * sizeof(u32));
    float* al_s    = (float*)alloc((size_t)NN * NH * sizeof(float));
    float* al_d    = (float*)alloc((size_t)NN * NH * sizeof(float));
    float* wedot   = (float*)alloc(16 * sizeof(float));
    float* partials = (float*)alloc(2048 * sizeof(float));
    float* stats   = (float*)alloc(16 * sizeof(float));
    (void)ws_size; (void)n_in; (void)in_sizes; (void)out_size;

    // --- CSR build ---
    hipMemsetAsync(partials, 0, 2048 * sizeof(float), stream);
    init_cnt_kernel<<<(NN + 255) / 256, 256, 0, stream>>>(cnt);
    hist_kernel<<<(EE + 255) / 256, 256, 0, stream>>>(ei, cnt, slot);
    scan1_kernel<<<NB_SCAN, 1024, 0, stream>>>(cnt, rowptr, bsum);
    scan2_kernel<<<1, 128, 0, stream>>>(bsum);
    scan3_kernel<<<NB_SCAN, 1024, 0, stream>>>(rowptr, bsum);
    scatter_kernel<<<(EE + 255) / 256, 256, 0, stream>>>(ei, ea, rowptr, slot, src_s, ea_s);
    selfloop_kernel<<<(NN + 255) / 256, 256, 0, stream>>>(rowptr, src_s, ea_s);
    wedot_kernel<<<1, 64, 0, stream>>>(We, a_edge, wedot);

    const int ngrid = (NN + 63) / 64;
    // --- layer 0 (input projection fused) ---
    in_gemm_kernel<<<ngrid, 256, 0, stream>>>(x, Win, b_in, Wg, h, xh,
                                              a_src, a_dst, al_s, al_d);
    for (int l = 0; l < NL; l++) {
        if (l > 0) {
            gemm_kernel<<<ngrid, 256, 0, stream>>>(
                h, Wg + (size_t)l * HID * HID, xh, g,
                ln_w + (size_t)(l - 1) * HID, ln_b + (size_t)(l - 1) * HID, stats, h,
                a_src + (size_t)l * HID, a_dst + (size_t)l * HID, al_s, al_d);
        }
        gat_agg_kernel<<<(NN + 3) / 4, 256, 0, stream>>>(
            rowptr, src_s, ea_s, xh, al_s, al_d, wedot + l * 4,
            bg + (size_t)l * HID, g, partials);
        stats_kernel<<<1, 1024, 0, stream>>>(partials, stats);
    }

    // --- final LN + residual + relu + output projection (fused) ---
    ln_out_kernel<<<(NN + 3) / 4, 256, 0, stream>>>(g, h, ln_w + (size_t)2 * HID,
                                                    ln_b + (size_t)2 * HID,
                                                    stats, Wout, bout, out);
}

// Round 5
// 594.390 us; speedup vs baseline: 1.7819x; 1.0805x over previous
//
#include <hip/hip_runtime.h>
#include <hip/hip_bf16.h>

#define NN 100000
#define EE 800000
#define HID 128
#define NH 4
#define CH 32
#define NL 3
#define NOUT 5
#define NEG_SLOPE 0.2f
#define LN_EPS 1e-5f
#define CAP 64             // LDS-cached edges per node row (deg > CAP falls to slow path)
#define NB_SCAN 98         // ceil((NN+1)/1024)

typedef unsigned int u32;

static __device__ __forceinline__ float bflo(u32 r) { return __uint_as_float(r << 16); }
static __device__ __forceinline__ float bfhi(u32 r) { return __uint_as_float(r & 0xffff0000u); }
static __device__ __forceinline__ unsigned short f2bf(float x) {
    union U { __hip_bfloat16 b; unsigned short s; } u;
    u.b = __float2bfloat16(x);
    return u.s;
}
static __device__ __forceinline__ float lrelu(float x) {
    return x > 0.f ? x : NEG_SLOPE * x;
}

// ---------------------------------------------------------------------------
// CSR build. cnt[n] starts at 1 (self-loop reserved at row slot 0); one atomic
// per real edge whose return value is the edge's slot -> scatter is atomic-free.
// ---------------------------------------------------------------------------
__global__ void init_kernel(int* __restrict__ cnt, float* __restrict__ partials) {
    int n = blockIdx.x * blockDim.x + threadIdx.x;
    if (n < NN) cnt[n] = 1;
    if (n < 2048) partials[n] = 0.f;
}

__global__ void hist_kernel(const int* __restrict__ ei, int* __restrict__ cnt,
                            int* __restrict__ slot) {
    int e = blockIdx.x * blockDim.x + threadIdx.x;
    if (e >= EE) return;
    int d = ei[EE + e];
    slot[e] = atomicAdd(&cnt[d], 1);
}

// hierarchical exclusive scan of cnt[0..NN] (element NN treated as 0) -> rowptr
__global__ __launch_bounds__(1024) void scan1_kernel(const int* __restrict__ cnt,
                                                     int* __restrict__ rowptr,
                                                     int* __restrict__ bsum) {
    __shared__ int ws[16];
    int gid = blockIdx.x * 1024 + threadIdx.x;
    int v = (gid < NN) ? cnt[gid] : 0;
    int lane = threadIdx.x & 63, wid = threadIdx.x >> 6;
    int s = v;
    #pragma unroll
    for (int off = 1; off < 64; off <<= 1) {
        int t = __shfl_up(s, off, 64);
        if (lane >= off) s += t;
    }
    if (lane == 63) ws[wid] = s;
    __syncthreads();
    int add = 0;
    for (int w2 = 0; w2 < wid; w2++) add += ws[w2];
    int incl = s + add;
    if (gid <= NN) rowptr[gid] = incl - v;   // exclusive
    if (threadIdx.x == 1023) bsum[blockIdx.x] = incl;
}

__global__ void scan2_kernel(int* __restrict__ bsum) {
    __shared__ int w0tot;
    int tid = threadIdx.x;                   // 128 threads
    int v = (tid < NB_SCAN) ? bsum[tid] : 0;
    int lane = tid & 63, wid = tid >> 6;
    int s = v;
    #pragma unroll
    for (int off = 1; off < 64; off <<= 1) {
        int t = __shfl_up(s, off, 64);
        if (lane >= off) s += t;
    }
    if (wid == 0 && lane == 63) w0tot = s;
    __syncthreads();
    int incl = s + (wid ? w0tot : 0);
    if (tid < NB_SCAN) bsum[tid] = incl - v; // exclusive
}

__global__ void scan3_kernel(int* __restrict__ rowptr, const int* __restrict__ bsum) {
    int gid = blockIdx.x * 1024 + threadIdx.x;
    if (gid <= NN) rowptr[gid] += bsum[blockIdx.x];
}

__global__ void scatter_kernel(const int* __restrict__ ei, const float* __restrict__ ea,
                               const int* __restrict__ rowptr, const int* __restrict__ slot,
                               int* __restrict__ src_s, float* __restrict__ ea_s) {
    int e = blockIdx.x * blockDim.x + threadIdx.x;
    if (e >= EE) return;
    int d = ei[EE + e];
    int pos = rowptr[d] + slot[e];           // slot >= 1; slot 0 is the self loop
    src_s[pos] = ei[e];
    ea_s[pos] = ea[e];
}

// self-loop attr = mean of the row's real-edge attrs (PyG fill_value='mean')
__global__ void selfloop_kernel(const int* __restrict__ rowptr, int* __restrict__ src_s,
                                float* __restrict__ ea_s) {
    int n = blockIdx.x * blockDim.x + threadIdx.x;
    if (n >= NN) return;
    int rs = rowptr[n], re = rowptr[n + 1];
    float s = 0.f;
    for (int i = rs + 1; i < re; i++) s += ea_s[i];
    ea_s[rs] = s / fmaxf((float)(re - rs - 1), 1.0f);
    src_s[rs] = n;
}

// wedot[l*4+h] = sum_c We[l][h*32+c] * a_edge[l][h*32+c]  (all layers at once)
__global__ void wedot_kernel(const float* __restrict__ We, const float* __restrict__ a_e,
                             float* __restrict__ wedot) {
    int t = threadIdx.x;
    if (t >= NL * NH) return;
    int l = t >> 2, hh = t & 3;
    float s = 0.f;
    #pragma unroll
    for (int c = 0; c < CH; c++)
        s += We[l * HID + hh * CH + c] * a_e[l * HID + hh * CH + c];
    wedot[t] = s;
}

// ---------------------------------------------------------------------------
// shared GEMM epilogue: pack xh to bf16 + compute al_s/al_d via 8-lane reduce
// ---------------------------------------------------------------------------
static __device__ __forceinline__ void store_xh_al(
        float acc[8][4], int n0, int r0, int c0, int cg,
        u32* __restrict__ xh, const float* __restrict__ asl, const float* __restrict__ adl,
        float* __restrict__ al_s, float* __restrict__ al_d) {
    float4 as4 = *(const float4*)&asl[c0];
    float4 ad4 = *(const float4*)&adl[c0];
    int hh = cg >> 3;
    #pragma unroll
    for (int i = 0; i < 8; i++) {
        int row = n0 + r0 + i;
        if (row < NN) {
            u32 lo = (u32)f2bf(acc[i][0]) | ((u32)f2bf(acc[i][1]) << 16);
            u32 hi = (u32)f2bf(acc[i][2]) | ((u32)f2bf(acc[i][3]) << 16);
            *(uint2*)&xh[(size_t)row * (HID / 2) + (c0 >> 1)] = make_uint2(lo, hi);
        }
        float ps = acc[i][0] * as4.x + acc[i][1] * as4.y + acc[i][2] * as4.z + acc[i][3] * as4.w;
        float pd = acc[i][0] * ad4.x + acc[i][1] * ad4.y + acc[i][2] * ad4.z + acc[i][3] * ad4.w;
        ps += __shfl_xor(ps, 1, 64); pd += __shfl_xor(pd, 1, 64);
        ps += __shfl_xor(ps, 2, 64); pd += __shfl_xor(pd, 2, 64);
        ps += __shfl_xor(ps, 4, 64); pd += __shfl_xor(pd, 4, 64);
        if ((cg & 7) == 0 && row < NN) {
            al_s[row * 4 + hh] = ps;
            al_d[row * 4 + hh] = pd;
        }
    }
}

// ---------------------------------------------------------------------------
// Layer 0 fused: h = x@Win + b_in (K=32), then xh = h@Wg0 (bf16), al dots.
// Tile 64 rows; h tile kept in LDS between the two GEMMs.
// ---------------------------------------------------------------------------
__global__ __launch_bounds__(256) void in_gemm_kernel(
        const float* __restrict__ x, const float* __restrict__ Win,
        const float* __restrict__ b_in, const float* __restrict__ Wg0,
        float* __restrict__ h, u32* __restrict__ xh,
        const float* __restrict__ a_src0, const float* __restrict__ a_dst0,
        float* __restrict__ al_s, float* __restrict__ al_d) {
    __shared__ float xs[64][36];
    __shared__ float ws[32][128];
    __shared__ float hs[64][128];
    int n0 = blockIdx.x * 64;
    int t = threadIdx.x;
    int cg = t & 31, rg = t >> 5;
    int c0 = cg * 4, r0 = rg * 8;
    // stage x (64 x 32)
    #pragma unroll
    for (int it = 0; it < 2; it++) {
        int idx = t + it * 256;
        int row = idx >> 3, kk = (idx & 7) * 4;
        float4 v = make_float4(0.f, 0.f, 0.f, 0.f);
        if (n0 + row < NN) v = *(const float4*)&x[(size_t)(n0 + row) * 32 + kk];
        *(float4*)&xs[row][kk] = v;
    }
    // stage Win (32 x 128)
    #pragma unroll
    for (int it = 0; it < 4; it++) {
        int idx = t + it * 256;
        int kr = idx >> 5, f4 = (idx & 31) * 4;
        *(float4*)&ws[kr][f4] = *(const float4*)&Win[kr * HID + f4];
    }
    __syncthreads();
    float acc[8][4] = {};
    #pragma unroll 8
    for (int k = 0; k < 32; k++) {
        float4 b4 = *(const float4*)&ws[k][c0];
        #pragma unroll
        for (int i = 0; i < 8; i++) {
            float a = xs[r0 + i][k];
            acc[i][0] += a * b4.x; acc[i][1] += a * b4.y;
            acc[i][2] += a * b4.z; acc[i][3] += a * b4.w;
        }
    }
    float4 bi = *(const float4*)&b_in[c0];
    #pragma unroll
    for (int i = 0; i < 8; i++) {
        acc[i][0] += bi.x; acc[i][1] += bi.y; acc[i][2] += bi.z; acc[i][3] += bi.w;
        int row = n0 + r0 + i;
        float4 v = make_float4(acc[i][0], acc[i][1], acc[i][2], acc[i][3]);
        *(float4*)&hs[r0 + i][c0] = v;
        if (row < NN) *(float4*)&h[(size_t)row * HID + c0] = v;
    }
    // second GEMM: xh = hs @ Wg0 (K=128, slabs of 32 overwrite ws)
    float acc2[8][4] = {};
    for (int ksl = 0; ksl < HID; ksl += 32) {
        __syncthreads();                     // prior ws readers done (+ hs visible, iter 0)
        #pragma unroll
        for (int it = 0; it < 4; it++) {
            int idx = t + it * 256;
            int kr = idx >> 5, f4 = (idx & 31) * 4;
            *(float4*)&ws[kr][f4] = *(const float4*)&Wg0[(size_t)(ksl + kr) * HID + f4];
        }
        __syncthreads();
        #pragma unroll 8
        for (int k = 0; k < 32; k++) {
            float4 b4 = *(const float4*)&ws[k][c0];
            #pragma unroll
            for (int i = 0; i < 8; i++) {
                float a = hs[r0 + i][ksl + k];
                acc2[i][0] += a * b4.x; acc2[i][1] += a * b4.y;
                acc2[i][2] += a * b4.z; acc2[i][3] += a * b4.w;
            }
        }
    }
    store_xh_al(acc2, n0, r0, c0, cg, xh, a_src0, a_dst0, al_s, al_d);
}

// ---------------------------------------------------------------------------
// Layers 1..2: hin = relu(LN(g)+h) computed on the fly (epilogue of prev
// layer), written back to h; xh = hin @ Wg (bf16); al dots in epilogue.
// ---------------------------------------------------------------------------
__global__ __launch_bounds__(256) void gemm_kernel(const float* __restrict__ h,
        const float* __restrict__ W, u32* __restrict__ xh, const float* __restrict__ g,
        const float* __restrict__ lnw, const float* __restrict__ lnb,
        const float* __restrict__ stats, float* __restrict__ hout,
        const float* __restrict__ asl, const float* __restrict__ adl,
        float* __restrict__ al_s, float* __restrict__ al_d) {
    __shared__ float hs[64][33];
    __shared__ float ws[32][128];
    float mean = stats[0], rstd = stats[1];
    int n0 = blockIdx.x * 64;
    int t = threadIdx.x;
    int cg = t & 31, rg = t >> 5;
    int c0 = cg * 4, r0 = rg * 8;
    float acc[8][4] = {};
    for (int ksl = 0; ksl < HID; ksl += 32) {
        #pragma unroll
        for (int it = 0; it < 2; it++) {
            int idx = t + it * 256;          // 0..511
            int row = idx >> 3;
            int kk = (idx & 7) * 4;
            int gr = n0 + row;
            float4 v = make_float4(0.f, 0.f, 0.f, 0.f);
            if (gr < NN) {
                size_t base = (size_t)gr * HID + ksl + kk;
                float4 gv = *(const float4*)&g[base];
                float4 hv = *(const float4*)&h[base];
                float4 w4 = *(const float4*)&lnw[ksl + kk];
                float4 b4 = *(const float4*)&lnb[ksl + kk];
                v.x = fmaxf((gv.x - mean) * rstd * w4.x + b4.x + hv.x, 0.f);
                v.y = fmaxf((gv.y - mean) * rstd * w4.y + b4.y + hv.y, 0.f);
                v.z = fmaxf((gv.z - mean) * rstd * w4.z + b4.z + hv.z, 0.f);
                v.w = fmaxf((gv.w - mean) * rstd * w4.w + b4.w + hv.w, 0.f);
                *(float4*)&hout[base] = v;
            }
            hs[row][kk] = v.x; hs[row][kk + 1] = v.y; hs[row][kk + 2] = v.z; hs[row][kk + 3] = v.w;
        }
        #pragma unroll
        for (int it = 0; it < 4; it++) {
            int idx = t + it * 256;          // 0..1023
            int kr = idx >> 5;
            int f4 = (idx & 31) * 4;
            *(float4*)&ws[kr][f4] = *(const float4*)&W[(size_t)(ksl + kr) * HID + f4];
        }
        __syncthreads();
        #pragma unroll 8
        for (int k = 0; k < 32; k++) {
            float4 b4 = *(const float4*)&ws[k][c0];
            #pragma unroll
            for (int i = 0; i < 8; i++) {
                float a = hs[r0 + i][k];
                acc[i][0] += a * b4.x; acc[i][1] += a * b4.y;
                acc[i][2] += a * b4.z; acc[i][3] += a * b4.w;
            }
        }
        __syncthreads();
    }
    store_xh_al(acc, n0, r0, c0, cg, xh, asl, adl, al_s, al_d);
}

// ---------------------------------------------------------------------------
// GAT aggregation, no-max softmax (logits are O(1) by construction: weights
// scale 0.1 -> |logit| < ~4; exp() safe in fp32; max subtraction cancels in
// alpha = ex/den exactly). 4 waves/block, one node per wave, wave-private LDS.
// Pass 1: lane-parallel logit->exp->LDS. Pass 2: channel-parallel gather+FMA
// with den folded in (no butterfly reductions at all).
// ---------------------------------------------------------------------------
__global__ __launch_bounds__(256) void gat_agg_kernel(const int* __restrict__ rowptr,
        const int* __restrict__ src_s, const float* __restrict__ ea_s,
        const u32* __restrict__ xh, const float* __restrict__ al_s,
        const float* __restrict__ al_d, const float* __restrict__ wedot,
        const float* __restrict__ bg, float* __restrict__ g,
        float* __restrict__ partials) {
    __shared__ float lds_ex[4][CAP * 4];
    __shared__ int lds_src[4][CAP];
    int wv = threadIdx.x >> 6, lane = threadIdx.x & 63;
    int n = blockIdx.x * 4 + wv;
    if (n >= NN) return;
    float* ex_w = lds_ex[wv];
    int* src_w = lds_src[wv];
    int rs = rowptr[n], re = rowptr[n + 1];
    int deg = re - rs;
    int nc = deg < CAP ? deg : CAP;
    float wd0 = wedot[0], wd1 = wedot[1], wd2 = wedot[2], wd3 = wedot[3];
    float4 aldv = *(const float4*)&al_d[n * 4];

    // Pass 1: exp(leaky_relu(logit)) for cached edges -> LDS (lane-parallel)
    for (int i = rs + lane; i < rs + nc; i += 64) {
        int s = src_s[i];
        float eav = ea_s[i];
        float4 als = *(const float4*)&al_s[s * 4];
        float e0 = __expf(lrelu(als.x + aldv.x + eav * wd0));
        float e1 = __expf(lrelu(als.y + aldv.y + eav * wd1));
        float e2 = __expf(lrelu(als.z + aldv.z + eav * wd2));
        float e3 = __expf(lrelu(als.w + aldv.w + eav * wd3));
        int k = i - rs;
        src_w[k] = s;
        *(float4*)&ex_w[k * 4] = make_float4(e0, e1, e2, e3);
    }
    // same-wave LDS ops are in-order; no barrier needed (wave-private rows)

    // Pass 2: lanes = (epar in {0,1}) x (cgroup: 4 channels each)
    int epar = lane >> 5, cgroup = lane & 31;
    int c0 = cgroup * 4;
    int head = cgroup >> 3;
    float a0 = 0.f, a1 = 0.f, a2 = 0.f, a3 = 0.f, den = 0.f;
    int j = epar;
    for (; j + 2 < nc; j += 4) {
        int s0 = src_w[j], s1 = src_w[j + 2];
        float e0 = ex_w[j * 4 + head], e1 = ex_w[(j + 2) * 4 + head];
        uint2 r0 = *(const uint2*)&xh[(size_t)s0 * (HID / 2) + (c0 >> 1)];
        uint2 r1 = *(const uint2*)&xh[(size_t)s1 * (HID / 2) + (c0 >> 1)];
        den += e0 + e1;
        a0 += e0 * bflo(r0.x); a1 += e0 * bfhi(r0.x);
        a2 += e0 * bflo(r0.y); a3 += e0 * bfhi(r0.y);
        a0 += e1 * bflo(r1.x); a1 += e1 * bfhi(r1.x);
        a2 += e1 * bflo(r1.y); a3 += e1 * bfhi(r1.y);
    }
    for (; j < nc; j += 2) {
        int s0 = src_w[j];
        float e0 = ex_w[j * 4 + head];
        uint2 r0 = *(const uint2*)&xh[(size_t)s0 * (HID / 2) + (c0 >> 1)];
        den += e0;
        a0 += e0 * bflo(r0.x); a1 += e0 * bfhi(r0.x);
        a2 += e0 * bflo(r0.y); a3 += e0 * bfhi(r0.y);
    }
    // rare tail: rows longer than CAP (recompute logits, still no max)
    if (deg > CAP) {
        float aldh = head == 0 ? aldv.x : head == 1 ? aldv.y : head == 2 ? aldv.z : aldv.w;
        float wdh  = head == 0 ? wd0 : head == 1 ? wd1 : head == 2 ? wd2 : wd3;
        for (int jt = CAP + epar; jt < deg; jt += 2) {
            int i = rs + jt;
            int s = src_s[i];
            float eav = ea_s[i];
            float ex = __expf(lrelu(al_s[s * 4 + head] + aldh + eav * wdh));
            den += ex;
            uint2 r0 = *(const uint2*)&xh[(size_t)s * (HID / 2) + (c0 >> 1)];
            a0 += ex * bflo(r0.x); a1 += ex * bfhi(r0.x);
            a2 += ex * bflo(r0.y); a3 += ex * bfhi(r0.y);
        }
    }
    // merge the two epar halves (den included -> no butterfly anywhere)
    a0 += __shfl_xor(a0, 32, 64); a1 += __shfl_xor(a1, 32, 64);
    a2 += __shfl_xor(a2, 32, 64); a3 += __shfl_xor(a3, 32, 64);
    den += __shfl_xor(den, 32, 64);

    float inv = 1.0f / (den + 1e-16f);
    float4 bgv = *(const float4*)&bg[c0];
    float o0 = a0 * inv + bgv.x, o1 = a1 * inv + bgv.y;
    float o2 = a2 * inv + bgv.z, o3 = a3 * inv + bgv.w;
    float ss = 0.f, sq = 0.f;
    if (epar == 0) {
        *(float4*)&g[(size_t)n * HID + c0] = make_float4(o0, o1, o2, o3);
        ss = o0 + o1 + o2 + o3;
        sq = o0 * o0 + o1 * o1 + o2 * o2 + o3 * o3;
    }
    #pragma unroll
    for (int off = 32; off; off >>= 1) {
        ss += __shfl_xor(ss, off, 64);
        sq += __shfl_xor(sq, off, 64);
    }
    if (lane == 0) {
        int sl = (n & 1023) * 2;
        atomicAdd(&partials[sl], ss);
        atomicAdd(&partials[sl + 1], sq);
    }
}

// reduce partials -> {mean, rstd}; re-zero partials for the next layer
__global__ void stats_kernel(float* __restrict__ partials, float* __restrict__ stats) {
    __shared__ float ls[16], lq[16];
    int tid = threadIdx.x;
    float s = partials[tid * 2], q = partials[tid * 2 + 1];
    partials[tid * 2] = 0.f;
    partials[tid * 2 + 1] = 0.f;
    #pragma unroll
    for (int off = 32; off; off >>= 1) {
        s += __shfl_xor(s, off, 64);
        q += __shfl_xor(q, off, 64);
    }
    int lane = tid & 63, wid = tid >> 6;
    if (lane == 0) { ls[wid] = s; lq[wid] = q; }
    __syncthreads();
    if (tid == 0) {
        float S = 0.f, Q = 0.f;
        for (int w2 = 0; w2 < 16; w2++) { S += ls[w2]; Q += lq[w2]; }
        const float M = (float)NN * (float)HID;
        float mean = S / M;
        float var = Q / M - mean * mean;
        stats[0] = mean;
        stats[1] = rsqrtf(fmaxf(var, 0.f) + LN_EPS);
    }
}

// final: out = relu(LN(g)+h) @ Wout + bout  (4 nodes/block, wave per node)
__global__ __launch_bounds__(256) void ln_out_kernel(const float* __restrict__ g,
        const float* __restrict__ h, const float* __restrict__ lnw,
        const float* __restrict__ lnb, const float* __restrict__ stats,
        const float* __restrict__ Wout, const float* __restrict__ bout,
        float* __restrict__ out) {
    __shared__ float wsh[HID * NOUT];
    int t = threadIdx.x;
    for (int i = t; i < HID * NOUT; i += 256) wsh[i] = Wout[i];
    __syncthreads();
    int wv = t >> 6, lane = t & 63;
    int n = blockIdx.x * 4 + wv;
    if (n >= NN) return;
    float mean = stats[0], rstd = stats[1];
    int c0 = lane * 2;
    float2 gv = *(const float2*)&g[(size_t)n * HID + c0];
    float2 hv = *(const float2*)&h[(size_t)n * HID + c0];
    float o0 = fmaxf((gv.x - mean) * rstd * lnw[c0]     + lnb[c0]     + hv.x, 0.f);
    float o1 = fmaxf((gv.y - mean) * rstd * lnw[c0 + 1] + lnb[c0 + 1] + hv.y, 0.f);
    float p[NOUT];
    #pragma unroll
    for (int jj = 0; jj < NOUT; jj++)
        p[jj] = o0 * wsh[c0 * NOUT + jj] + o1 * wsh[(c0 + 1) * NOUT + jj];
    #pragma unroll
    for (int off = 32; off; off >>= 1) {
        #pragma unroll
        for (int jj = 0; jj < NOUT; jj++) p[jj] += __shfl_xor(p[jj], off, 64);
    }
    if (lane == 0) {
        #pragma unroll
        for (int jj = 0; jj < NOUT; jj++)
            out[(size_t)n * NOUT + jj] = p[jj] + bout[jj];
    }
}

// ---------------------------------------------------------------------------
extern "C" void kernel_launch(void* const* d_in, const int* in_sizes, int n_in,
                              void* d_out, int out_size, void* d_ws, size_t ws_size,
                              hipStream_t stream) {
    const float* x      = (const float*)d_in[0];
    const int*   ei     = (const int*)d_in[1];
    const float* ea     = (const float*)d_in[2];
    const float* Win    = (const float*)d_in[3];
    const float* b_in   = (const float*)d_in[4];
    const float* Wg     = (const float*)d_in[5];
    const float* bg     = (const float*)d_in[6];
    const float* a_src  = (const float*)d_in[7];
    const float* a_dst  = (const float*)d_in[8];
    const float* We     = (const float*)d_in[9];
    const float* a_edge = (const float*)d_in[10];
    const float* ln_w   = (const float*)d_in[11];
    const float* ln_b   = (const float*)d_in[12];
    const float* Wout   = (const float*)d_in[13];
    const float* bout   = (const float*)d_in[14];
    float* out = (float*)d_out;

    char* w = (char*)d_ws;
    size_t off = 0;
    auto alloc = [&](size_t bytes) -> void* {
        void* p = w + off;
        off = (off + bytes + 255) & ~(size_t)255;
        return p;
    };
    int*   slot    = (int*)alloc((size_t)EE * sizeof(int));
    int*   cnt     = (int*)alloc(NN * sizeof(int));
    int*   rowptr  = (int*)alloc((NN + 1) * sizeof(int));
    int*   bsum    = (int*)alloc(NB_SCAN * sizeof(int));
    int*   src_s   = (int*)alloc((size_t)(EE + NN) * sizeof(int));
    float* ea_s    = (float*)alloc((size_t)(EE + NN) * sizeof(float));
    float* h       = (float*)alloc((size_t)NN * HID * sizeof(float));
    float* g       = (float*)alloc((size_t)NN * HID * sizeof(float));
    u32*   xh      = (u32*)alloc((size_t)NN * (HID / 2) * sizeof(u32));
    float* al_s    = (float*)alloc((size_t)NN * NH * sizeof(float));
    float* al_d    = (float*)alloc((size_t)NN * NH * sizeof(float));
    float* wedot   = (float*)alloc(16 * sizeof(float));
    float* partials = (float*)alloc(2048 * sizeof(float));
    float* stats   = (float*)alloc(16 * sizeof(float));
    (void)ws_size; (void)n_in; (void)in_sizes; (void)out_size;

    // --- CSR build ---
    init_kernel<<<(NN + 255) / 256, 256, 0, stream>>>(cnt, partials);
    hist_kernel<<<(EE + 255) / 256, 256, 0, stream>>>(ei, cnt, slot);
    scan1_kernel<<<NB_SCAN, 1024, 0, stream>>>(cnt, rowptr, bsum);
    scan2_kernel<<<1, 128, 0, stream>>>(bsum);
    scan3_kernel<<<NB_SCAN, 1024, 0, stream>>>(rowptr, bsum);
    scatter_kernel<<<(EE + 255) / 256, 256, 0, stream>>>(ei, ea, rowptr, slot, src_s, ea_s);
    selfloop_kernel<<<(NN + 255) / 256, 256, 0, stream>>>(rowptr, src_s, ea_s);
    wedot_kernel<<<1, 64, 0, stream>>>(We, a_edge, wedot);

    const int ngrid = (NN + 63) / 64;
    // --- layer 0 (input projection fused) ---
    in_gemm_kernel<<<ngrid, 256, 0, stream>>>(x, Win, b_in, Wg, h, xh,
                                              a_src, a_dst, al_s, al_d);
    for (int l = 0; l < NL; l++) {
        if (l > 0) {
            gemm_kernel<<<ngrid, 256, 0, stream>>>(
                h, Wg + (size_t)l * HID * HID, xh, g,
                ln_w + (size_t)(l - 1) * HID, ln_b + (size_t)(l - 1) * HID, stats, h,
                a_src + (size_t)l * HID, a_dst + (size_t)l * HID, al_s, al_d);
        }
        gat_agg_kernel<<<(NN + 3) / 4, 256, 0, stream>>>(
            rowptr, src_s, ea_s, xh, al_s, al_d, wedot + l * 4,
            bg + (size_t)l * HID, g, partials);
        stats_kernel<<<1, 1024, 0, stream>>>(partials, stats);
    }

    // --- final LN + residual + relu + output projection (fused) ---
    ln_out_kernel<<<(NN + 3) / 4, 256, 0, stream>>>(g, h, ln_w + (size_t)2 * HID,
                                                    ln_b + (size_t)2 * HID,
                                                    stats, Wout, bout, out);
}

// Round 6
// 541.757 us; speedup vs baseline: 1.9550x; 1.0972x over previous
//
#include <hip/hip_runtime.h>
#include <hip/hip_bf16.h>

#define NN 100000
#define EE 800000
#define HID 128
#define NH 4
#define CH 32
#define NL 3
#define NOUT 5
#define NEG_SLOPE 0.2f
#define LN_EPS 1e-5f
#define CAP 64             // LDS-cached edges per node row (deg > CAP falls to slow path)
#define NB_SCAN 98         // ceil((NN+1)/1024)
#define HQ (HID / 2)       // u32-packed bf16 pairs per row

typedef unsigned int u32;

static __device__ __forceinline__ float bflo(u32 r) { return __uint_as_float(r << 16); }
static __device__ __forceinline__ float bfhi(u32 r) { return __uint_as_float(r & 0xffff0000u); }
static __device__ __forceinline__ unsigned short f2bf(float x) {
    union U { __hip_bfloat16 b; unsigned short s; } u;
    u.b = __float2bfloat16(x);
    return u.s;
}
static __device__ __forceinline__ u32 pack2(float a, float b) {
    return (u32)f2bf(a) | ((u32)f2bf(b) << 16);
}
static __device__ __forceinline__ float lrelu(float x) {
    return x > 0.f ? x : NEG_SLOPE * x;
}

// ---------------------------------------------------------------------------
// CSR build. cnt[n] starts at 1 (self-loop reserved at row slot 0); one atomic
// per real edge whose return value is the edge's slot -> scatter is atomic-free.
// ---------------------------------------------------------------------------
__global__ void init_kernel(int* __restrict__ cnt, float* __restrict__ partials) {
    int n = blockIdx.x * blockDim.x + threadIdx.x;
    if (n < NN) cnt[n] = 1;
    if (n < 2048) partials[n] = 0.f;
}

__global__ void hist_kernel(const int* __restrict__ ei, int* __restrict__ cnt,
                            int* __restrict__ slot) {
    int e = blockIdx.x * blockDim.x + threadIdx.x;
    if (e >= EE) return;
    int d = ei[EE + e];
    slot[e] = atomicAdd(&cnt[d], 1);
}

// hierarchical exclusive scan of cnt[0..NN] (element NN treated as 0) -> rowptr
__global__ __launch_bounds__(1024) void scan1_kernel(const int* __restrict__ cnt,
                                                     int* __restrict__ rowptr,
                                                     int* __restrict__ bsum) {
    __shared__ int ws[16];
    int gid = blockIdx.x * 1024 + threadIdx.x;
    int v = (gid < NN) ? cnt[gid] : 0;
    int lane = threadIdx.x & 63, wid = threadIdx.x >> 6;
    int s = v;
    #pragma unroll
    for (int off = 1; off < 64; off <<= 1) {
        int t = __shfl_up(s, off, 64);
        if (lane >= off) s += t;
    }
    if (lane == 63) ws[wid] = s;
    __syncthreads();
    int add = 0;
    for (int w2 = 0; w2 < wid; w2++) add += ws[w2];
    int incl = s + add;
    if (gid <= NN) rowptr[gid] = incl - v;   // exclusive
    if (threadIdx.x == 1023) bsum[blockIdx.x] = incl;
}

__global__ void scan2_kernel(int* __restrict__ bsum) {
    __shared__ int w0tot;
    int tid = threadIdx.x;                   // 128 threads
    int v = (tid < NB_SCAN) ? bsum[tid] : 0;
    int lane = tid & 63, wid = tid >> 6;
    int s = v;
    #pragma unroll
    for (int off = 1; off < 64; off <<= 1) {
        int t = __shfl_up(s, off, 64);
        if (lane >= off) s += t;
    }
    if (wid == 0 && lane == 63) w0tot = s;
    __syncthreads();
    int incl = s + (wid ? w0tot : 0);
    if (tid < NB_SCAN) bsum[tid] = incl - v; // exclusive
}

__global__ void scan3_kernel(int* __restrict__ rowptr, const int* __restrict__ bsum) {
    int gid = blockIdx.x * 1024 + threadIdx.x;
    if (gid <= NN) rowptr[gid] += bsum[blockIdx.x];
}

__global__ void scatter_kernel(const int* __restrict__ ei, const float* __restrict__ ea,
                               const int* __restrict__ rowptr, const int* __restrict__ slot,
                               int* __restrict__ src_s, float* __restrict__ ea_s) {
    int e = blockIdx.x * blockDim.x + threadIdx.x;
    if (e >= EE) return;
    int d = ei[EE + e];
    int pos = rowptr[d] + slot[e];           // slot >= 1; slot 0 is the self loop
    src_s[pos] = ei[e];
    ea_s[pos] = ea[e];
}

// self-loop attr = mean of the row's real-edge attrs (PyG fill_value='mean')
__global__ void selfloop_kernel(const int* __restrict__ rowptr, int* __restrict__ src_s,
                                float* __restrict__ ea_s) {
    int n = blockIdx.x * blockDim.x + threadIdx.x;
    if (n >= NN) return;
    int rs = rowptr[n], re = rowptr[n + 1];
    float s = 0.f;
    for (int i = rs + 1; i < re; i++) s += ea_s[i];
    ea_s[rs] = s / fmaxf((float)(re - rs - 1), 1.0f);
    src_s[rs] = n;
}

// wedot[l*4+h] = sum_c We[l][h*32+c] * a_edge[l][h*32+c]  (all layers at once)
__global__ void wedot_kernel(const float* __restrict__ We, const float* __restrict__ a_e,
                             float* __restrict__ wedot) {
    int t = threadIdx.x;
    if (t >= NL * NH) return;
    int l = t >> 2, hh = t & 3;
    float s = 0.f;
    #pragma unroll
    for (int c = 0; c < CH; c++)
        s += We[l * HID + hh * CH + c] * a_e[l * HID + hh * CH + c];
    wedot[t] = s;
}

// wf[r][c] (r<32) = sum_k Win[r][k]*Wg0[k][c];  wf[32][c] = sum_k b_in[k]*Wg0[k][c]
__global__ void wfuse_kernel(const float* __restrict__ Win, const float* __restrict__ b_in,
                             const float* __restrict__ Wg0, float* __restrict__ wf) {
    int r = blockIdx.x;                      // 0..32
    int c = threadIdx.x;                     // 0..127
    float acc = 0.f;
    for (int k = 0; k < HID; k++) {
        float a = (r < 32) ? Win[r * HID + k] : b_in[k];
        acc += a * Wg0[(size_t)k * HID + c];
    }
    wf[r * HID + c] = acc;
}

// ---------------------------------------------------------------------------
// shared GEMM epilogue: pack xh to bf16 + compute al_s/al_d via 8-lane reduce
// ---------------------------------------------------------------------------
static __device__ __forceinline__ void store_xh_al(
        float acc[8][4], int n0, int r0, int c0, int cg,
        u32* __restrict__ xh, const float* __restrict__ asl, const float* __restrict__ adl,
        float* __restrict__ al_s, float* __restrict__ al_d) {
    float4 as4 = *(const float4*)&asl[c0];
    float4 ad4 = *(const float4*)&adl[c0];
    int hh = cg >> 3;
    #pragma unroll
    for (int i = 0; i < 8; i++) {
        int row = n0 + r0 + i;
        if (row < NN) {
            u32 lo = pack2(acc[i][0], acc[i][1]);
            u32 hi = pack2(acc[i][2], acc[i][3]);
            *(uint2*)&xh[(size_t)row * HQ + (c0 >> 1)] = make_uint2(lo, hi);
        }
        float ps = acc[i][0] * as4.x + acc[i][1] * as4.y + acc[i][2] * as4.z + acc[i][3] * as4.w;
        float pd = acc[i][0] * ad4.x + acc[i][1] * ad4.y + acc[i][2] * ad4.z + acc[i][3] * ad4.w;
        ps += __shfl_xor(ps, 1, 64); pd += __shfl_xor(pd, 1, 64);
        ps += __shfl_xor(ps, 2, 64); pd += __shfl_xor(pd, 2, 64);
        ps += __shfl_xor(ps, 4, 64); pd += __shfl_xor(pd, 4, 64);
        if ((cg & 7) == 0 && row < NN) {
            al_s[row * 4 + hh] = ps;
            al_d[row * 4 + hh] = pd;
        }
    }
}

// ---------------------------------------------------------------------------
// Layer 0, algebraically fused: h = x@Win + b_in  AND  xh = x@Wf + bf,
// both K=32 GEMMs off the same LDS x-tile. h/xh stored packed bf16.
// ---------------------------------------------------------------------------
__global__ __launch_bounds__(256) void in_gemm_kernel(
        const float* __restrict__ x, const float* __restrict__ Win,
        const float* __restrict__ b_in, const float* __restrict__ wf,
        u32* __restrict__ h, u32* __restrict__ xh,
        const float* __restrict__ a_src0, const float* __restrict__ a_dst0,
        float* __restrict__ al_s, float* __restrict__ al_d) {
    __shared__ float xs[64][36];
    __shared__ float ws[32][128];
    int n0 = blockIdx.x * 64;
    int t = threadIdx.x;
    int cg = t & 31, rg = t >> 5;
    int c0 = cg * 4, r0 = rg * 8;
    // stage x (64 x 32)
    #pragma unroll
    for (int it = 0; it < 2; it++) {
        int idx = t + it * 256;
        int row = idx >> 3, kk = (idx & 7) * 4;
        float4 v = make_float4(0.f, 0.f, 0.f, 0.f);
        if (n0 + row < NN) v = *(const float4*)&x[(size_t)(n0 + row) * 32 + kk];
        *(float4*)&xs[row][kk] = v;
    }
    // stage Win (32 x 128)
    #pragma unroll
    for (int it = 0; it < 4; it++) {
        int idx = t + it * 256;
        int kr = idx >> 5, f4 = (idx & 31) * 4;
        *(float4*)&ws[kr][f4] = *(const float4*)&Win[kr * HID + f4];
    }
    __syncthreads();
    // GEMM 1: h = x @ Win + b_in
    {
        float acc[8][4] = {};
        #pragma unroll 8
        for (int k = 0; k < 32; k++) {
            float4 b4 = *(const float4*)&ws[k][c0];
            #pragma unroll
            for (int i = 0; i < 8; i++) {
                float a = xs[r0 + i][k];
                acc[i][0] += a * b4.x; acc[i][1] += a * b4.y;
                acc[i][2] += a * b4.z; acc[i][3] += a * b4.w;
            }
        }
        float4 bi = *(const float4*)&b_in[c0];
        #pragma unroll
        for (int i = 0; i < 8; i++) {
            int row = n0 + r0 + i;
            if (row < NN) {
                u32 lo = pack2(acc[i][0] + bi.x, acc[i][1] + bi.y);
                u32 hi = pack2(acc[i][2] + bi.z, acc[i][3] + bi.w);
                *(uint2*)&h[(size_t)row * HQ + (c0 >> 1)] = make_uint2(lo, hi);
            }
        }
    }
    __syncthreads();                          // all ws readers done
    // stage Wf (32 x 128)
    #pragma unroll
    for (int it = 0; it < 4; it++) {
        int idx = t + it * 256;
        int kr = idx >> 5, f4 = (idx & 31) * 4;
        *(float4*)&ws[kr][f4] = *(const float4*)&wf[kr * HID + f4];
    }
    __syncthreads();
    // GEMM 2: xh = x @ Wf + bf
    float acc2[8][4] = {};
    #pragma unroll 8
    for (int k = 0; k < 32; k++) {
        float4 b4 = *(const float4*)&ws[k][c0];
        #pragma unroll
        for (int i = 0; i < 8; i++) {
            float a = xs[r0 + i][k];
            acc2[i][0] += a * b4.x; acc2[i][1] += a * b4.y;
            acc2[i][2] += a * b4.z; acc2[i][3] += a * b4.w;
        }
    }
    float4 bf4 = *(const float4*)&wf[32 * HID + c0];
    #pragma unroll
    for (int i = 0; i < 8; i++) {
        acc2[i][0] += bf4.x; acc2[i][1] += bf4.y; acc2[i][2] += bf4.z; acc2[i][3] += bf4.w;
    }
    store_xh_al(acc2, n0, r0, c0, cg, xh, a_src0, a_dst0, al_s, al_d);
}

// ---------------------------------------------------------------------------
// Layers 1..2: hin = relu(LN(g)+h) computed on the fly (epilogue of prev
// layer), written back packed; xh = hin @ Wg (bf16); al dots in epilogue.
// g/h/hout are bf16-packed u32; staging at 8-value (uint4) granularity.
// ---------------------------------------------------------------------------
__global__ __launch_bounds__(256) void gemm_kernel(const u32* __restrict__ h,
        const float* __restrict__ W, u32* __restrict__ xh, const u32* __restrict__ g,
        const float* __restrict__ lnw, const float* __restrict__ lnb,
        const float* __restrict__ stats, u32* __restrict__ hout,
        const float* __restrict__ asl, const float* __restrict__ adl,
        float* __restrict__ al_s, float* __restrict__ al_d) {
    __shared__ float hs[64][36];
    __shared__ float ws[32][128];
    float mean = stats[0], rstd = stats[1];
    int n0 = blockIdx.x * 64;
    int t = threadIdx.x;
    int cg = t & 31, rg = t >> 5;
    int c0 = cg * 4, r0 = rg * 8;
    float acc[8][4] = {};
    for (int ksl = 0; ksl < HID; ksl += 32) {
        // stage hin slab 64 rows x 32 cols: one uint4 (8 bf16 pairs? no: 8 values) each
        {
            int row = t >> 2;
            int kk = (t & 3) * 8;
            int gr = n0 + row;
            float v[8] = {};
            if (gr < NN) {
                size_t base = (size_t)gr * HQ + ((ksl + kk) >> 1);
                uint4 gp = *(const uint4*)&g[base];
                uint4 hp = *(const uint4*)&h[base];
                float4 wA = *(const float4*)&lnw[ksl + kk];
                float4 wB = *(const float4*)&lnw[ksl + kk + 4];
                float4 bA = *(const float4*)&lnb[ksl + kk];
                float4 bB = *(const float4*)&lnb[ksl + kk + 4];
                v[0] = fmaxf((bflo(gp.x) - mean) * rstd * wA.x + bA.x + bflo(hp.x), 0.f);
                v[1] = fmaxf((bfhi(gp.x) - mean) * rstd * wA.y + bA.y + bfhi(hp.x), 0.f);
                v[2] = fmaxf((bflo(gp.y) - mean) * rstd * wA.z + bA.z + bflo(hp.y), 0.f);
                v[3] = fmaxf((bfhi(gp.y) - mean) * rstd * wA.w + bA.w + bfhi(hp.y), 0.f);
                v[4] = fmaxf((bflo(gp.z) - mean) * rstd * wB.x + bB.x + bflo(hp.z), 0.f);
                v[5] = fmaxf((bfhi(gp.z) - mean) * rstd * wB.y + bB.y + bfhi(hp.z), 0.f);
                v[6] = fmaxf((bflo(gp.w) - mean) * rstd * wB.z + bB.z + bflo(hp.w), 0.f);
                v[7] = fmaxf((bfhi(gp.w) - mean) * rstd * wB.w + bB.w + bfhi(hp.w), 0.f);
                uint4 op;
                op.x = pack2(v[0], v[1]); op.y = pack2(v[2], v[3]);
                op.z = pack2(v[4], v[5]); op.w = pack2(v[6], v[7]);
                *(uint4*)&hout[base] = op;
            }
            #pragma unroll
            for (int q = 0; q < 8; q++) hs[row][kk + q] = v[q];
        }
        #pragma unroll
        for (int it = 0; it < 4; it++) {
            int idx = t + it * 256;          // 0..1023
            int kr = idx >> 5;
            int f4 = (idx & 31) * 4;
            *(float4*)&ws[kr][f4] = *(const float4*)&W[(size_t)(ksl + kr) * HID + f4];
        }
        __syncthreads();
        #pragma unroll 8
        for (int k = 0; k < 32; k++) {
            float4 b4 = *(const float4*)&ws[k][c0];
            #pragma unroll
            for (int i = 0; i < 8; i++) {
                float a = hs[r0 + i][k];
                acc[i][0] += a * b4.x; acc[i][1] += a * b4.y;
                acc[i][2] += a * b4.z; acc[i][3] += a * b4.w;
            }
        }
        __syncthreads();
    }
    store_xh_al(acc, n0, r0, c0, cg, xh, asl, adl, al_s, al_d);
}

// ---------------------------------------------------------------------------
// GAT aggregation, no-max softmax (logits are O(1) by construction). 4 waves/
// block, one node per wave, wave-private LDS. Pass 1: lane-parallel
// logit->exp->LDS. Pass 2: channel-parallel gather+FMA with den folded in.
// ---------------------------------------------------------------------------
__global__ __launch_bounds__(256) void gat_agg_kernel(const int* __restrict__ rowptr,
        const int* __restrict__ src_s, const float* __restrict__ ea_s,
        const u32* __restrict__ xh, const float* __restrict__ al_s,
        const float* __restrict__ al_d, const float* __restrict__ wedot,
        const float* __restrict__ bg, u32* __restrict__ g,
        float* __restrict__ partials) {
    __shared__ float lds_ex[4][CAP * 4];
    __shared__ int lds_src[4][CAP];
    int wv = threadIdx.x >> 6, lane = threadIdx.x & 63;
    int n = blockIdx.x * 4 + wv;
    if (n >= NN) return;
    float* ex_w = lds_ex[wv];
    int* src_w = lds_src[wv];
    int rs = rowptr[n], re = rowptr[n + 1];
    int deg = re - rs;
    int nc = deg < CAP ? deg : CAP;
    float wd0 = wedot[0], wd1 = wedot[1], wd2 = wedot[2], wd3 = wedot[3];
    float4 aldv = *(const float4*)&al_d[n * 4];

    // Pass 1: exp(leaky_relu(logit)) for cached edges -> LDS (lane-parallel)
    for (int i = rs + lane; i < rs + nc; i += 64) {
        int s = src_s[i];
        float eav = ea_s[i];
        float4 als = *(const float4*)&al_s[s * 4];
        float e0 = __expf(lrelu(als.x + aldv.x + eav * wd0));
        float e1 = __expf(lrelu(als.y + aldv.y + eav * wd1));
        float e2 = __expf(lrelu(als.z + aldv.z + eav * wd2));
        float e3 = __expf(lrelu(als.w + aldv.w + eav * wd3));
        int k = i - rs;
        src_w[k] = s;
        *(float4*)&ex_w[k * 4] = make_float4(e0, e1, e2, e3);
    }
    // same-wave LDS ops are in-order; no barrier needed (wave-private rows)

    // Pass 2: lanes = (epar in {0,1}) x (cgroup: 4 channels each)
    int epar = lane >> 5, cgroup = lane & 31;
    int c0 = cgroup * 4;
    int head = cgroup >> 3;
    float a0 = 0.f, a1 = 0.f, a2 = 0.f, a3 = 0.f, den = 0.f;
    int j = epar;
    for (; j + 2 < nc; j += 4) {
        int s0 = src_w[j], s1 = src_w[j + 2];
        float e0 = ex_w[j * 4 + head], e1 = ex_w[(j + 2) * 4 + head];
        uint2 r0 = *(const uint2*)&xh[(size_t)s0 * HQ + (c0 >> 1)];
        uint2 r1 = *(const uint2*)&xh[(size_t)s1 * HQ + (c0 >> 1)];
        den += e0 + e1;
        a0 += e0 * bflo(r0.x); a1 += e0 * bfhi(r0.x);
        a2 += e0 * bflo(r0.y); a3 += e0 * bfhi(r0.y);
        a0 += e1 * bflo(r1.x); a1 += e1 * bfhi(r1.x);
        a2 += e1 * bflo(r1.y); a3 += e1 * bfhi(r1.y);
    }
    for (; j < nc; j += 2) {
        int s0 = src_w[j];
        float e0 = ex_w[j * 4 + head];
        uint2 r0 = *(const uint2*)&xh[(size_t)s0 * HQ + (c0 >> 1)];
        den += e0;
        a0 += e0 * bflo(r0.x); a1 += e0 * bfhi(r0.x);
        a2 += e0 * bflo(r0.y); a3 += e0 * bfhi(r0.y);
    }
    // rare tail: rows longer than CAP (recompute logits, still no max)
    if (deg > CAP) {
        float aldh = head == 0 ? aldv.x : head == 1 ? aldv.y : head == 2 ? aldv.z : aldv.w;
        float wdh  = head == 0 ? wd0 : head == 1 ? wd1 : head == 2 ? wd2 : wd3;
        for (int jt = CAP + epar; jt < deg; jt += 2) {
            int i = rs + jt;
            int s = src_s[i];
            float eav = ea_s[i];
            float ex = __expf(lrelu(al_s[s * 4 + head] + aldh + eav * wdh));
            den += ex;
            uint2 r0 = *(const uint2*)&xh[(size_t)s * HQ + (c0 >> 1)];
            a0 += ex * bflo(r0.x); a1 += ex * bfhi(r0.x);
            a2 += ex * bflo(r0.y); a3 += ex * bfhi(r0.y);
        }
    }
    // merge the two epar halves (den included -> no butterfly anywhere)
    a0 += __shfl_xor(a0, 32, 64); a1 += __shfl_xor(a1, 32, 64);
    a2 += __shfl_xor(a2, 32, 64); a3 += __shfl_xor(a3, 32, 64);
    den += __shfl_xor(den, 32, 64);

    float inv = 1.0f / (den + 1e-16f);
    float4 bgv = *(const float4*)&bg[c0];
    float o0 = a0 * inv + bgv.x, o1 = a1 * inv + bgv.y;
    float o2 = a2 * inv + bgv.z, o3 = a3 * inv + bgv.w;
    float ss = 0.f, sq = 0.f;
    if (epar == 0) {
        // pack g to bf16 (LN stats below use pre-rounding fp32 values)
        u32 lo = pack2(o0, o1), hi = pack2(o2, o3);
        *(uint2*)&g[(size_t)n * HQ + (c0 >> 1)] = make_uint2(lo, hi);
        ss = o0 + o1 + o2 + o3;
        sq = o0 * o0 + o1 * o1 + o2 * o2 + o3 * o3;
    }
    #pragma unroll
    for (int off = 32; off; off >>= 1) {
        ss += __shfl_xor(ss, off, 64);
        sq += __shfl_xor(sq, off, 64);
    }
    if (lane == 0) {
        int sl = (n & 1023) * 2;
        atomicAdd(&partials[sl], ss);
        atomicAdd(&partials[sl + 1], sq);
    }
}

// reduce partials -> {mean, rstd}; re-zero partials for the next layer
__global__ void stats_kernel(float* __restrict__ partials, float* __restrict__ stats) {
    __shared__ float ls[16], lq[16];
    int tid = threadIdx.x;
    float s = partials[tid * 2], q = partials[tid * 2 + 1];
    partials[tid * 2] = 0.f;
    partials[tid * 2 + 1] = 0.f;
    #pragma unroll
    for (int off = 32; off; off >>= 1) {
        s += __shfl_xor(s, off, 64);
        q += __shfl_xor(q, off, 64);
    }
    int lane = tid & 63, wid = tid >> 6;
    if (lane == 0) { ls[wid] = s; lq[wid] = q; }
    __syncthreads();
    if (tid == 0) {
        float S = 0.f, Q = 0.f;
        for (int w2 = 0; w2 < 16; w2++) { S += ls[w2]; Q += lq[w2]; }
        const float M = (float)NN * (float)HID;
        float mean = S / M;
        float var = Q / M - mean * mean;
        stats[0] = mean;
        stats[1] = rsqrtf(fmaxf(var, 0.f) + LN_EPS);
    }
}

// final: out = relu(LN(g)+h) @ Wout + bout  (4 nodes/block, wave per node)
__global__ __launch_bounds__(256) void ln_out_kernel(const u32* __restrict__ g,
        const u32* __restrict__ h, const float* __restrict__ lnw,
        const float* __restrict__ lnb, const float* __restrict__ stats,
        const float* __restrict__ Wout, const float* __restrict__ bout,
        float* __restrict__ out) {
    __shared__ float wsh[HID * NOUT];
    int t = threadIdx.x;
    for (int i = t; i < HID * NOUT; i += 256) wsh[i] = Wout[i];
    __syncthreads();
    int wv = t >> 6, lane = t & 63;
    int n = blockIdx.x * 4 + wv;
    if (n >= NN) return;
    float mean = stats[0], rstd = stats[1];
    int c0 = lane * 2;
    u32 gv = g[(size_t)n * HQ + lane];
    u32 hv = h[(size_t)n * HQ + lane];
    float o0 = fmaxf((bflo(gv) - mean) * rstd * lnw[c0]     + lnb[c0]     + bflo(hv), 0.f);
    float o1 = fmaxf((bfhi(gv) - mean) * rstd * lnw[c0 + 1] + lnb[c0 + 1] + bfhi(hv), 0.f);
    float p[NOUT];
    #pragma unroll
    for (int jj = 0; jj < NOUT; jj++)
        p[jj] = o0 * wsh[c0 * NOUT + jj] + o1 * wsh[(c0 + 1) * NOUT + jj];
    #pragma unroll
    for (int off = 32; off; off >>= 1) {
        #pragma unroll
        for (int jj = 0; jj < NOUT; jj++) p[jj] += __shfl_xor(p[jj], off, 64);
    }
    if (lane == 0) {
        #pragma unroll
        for (int jj = 0; jj < NOUT; jj++)
            out[(size_t)n * NOUT + jj] = p[jj] + bout[jj];
    }
}

// ---------------------------------------------------------------------------
extern "C" void kernel_launch(void* const* d_in, const int* in_sizes, int n_in,
                              void* d_out, int out_size, void* d_ws, size_t ws_size,
                              hipStream_t stream) {
    const float* x      = (const float*)d_in[0];
    const int*   ei     = (const int*)d_in[1];
    const float* ea     = (const float*)d_in[2];
    const float* Win    = (const float*)d_in[3];
    const float* b_in   = (const float*)d_in[4];
    const float* Wg     = (const float*)d_in[5];
    const float* bg     = (const float*)d_in[6];
    const float* a_src  = (const float*)d_in[7];
    const float* a_dst  = (const float*)d_in[8];
    const float* We     = (const float*)d_in[9];
    const float* a_edge = (const float*)d_in[10];
    const float* ln_w   = (const float*)d_in[11];
    const float* ln_b   = (const float*)d_in[12];
    const float* Wout   = (const float*)d_in[13];
    const float* bout   = (const float*)d_in[14];
    float* out = (float*)d_out;

    char* w = (char*)d_ws;
    size_t off = 0;
    auto alloc = [&](size_t bytes) -> void* {
        void* p = w + off;
        off = (off + bytes + 255) & ~(size_t)255;
        return p;
    };
    int*   slot    = (int*)alloc((size_t)EE * sizeof(int));
    int*   cnt     = (int*)alloc(NN * sizeof(int));
    int*   rowptr  = (int*)alloc((NN + 1) * sizeof(int));
    int*   bsum    = (int*)alloc(NB_SCAN * sizeof(int));
    int*   src_s   = (int*)alloc((size_t)(EE + NN) * sizeof(int));
    float* ea_s    = (float*)alloc((size_t)(EE + NN) * sizeof(float));
    u32*   h       = (u32*)alloc((size_t)NN * HQ * sizeof(u32));
    u32*   g       = (u32*)alloc((size_t)NN * HQ * sizeof(u32));
    u32*   xh      = (u32*)alloc((size_t)NN * HQ * sizeof(u32));
    float* al_s    = (float*)alloc((size_t)NN * NH * sizeof(float));
    float* al_d    = (float*)alloc((size_t)NN * NH * sizeof(float));
    float* wedot   = (float*)alloc(16 * sizeof(float));
    float* wf      = (float*)alloc(33 * HID * sizeof(float));
    float* partials = (float*)alloc(2048 * sizeof(float));
    float* stats   = (float*)alloc(16 * sizeof(float));
    (void)ws_size; (void)n_in; (void)in_sizes; (void)out_size;

    // --- CSR build + weight prep ---
    init_kernel<<<(NN + 255) / 256, 256, 0, stream>>>(cnt, partials);
    hist_kernel<<<(EE + 255) / 256, 256, 0, stream>>>(ei, cnt, slot);
    scan1_kernel<<<NB_SCAN, 1024, 0, stream>>>(cnt, rowptr, bsum);
    scan2_kernel<<<1, 128, 0, stream>>>(bsum);
    scan3_kernel<<<NB_SCAN, 1024, 0, stream>>>(rowptr, bsum);
    scatter_kernel<<<(EE + 255) / 256, 256, 0, stream>>>(ei, ea, rowptr, slot, src_s, ea_s);
    selfloop_kernel<<<(NN + 255) / 256, 256, 0, stream>>>(rowptr, src_s, ea_s);
    wedot_kernel<<<1, 64, 0, stream>>>(We, a_edge, wedot);
    wfuse_kernel<<<33, 128, 0, stream>>>(Win, b_in, Wg, wf);

    const int ngrid = (NN + 63) / 64;
    // --- layer 0 (input projection algebraically fused) ---
    in_gemm_kernel<<<ngrid, 256, 0, stream>>>(x, Win, b_in, wf, h, xh,
                                              a_src, a_dst, al_s, al_d);
    for (int l = 0; l < NL; l++) {
        if (l > 0) {
            gemm_kernel<<<ngrid, 256, 0, stream>>>(
                h, Wg + (size_t)l * HID * HID, xh, g,
                ln_w + (size_t)(l - 1) * HID, ln_b + (size_t)(l - 1) * HID, stats, h,
                a_src + (size_t)l * HID, a_dst + (size_t)l * HID, al_s, al_d);
        }
        gat_agg_kernel<<<(NN + 3) / 4, 256, 0, stream>>>(
            rowptr, src_s, ea_s, xh, al_s, al_d, wedot + l * 4,
            bg + (size_t)l * HID, g, partials);
        stats_kernel<<<1, 1024, 0, stream>>>(partials, stats);
    }

    // --- final LN + residual + relu + output projection (fused) ---
    ln_out_kernel<<<(NN + 3) / 4, 256, 0, stream>>>(g, h, ln_w + (size_t)2 * HID,
                                                    ln_b + (size_t)2 * HID,
                                                    stats, Wout, bout, out);
}

// Round 7
// 492.985 us; speedup vs baseline: 2.1484x; 1.0989x over previous
//
#include <hip/hip_runtime.h>
#include <hip/hip_bf16.h>

#define NN 100000
#define EE 800000
#define HID 128
#define NH 4
#define CH 32
#define NL 3
#define NOUT 5
#define NEG_SLOPE 0.2f
#define LN_EPS 1e-5f
#define CAP 64             // LDS-cached edges per node row (deg > CAP falls to slow path)
#define NB_SCAN 98         // ceil((NN+1)/1024)
#define HQ (HID / 2)       // u32-packed bf16 pairs per row
#define WB_LSZ 9216        // u32 per layer of packed B-frags: 4ks*9ct*64lane*4

typedef unsigned int u32;
typedef __attribute__((ext_vector_type(8))) short bf16x8;
typedef __attribute__((ext_vector_type(4))) float f32x4;

static __device__ __forceinline__ float bflo(u32 r) { return __uint_as_float(r << 16); }
static __device__ __forceinline__ float bfhi(u32 r) { return __uint_as_float(r & 0xffff0000u); }
static __device__ __forceinline__ unsigned short f2bf(float x) {
    union U { __hip_bfloat16 b; unsigned short s; } u;
    u.b = __float2bfloat16(x);
    return u.s;
}
static __device__ __forceinline__ u32 pack2(float a, float b) {
    return (u32)f2bf(a) | ((u32)f2bf(b) << 16);
}
static __device__ __forceinline__ float lrelu(float x) {
    return x > 0.f ? x : NEG_SLOPE * x;
}

// ---------------------------------------------------------------------------
// CSR build. cnt[n] starts at 1 (self-loop reserved at row slot 0); one atomic
// per real edge whose return value is the edge's slot -> scatter is atomic-free.
// ---------------------------------------------------------------------------
__global__ void init_kernel(int* __restrict__ cnt, float* __restrict__ partials) {
    int n = blockIdx.x * blockDim.x + threadIdx.x;
    if (n < NN) cnt[n] = 1;
    if (n < 2048) partials[n] = 0.f;
}

__global__ void hist_kernel(const int* __restrict__ ei, int* __restrict__ cnt,
                            int* __restrict__ slot) {
    int e = blockIdx.x * blockDim.x + threadIdx.x;
    if (e >= EE) return;
    int d = ei[EE + e];
    slot[e] = atomicAdd(&cnt[d], 1);
}

// hierarchical exclusive scan of cnt[0..NN] (element NN treated as 0) -> rowptr
__global__ __launch_bounds__(1024) void scan1_kernel(const int* __restrict__ cnt,
                                                     int* __restrict__ rowptr,
                                                     int* __restrict__ bsum) {
    __shared__ int ws[16];
    int gid = blockIdx.x * 1024 + threadIdx.x;
    int v = (gid < NN) ? cnt[gid] : 0;
    int lane = threadIdx.x & 63, wid = threadIdx.x >> 6;
    int s = v;
    #pragma unroll
    for (int off = 1; off < 64; off <<= 1) {
        int t = __shfl_up(s, off, 64);
        if (lane >= off) s += t;
    }
    if (lane == 63) ws[wid] = s;
    __syncthreads();
    int add = 0;
    for (int w2 = 0; w2 < wid; w2++) add += ws[w2];
    int incl = s + add;
    if (gid <= NN) rowptr[gid] = incl - v;   // exclusive
    if (threadIdx.x == 1023) bsum[blockIdx.x] = incl;
}

__global__ void scan2_kernel(int* __restrict__ bsum) {
    __shared__ int w0tot;
    int tid = threadIdx.x;                   // 128 threads
    int v = (tid < NB_SCAN) ? bsum[tid] : 0;
    int lane = tid & 63, wid = tid >> 6;
    int s = v;
    #pragma unroll
    for (int off = 1; off < 64; off <<= 1) {
        int t = __shfl_up(s, off, 64);
        if (lane >= off) s += t;
    }
    if (wid == 0 && lane == 63) w0tot = s;
    __syncthreads();
    int incl = s + (wid ? w0tot : 0);
    if (tid < NB_SCAN) bsum[tid] = incl - v; // exclusive
}

__global__ void scan3_kernel(int* __restrict__ rowptr, const int* __restrict__ bsum) {
    int gid = blockIdx.x * 1024 + threadIdx.x;
    if (gid <= NN) rowptr[gid] += bsum[blockIdx.x];
}

__global__ void scatter_kernel(const int* __restrict__ ei, const float* __restrict__ ea,
                               const int* __restrict__ rowptr, const int* __restrict__ slot,
                               int* __restrict__ src_s, float* __restrict__ ea_s) {
    int e = blockIdx.x * blockDim.x + threadIdx.x;
    if (e >= EE) return;
    int d = ei[EE + e];
    int pos = rowptr[d] + slot[e];           // slot >= 1; slot 0 is the self loop
    src_s[pos] = ei[e];
    ea_s[pos] = ea[e];
}

// self-loop attr = mean of the row's real-edge attrs (PyG fill_value='mean')
__global__ void selfloop_kernel(const int* __restrict__ rowptr, int* __restrict__ src_s,
                                float* __restrict__ ea_s) {
    int n = blockIdx.x * blockDim.x + threadIdx.x;
    if (n >= NN) return;
    int rs = rowptr[n], re = rowptr[n + 1];
    float s = 0.f;
    for (int i = rs + 1; i < re; i++) s += ea_s[i];
    ea_s[rs] = s / fmaxf((float)(re - rs - 1), 1.0f);
    src_s[rs] = n;
}

// wedot[l*4+h] = sum_c We[l][h*32+c] * a_edge[l][h*32+c]  (all layers at once)
__global__ void wedot_kernel(const float* __restrict__ We, const float* __restrict__ a_e,
                             float* __restrict__ wedot) {
    int t = threadIdx.x;
    if (t >= NL * NH) return;
    int l = t >> 2, hh = t & 3;
    float s = 0.f;
    #pragma unroll
    for (int c = 0; c < CH; c++)
        s += We[l * HID + hh * CH + c] * a_e[l * HID + hh * CH + c];
    wedot[t] = s;
}

// wf[r][c] (r<32) = sum_k Win[r][k]*Wg0[k][c];  wf[32][c] = sum_k b_in[k]*Wg0[k][c]
__global__ void wfuse_kernel(const float* __restrict__ Win, const float* __restrict__ b_in,
                             const float* __restrict__ Wg0, float* __restrict__ wf) {
    int r = blockIdx.x;                      // 0..32
    int c = threadIdx.x;                     // 0..127
    float acc = 0.f;
    for (int k = 0; k < HID; k++) {
        float a = (r < 32) ? Win[r * HID + k] : b_in[k];
        acc += a * Wg0[(size_t)k * HID + c];
    }
    wf[r * HID + c] = acc;
}

// WgA[l][k][j] = head-masked dot: j<4 -> sum_{c in head j} Wg[l][k][c]*a_src[l][c]
//               j>=4 -> same with a_dst (head j-4).  Layers 1..2 only.
__global__ __launch_bounds__(1024) void wga_kernel(const float* __restrict__ Wg,
        const float* __restrict__ a_src, const float* __restrict__ a_dst,
        float* __restrict__ wga) {
    int l = blockIdx.x + 1;                  // layer 1..2
    int t = threadIdx.x;                     // k*8 + jj
    int k = t >> 3, jj = t & 7;
    int hh = jj & 3;
    const float* a = (jj < 4) ? (a_src + l * HID + hh * CH) : (a_dst + l * HID + hh * CH);
    const float* wrow = Wg + (size_t)l * HID * HID + (size_t)k * HID + hh * CH;
    float s = 0.f;
    #pragma unroll
    for (int c = 0; c < CH; c++) s += wrow[c] * a[c];
    wga[(l - 1) * 1024 + t] = s;
}

// pack Wg[1..2] (+ WgA as 9th col-tile) into bf16 MFMA B-fragment layout:
// frag (ks,ct): lane q*16+n holds B[ks*32+q*8+j][ct*16+n], j=0..7 (16B/lane).
__global__ void pack_kernel(const float* __restrict__ Wg, const float* __restrict__ wga,
                            u32* __restrict__ wb) {
    int idx = blockIdx.x * blockDim.x + threadIdx.x;   // 0..4607
    if (idx >= 2 * 2304) return;
    int l = idx / 2304;                      // 0 -> layer1, 1 -> layer2
    int rem = idx % 2304;
    int ks = rem / 576;
    int ct = (rem % 576) / 64;
    int lane = rem % 64;
    int q = lane >> 4, n = lane & 15;
    const float* W = Wg + (size_t)(l + 1) * HID * HID;
    float v[8];
    #pragma unroll
    for (int j = 0; j < 8; j++) {
        int k = ks * 32 + q * 8 + j;
        if (ct < 8) {
            v[j] = W[(size_t)k * HID + ct * 16 + n];
        } else {
            v[j] = (n < 8) ? wga[l * 1024 + k * 8 + n] : 0.f;
        }
    }
    u32* dst = wb + (size_t)l * WB_LSZ + (size_t)((ks * 9 + ct) * 64 + lane) * 4;
    dst[0] = pack2(v[0], v[1]); dst[1] = pack2(v[2], v[3]);
    dst[2] = pack2(v[4], v[5]); dst[3] = pack2(v[6], v[7]);
}

// ---------------------------------------------------------------------------
// shared FMA-GEMM epilogue (layer 0): pack xh to bf16 + al dots via 8-lane reduce
// ---------------------------------------------------------------------------
static __device__ __forceinline__ void store_xh_al(
        float acc[8][4], int n0, int r0, int c0, int cg,
        u32* __restrict__ xh, const float* __restrict__ asl, const float* __restrict__ adl,
        float* __restrict__ al_s, float* __restrict__ al_d) {
    float4 as4 = *(const float4*)&asl[c0];
    float4 ad4 = *(const float4*)&adl[c0];
    int hh = cg >> 3;
    #pragma unroll
    for (int i = 0; i < 8; i++) {
        int row = n0 + r0 + i;
        if (row < NN) {
            u32 lo = pack2(acc[i][0], acc[i][1]);
            u32 hi = pack2(acc[i][2], acc[i][3]);
            *(uint2*)&xh[(size_t)row * HQ + (c0 >> 1)] = make_uint2(lo, hi);
        }
        float ps = acc[i][0] * as4.x + acc[i][1] * as4.y + acc[i][2] * as4.z + acc[i][3] * as4.w;
        float pd = acc[i][0] * ad4.x + acc[i][1] * ad4.y + acc[i][2] * ad4.z + acc[i][3] * ad4.w;
        ps += __shfl_xor(ps, 1, 64); pd += __shfl_xor(pd, 1, 64);
        ps += __shfl_xor(ps, 2, 64); pd += __shfl_xor(pd, 2, 64);
        ps += __shfl_xor(ps, 4, 64); pd += __shfl_xor(pd, 4, 64);
        if ((cg & 7) == 0 && row < NN) {
            al_s[row * 4 + hh] = ps;
            al_d[row * 4 + hh] = pd;
        }
    }
}

// ---------------------------------------------------------------------------
// Layer 0, algebraically fused: h = x@Win + b_in  AND  xh = x@Wf + bf,
// both K=32 GEMMs off the same LDS x-tile. h/xh stored packed bf16.
// ---------------------------------------------------------------------------
__global__ __launch_bounds__(256) void in_gemm_kernel(
        const float* __restrict__ x, const float* __restrict__ Win,
        const float* __restrict__ b_in, const float* __restrict__ wf,
        u32* __restrict__ h, u32* __restrict__ xh,
        const float* __restrict__ a_src0, const float* __restrict__ a_dst0,
        float* __restrict__ al_s, float* __restrict__ al_d) {
    __shared__ float xs[64][36];
    __shared__ float ws[32][128];
    int n0 = blockIdx.x * 64;
    int t = threadIdx.x;
    int cg = t & 31, rg = t >> 5;
    int c0 = cg * 4, r0 = rg * 8;
    // stage x (64 x 32)
    #pragma unroll
    for (int it = 0; it < 2; it++) {
        int idx = t + it * 256;
        int row = idx >> 3, kk = (idx & 7) * 4;
        float4 v = make_float4(0.f, 0.f, 0.f, 0.f);
        if (n0 + row < NN) v = *(const float4*)&x[(size_t)(n0 + row) * 32 + kk];
        *(float4*)&xs[row][kk] = v;
    }
    // stage Win (32 x 128)
    #pragma unroll
    for (int it = 0; it < 4; it++) {
        int idx = t + it * 256;
        int kr = idx >> 5, f4 = (idx & 31) * 4;
        *(float4*)&ws[kr][f4] = *(const float4*)&Win[kr * HID + f4];
    }
    __syncthreads();
    // GEMM 1: h = x @ Win + b_in
    {
        float acc[8][4] = {};
        #pragma unroll 8
        for (int k = 0; k < 32; k++) {
            float4 b4 = *(const float4*)&ws[k][c0];
            #pragma unroll
            for (int i = 0; i < 8; i++) {
                float a = xs[r0 + i][k];
                acc[i][0] += a * b4.x; acc[i][1] += a * b4.y;
                acc[i][2] += a * b4.z; acc[i][3] += a * b4.w;
            }
        }
        float4 bi = *(const float4*)&b_in[c0];
        #pragma unroll
        for (int i = 0; i < 8; i++) {
            int row = n0 + r0 + i;
            if (row < NN) {
                u32 lo = pack2(acc[i][0] + bi.x, acc[i][1] + bi.y);
                u32 hi = pack2(acc[i][2] + bi.z, acc[i][3] + bi.w);
                *(uint2*)&h[(size_t)row * HQ + (c0 >> 1)] = make_uint2(lo, hi);
            }
        }
    }
    __syncthreads();                          // all ws readers done
    // stage Wf (32 x 128)
    #pragma unroll
    for (int it = 0; it < 4; it++) {
        int idx = t + it * 256;
        int kr = idx >> 5, f4 = (idx & 31) * 4;
        *(float4*)&ws[kr][f4] = *(const float4*)&wf[kr * HID + f4];
    }
    __syncthreads();
    // GEMM 2: xh = x @ Wf + bf
    float acc2[8][4] = {};
    #pragma unroll 8
    for (int k = 0; k < 32; k++) {
        float4 b4 = *(const float4*)&ws[k][c0];
        #pragma unroll
        for (int i = 0; i < 8; i++) {
            float a = xs[r0 + i][k];
            acc2[i][0] += a * b4.x; acc2[i][1] += a * b4.y;
            acc2[i][2] += a * b4.z; acc2[i][3] += a * b4.w;
        }
    }
    float4 bf4 = *(const float4*)&wf[32 * HID + c0];
    #pragma unroll
    for (int i = 0; i < 8; i++) {
        acc2[i][0] += bf4.x; acc2[i][1] += bf4.y; acc2[i][2] += bf4.z; acc2[i][3] += bf4.w;
    }
    store_xh_al(acc2, n0, r0, c0, cg, xh, a_src0, a_dst0, al_s, al_d);
}

// ---------------------------------------------------------------------------
// Layers 1..2 via MFMA: hin = relu(LN(g)+h) (epilogue of prev layer, written
// back packed) staged to LDS in A-fragment order (bf16); xh = hin @ Wg via
// v_mfma_f32_16x16x32_bf16 with pre-packed B-frags; al via 9th col-tile.
// A-frag: lane q*16+m holds A[m][q*8..q*8+7].  C/D: col=lane&15, row=q*4+reg.
// ---------------------------------------------------------------------------
__global__ __launch_bounds__(256) void gemm_mfma_kernel(const u32* __restrict__ h,
        const u32* __restrict__ wb, u32* __restrict__ xh, const u32* __restrict__ g,
        const float* __restrict__ lnw, const float* __restrict__ lnb,
        const float* __restrict__ stats, u32* __restrict__ hout,
        float* __restrict__ al_s, float* __restrict__ al_d) {
    __shared__ u32 hsu[4096];                // 16KB, frag-ordered [rt][ks][lane][4]
    float mean = stats[0], rstd = stats[1];
    int n0 = blockIdx.x * 64;
    int t = threadIdx.x;
    int wv = t >> 6, lane = t & 63;
    int q = lane >> 4, n16 = lane & 15;

    // load B frags: wave w owns col-tiles 2w, 2w+1; wave 3 also the al tile (ct=8)
    bf16x8 bfrag[2][4];
    #pragma unroll
    for (int ks = 0; ks < 4; ks++) {
        #pragma unroll
        for (int cc = 0; cc < 2; cc++) {
            int ct = wv * 2 + cc;
            uint4 r = *(const uint4*)&wb[(size_t)((ks * 9 + ct) * 64 + lane) * 4];
            bfrag[cc][ks] = __builtin_bit_cast(bf16x8, r);
        }
    }
    bf16x8 bal[4];
    #pragma unroll
    for (int ks = 0; ks < 4; ks++) {
        uint4 r = *(const uint4*)&wb[(size_t)((ks * 9 + 8) * 64 + lane) * 4];
        bal[ks] = __builtin_bit_cast(bf16x8, r);
    }

    // stage hin = relu(LN(g)+h) -> hout (global) and LDS A-frags (bf16)
    {
        int row = t >> 2;                    // 0..63
        int qq = t & 3;                      // col-block within slab
        int gr = n0 + row;
        int rt = row >> 4, m = row & 15;
        #pragma unroll
        for (int ks = 0; ks < 4; ks++) {
            int kk = ks * 32 + qq * 8;
            uint4 op = make_uint4(0u, 0u, 0u, 0u);
            if (gr < NN) {
                size_t base = (size_t)gr * HQ + (kk >> 1);
                uint4 gp = *(const uint4*)&g[base];
                uint4 hp = *(const uint4*)&h[base];
                float4 wA = *(const float4*)&lnw[kk];
                float4 wB = *(const float4*)&lnw[kk + 4];
                float4 bA = *(const float4*)&lnb[kk];
                float4 bB = *(const float4*)&lnb[kk + 4];
                float v0 = fmaxf((bflo(gp.x) - mean) * rstd * wA.x + bA.x + bflo(hp.x), 0.f);
                float v1 = fmaxf((bfhi(gp.x) - mean) * rstd * wA.y + bA.y + bfhi(hp.x), 0.f);
                float v2 = fmaxf((bflo(gp.y) - mean) * rstd * wA.z + bA.z + bflo(hp.y), 0.f);
                float v3 = fmaxf((bfhi(gp.y) - mean) * rstd * wA.w + bA.w + bfhi(hp.y), 0.f);
                float v4 = fmaxf((bflo(gp.z) - mean) * rstd * wB.x + bB.x + bflo(hp.z), 0.f);
                float v5 = fmaxf((bfhi(gp.z) - mean) * rstd * wB.y + bB.y + bfhi(hp.z), 0.f);
                float v6 = fmaxf((bflo(gp.w) - mean) * rstd * wB.z + bB.z + bflo(hp.w), 0.f);
                float v7 = fmaxf((bfhi(gp.w) - mean) * rstd * wB.w + bB.w + bfhi(hp.w), 0.f);
                op.x = pack2(v0, v1); op.y = pack2(v2, v3);
                op.z = pack2(v4, v5); op.w = pack2(v6, v7);
                *(uint4*)&hout[base] = op;
            }
            *(uint4*)&hsu[((rt * 4 + ks) * 64 + qq * 16 + m) * 4] = op;
        }
    }
    __syncthreads();

    // MFMA: 4 row-tiles x 2 col-tiles (+ al tile on wave 3), K=128 in 4 slabs
    f32x4 acc[4][2];
    f32x4 accal[4];
    #pragma unroll
    for (int rt = 0; rt < 4; rt++) {
        acc[rt][0] = (f32x4){0.f, 0.f, 0.f, 0.f};
        acc[rt][1] = (f32x4){0.f, 0.f, 0.f, 0.f};
        accal[rt]  = (f32x4){0.f, 0.f, 0.f, 0.f};
    }
    #pragma unroll
    for (int rt = 0; rt < 4; rt++) {
        #pragma unroll
        for (int ks = 0; ks < 4; ks++) {
            uint4 araw = *(const uint4*)&hsu[((rt * 4 + ks) * 64 + lane) * 4];
            bf16x8 af = __builtin_bit_cast(bf16x8, araw);
            acc[rt][0] = __builtin_amdgcn_mfma_f32_16x16x32_bf16(af, bfrag[0][ks], acc[rt][0], 0, 0, 0);
            acc[rt][1] = __builtin_amdgcn_mfma_f32_16x16x32_bf16(af, bfrag[1][ks], acc[rt][1], 0, 0, 0);
            if (wv == 3)
                accal[rt] = __builtin_amdgcn_mfma_f32_16x16x32_bf16(af, bal[ks], accal[rt], 0, 0, 0);
        }
    }

    // epilogue: xh (pair-pack via shfl), al from the 9th tile
    #pragma unroll
    for (int rt = 0; rt < 4; rt++) {
        #pragma unroll
        for (int reg = 0; reg < 4; reg++) {
            int row = n0 + rt * 16 + q * 4 + reg;
            #pragma unroll
            for (int cc = 0; cc < 2; cc++) {
                float v = acc[rt][cc][reg];
                float vp = __shfl_xor(v, 1, 64);
                if (!(n16 & 1) && row < NN) {
                    int colp = (wv * 2 + cc) * 8 + (n16 >> 1);
                    xh[(size_t)row * HQ + colp] = pack2(v, vp);
                }
            }
            if (wv == 3 && row < NN && n16 < 8) {
                float v = accal[rt][reg];
                if (n16 < 4) al_s[row * 4 + n16] = v;
                else         al_d[row * 4 + (n16 - 4)] = v;
            }
        }
    }
}

// ---------------------------------------------------------------------------
// GAT aggregation, no-max softmax (logits O(1) by construction). 4 waves/
// block, one node per wave, wave-private LDS. Pass 1: lane-parallel
// logit->exp->LDS. Pass 2: channel-parallel gather+FMA with den folded in.
// ---------------------------------------------------------------------------
__global__ __launch_bounds__(256) void gat_agg_kernel(const int* __restrict__ rowptr,
        const int* __restrict__ src_s, const float* __restrict__ ea_s,
        const u32* __restrict__ xh, const float* __restrict__ al_s,
        const float* __restrict__ al_d, const float* __restrict__ wedot,
        const float* __restrict__ bg, u32* __restrict__ g,
        float* __restrict__ partials) {
    __shared__ float lds_ex[4][CAP * 4];
    __shared__ int lds_src[4][CAP];
    int wv = threadIdx.x >> 6, lane = threadIdx.x & 63;
    int n = blockIdx.x * 4 + wv;
    if (n >= NN) return;
    float* ex_w = lds_ex[wv];
    int* src_w = lds_src[wv];
    int rs = rowptr[n], re = rowptr[n + 1];
    int deg = re - rs;
    int nc = deg < CAP ? deg : CAP;
    float wd0 = wedot[0], wd1 = wedot[1], wd2 = wedot[2], wd3 = wedot[3];
    float4 aldv = *(const float4*)&al_d[n * 4];

    for (int i = rs + lane; i < rs + nc; i += 64) {
        int s = src_s[i];
        float eav = ea_s[i];
        float4 als = *(const float4*)&al_s[s * 4];
        float e0 = __expf(lrelu(als.x + aldv.x + eav * wd0));
        float e1 = __expf(lrelu(als.y + aldv.y + eav * wd1));
        float e2 = __expf(lrelu(als.z + aldv.z + eav * wd2));
        float e3 = __expf(lrelu(als.w + aldv.w + eav * wd3));
        int k = i - rs;
        src_w[k] = s;
        *(float4*)&ex_w[k * 4] = make_float4(e0, e1, e2, e3);
    }

    int epar = lane >> 5, cgroup = lane & 31;
    int c0 = cgroup * 4;
    int head = cgroup >> 3;
    float a0 = 0.f, a1 = 0.f, a2 = 0.f, a3 = 0.f, den = 0.f;
    int j = epar;
    for (; j + 2 < nc; j += 4) {
        int s0 = src_w[j], s1 = src_w[j + 2];
        float e0 = ex_w[j * 4 + head], e1 = ex_w[(j + 2) * 4 + head];
        uint2 r0 = *(const uint2*)&xh[(size_t)s0 * HQ + (c0 >> 1)];
        uint2 r1 = *(const uint2*)&xh[(size_t)s1 * HQ + (c0 >> 1)];
        den += e0 + e1;
        a0 += e0 * bflo(r0.x); a1 += e0 * bfhi(r0.x);
        a2 += e0 * bflo(r0.y); a3 += e0 * bfhi(r0.y);
        a0 += e1 * bflo(r1.x); a1 += e1 * bfhi(r1.x);
        a2 += e1 * bflo(r1.y); a3 += e1 * bfhi(r1.y);
    }
    for (; j < nc; j += 2) {
        int s0 = src_w[j];
        float e0 = ex_w[j * 4 + head];
        uint2 r0 = *(const uint2*)&xh[(size_t)s0 * HQ + (c0 >> 1)];
        den += e0;
        a0 += e0 * bflo(r0.x); a1 += e0 * bfhi(r0.x);
        a2 += e0 * bflo(r0.y); a3 += e0 * bfhi(r0.y);
    }
    if (deg > CAP) {
        float aldh = head == 0 ? aldv.x : head == 1 ? aldv.y : head == 2 ? aldv.z : aldv.w;
        float wdh  = head == 0 ? wd0 : head == 1 ? wd1 : head == 2 ? wd2 : wd3;
        for (int jt = CAP + epar; jt < deg; jt += 2) {
            int i = rs + jt;
            int s = src_s[i];
            float eav = ea_s[i];
            float ex = __expf(lrelu(al_s[s * 4 + head] + aldh + eav * wdh));
            den += ex;
            uint2 r0 = *(const uint2*)&xh[(size_t)s * HQ + (c0 >> 1)];
            a0 += ex * bflo(r0.x); a1 += ex * bfhi(r0.x);
            a2 += ex * bflo(r0.y); a3 += ex * bfhi(r0.y);
        }
    }
    a0 += __shfl_xor(a0, 32, 64); a1 += __shfl_xor(a1, 32, 64);
    a2 += __shfl_xor(a2, 32, 64); a3 += __shfl_xor(a3, 32, 64);
    den += __shfl_xor(den, 32, 64);

    float inv = 1.0f / (den + 1e-16f);
    float4 bgv = *(const float4*)&bg[c0];
    float o0 = a0 * inv + bgv.x, o1 = a1 * inv + bgv.y;
    float o2 = a2 * inv + bgv.z, o3 = a3 * inv + bgv.w;
    float ss = 0.f, sq = 0.f;
    if (epar == 0) {
        u32 lo = pack2(o0, o1), hi = pack2(o2, o3);
        *(uint2*)&g[(size_t)n * HQ + (c0 >> 1)] = make_uint2(lo, hi);
        ss = o0 + o1 + o2 + o3;
        sq = o0 * o0 + o1 * o1 + o2 * o2 + o3 * o3;
    }
    #pragma unroll
    for (int off = 32; off; off >>= 1) {
        ss += __shfl_xor(ss, off, 64);
        sq += __shfl_xor(sq, off, 64);
    }
    if (lane == 0) {
        int sl = (n & 1023) * 2;
        atomicAdd(&partials[sl], ss);
        atomicAdd(&partials[sl + 1], sq);
    }
}

// reduce partials -> {mean, rstd}; re-zero partials for the next layer
__global__ void stats_kernel(float* __restrict__ partials, float* __restrict__ stats) {
    __shared__ float ls[16], lq[16];
    int tid = threadIdx.x;
    float s = partials[tid * 2], q = partials[tid * 2 + 1];
    partials[tid * 2] = 0.f;
    partials[tid * 2 + 1] = 0.f;
    #pragma unroll
    for (int off = 32; off; off >>= 1) {
        s += __shfl_xor(s, off, 64);
        q += __shfl_xor(q, off, 64);
    }
    int lane = tid & 63, wid = tid >> 6;
    if (lane == 0) { ls[wid] = s; lq[wid] = q; }
    __syncthreads();
    if (tid == 0) {
        float S = 0.f, Q = 0.f;
        for (int w2 = 0; w2 < 16; w2++) { S += ls[w2]; Q += lq[w2]; }
        const float M = (float)NN * (float)HID;
        float mean = S / M;
        float var = Q / M - mean * mean;
        stats[0] = mean;
        stats[1] = rsqrtf(fmaxf(var, 0.f) + LN_EPS);
    }
}

// final: out = relu(LN(g)+h) @ Wout + bout  (4 nodes/block, wave per node)
__global__ __launch_bounds__(256) void ln_out_kernel(const u32* __restrict__ g,
        const u32* __restrict__ h, const float* __restrict__ lnw,
        const float* __restrict__ lnb, const float* __restrict__ stats,
        const float* __restrict__ Wout, const float* __restrict__ bout,
        float* __restrict__ out) {
    __shared__ float wsh[HID * NOUT];
    int t = threadIdx.x;
    for (int i = t; i < HID * NOUT; i += 256) wsh[i] = Wout[i];
    __syncthreads();
    int wv = t >> 6, lane = t & 63;
    int n = blockIdx.x * 4 + wv;
    if (n >= NN) return;
    float mean = stats[0], rstd = stats[1];
    int c0 = lane * 2;
    u32 gv = g[(size_t)n * HQ + lane];
    u32 hv = h[(size_t)n * HQ + lane];
    float o0 = fmaxf((bflo(gv) - mean) * rstd * lnw[c0]     + lnb[c0]     + bflo(hv), 0.f);
    float o1 = fmaxf((bfhi(gv) - mean) * rstd * lnw[c0 + 1] + lnb[c0 + 1] + bfhi(hv), 0.f);
    float p[NOUT];
    #pragma unroll
    for (int jj = 0; jj < NOUT; jj++)
        p[jj] = o0 * wsh[c0 * NOUT + jj] + o1 * wsh[(c0 + 1) * NOUT + jj];
    #pragma unroll
    for (int off = 32; off; off >>= 1) {
        #pragma unroll
        for (int jj = 0; jj < NOUT; jj++) p[jj] += __shfl_xor(p[jj], off, 64);
    }
    if (lane == 0) {
        #pragma unroll
        for (int jj = 0; jj < NOUT; jj++)
            out[(size_t)n * NOUT + jj] = p[jj] + bout[jj];
    }
}

// ---------------------------------------------------------------------------
extern "C" void kernel_launch(void* const* d_in, const int* in_sizes, int n_in,
                              void* d_out, int out_size, void* d_ws, size_t ws_size,
                              hipStream_t stream) {
    const float* x      = (const float*)d_in[0];
    const int*   ei     = (const int*)d_in[1];
    const float* ea     = (const float*)d_in[2];
    const float* Win    = (const float*)d_in[3];
    const float* b_in   = (const float*)d_in[4];
    const float* Wg     = (const float*)d_in[5];
    const float* bg     = (const float*)d_in[6];
    const float* a_src  = (const float*)d_in[7];
    const float* a_dst  = (const float*)d_in[8];
    const float* We     = (const float*)d_in[9];
    const float* a_edge = (const float*)d_in[10];
    const float* ln_w   = (const float*)d_in[11];
    const float* ln_b   = (const float*)d_in[12];
    const float* Wout   = (const float*)d_in[13];
    const float* bout   = (const float*)d_in[14];
    float* out = (float*)d_out;

    char* w = (char*)d_ws;
    size_t off = 0;
    auto alloc = [&](size_t bytes) -> void* {
        void* p = w + off;
        off = (off + bytes + 255) & ~(size_t)255;
        return p;
    };
    int*   slot    = (int*)alloc((size_t)EE * sizeof(int));
    int*   cnt     = (int*)alloc(NN * sizeof(int));
    int*   rowptr  = (int*)alloc((NN + 1) * sizeof(int));
    int*   bsum    = (int*)alloc(NB_SCAN * sizeof(int));
    int*   src_s   = (int*)alloc((size_t)(EE + NN) * sizeof(int));
    float* ea_s    = (float*)alloc((size_t)(EE + NN) * sizeof(float));
    u32*   h       = (u32*)alloc((size_t)NN * HQ * sizeof(u32));
    u32*   g       = (u32*)alloc((size_t)NN * HQ * sizeof(u32));
    u32*   xh      = (u32*)alloc((size_t)NN * HQ * sizeof(u32));
    float* al_s    = (float*)alloc((size_t)NN * NH * sizeof(float));
    float* al_d    = (float*)alloc((size_t)NN * NH * sizeof(float));
    float* wedot   = (float*)alloc(16 * sizeof(float));
    float* wf      = (float*)alloc(33 * HID * sizeof(float));
    float* wga     = (float*)alloc(2048 * sizeof(float));
    u32*   wb      = (u32*)alloc((size_t)2 * WB_LSZ * sizeof(u32));
    float* partials = (float*)alloc(2048 * sizeof(float));
    float* stats   = (float*)alloc(16 * sizeof(float));
    (void)ws_size; (void)n_in; (void)in_sizes; (void)out_size;

    // --- CSR build + weight prep ---
    init_kernel<<<(NN + 255) / 256, 256, 0, stream>>>(cnt, partials);
    hist_kernel<<<(EE + 255) / 256, 256, 0, stream>>>(ei, cnt, slot);
    scan1_kernel<<<NB_SCAN, 1024, 0, stream>>>(cnt, rowptr, bsum);
    scan2_kernel<<<1, 128, 0, stream>>>(bsum);
    scan3_kernel<<<NB_SCAN, 1024, 0, stream>>>(rowptr, bsum);
    scatter_kernel<<<(EE + 255) / 256, 256, 0, stream>>>(ei, ea, rowptr, slot, src_s, ea_s);
    selfloop_kernel<<<(NN + 255) / 256, 256, 0, stream>>>(rowptr, src_s, ea_s);
    wedot_kernel<<<1, 64, 0, stream>>>(We, a_edge, wedot);
    wfuse_kernel<<<33, 128, 0, stream>>>(Win, b_in, Wg, wf);
    wga_kernel<<<2, 1024, 0, stream>>>(Wg, a_src, a_dst, wga);
    pack_kernel<<<18, 256, 0, stream>>>(Wg, wga, wb);

    const int ngrid = (NN + 63) / 64;
    // --- layer 0 (input projection algebraically fused) ---
    in_gemm_kernel<<<ngrid, 256, 0, stream>>>(x, Win, b_in, wf, h, xh,
                                              a_src, a_dst, al_s, al_d);
    for (int l = 0; l < NL; l++) {
        if (l > 0) {
            gemm_mfma_kernel<<<ngrid, 256, 0, stream>>>(
                h, wb + (size_t)(l - 1) * WB_LSZ, xh, g,
                ln_w + (size_t)(l - 1) * HID, ln_b + (size_t)(l - 1) * HID, stats, h,
                al_s, al_d);
        }
        gat_agg_kernel<<<(NN + 3) / 4, 256, 0, stream>>>(
            rowptr, src_s, ea_s, xh, al_s, al_d, wedot + l * 4,
            bg + (size_t)l * HID, g, partials);
        stats_kernel<<<1, 1024, 0, stream>>>(partials, stats);
    }

    // --- final LN + residual + relu + output projection (fused) ---
    ln_out_kernel<<<(NN + 3) / 4, 256, 0, stream>>>(g, h, ln_w + (size_t)2 * HID,
                                                    ln_b + (size_t)2 * HID,
                                                    stats, Wout, bout, out);
}

// Round 8
// 482.965 us; speedup vs baseline: 2.1930x; 1.0207x over previous
//
#include <hip/hip_runtime.h>
#include <hip/hip_bf16.h>

#define NN 100000
#define EE 800000
#define HID 128
#define NH 4
#define CH 32
#define NL 3
#define NOUT 5
#define NEG_SLOPE 0.2f
#define LN_EPS 1e-5f
#define CAP 64             // LDS-cached edges per node row (deg > CAP falls to slow path)
#define NB_SCAN 98         // ceil((NN+1)/1024)
#define HQ (HID / 2)       // u32-packed bf16 pairs per row
#define WB_LSZ 9216        // u32 per layer of packed B-frags: 4ks*9ct*64lane*4

typedef unsigned int u32;
typedef __attribute__((ext_vector_type(8))) short bf16x8;
typedef __attribute__((ext_vector_type(4))) float f32x4;

static __device__ __forceinline__ float bflo(u32 r) { return __uint_as_float(r << 16); }
static __device__ __forceinline__ float bfhi(u32 r) { return __uint_as_float(r & 0xffff0000u); }
static __device__ __forceinline__ unsigned short f2bf(float x) {
    union U { __hip_bfloat16 b; unsigned short s; } u;
    u.b = __float2bfloat16(x);
    return u.s;
}
static __device__ __forceinline__ u32 pack2(float a, float b) {
    return (u32)f2bf(a) | ((u32)f2bf(b) << 16);
}
static __device__ __forceinline__ float lrelu(float x) {
    return x > 0.f ? x : NEG_SLOPE * x;
}

// ---------------------------------------------------------------------------
// CSR build. cnt[n] starts at 1 (self-loop reserved at row slot 0); one atomic
// per real edge whose return value is the edge's slot -> scatter is atomic-free.
// ---------------------------------------------------------------------------
__global__ void init_kernel(int* __restrict__ cnt, float* __restrict__ partials) {
    int n = blockIdx.x * blockDim.x + threadIdx.x;
    if (n < NN) cnt[n] = 1;
    if (n < 2048) partials[n] = 0.f;
}

__global__ void hist_kernel(const int* __restrict__ ei, int* __restrict__ cnt,
                            int* __restrict__ slot) {
    int e = blockIdx.x * blockDim.x + threadIdx.x;
    if (e >= EE) return;
    int d = ei[EE + e];
    slot[e] = atomicAdd(&cnt[d], 1);
}

// hierarchical exclusive scan of cnt[0..NN] (element NN treated as 0) -> rowptr
__global__ __launch_bounds__(1024) void scan1_kernel(const int* __restrict__ cnt,
                                                     int* __restrict__ rowptr,
                                                     int* __restrict__ bsum) {
    __shared__ int ws[16];
    int gid = blockIdx.x * 1024 + threadIdx.x;
    int v = (gid < NN) ? cnt[gid] : 0;
    int lane = threadIdx.x & 63, wid = threadIdx.x >> 6;
    int s = v;
    #pragma unroll
    for (int off = 1; off < 64; off <<= 1) {
        int t = __shfl_up(s, off, 64);
        if (lane >= off) s += t;
    }
    if (lane == 63) ws[wid] = s;
    __syncthreads();
    int add = 0;
    for (int w2 = 0; w2 < wid; w2++) add += ws[w2];
    int incl = s + add;
    if (gid <= NN) rowptr[gid] = incl - v;   // exclusive
    if (threadIdx.x == 1023) bsum[blockIdx.x] = incl;
}

__global__ void scan2_kernel(int* __restrict__ bsum) {
    __shared__ int w0tot;
    int tid = threadIdx.x;                   // 128 threads
    int v = (tid < NB_SCAN) ? bsum[tid] : 0;
    int lane = tid & 63, wid = tid >> 6;
    int s = v;
    #pragma unroll
    for (int off = 1; off < 64; off <<= 1) {
        int t = __shfl_up(s, off, 64);
        if (lane >= off) s += t;
    }
    if (wid == 0 && lane == 63) w0tot = s;
    __syncthreads();
    int incl = s + (wid ? w0tot : 0);
    if (tid < NB_SCAN) bsum[tid] = incl - v; // exclusive
}

__global__ void scan3_kernel(int* __restrict__ rowptr, const int* __restrict__ bsum) {
    int gid = blockIdx.x * 1024 + threadIdx.x;
    if (gid <= NN) rowptr[gid] += bsum[blockIdx.x];
}

__global__ void scatter_kernel(const int* __restrict__ ei, const float* __restrict__ ea,
                               const int* __restrict__ rowptr, const int* __restrict__ slot,
                               int* __restrict__ src_s, float* __restrict__ ea_s) {
    int e = blockIdx.x * blockDim.x + threadIdx.x;
    if (e >= EE) return;
    int d = ei[EE + e];
    int pos = rowptr[d] + slot[e];           // slot >= 1; slot 0 is the self loop
    src_s[pos] = ei[e];
    ea_s[pos] = ea[e];
}

// self-loop attr = mean of the row's real-edge attrs (PyG fill_value='mean')
__global__ void selfloop_kernel(const int* __restrict__ rowptr, int* __restrict__ src_s,
                                float* __restrict__ ea_s) {
    int n = blockIdx.x * blockDim.x + threadIdx.x;
    if (n >= NN) return;
    int rs = rowptr[n], re = rowptr[n + 1];
    float s = 0.f;
    for (int i = rs + 1; i < re; i++) s += ea_s[i];
    ea_s[rs] = s / fmaxf((float)(re - rs - 1), 1.0f);
    src_s[rs] = n;
}

// wedot[l*4+h] = sum_c We[l][h*32+c] * a_edge[l][h*32+c]  (all layers at once)
__global__ void wedot_kernel(const float* __restrict__ We, const float* __restrict__ a_e,
                             float* __restrict__ wedot) {
    int t = threadIdx.x;
    if (t >= NL * NH) return;
    int l = t >> 2, hh = t & 3;
    float s = 0.f;
    #pragma unroll
    for (int c = 0; c < CH; c++)
        s += We[l * HID + hh * CH + c] * a_e[l * HID + hh * CH + c];
    wedot[t] = s;
}

// wf[r][c] (r<32) = sum_k Win[r][k]*Wg0[k][c];  wf[32][c] = sum_k b_in[k]*Wg0[k][c]
__global__ void wfuse_kernel(const float* __restrict__ Win, const float* __restrict__ b_in,
                             const float* __restrict__ Wg0, float* __restrict__ wf) {
    int r = blockIdx.x;                      // 0..32
    int c = threadIdx.x;                     // 0..127
    float acc = 0.f;
    for (int k = 0; k < HID; k++) {
        float a = (r < 32) ? Win[r * HID + k] : b_in[k];
        acc += a * Wg0[(size_t)k * HID + c];
    }
    wf[r * HID + c] = acc;
}

// WgA[l][k][j] = head-masked dot: j<4 -> sum_{c in head j} Wg[l][k][c]*a_src[l][c]
//               j>=4 -> same with a_dst (head j-4).  Layers 1..2 only.
__global__ __launch_bounds__(1024) void wga_kernel(const float* __restrict__ Wg,
        const float* __restrict__ a_src, const float* __restrict__ a_dst,
        float* __restrict__ wga) {
    int l = blockIdx.x + 1;                  // layer 1..2
    int t = threadIdx.x;                     // k*8 + jj
    int k = t >> 3, jj = t & 7;
    int hh = jj & 3;
    const float* a = (jj < 4) ? (a_src + l * HID + hh * CH) : (a_dst + l * HID + hh * CH);
    const float* wrow = Wg + (size_t)l * HID * HID + (size_t)k * HID + hh * CH;
    float s = 0.f;
    #pragma unroll
    for (int c = 0; c < CH; c++) s += wrow[c] * a[c];
    wga[(l - 1) * 1024 + t] = s;
}

// pack Wg[1..2] (+ WgA as 9th col-tile) into bf16 MFMA B-fragment layout:
// frag (ks,ct): lane q*16+n holds B[ks*32+q*8+j][ct*16+n], j=0..7 (16B/lane).
__global__ void pack_kernel(const float* __restrict__ Wg, const float* __restrict__ wga,
                            u32* __restrict__ wb) {
    int idx = blockIdx.x * blockDim.x + threadIdx.x;   // 0..4607
    if (idx >= 2 * 2304) return;
    int l = idx / 2304;                      // 0 -> layer1, 1 -> layer2
    int rem = idx % 2304;
    int ks = rem / 576;
    int ct = (rem % 576) / 64;
    int lane = rem % 64;
    int q = lane >> 4, n = lane & 15;
    const float* W = Wg + (size_t)(l + 1) * HID * HID;
    float v[8];
    #pragma unroll
    for (int j = 0; j < 8; j++) {
        int k = ks * 32 + q * 8 + j;
        if (ct < 8) {
            v[j] = W[(size_t)k * HID + ct * 16 + n];
        } else {
            v[j] = (n < 8) ? wga[l * 1024 + k * 8 + n] : 0.f;
        }
    }
    u32* dst = wb + (size_t)l * WB_LSZ + (size_t)((ks * 9 + ct) * 64 + lane) * 4;
    dst[0] = pack2(v[0], v[1]); dst[1] = pack2(v[2], v[3]);
    dst[2] = pack2(v[4], v[5]); dst[3] = pack2(v[6], v[7]);
}

// ---------------------------------------------------------------------------
// shared FMA-GEMM epilogue (layer 0): pack xh to bf16 + al dots via 8-lane reduce
// ---------------------------------------------------------------------------
static __device__ __forceinline__ void store_xh_al(
        float acc[8][4], int n0, int r0, int c0, int cg,
        u32* __restrict__ xh, const float* __restrict__ asl, const float* __restrict__ adl,
        float* __restrict__ al_s, float* __restrict__ al_d) {
    float4 as4 = *(const float4*)&asl[c0];
    float4 ad4 = *(const float4*)&adl[c0];
    int hh = cg >> 3;
    #pragma unroll
    for (int i = 0; i < 8; i++) {
        int row = n0 + r0 + i;
        if (row < NN) {
            u32 lo = pack2(acc[i][0], acc[i][1]);
            u32 hi = pack2(acc[i][2], acc[i][3]);
            *(uint2*)&xh[(size_t)row * HQ + (c0 >> 1)] = make_uint2(lo, hi);
        }
        float ps = acc[i][0] * as4.x + acc[i][1] * as4.y + acc[i][2] * as4.z + acc[i][3] * as4.w;
        float pd = acc[i][0] * ad4.x + acc[i][1] * ad4.y + acc[i][2] * ad4.z + acc[i][3] * ad4.w;
        ps += __shfl_xor(ps, 1, 64); pd += __shfl_xor(pd, 1, 64);
        ps += __shfl_xor(ps, 2, 64); pd += __shfl_xor(pd, 2, 64);
        ps += __shfl_xor(ps, 4, 64); pd += __shfl_xor(pd, 4, 64);
        if ((cg & 7) == 0 && row < NN) {
            al_s[row * 4 + hh] = ps;
            al_d[row * 4 + hh] = pd;
        }
    }
}

// ---------------------------------------------------------------------------
// Layer 0, algebraically fused: h = x@Win + b_in  AND  xh = x@Wf + bf,
// both K=32 GEMMs off the same LDS x-tile. h/xh stored packed bf16.
// ---------------------------------------------------------------------------
__global__ __launch_bounds__(256) void in_gemm_kernel(
        const float* __restrict__ x, const float* __restrict__ Win,
        const float* __restrict__ b_in, const float* __restrict__ wf,
        u32* __restrict__ h, u32* __restrict__ xh,
        const float* __restrict__ a_src0, const float* __restrict__ a_dst0,
        float* __restrict__ al_s, float* __restrict__ al_d) {
    __shared__ float xs[64][36];
    __shared__ float ws[32][128];
    int n0 = blockIdx.x * 64;
    int t = threadIdx.x;
    int cg = t & 31, rg = t >> 5;
    int c0 = cg * 4, r0 = rg * 8;
    // stage x (64 x 32)
    #pragma unroll
    for (int it = 0; it < 2; it++) {
        int idx = t + it * 256;
        int row = idx >> 3, kk = (idx & 7) * 4;
        float4 v = make_float4(0.f, 0.f, 0.f, 0.f);
        if (n0 + row < NN) v = *(const float4*)&x[(size_t)(n0 + row) * 32 + kk];
        *(float4*)&xs[row][kk] = v;
    }
    // stage Win (32 x 128)
    #pragma unroll
    for (int it = 0; it < 4; it++) {
        int idx = t + it * 256;
        int kr = idx >> 5, f4 = (idx & 31) * 4;
        *(float4*)&ws[kr][f4] = *(const float4*)&Win[kr * HID + f4];
    }
    __syncthreads();
    // GEMM 1: h = x @ Win + b_in
    {
        float acc[8][4] = {};
        #pragma unroll 8
        for (int k = 0; k < 32; k++) {
            float4 b4 = *(const float4*)&ws[k][c0];
            #pragma unroll
            for (int i = 0; i < 8; i++) {
                float a = xs[r0 + i][k];
                acc[i][0] += a * b4.x; acc[i][1] += a * b4.y;
                acc[i][2] += a * b4.z; acc[i][3] += a * b4.w;
            }
        }
        float4 bi = *(const float4*)&b_in[c0];
        #pragma unroll
        for (int i = 0; i < 8; i++) {
            int row = n0 + r0 + i;
            if (row < NN) {
                u32 lo = pack2(acc[i][0] + bi.x, acc[i][1] + bi.y);
                u32 hi = pack2(acc[i][2] + bi.z, acc[i][3] + bi.w);
                *(uint2*)&h[(size_t)row * HQ + (c0 >> 1)] = make_uint2(lo, hi);
            }
        }
    }
    __syncthreads();                          // all ws readers done
    // stage Wf (32 x 128)
    #pragma unroll
    for (int it = 0; it < 4; it++) {
        int idx = t + it * 256;
        int kr = idx >> 5, f4 = (idx & 31) * 4;
        *(float4*)&ws[kr][f4] = *(const float4*)&wf[kr * HID + f4];
    }
    __syncthreads();
    // GEMM 2: xh = x @ Wf + bf
    float acc2[8][4] = {};
    #pragma unroll 8
    for (int k = 0; k < 32; k++) {
        float4 b4 = *(const float4*)&ws[k][c0];
        #pragma unroll
        for (int i = 0; i < 8; i++) {
            float a = xs[r0 + i][k];
            acc2[i][0] += a * b4.x; acc2[i][1] += a * b4.y;
            acc2[i][2] += a * b4.z; acc2[i][3] += a * b4.w;
        }
    }
    float4 bf4 = *(const float4*)&wf[32 * HID + c0];
    #pragma unroll
    for (int i = 0; i < 8; i++) {
        acc2[i][0] += bf4.x; acc2[i][1] += bf4.y; acc2[i][2] += bf4.z; acc2[i][3] += bf4.w;
    }
    store_xh_al(acc2, n0, r0, c0, cg, xh, a_src0, a_dst0, al_s, al_d);
}

// ---------------------------------------------------------------------------
// Layers 1..2 via MFMA: hin = relu(LN(g)+h) (epilogue of prev layer, written
// back packed) staged to LDS in A-fragment order (bf16); xh = hin @ Wg via
// v_mfma_f32_16x16x32_bf16 with pre-packed B-frags; al via 9th col-tile.
// A-frag: lane q*16+m holds A[m][q*8..q*8+7].  C/D: col=lane&15, row=q*4+reg.
// ---------------------------------------------------------------------------
__global__ __launch_bounds__(256) void gemm_mfma_kernel(const u32* __restrict__ h,
        const u32* __restrict__ wb, u32* __restrict__ xh, const u32* __restrict__ g,
        const float* __restrict__ lnw, const float* __restrict__ lnb,
        const float* __restrict__ stats, u32* __restrict__ hout,
        float* __restrict__ al_s, float* __restrict__ al_d) {
    __shared__ u32 hsu[4096];                // 16KB, frag-ordered [rt][ks][lane][4]
    float mean = stats[0], rstd = stats[1];
    int n0 = blockIdx.x * 64;
    int t = threadIdx.x;
    int wv = t >> 6, lane = t & 63;
    int q = lane >> 4, n16 = lane & 15;

    // load B frags: wave w owns col-tiles 2w, 2w+1; wave 3 also the al tile (ct=8)
    bf16x8 bfrag[2][4];
    #pragma unroll
    for (int ks = 0; ks < 4; ks++) {
        #pragma unroll
        for (int cc = 0; cc < 2; cc++) {
            int ct = wv * 2 + cc;
            uint4 r = *(const uint4*)&wb[(size_t)((ks * 9 + ct) * 64 + lane) * 4];
            bfrag[cc][ks] = __builtin_bit_cast(bf16x8, r);
        }
    }
    bf16x8 bal[4];
    #pragma unroll
    for (int ks = 0; ks < 4; ks++) {
        uint4 r = *(const uint4*)&wb[(size_t)((ks * 9 + 8) * 64 + lane) * 4];
        bal[ks] = __builtin_bit_cast(bf16x8, r);
    }

    // stage hin = relu(LN(g)+h) -> hout (global) and LDS A-frags (bf16)
    {
        int row = t >> 2;                    // 0..63
        int qq = t & 3;                      // col-block within slab
        int gr = n0 + row;
        int rt = row >> 4, m = row & 15;
        #pragma unroll
        for (int ks = 0; ks < 4; ks++) {
            int kk = ks * 32 + qq * 8;
            uint4 op = make_uint4(0u, 0u, 0u, 0u);
            if (gr < NN) {
                size_t base = (size_t)gr * HQ + (kk >> 1);
                uint4 gp = *(const uint4*)&g[base];
                uint4 hp = *(const uint4*)&h[base];
                float4 wA = *(const float4*)&lnw[kk];
                float4 wB = *(const float4*)&lnw[kk + 4];
                float4 bA = *(const float4*)&lnb[kk];
                float4 bB = *(const float4*)&lnb[kk + 4];
                float v0 = fmaxf((bflo(gp.x) - mean) * rstd * wA.x + bA.x + bflo(hp.x), 0.f);
                float v1 = fmaxf((bfhi(gp.x) - mean) * rstd * wA.y + bA.y + bfhi(hp.x), 0.f);
                float v2 = fmaxf((bflo(gp.y) - mean) * rstd * wA.z + bA.z + bflo(hp.y), 0.f);
                float v3 = fmaxf((bfhi(gp.y) - mean) * rstd * wA.w + bA.w + bfhi(hp.y), 0.f);
                float v4 = fmaxf((bflo(gp.z) - mean) * rstd * wB.x + bB.x + bflo(hp.z), 0.f);
                float v5 = fmaxf((bfhi(gp.z) - mean) * rstd * wB.y + bB.y + bfhi(hp.z), 0.f);
                float v6 = fmaxf((bflo(gp.w) - mean) * rstd * wB.z + bB.z + bflo(hp.w), 0.f);
                float v7 = fmaxf((bfhi(gp.w) - mean) * rstd * wB.w + bB.w + bfhi(hp.w), 0.f);
                op.x = pack2(v0, v1); op.y = pack2(v2, v3);
                op.z = pack2(v4, v5); op.w = pack2(v6, v7);
                *(uint4*)&hout[base] = op;
            }
            *(uint4*)&hsu[((rt * 4 + ks) * 64 + qq * 16 + m) * 4] = op;
        }
    }
    __syncthreads();

    // MFMA: 4 row-tiles x 2 col-tiles (+ al tile on wave 3), K=128 in 4 slabs
    f32x4 acc[4][2];
    f32x4 accal[4];
    #pragma unroll
    for (int rt = 0; rt < 4; rt++) {
        acc[rt][0] = (f32x4){0.f, 0.f, 0.f, 0.f};
        acc[rt][1] = (f32x4){0.f, 0.f, 0.f, 0.f};
        accal[rt]  = (f32x4){0.f, 0.f, 0.f, 0.f};
    }
    #pragma unroll
    for (int rt = 0; rt < 4; rt++) {
        #pragma unroll
        for (int ks = 0; ks < 4; ks++) {
            uint4 araw = *(const uint4*)&hsu[((rt * 4 + ks) * 64 + lane) * 4];
            bf16x8 af = __builtin_bit_cast(bf16x8, araw);
            acc[rt][0] = __builtin_amdgcn_mfma_f32_16x16x32_bf16(af, bfrag[0][ks], acc[rt][0], 0, 0, 0);
            acc[rt][1] = __builtin_amdgcn_mfma_f32_16x16x32_bf16(af, bfrag[1][ks], acc[rt][1], 0, 0, 0);
            if (wv == 3)
                accal[rt] = __builtin_amdgcn_mfma_f32_16x16x32_bf16(af, bal[ks], accal[rt], 0, 0, 0);
        }
    }

    // epilogue: xh (pair-pack via shfl), al from the 9th tile
    #pragma unroll
    for (int rt = 0; rt < 4; rt++) {
        #pragma unroll
        for (int reg = 0; reg < 4; reg++) {
            int row = n0 + rt * 16 + q * 4 + reg;
            #pragma unroll
            for (int cc = 0; cc < 2; cc++) {
                float v = acc[rt][cc][reg];
                float vp = __shfl_xor(v, 1, 64);
                if (!(n16 & 1) && row < NN) {
                    int colp = (wv * 2 + cc) * 8 + (n16 >> 1);
                    xh[(size_t)row * HQ + colp] = pack2(v, vp);
                }
            }
            if (wv == 3 && row < NN && n16 < 8) {
                float v = accal[rt][reg];
                if (n16 < 4) al_s[row * 4 + n16] = v;
                else         al_d[row * 4 + (n16 - 4)] = v;
            }
        }
    }
}

// ---------------------------------------------------------------------------
// GAT aggregation, no-max softmax. 4 waves/block, one node per wave, wave-
// private LDS. Pass 1: lane-parallel logit->exp->LDS. Pass 2: lanes =
// (epar=4) x (16 channel-groups, 8 ch each): uint4 gathers, 2x unrolled ->
// 4x bytes-in-flight per wave vs uint2/epar2 (memory-concurrency bound fix).
// den folded into the FMA loop; single xor16+xor32 merge at the end.
// ---------------------------------------------------------------------------
__global__ __launch_bounds__(256) void gat_agg_kernel(const int* __restrict__ rowptr,
        const int* __restrict__ src_s, const float* __restrict__ ea_s,
        const u32* __restrict__ xh, const float* __restrict__ al_s,
        const float* __restrict__ al_d, const float* __restrict__ wedot,
        const float* __restrict__ bg, u32* __restrict__ g,
        float* __restrict__ partials) {
    __shared__ float lds_ex[4][CAP * 4];
    __shared__ int lds_src[4][CAP];
    int wv = threadIdx.x >> 6, lane = threadIdx.x & 63;
    int n = blockIdx.x * 4 + wv;
    if (n >= NN) return;
    float* ex_w = lds_ex[wv];
    int* src_w = lds_src[wv];
    int rs = rowptr[n], re = rowptr[n + 1];
    int deg = re - rs;
    int nc = deg < CAP ? deg : CAP;
    float wd0 = wedot[0], wd1 = wedot[1], wd2 = wedot[2], wd3 = wedot[3];
    float4 aldv = *(const float4*)&al_d[n * 4];

    // Pass 1: exp(leaky_relu(logit)) for cached edges -> LDS (lane-parallel)
    for (int i = rs + lane; i < rs + nc; i += 64) {
        int s = src_s[i];
        float eav = ea_s[i];
        float4 als = *(const float4*)&al_s[s * 4];
        float e0 = __expf(lrelu(als.x + aldv.x + eav * wd0));
        float e1 = __expf(lrelu(als.y + aldv.y + eav * wd1));
        float e2 = __expf(lrelu(als.z + aldv.z + eav * wd2));
        float e3 = __expf(lrelu(als.w + aldv.w + eav * wd3));
        int k = i - rs;
        src_w[k] = s;
        *(float4*)&ex_w[k * 4] = make_float4(e0, e1, e2, e3);
    }
    // same-wave LDS ops are in-order; no barrier needed (wave-private rows)

    // Pass 2: lanes = (epar in 0..3) x (cg16: 8 channels each, uint4 loads)
    int epar = lane >> 4, cg16 = lane & 15;
    int c4 = cg16 * 4;                       // u32 offset of this lane's 8 channels
    int head = cg16 >> 2;
    float a0 = 0.f, a1 = 0.f, a2 = 0.f, a3 = 0.f;
    float a4 = 0.f, a5 = 0.f, a6 = 0.f, a7 = 0.f, den = 0.f;
    int j = epar;
    for (; j + 4 < nc; j += 8) {             // 2x unroll: 2 uint4 loads in flight
        int s0 = src_w[j], s1 = src_w[j + 4];
        float e0 = ex_w[j * 4 + head], e1 = ex_w[(j + 4) * 4 + head];
        uint4 r0 = *(const uint4*)&xh[(size_t)s0 * HQ + c4];
        uint4 r1 = *(const uint4*)&xh[(size_t)s1 * HQ + c4];
        den += e0 + e1;
        a0 += e0 * bflo(r0.x); a1 += e0 * bfhi(r0.x);
        a2 += e0 * bflo(r0.y); a3 += e0 * bfhi(r0.y);
        a4 += e0 * bflo(r0.z); a5 += e0 * bfhi(r0.z);
        a6 += e0 * bflo(r0.w); a7 += e0 * bfhi(r0.w);
        a0 += e1 * bflo(r1.x); a1 += e1 * bfhi(r1.x);
        a2 += e1 * bflo(r1.y); a3 += e1 * bfhi(r1.y);
        a4 += e1 * bflo(r1.z); a5 += e1 * bfhi(r1.z);
        a6 += e1 * bflo(r1.w); a7 += e1 * bfhi(r1.w);
    }
    for (; j < nc; j += 4) {
        int s0 = src_w[j];
        float e0 = ex_w[j * 4 + head];
        uint4 r0 = *(const uint4*)&xh[(size_t)s0 * HQ + c4];
        den += e0;
        a0 += e0 * bflo(r0.x); a1 += e0 * bfhi(r0.x);
        a2 += e0 * bflo(r0.y); a3 += e0 * bfhi(r0.y);
        a4 += e0 * bflo(r0.z); a5 += e0 * bfhi(r0.z);
        a6 += e0 * bflo(r0.w); a7 += e0 * bfhi(r0.w);
    }
    // rare tail: rows longer than CAP (recompute logits, still no max)
    if (deg > CAP) {
        float aldh = head == 0 ? aldv.x : head == 1 ? aldv.y : head == 2 ? aldv.z : aldv.w;
        float wdh  = head == 0 ? wd0 : head == 1 ? wd1 : head == 2 ? wd2 : wd3;
        for (int jt = CAP + epar; jt < deg; jt += 4) {
            int i = rs + jt;
            int s = src_s[i];
            float eav = ea_s[i];
            float ex = __expf(lrelu(al_s[s * 4 + head] + aldh + eav * wdh));
            den += ex;
            uint4 r0 = *(const uint4*)&xh[(size_t)s * HQ + c4];
            a0 += ex * bflo(r0.x); a1 += ex * bfhi(r0.x);
            a2 += ex * bflo(r0.y); a3 += ex * bfhi(r0.y);
            a4 += ex * bflo(r0.z); a5 += ex * bfhi(r0.z);
            a6 += ex * bflo(r0.w); a7 += ex * bfhi(r0.w);
        }
    }
    // merge the 4 epar groups (head is invariant under xor 16/32)
    #pragma unroll
    for (int off = 16; off <= 32; off <<= 1) {
        a0 += __shfl_xor(a0, off, 64); a1 += __shfl_xor(a1, off, 64);
        a2 += __shfl_xor(a2, off, 64); a3 += __shfl_xor(a3, off, 64);
        a4 += __shfl_xor(a4, off, 64); a5 += __shfl_xor(a5, off, 64);
        a6 += __shfl_xor(a6, off, 64); a7 += __shfl_xor(a7, off, 64);
        den += __shfl_xor(den, off, 64);
    }

    float inv = 1.0f / (den + 1e-16f);
    int c0 = cg16 * 8;
    float4 bgA = *(const float4*)&bg[c0];
    float4 bgB = *(const float4*)&bg[c0 + 4];
    float o0 = a0 * inv + bgA.x, o1 = a1 * inv + bgA.y;
    float o2 = a2 * inv + bgA.z, o3 = a3 * inv + bgA.w;
    float o4 = a4 * inv + bgB.x, o5 = a5 * inv + bgB.y;
    float o6 = a6 * inv + bgB.z, o7 = a7 * inv + bgB.w;
    float ss = 0.f, sq = 0.f;
    if (epar == 0) {
        uint4 op;
        op.x = pack2(o0, o1); op.y = pack2(o2, o3);
        op.z = pack2(o4, o5); op.w = pack2(o6, o7);
        *(uint4*)&g[(size_t)n * HQ + c4] = op;
        ss = o0 + o1 + o2 + o3 + o4 + o5 + o6 + o7;
        sq = o0 * o0 + o1 * o1 + o2 * o2 + o3 * o3
           + o4 * o4 + o5 * o5 + o6 * o6 + o7 * o7;
    }
    #pragma unroll
    for (int off = 1; off <= 8; off <<= 1) {
        ss += __shfl_xor(ss, off, 64);
        sq += __shfl_xor(sq, off, 64);
    }
    if (lane == 0) {
        int sl = (n & 1023) * 2;
        atomicAdd(&partials[sl], ss);
        atomicAdd(&partials[sl + 1], sq);
    }
}

// reduce partials -> {mean, rstd}; re-zero partials for the next layer
__global__ void stats_kernel(float* __restrict__ partials, float* __restrict__ stats) {
    __shared__ float ls[16], lq[16];
    int tid = threadIdx.x;
    float s = partials[tid * 2], q = partials[tid * 2 + 1];
    partials[tid * 2] = 0.f;
    partials[tid * 2 + 1] = 0.f;
    #pragma unroll
    for (int off = 32; off; off >>= 1) {
        s += __shfl_xor(s, off, 64);
        q += __shfl_xor(q, off, 64);
    }
    int lane = tid & 63, wid = tid >> 6;
    if (lane == 0) { ls[wid] = s; lq[wid] = q; }
    __syncthreads();
    if (tid == 0) {
        float S = 0.f, Q = 0.f;
        for (int w2 = 0; w2 < 16; w2++) { S += ls[w2]; Q += lq[w2]; }
        const float M = (float)NN * (float)HID;
        float mean = S / M;
        float var = Q / M - mean * mean;
        stats[0] = mean;
        stats[1] = rsqrtf(fmaxf(var, 0.f) + LN_EPS);
    }
}

// final: out = relu(LN(g)+h) @ Wout + bout  (4 nodes/block, wave per node)
__global__ __launch_bounds__(256) void ln_out_kernel(const u32* __restrict__ g,
        const u32* __restrict__ h, const float* __restrict__ lnw,
        const float* __restrict__ lnb, const float* __restrict__ stats,
        const float* __restrict__ Wout, const float* __restrict__ bout,
        float* __restrict__ out) {
    __shared__ float wsh[HID * NOUT];
    int t = threadIdx.x;
    for (int i = t; i < HID * NOUT; i += 256) wsh[i] = Wout[i];
    __syncthreads();
    int wv = t >> 6, lane = t & 63;
    int n = blockIdx.x * 4 + wv;
    if (n >= NN) return;
    float mean = stats[0], rstd = stats[1];
    int c0 = lane * 2;
    u32 gv = g[(size_t)n * HQ + lane];
    u32 hv = h[(size_t)n * HQ + lane];
    float o0 = fmaxf((bflo(gv) - mean) * rstd * lnw[c0]     + lnb[c0]     + bflo(hv), 0.f);
    float o1 = fmaxf((bfhi(gv) - mean) * rstd * lnw[c0 + 1] + lnb[c0 + 1] + bfhi(hv), 0.f);
    float p[NOUT];
    #pragma unroll
    for (int jj = 0; jj < NOUT; jj++)
        p[jj] = o0 * wsh[c0 * NOUT + jj] + o1 * wsh[(c0 + 1) * NOUT + jj];
    #pragma unroll
    for (int off = 32; off; off >>= 1) {
        #pragma unroll
        for (int jj = 0; jj < NOUT; jj++) p[jj] += __shfl_xor(p[jj], off, 64);
    }
    if (lane == 0) {
        #pragma unroll
        for (int jj = 0; jj < NOUT; jj++)
            out[(size_t)n * NOUT + jj] = p[jj] + bout[jj];
    }
}

// ---------------------------------------------------------------------------
extern "C" void kernel_launch(void* const* d_in, const int* in_sizes, int n_in,
                              void* d_out, int out_size, void* d_ws, size_t ws_size,
                              hipStream_t stream) {
    const float* x      = (const float*)d_in[0];
    const int*   ei     = (const int*)d_in[1];
    const float* ea     = (const float*)d_in[2];
    const float* Win    = (const float*)d_in[3];
    const float* b_in   = (const float*)d_in[4];
    const float* Wg     = (const float*)d_in[5];
    const float* bg     = (const float*)d_in[6];
    const float* a_src  = (const float*)d_in[7];
    const float* a_dst  = (const float*)d_in[8];
    const float* We     = (const float*)d_in[9];
    const float* a_edge = (const float*)d_in[10];
    const float* ln_w   = (const float*)d_in[11];
    const float* ln_b   = (const float*)d_in[12];
    const float* Wout   = (const float*)d_in[13];
    const float* bout   = (const float*)d_in[14];
    float* out = (float*)d_out;

    char* w = (char*)d_ws;
    size_t off = 0;
    auto alloc = [&](size_t bytes) -> void* {
        void* p = w + off;
        off = (off + bytes + 255) & ~(size_t)255;
        return p;
    };
    int*   slot    = (int*)alloc((size_t)EE * sizeof(int));
    int*   cnt     = (int*)alloc(NN * sizeof(int));
    int*   rowptr  = (int*)alloc((NN + 1) * sizeof(int));
    int*   bsum    = (int*)alloc(NB_SCAN * sizeof(int));
    int*   src_s   = (int*)alloc((size_t)(EE + NN) * sizeof(int));
    float* ea_s    = (float*)alloc((size_t)(EE + NN) * sizeof(float));
    u32*   h       = (u32*)alloc((size_t)NN * HQ * sizeof(u32));
    u32*   g       = (u32*)alloc((size_t)NN * HQ * sizeof(u32));
    u32*   xh      = (u32*)alloc((size_t)NN * HQ * sizeof(u32));
    float* al_s    = (float*)alloc((size_t)NN * NH * sizeof(float));
    float* al_d    = (float*)alloc((size_t)NN * NH * sizeof(float));
    float* wedot   = (float*)alloc(16 * sizeof(float));
    float* wf      = (float*)alloc(33 * HID * sizeof(float));
    float* wga     = (float*)alloc(2048 * sizeof(float));
    u32*   wb      = (u32*)alloc((size_t)2 * WB_LSZ * sizeof(u32));
    float* partials = (float*)alloc(2048 * sizeof(float));
    float* stats   = (float*)alloc(16 * sizeof(float));
    (void)ws_size; (void)n_in; (void)in_sizes; (void)out_size;

    // --- CSR build + weight prep ---
    init_kernel<<<(NN + 255) / 256, 256, 0, stream>>>(cnt, partials);
    hist_kernel<<<(EE + 255) / 256, 256, 0, stream>>>(ei, cnt, slot);
    scan1_kernel<<<NB_SCAN, 1024, 0, stream>>>(cnt, rowptr, bsum);
    scan2_kernel<<<1, 128, 0, stream>>>(bsum);
    scan3_kernel<<<NB_SCAN, 1024, 0, stream>>>(rowptr, bsum);
    scatter_kernel<<<(EE + 255) / 256, 256, 0, stream>>>(ei, ea, rowptr, slot, src_s, ea_s);
    selfloop_kernel<<<(NN + 255) / 256, 256, 0, stream>>>(rowptr, src_s, ea_s);
    wedot_kernel<<<1, 64, 0, stream>>>(We, a_edge, wedot);
    wfuse_kernel<<<33, 128, 0, stream>>>(Win, b_in, Wg, wf);
    wga_kernel<<<2, 1024, 0, stream>>>(Wg, a_src, a_dst, wga);
    pack_kernel<<<18, 256, 0, stream>>>(Wg, wga, wb);

    const int ngrid = (NN + 63) / 64;
    // --- layer 0 (input projection algebraically fused) ---
    in_gemm_kernel<<<ngrid, 256, 0, stream>>>(x, Win, b_in, wf, h, xh,
                                              a_src, a_dst, al_s, al_d);
    for (int l = 0; l < NL; l++) {
        if (l > 0) {
            gemm_mfma_kernel<<<ngrid, 256, 0, stream>>>(
                h, wb + (size_t)(l - 1) * WB_LSZ, xh, g,
                ln_w + (size_t)(l - 1) * HID, ln_b + (size_t)(l - 1) * HID, stats, h,
                al_s, al_d);
        }
        gat_agg_kernel<<<(NN + 3) / 4, 256, 0, stream>>>(
            rowptr, src_s, ea_s, xh, al_s, al_d, wedot + l * 4,
            bg + (size_t)l * HID, g, partials);
        stats_kernel<<<1, 1024, 0, stream>>>(partials, stats);
    }

    // --- final LN + residual + relu + output projection (fused) ---
    ln_out_kernel<<<(NN + 3) / 4, 256, 0, stream>>>(g, h, ln_w + (size_t)2 * HID,
                                                    ln_b + (size_t)2 * HID,
                                                    stats, Wout, bout, out);
}

// Round 9
// 417.238 us; speedup vs baseline: 2.5384x; 1.1575x over previous
//
#include <hip/hip_runtime.h>
#include <hip/hip_bf16.h>

#define NN 100000
#define EE 800000
#define HID 128
#define NH 4
#define CH 32
#define NL 3
#define NOUT 5
#define NEG_SLOPE 0.2f
#define LN_EPS 1e-5f
#define GCAP 96            // LDS-cached edges per 4-node wave group
#define NB_SCAN 98         // ceil((NN+1)/1024)
#define HQ (HID / 2)       // u32-packed bf16 pairs per row
#define WB_LSZ 9216        // u32 per layer of packed B-frags: 4ks*9ct*64lane*4
#define NB_INIT 391        // ceil(NN/256)

typedef unsigned int u32;
typedef __attribute__((ext_vector_type(8))) short bf16x8;
typedef __attribute__((ext_vector_type(4))) float f32x4;

static __device__ __forceinline__ float bflo(u32 r) { return __uint_as_float(r << 16); }
static __device__ __forceinline__ float bfhi(u32 r) { return __uint_as_float(r & 0xffff0000u); }
static __device__ __forceinline__ unsigned short f2bf(float x) {
    union U { __hip_bfloat16 b; unsigned short s; } u;
    u.b = __float2bfloat16(x);
    return u.s;
}
static __device__ __forceinline__ u32 pack2(float a, float b) {
    return (u32)f2bf(a) | ((u32)f2bf(b) << 16);
}
static __device__ __forceinline__ float lrelu(float x) {
    return x > 0.f ? x : NEG_SLOPE * x;
}

// ---------------------------------------------------------------------------
// prep: cnt/partials init + wedot + wfuse + pack (wga inline), one dispatch.
// blocks 0..390 init; 391 wedot; 392..408 wfuse; 409..426 pack.
// ---------------------------------------------------------------------------
__global__ void prep_kernel(int* __restrict__ cnt, float* __restrict__ partials,
                            const float* __restrict__ We, const float* __restrict__ a_e,
                            float* __restrict__ wedot,
                            const float* __restrict__ Win, const float* __restrict__ b_in,
                            const float* __restrict__ Wg, float* __restrict__ wf,
                            const float* __restrict__ a_src, const float* __restrict__ a_dst,
                            u32* __restrict__ wb) {
    int b = blockIdx.x, t = threadIdx.x;
    if (b < NB_INIT) {
        int n = b * 256 + t;
        if (n < NN) cnt[n] = 1;
        if (n < 2048) partials[n] = 0.f;
        return;
    }
    if (b == NB_INIT) {
        if (t < NL * NH) {
            int l = t >> 2, hh = t & 3;
            float s = 0.f;
            #pragma unroll
            for (int c = 0; c < CH; c++)
                s += We[l * HID + hh * CH + c] * a_e[l * HID + hh * CH + c];
            wedot[t] = s;
        }
        return;
    }
    if (b < NB_INIT + 18) {
        // wfuse: wf[r][c] = sum_k (r<32 ? Win[r][k] : b_in[k]) * Wg0[k][c]
        int idx = (b - NB_INIT - 1) * 256 + t;
        if (idx >= 33 * HID) return;
        int r = idx >> 7, c = idx & 127;
        float acc = 0.f;
        for (int k = 0; k < HID; k++) {
            float a = (r < 32) ? Win[r * HID + k] : b_in[k];
            acc += a * Wg[(size_t)k * HID + c];
        }
        wf[r * HID + c] = acc;
        return;
    }
    // pack Wg[1..2] (+ head-masked al columns as 9th col-tile) into B-frags
    {
        int idx = (b - NB_INIT - 18) * 256 + t;   // 0..4607
        if (idx >= 2 * 2304) return;
        int l = idx / 2304;                  // 0 -> layer1, 1 -> layer2
        int rem = idx % 2304;
        int ks = rem / 576;
        int ct = (rem % 576) / 64;
        int lane = rem % 64;
        int q = lane >> 4, n = lane & 15;
        const float* W = Wg + (size_t)(l + 1) * HID * HID;
        float v[8];
        if (ct < 8) {
            #pragma unroll
            for (int j = 0; j < 8; j++) {
                int k = ks * 32 + q * 8 + j;
                v[j] = W[(size_t)k * HID + ct * 16 + n];
            }
        } else {
            #pragma unroll
            for (int j = 0; j < 8; j++) v[j] = 0.f;
            if (n < 8) {
                const float* a = (n < 4) ? (a_src + (l + 1) * HID + (n & 3) * CH)
                                         : (a_dst + (l + 1) * HID + (n & 3) * CH);
                #pragma unroll
                for (int j = 0; j < 8; j++) {
                    int k = ks * 32 + q * 8 + j;
                    const float* wrow = W + (size_t)k * HID + (n & 3) * CH;
                    float s = 0.f;
                    for (int c = 0; c < CH; c++) s += wrow[c] * a[c];
                    v[j] = s;
                }
            }
        }
        u32* dst = wb + (size_t)l * WB_LSZ + (size_t)((ks * 9 + ct) * 64 + lane) * 4;
        dst[0] = pack2(v[0], v[1]); dst[1] = pack2(v[2], v[3]);
        dst[2] = pack2(v[4], v[5]); dst[3] = pack2(v[6], v[7]);
    }
}

// ---------------------------------------------------------------------------
// CSR build. cnt[n] starts at 1 (self-loop reserved at row slot 0).
// ---------------------------------------------------------------------------
__global__ void hist_kernel(const int* __restrict__ ei, int* __restrict__ cnt,
                            int* __restrict__ slot) {
    int e = blockIdx.x * blockDim.x + threadIdx.x;
    if (e >= EE) return;
    int d = ei[EE + e];
    slot[e] = atomicAdd(&cnt[d], 1);
}

__global__ __launch_bounds__(1024) void scan1_kernel(const int* __restrict__ cnt,
                                                     int* __restrict__ rowptr,
                                                     int* __restrict__ bsum) {
    __shared__ int ws[16];
    int gid = blockIdx.x * 1024 + threadIdx.x;
    int v = (gid < NN) ? cnt[gid] : 0;
    int lane = threadIdx.x & 63, wid = threadIdx.x >> 6;
    int s = v;
    #pragma unroll
    for (int off = 1; off < 64; off <<= 1) {
        int t = __shfl_up(s, off, 64);
        if (lane >= off) s += t;
    }
    if (lane == 63) ws[wid] = s;
    __syncthreads();
    int add = 0;
    for (int w2 = 0; w2 < wid; w2++) add += ws[w2];
    int incl = s + add;
    if (gid <= NN) rowptr[gid] = incl - v;   // exclusive
    if (threadIdx.x == 1023) bsum[blockIdx.x] = incl;
}

__global__ void scan2_kernel(int* __restrict__ bsum) {
    __shared__ int w0tot;
    int tid = threadIdx.x;                   // 128 threads
    int v = (tid < NB_SCAN) ? bsum[tid] : 0;
    int lane = tid & 63, wid = tid >> 6;
    int s = v;
    #pragma unroll
    for (int off = 1; off < 64; off <<= 1) {
        int t = __shfl_up(s, off, 64);
        if (lane >= off) s += t;
    }
    if (wid == 0 && lane == 63) w0tot = s;
    __syncthreads();
    int incl = s + (wid ? w0tot : 0);
    if (tid < NB_SCAN) bsum[tid] = incl - v; // exclusive
}

__global__ void scan3_kernel(int* __restrict__ rowptr, const int* __restrict__ bsum) {
    int gid = blockIdx.x * 1024 + threadIdx.x;
    if (gid <= NN) rowptr[gid] += bsum[blockIdx.x];
}

// packed edge record: {src, ea bits} -> ONE 8B random store per edge
__global__ void scatter_kernel(const int* __restrict__ ei, const float* __restrict__ ea,
                               const int* __restrict__ rowptr, const int* __restrict__ slot,
                               uint2* __restrict__ edges) {
    int e = blockIdx.x * blockDim.x + threadIdx.x;
    if (e >= EE) return;
    int d = ei[EE + e];
    int pos = rowptr[d] + slot[e];           // slot >= 1; slot 0 is the self loop
    edges[pos] = make_uint2((u32)ei[e], __float_as_uint(ea[e]));
}

// self-loop attr = mean of the row's real-edge attrs (PyG fill_value='mean')
__global__ void selfloop_kernel(const int* __restrict__ rowptr, uint2* __restrict__ edges) {
    int n = blockIdx.x * blockDim.x + threadIdx.x;
    if (n >= NN) return;
    int rs = rowptr[n], re = rowptr[n + 1];
    float s = 0.f;
    for (int i = rs + 1; i < re; i++) s += __uint_as_float(edges[i].y);
    float m = s / fmaxf((float)(re - rs - 1), 1.0f);
    edges[rs] = make_uint2((u32)n, __float_as_uint(m));
}

// ---------------------------------------------------------------------------
// shared FMA-GEMM epilogue (layer 0): pack xh to bf16 + al dots via 8-lane reduce
// ---------------------------------------------------------------------------
static __device__ __forceinline__ void store_xh_al(
        float acc[8][4], int n0, int r0, int c0, int cg,
        u32* __restrict__ xh, const float* __restrict__ asl, const float* __restrict__ adl,
        float* __restrict__ al_s, float* __restrict__ al_d) {
    float4 as4 = *(const float4*)&asl[c0];
    float4 ad4 = *(const float4*)&adl[c0];
    int hh = cg >> 3;
    #pragma unroll
    for (int i = 0; i < 8; i++) {
        int row = n0 + r0 + i;
        if (row < NN) {
            u32 lo = pack2(acc[i][0], acc[i][1]);
            u32 hi = pack2(acc[i][2], acc[i][3]);
            *(uint2*)&xh[(size_t)row * HQ + (c0 >> 1)] = make_uint2(lo, hi);
        }
        float ps = acc[i][0] * as4.x + acc[i][1] * as4.y + acc[i][2] * as4.z + acc[i][3] * as4.w;
        float pd = acc[i][0] * ad4.x + acc[i][1] * ad4.y + acc[i][2] * ad4.z + acc[i][3] * ad4.w;
        ps += __shfl_xor(ps, 1, 64); pd += __shfl_xor(pd, 1, 64);
        ps += __shfl_xor(ps, 2, 64); pd += __shfl_xor(pd, 2, 64);
        ps += __shfl_xor(ps, 4, 64); pd += __shfl_xor(pd, 4, 64);
        if ((cg & 7) == 0 && row < NN) {
            al_s[row * 4 + hh] = ps;
            al_d[row * 4 + hh] = pd;
        }
    }
}

// ---------------------------------------------------------------------------
// Layer 0, algebraically fused: h = x@Win + b_in  AND  xh = x@Wf + bf,
// both K=32 GEMMs off the same LDS x-tile. h/xh stored packed bf16.
// ---------------------------------------------------------------------------
__global__ __launch_bounds__(256) void in_gemm_kernel(
        const float* __restrict__ x, const float* __restrict__ Win,
        const float* __restrict__ b_in, const float* __restrict__ wf,
        u32* __restrict__ h, u32* __restrict__ xh,
        const float* __restrict__ a_src0, const float* __restrict__ a_dst0,
        float* __restrict__ al_s, float* __restrict__ al_d) {
    __shared__ float xs[64][36];
    __shared__ float ws[32][128];
    int n0 = blockIdx.x * 64;
    int t = threadIdx.x;
    int cg = t & 31, rg = t >> 5;
    int c0 = cg * 4, r0 = rg * 8;
    #pragma unroll
    for (int it = 0; it < 2; it++) {
        int idx = t + it * 256;
        int row = idx >> 3, kk = (idx & 7) * 4;
        float4 v = make_float4(0.f, 0.f, 0.f, 0.f);
        if (n0 + row < NN) v = *(const float4*)&x[(size_t)(n0 + row) * 32 + kk];
        *(float4*)&xs[row][kk] = v;
    }
    #pragma unroll
    for (int it = 0; it < 4; it++) {
        int idx = t + it * 256;
        int kr = idx >> 5, f4 = (idx & 31) * 4;
        *(float4*)&ws[kr][f4] = *(const float4*)&Win[kr * HID + f4];
    }
    __syncthreads();
    {
        float acc[8][4] = {};
        #pragma unroll 8
        for (int k = 0; k < 32; k++) {
            float4 b4 = *(const float4*)&ws[k][c0];
            #pragma unroll
            for (int i = 0; i < 8; i++) {
                float a = xs[r0 + i][k];
                acc[i][0] += a * b4.x; acc[i][1] += a * b4.y;
                acc[i][2] += a * b4.z; acc[i][3] += a * b4.w;
            }
        }
        float4 bi = *(const float4*)&b_in[c0];
        #pragma unroll
        for (int i = 0; i < 8; i++) {
            int row = n0 + r0 + i;
            if (row < NN) {
                u32 lo = pack2(acc[i][0] + bi.x, acc[i][1] + bi.y);
                u32 hi = pack2(acc[i][2] + bi.z, acc[i][3] + bi.w);
                *(uint2*)&h[(size_t)row * HQ + (c0 >> 1)] = make_uint2(lo, hi);
            }
        }
    }
    __syncthreads();
    #pragma unroll
    for (int it = 0; it < 4; it++) {
        int idx = t + it * 256;
        int kr = idx >> 5, f4 = (idx & 31) * 4;
        *(float4*)&ws[kr][f4] = *(const float4*)&wf[kr * HID + f4];
    }
    __syncthreads();
    float acc2[8][4] = {};
    #pragma unroll 8
    for (int k = 0; k < 32; k++) {
        float4 b4 = *(const float4*)&ws[k][c0];
        #pragma unroll
        for (int i = 0; i < 8; i++) {
            float a = xs[r0 + i][k];
            acc2[i][0] += a * b4.x; acc2[i][1] += a * b4.y;
            acc2[i][2] += a * b4.z; acc2[i][3] += a * b4.w;
        }
    }
    float4 bf4 = *(const float4*)&wf[32 * HID + c0];
    #pragma unroll
    for (int i = 0; i < 8; i++) {
        acc2[i][0] += bf4.x; acc2[i][1] += bf4.y; acc2[i][2] += bf4.z; acc2[i][3] += bf4.w;
    }
    store_xh_al(acc2, n0, r0, c0, cg, xh, a_src0, a_dst0, al_s, al_d);
}

// ---------------------------------------------------------------------------
// Layers 1..2 via MFMA (unchanged from round 7/8)
// ---------------------------------------------------------------------------
__global__ __launch_bounds__(256) void gemm_mfma_kernel(const u32* __restrict__ h,
        const u32* __restrict__ wb, u32* __restrict__ xh, const u32* __restrict__ g,
        const float* __restrict__ lnw, const float* __restrict__ lnb,
        const float* __restrict__ stats, u32* __restrict__ hout,
        float* __restrict__ al_s, float* __restrict__ al_d) {
    __shared__ u32 hsu[4096];                // 16KB, frag-ordered [rt][ks][lane][4]
    float mean = stats[0], rstd = stats[1];
    int n0 = blockIdx.x * 64;
    int t = threadIdx.x;
    int wv = t >> 6, lane = t & 63;
    int q = lane >> 4, n16 = lane & 15;

    bf16x8 bfrag[2][4];
    #pragma unroll
    for (int ks = 0; ks < 4; ks++) {
        #pragma unroll
        for (int cc = 0; cc < 2; cc++) {
            int ct = wv * 2 + cc;
            uint4 r = *(const uint4*)&wb[(size_t)((ks * 9 + ct) * 64 + lane) * 4];
            bfrag[cc][ks] = __builtin_bit_cast(bf16x8, r);
        }
    }
    bf16x8 bal[4];
    #pragma unroll
    for (int ks = 0; ks < 4; ks++) {
        uint4 r = *(const uint4*)&wb[(size_t)((ks * 9 + 8) * 64 + lane) * 4];
        bal[ks] = __builtin_bit_cast(bf16x8, r);
    }

    {
        int row = t >> 2;
        int qq = t & 3;
        int gr = n0 + row;
        int rt = row >> 4, m = row & 15;
        #pragma unroll
        for (int ks = 0; ks < 4; ks++) {
            int kk = ks * 32 + qq * 8;
            uint4 op = make_uint4(0u, 0u, 0u, 0u);
            if (gr < NN) {
                size_t base = (size_t)gr * HQ + (kk >> 1);
                uint4 gp = *(const uint4*)&g[base];
                uint4 hp = *(const uint4*)&h[base];
                float4 wA = *(const float4*)&lnw[kk];
                float4 wB = *(const float4*)&lnw[kk + 4];
                float4 bA = *(const float4*)&lnb[kk];
                float4 bB = *(const float4*)&lnb[kk + 4];
                float v0 = fmaxf((bflo(gp.x) - mean) * rstd * wA.x + bA.x + bflo(hp.x), 0.f);
                float v1 = fmaxf((bfhi(gp.x) - mean) * rstd * wA.y + bA.y + bfhi(hp.x), 0.f);
                float v2 = fmaxf((bflo(gp.y) - mean) * rstd * wA.z + bA.z + bflo(hp.y), 0.f);
                float v3 = fmaxf((bfhi(gp.y) - mean) * rstd * wA.w + bA.w + bfhi(hp.y), 0.f);
                float v4 = fmaxf((bflo(gp.z) - mean) * rstd * wB.x + bB.x + bflo(hp.z), 0.f);
                float v5 = fmaxf((bfhi(gp.z) - mean) * rstd * wB.y + bB.y + bfhi(hp.z), 0.f);
                float v6 = fmaxf((bflo(gp.w) - mean) * rstd * wB.z + bB.z + bflo(hp.w), 0.f);
                float v7 = fmaxf((bfhi(gp.w) - mean) * rstd * wB.w + bB.w + bfhi(hp.w), 0.f);
                op.x = pack2(v0, v1); op.y = pack2(v2, v3);
                op.z = pack2(v4, v5); op.w = pack2(v6, v7);
                *(uint4*)&hout[base] = op;
            }
            *(uint4*)&hsu[((rt * 4 + ks) * 64 + qq * 16 + m) * 4] = op;
        }
    }
    __syncthreads();

    f32x4 acc[4][2];
    f32x4 accal[4];
    #pragma unroll
    for (int rt = 0; rt < 4; rt++) {
        acc[rt][0] = (f32x4){0.f, 0.f, 0.f, 0.f};
        acc[rt][1] = (f32x4){0.f, 0.f, 0.f, 0.f};
        accal[rt]  = (f32x4){0.f, 0.f, 0.f, 0.f};
    }
    #pragma unroll
    for (int rt = 0; rt < 4; rt++) {
        #pragma unroll
        for (int ks = 0; ks < 4; ks++) {
            uint4 araw = *(const uint4*)&hsu[((rt * 4 + ks) * 64 + lane) * 4];
            bf16x8 af = __builtin_bit_cast(bf16x8, araw);
            acc[rt][0] = __builtin_amdgcn_mfma_f32_16x16x32_bf16(af, bfrag[0][ks], acc[rt][0], 0, 0, 0);
            acc[rt][1] = __builtin_amdgcn_mfma_f32_16x16x32_bf16(af, bfrag[1][ks], acc[rt][1], 0, 0, 0);
            if (wv == 3)
                accal[rt] = __builtin_amdgcn_mfma_f32_16x16x32_bf16(af, bal[ks], accal[rt], 0, 0, 0);
        }
    }

    #pragma unroll
    for (int rt = 0; rt < 4; rt++) {
        #pragma unroll
        for (int reg = 0; reg < 4; reg++) {
            int row = n0 + rt * 16 + q * 4 + reg;
            #pragma unroll
            for (int cc = 0; cc < 2; cc++) {
                float v = acc[rt][cc][reg];
                float vp = __shfl_xor(v, 1, 64);
                if (!(n16 & 1) && row < NN) {
                    int colp = (wv * 2 + cc) * 8 + (n16 >> 1);
                    xh[(size_t)row * HQ + colp] = pack2(v, vp);
                }
            }
            if (wv == 3 && row < NN && n16 < 8) {
                float v = accal[rt][reg];
                if (n16 < 4) al_s[row * 4 + n16] = v;
                else         al_d[row * 4 + (n16 - 4)] = v;
            }
        }
    }
}

// ---------------------------------------------------------------------------
// GAT aggregation v3: one wave = 4 consecutive nodes (contiguous CSR span).
// Pass 1: lane-parallel over the combined span (~36 edges) with per-lane
// edge->node resolve; exp values + src cached in wave-private LDS.
// Pass 2: 16 lanes per node, full 256B row per uint4 iteration, epar=1 ->
// no merge shuffles, den accumulated redundantly (free). 2x unrolled.
// ---------------------------------------------------------------------------
__global__ __launch_bounds__(256) void gat_agg_kernel(const int* __restrict__ rowptr,
        const uint2* __restrict__ edges, const u32* __restrict__ xh,
        const float* __restrict__ al_s, const float* __restrict__ al_d,
        const float* __restrict__ wedot, const float* __restrict__ bg,
        u32* __restrict__ g, float* __restrict__ partials) {
    __shared__ float lds_ex[4][GCAP * 4];
    __shared__ int lds_src[4][GCAP];
    int wv = threadIdx.x >> 6, lane = threadIdx.x & 63;
    int base = (blockIdx.x * 4 + wv) * 4;
    if (base >= NN) return;
    float* ex_w = lds_ex[wv];
    int* src_w = lds_src[wv];
    int b1 = base + 1 < NN ? base + 1 : NN;
    int b2 = base + 2 < NN ? base + 2 : NN;
    int b3 = base + 3 < NN ? base + 3 : NN;
    int b4 = base + 4 < NN ? base + 4 : NN;
    int r0 = rowptr[base], r1 = rowptr[b1], r2 = rowptr[b2], r3 = rowptr[b3], r4 = rowptr[b4];
    int span = r4 - r0;
    int ncached = span < GCAP ? span : GCAP;
    float wd0 = wedot[0], wd1 = wedot[1], wd2 = wedot[2], wd3 = wedot[3];

    // Pass 1: logits+exp for the whole 4-node span, lane-parallel
    for (int i = lane; i < ncached; i += 64) {
        int gi = r0 + i;
        uint2 e = edges[gi];
        int s = (int)e.x;
        float eav = __uint_as_float(e.y);
        int d = (gi >= r1) + (gi >= r2) + (gi >= r3);
        float4 aldv = *(const float4*)&al_d[(base + d) * 4];
        float4 als = *(const float4*)&al_s[s * 4];
        float e0 = __expf(lrelu(als.x + aldv.x + eav * wd0));
        float e1 = __expf(lrelu(als.y + aldv.y + eav * wd1));
        float e2 = __expf(lrelu(als.z + aldv.z + eav * wd2));
        float e3 = __expf(lrelu(als.w + aldv.w + eav * wd3));
        src_w[i] = s;
        *(float4*)&ex_w[i * 4] = make_float4(e0, e1, e2, e3);
    }
    // wave-private LDS rows; same-wave ops in order -> no barrier

    // Pass 2: 16 lanes per node, 8 channels each (one uint4 = full share)
    int nl = lane >> 4, cg = lane & 15;
    int n = base + nl;
    bool nvalid = n < NN;
    int ls = (nl == 0 ? r0 : nl == 1 ? r1 : nl == 2 ? r2 : r3) - r0;
    int le = (nl == 0 ? r1 : nl == 1 ? r2 : nl == 2 ? r3 : r4) - r0;
    int lec = le < ncached ? le : ncached;
    int head = cg >> 2;
    int c4 = cg * 4;                          // u32 offset of lane's 8 channels
    float a0 = 0.f, a1 = 0.f, a2 = 0.f, a3 = 0.f;
    float a4 = 0.f, a5 = 0.f, a6 = 0.f, a7 = 0.f, den = 0.f;
    int j = ls;
    for (; j + 1 < lec; j += 2) {             // 2 uint4 loads in flight
        int s0 = src_w[j], s1 = src_w[j + 1];
        float e0 = ex_w[j * 4 + head], e1 = ex_w[(j + 1) * 4 + head];
        uint4 x0 = *(const uint4*)&xh[(size_t)s0 * HQ + c4];
        uint4 x1 = *(const uint4*)&xh[(size_t)s1 * HQ + c4];
        den += e0 + e1;
        a0 += e0 * bflo(x0.x); a1 += e0 * bfhi(x0.x);
        a2 += e0 * bflo(x0.y); a3 += e0 * bfhi(x0.y);
        a4 += e0 * bflo(x0.z); a5 += e0 * bfhi(x0.z);
        a6 += e0 * bflo(x0.w); a7 += e0 * bfhi(x0.w);
        a0 += e1 * bflo(x1.x); a1 += e1 * bfhi(x1.x);
        a2 += e1 * bflo(x1.y); a3 += e1 * bfhi(x1.y);
        a4 += e1 * bflo(x1.z); a5 += e1 * bfhi(x1.z);
        a6 += e1 * bflo(x1.w); a7 += e1 * bfhi(x1.w);
    }
    if (j < lec) {
        int s0 = src_w[j];
        float e0 = ex_w[j * 4 + head];
        uint4 x0 = *(const uint4*)&xh[(size_t)s0 * HQ + c4];
        den += e0;
        a0 += e0 * bflo(x0.x); a1 += e0 * bfhi(x0.x);
        a2 += e0 * bflo(x0.y); a3 += e0 * bfhi(x0.y);
        a4 += e0 * bflo(x0.z); a5 += e0 * bfhi(x0.z);
        a6 += e0 * bflo(x0.w); a7 += e0 * bfhi(x0.w);
        j++;
    }
    // tail beyond LDS cache (vanishingly rare): recompute logits for this head
    if (le > lec && nvalid) {
        float aldh = al_d[n * 4 + head];
        float wdh = wedot[head];
        for (int jt = (ls > lec ? ls : lec); jt < le; jt++) {
            uint2 e = edges[r0 + jt];
            int s = (int)e.x;
            float eav = __uint_as_float(e.y);
            float ex = __expf(lrelu(al_s[s * 4 + head] + aldh + eav * wdh));
            den += ex;
            uint4 x0 = *(const uint4*)&xh[(size_t)s * HQ + c4];
            a0 += ex * bflo(x0.x); a1 += ex * bfhi(x0.x);
            a2 += ex * bflo(x0.y); a3 += ex * bfhi(x0.y);
            a4 += ex * bflo(x0.z); a5 += ex * bfhi(x0.z);
            a6 += ex * bflo(x0.w); a7 += ex * bfhi(x0.w);
        }
    }

    // no cross-lane merge: each node's 16 lanes own disjoint channels and
    // carry identical den. Epilogue:
    float inv = 1.0f / (den + 1e-16f);
    int c0 = cg * 8;
    float4 bgA = *(const float4*)&bg[c0];
    float4 bgB = *(const float4*)&bg[c0 + 4];
    float o0 = a0 * inv + bgA.x, o1 = a1 * inv + bgA.y;
    float o2 = a2 * inv + bgA.z, o3 = a3 * inv + bgA.w;
    float o4 = a4 * inv + bgB.x, o5 = a5 * inv + bgB.y;
    float o6 = a6 * inv + bgB.z, o7 = a7 * inv + bgB.w;
    float ss = 0.f, sq = 0.f;
    if (nvalid) {
        uint4 op;
        op.x = pack2(o0, o1); op.y = pack2(o2, o3);
        op.z = pack2(o4, o5); op.w = pack2(o6, o7);
        *(uint4*)&g[(size_t)n * HQ + c4] = op;
        ss = o0 + o1 + o2 + o3 + o4 + o5 + o6 + o7;
        sq = o0 * o0 + o1 * o1 + o2 * o2 + o3 * o3
           + o4 * o4 + o5 * o5 + o6 * o6 + o7 * o7;
    }
    // one butterfly + one atomic per wave (sums 4 nodes; valid for global LN)
    #pragma unroll
    for (int off = 1; off <= 32; off <<= 1) {
        ss += __shfl_xor(ss, off, 64);
        sq += __shfl_xor(sq, off, 64);
    }
    if (lane == 0) {
        int sl = ((blockIdx.x * 4 + wv) & 1023) * 2;
        atomicAdd(&partials[sl], ss);
        atomicAdd(&partials[sl + 1], sq);
    }
}

// reduce partials -> {mean, rstd}; re-zero partials for the next layer
__global__ void stats_kernel(float* __restrict__ partials, float* __restrict__ stats) {
    __shared__ float ls[16], lq[16];
    int tid = threadIdx.x;
    float s = partials[tid * 2], q = partials[tid * 2 + 1];
    partials[tid * 2] = 0.f;
    partials[tid * 2 + 1] = 0.f;
    #pragma unroll
    for (int off = 32; off; off >>= 1) {
        s += __shfl_xor(s, off, 64);
        q += __shfl_xor(q, off, 64);
    }
    int lane = tid & 63, wid = tid >> 6;
    if (lane == 0) { ls[wid] = s; lq[wid] = q; }
    __syncthreads();
    if (tid == 0) {
        float S = 0.f, Q = 0.f;
        for (int w2 = 0; w2 < 16; w2++) { S += ls[w2]; Q += lq[w2]; }
        const float M = (float)NN * (float)HID;
        float mean = S / M;
        float var = Q / M - mean * mean;
        stats[0] = mean;
        stats[1] = rsqrtf(fmaxf(var, 0.f) + LN_EPS);
    }
}

// final: out = relu(LN(g)+h) @ Wout + bout  (4 nodes/block, wave per node)
__global__ __launch_bounds__(256) void ln_out_kernel(const u32* __restrict__ g,
        const u32* __restrict__ h, const float* __restrict__ lnw,
        const float* __restrict__ lnb, const float* __restrict__ stats,
        const float* __restrict__ Wout, const float* __restrict__ bout,
        float* __restrict__ out) {
    __shared__ float wsh[HID * NOUT];
    int t = threadIdx.x;
    for (int i = t; i < HID * NOUT; i += 256) wsh[i] = Wout[i];
    __syncthreads();
    int wv = t >> 6, lane = t & 63;
    int n = blockIdx.x * 4 + wv;
    if (n >= NN) return;
    float mean = stats[0], rstd = stats[1];
    int c0 = lane * 2;
    u32 gv = g[(size_t)n * HQ + lane];
    u32 hv = h[(size_t)n * HQ + lane];
    float o0 = fmaxf((bflo(gv) - mean) * rstd * lnw[c0]     + lnb[c0]     + bflo(hv), 0.f);
    float o1 = fmaxf((bfhi(gv) - mean) * rstd * lnw[c0 + 1] + lnb[c0 + 1] + bfhi(hv), 0.f);
    float p[NOUT];
    #pragma unroll
    for (int jj = 0; jj < NOUT; jj++)
        p[jj] = o0 * wsh[c0 * NOUT + jj] + o1 * wsh[(c0 + 1) * NOUT + jj];
    #pragma unroll
    for (int off = 32; off; off >>= 1) {
        #pragma unroll
        for (int jj = 0; jj < NOUT; jj++) p[jj] += __shfl_xor(p[jj], off, 64);
    }
    if (lane == 0) {
        #pragma unroll
        for (int jj = 0; jj < NOUT; jj++)
            out[(size_t)n * NOUT + jj] = p[jj] + bout[jj];
    }
}

// ---------------------------------------------------------------------------
extern "C" void kernel_launch(void* const* d_in, const int* in_sizes, int n_in,
                              void* d_out, int out_size, void* d_ws, size_t ws_size,
                              hipStream_t stream) {
    const float* x      = (const float*)d_in[0];
    const int*   ei     = (const int*)d_in[1];
    const float* ea     = (const float*)d_in[2];
    const float* Win    = (const float*)d_in[3];
    const float* b_in   = (const float*)d_in[4];
    const float* Wg     = (const float*)d_in[5];
    const float* bg     = (const float*)d_in[6];
    const float* a_src  = (const float*)d_in[7];
    const float* a_dst  = (const float*)d_in[8];
    const float* We     = (const float*)d_in[9];
    const float* a_edge = (const float*)d_in[10];
    const float* ln_w   = (const float*)d_in[11];
    const float* ln_b   = (const float*)d_in[12];
    const float* Wout   = (const float*)d_in[13];
    const float* bout   = (const float*)d_in[14];
    float* out = (float*)d_out;

    char* w = (char*)d_ws;
    size_t off = 0;
    auto alloc = [&](size_t bytes) -> void* {
        void* p = w + off;
        off = (off + bytes + 255) & ~(size_t)255;
        return p;
    };
    int*   slot    = (int*)alloc((size_t)EE * sizeof(int));
    int*   cnt     = (int*)alloc(NN * sizeof(int));
    int*   rowptr  = (int*)alloc((NN + 1) * sizeof(int));
    int*   bsum    = (int*)alloc(NB_SCAN * sizeof(int));
    uint2* edges   = (uint2*)alloc((size_t)(EE + NN) * sizeof(uint2));
    u32*   h       = (u32*)alloc((size_t)NN * HQ * sizeof(u32));
    u32*   g       = (u32*)alloc((size_t)NN * HQ * sizeof(u32));
    u32*   xh      = (u32*)alloc((size_t)NN * HQ * sizeof(u32));
    float* al_s    = (float*)alloc((size_t)NN * NH * sizeof(float));
    float* al_d    = (float*)alloc((size_t)NN * NH * sizeof(float));
    float* wedot   = (float*)alloc(16 * sizeof(float));
    float* wf      = (float*)alloc(33 * HID * sizeof(float));
    u32*   wb      = (u32*)alloc((size_t)2 * WB_LSZ * sizeof(u32));
    float* partials = (float*)alloc(2048 * sizeof(float));
    float* stats   = (float*)alloc(16 * sizeof(float));
    (void)ws_size; (void)n_in; (void)in_sizes; (void)out_size;

    // --- prep (init + wedot + wfuse + pack) + CSR build ---
    prep_kernel<<<NB_INIT + 18 + 18, 256, 0, stream>>>(cnt, partials, We, a_edge, wedot,
                                                       Win, b_in, Wg, wf, a_src, a_dst, wb);
    hist_kernel<<<(EE + 255) / 256, 256, 0, stream>>>(ei, cnt, slot);
    scan1_kernel<<<NB_SCAN, 1024, 0, stream>>>(cnt, rowptr, bsum);
    scan2_kernel<<<1, 128, 0, stream>>>(bsum);
    scan3_kernel<<<NB_SCAN, 1024, 0, stream>>>(rowptr, bsum);
    scatter_kernel<<<(EE + 255) / 256, 256, 0, stream>>>(ei, ea, rowptr, slot, edges);
    selfloop_kernel<<<(NN + 255) / 256, 256, 0, stream>>>(rowptr, edges);

    const int ngrid = (NN + 63) / 64;
    in_gemm_kernel<<<ngrid, 256, 0, stream>>>(x, Win, b_in, wf, h, xh,
                                              a_src, a_dst, al_s, al_d);
    for (int l = 0; l < NL; l++) {
        if (l > 0) {
            gemm_mfma_kernel<<<ngrid, 256, 0, stream>>>(
                h, wb + (size_t)(l - 1) * WB_LSZ, xh, g,
                ln_w + (size_t)(l - 1) * HID, ln_b + (size_t)(l - 1) * HID, stats, h,
                al_s, al_d);
        }
        gat_agg_kernel<<<(NN + 15) / 16, 256, 0, stream>>>(
            rowptr, edges, xh, al_s, al_d, wedot + l * 4,
            bg + (size_t)l * HID, g, partials);
        stats_kernel<<<1, 1024, 0, stream>>>(partials, stats);
    }

    ln_out_kernel<<<(NN + 3) / 4, 256, 0, stream>>>(g, h, ln_w + (size_t)2 * HID,
                                                    ln_b + (size_t)2 * HID,
                                                    stats, Wout, bout, out);
}

// Round 10
// 402.637 us; speedup vs baseline: 2.6305x; 1.0363x over previous
//
#include <hip/hip_runtime.h>
#include <hip/hip_bf16.h>

#define NN 100000
#define EE 800000
#define HID 128
#define NH 4
#define CH 32
#define NL 3
#define NOUT 5
#define NEG_SLOPE 0.2f
#define LN_EPS 1e-5f
#define GCAP 96            // LDS-cached edges per 4-node wave group
#define NB_SCAN 98         // ceil((NN+1)/1024)
#define HQ (HID / 2)       // u32-packed bf16 pairs per row
#define WB_LSZ 9216        // u32 per layer of packed B-frags: 4ks*9ct*64lane*4
#define NB_INIT 391        // ceil(NN/256)

typedef unsigned int u32;
typedef __attribute__((ext_vector_type(8))) short bf16x8;
typedef __attribute__((ext_vector_type(4))) float f32x4;

static __device__ __forceinline__ float bflo(u32 r) { return __uint_as_float(r << 16); }
static __device__ __forceinline__ float bfhi(u32 r) { return __uint_as_float(r & 0xffff0000u); }
static __device__ __forceinline__ unsigned short f2bf(float x) {
    union U { __hip_bfloat16 b; unsigned short s; } u;
    u.b = __float2bfloat16(x);
    return u.s;
}
static __device__ __forceinline__ u32 pack2(float a, float b) {
    return (u32)f2bf(a) | ((u32)f2bf(b) << 16);
}
static __device__ __forceinline__ float lrelu(float x) {
    return x > 0.f ? x : NEG_SLOPE * x;
}

// ---------------------------------------------------------------------------
// prep: cnt/partials init + wedot + wfuse + pack (wga inline), one dispatch.
// ---------------------------------------------------------------------------
__global__ void prep_kernel(int* __restrict__ cnt, float* __restrict__ partials,
                            const float* __restrict__ We, const float* __restrict__ a_e,
                            float* __restrict__ wedot,
                            const float* __restrict__ Win, const float* __restrict__ b_in,
                            const float* __restrict__ Wg, float* __restrict__ wf,
                            const float* __restrict__ a_src, const float* __restrict__ a_dst,
                            u32* __restrict__ wb) {
    int b = blockIdx.x, t = threadIdx.x;
    if (b < NB_INIT) {
        int n = b * 256 + t;
        if (n < NN) cnt[n] = 1;
        if (n < 3 * 2048) partials[n] = 0.f;
        return;
    }
    if (b == NB_INIT) {
        if (t < NL * NH) {
            int l = t >> 2, hh = t & 3;
            float s = 0.f;
            #pragma unroll
            for (int c = 0; c < CH; c++)
                s += We[l * HID + hh * CH + c] * a_e[l * HID + hh * CH + c];
            wedot[t] = s;
        }
        return;
    }
    if (b < NB_INIT + 18) {
        // wfuse: wf[r][c] = sum_k (r<32 ? Win[r][k] : b_in[k]) * Wg0[k][c]
        int idx = (b - NB_INIT - 1) * 256 + t;
        if (idx >= 33 * HID) return;
        int r = idx >> 7, c = idx & 127;
        float acc = 0.f;
        for (int k = 0; k < HID; k++) {
            float a = (r < 32) ? Win[r * HID + k] : b_in[k];
            acc += a * Wg[(size_t)k * HID + c];
        }
        wf[r * HID + c] = acc;
        return;
    }
    // pack Wg[1..2] (+ head-masked al columns as 9th col-tile) into B-frags
    {
        int idx = (b - NB_INIT - 18) * 256 + t;   // 0..4607
        if (idx >= 2 * 2304) return;
        int l = idx / 2304;                  // 0 -> layer1, 1 -> layer2
        int rem = idx % 2304;
        int ks = rem / 576;
        int ct = (rem % 576) / 64;
        int lane = rem % 64;
        int q = lane >> 4, n = lane & 15;
        const float* W = Wg + (size_t)(l + 1) * HID * HID;
        float v[8];
        if (ct < 8) {
            #pragma unroll
            for (int j = 0; j < 8; j++) {
                int k = ks * 32 + q * 8 + j;
                v[j] = W[(size_t)k * HID + ct * 16 + n];
            }
        } else {
            #pragma unroll
            for (int j = 0; j < 8; j++) v[j] = 0.f;
            if (n < 8) {
                const float* a = (n < 4) ? (a_src + (l + 1) * HID + (n & 3) * CH)
                                         : (a_dst + (l + 1) * HID + (n & 3) * CH);
                #pragma unroll
                for (int j = 0; j < 8; j++) {
                    int k = ks * 32 + q * 8 + j;
                    const float* wrow = W + (size_t)k * HID + (n & 3) * CH;
                    float s = 0.f;
                    for (int c = 0; c < CH; c++) s += wrow[c] * a[c];
                    v[j] = s;
                }
            }
        }
        u32* dst = wb + (size_t)l * WB_LSZ + (size_t)((ks * 9 + ct) * 64 + lane) * 4;
        dst[0] = pack2(v[0], v[1]); dst[1] = pack2(v[2], v[3]);
        dst[2] = pack2(v[4], v[5]); dst[3] = pack2(v[6], v[7]);
    }
}

// ---------------------------------------------------------------------------
// CSR build. cnt[n] starts at 1 (self-loop reserved at row slot 0).
// slot packs (d<<8)|s: deg is Poisson(8), max ~30 << 256.
// ---------------------------------------------------------------------------
__global__ void hist_kernel(const int* __restrict__ ei, int* __restrict__ cnt,
                            u32* __restrict__ slot) {
    int e = blockIdx.x * blockDim.x + threadIdx.x;
    if (e >= EE) return;
    int d = ei[EE + e];
    int s = atomicAdd(&cnt[d], 1);
    slot[e] = ((u32)d << 8) | (u32)s;
}

__global__ __launch_bounds__(1024) void scan1_kernel(const int* __restrict__ cnt,
                                                     int* __restrict__ rowptr,
                                                     int* __restrict__ bsum) {
    __shared__ int ws[16];
    int gid = blockIdx.x * 1024 + threadIdx.x;
    int v = (gid < NN) ? cnt[gid] : 0;
    int lane = threadIdx.x & 63, wid = threadIdx.x >> 6;
    int s = v;
    #pragma unroll
    for (int off = 1; off < 64; off <<= 1) {
        int t = __shfl_up(s, off, 64);
        if (lane >= off) s += t;
    }
    if (lane == 63) ws[wid] = s;
    __syncthreads();
    int add = 0;
    for (int w2 = 0; w2 < wid; w2++) add += ws[w2];
    int incl = s + add;
    if (gid <= NN) rowptr[gid] = incl - v;   // exclusive
    if (threadIdx.x == 1023) bsum[blockIdx.x] = incl;
}

__global__ void scan2_kernel(int* __restrict__ bsum) {
    __shared__ int w0tot;
    int tid = threadIdx.x;                   // 128 threads
    int v = (tid < NB_SCAN) ? bsum[tid] : 0;
    int lane = tid & 63, wid = tid >> 6;
    int s = v;
    #pragma unroll
    for (int off = 1; off < 64; off <<= 1) {
        int t = __shfl_up(s, off, 64);
        if (lane >= off) s += t;
    }
    if (wid == 0 && lane == 63) w0tot = s;
    __syncthreads();
    int incl = s + (wid ? w0tot : 0);
    if (tid < NB_SCAN) bsum[tid] = incl - v; // exclusive
}

__global__ void scan3_kernel(int* __restrict__ rowptr, const int* __restrict__ bsum) {
    int gid = blockIdx.x * 1024 + threadIdx.x;
    if (gid <= NN) rowptr[gid] += bsum[blockIdx.x];
}

// packed edge record: {src, ea bits} -> ONE 8B random store per edge
__global__ void scatter_kernel(const int* __restrict__ ei, const float* __restrict__ ea,
                               const int* __restrict__ rowptr, const u32* __restrict__ slot,
                               uint2* __restrict__ edges) {
    int e = blockIdx.x * blockDim.x + threadIdx.x;
    if (e >= EE) return;
    u32 p = slot[e];
    int d = (int)(p >> 8);
    int pos = rowptr[d] + (int)(p & 255u);
    edges[pos] = make_uint2((u32)ei[e], __float_as_uint(ea[e]));
}

// self-loop attr = mean of the row's real-edge attrs (PyG fill_value='mean')
__global__ void selfloop_kernel(const int* __restrict__ rowptr, uint2* __restrict__ edges) {
    int n = blockIdx.x * blockDim.x + threadIdx.x;
    if (n >= NN) return;
    int rs = rowptr[n], re = rowptr[n + 1];
    float s = 0.f;
    for (int i = rs + 1; i < re; i++) s += __uint_as_float(edges[i].y);
    float m = s / fmaxf((float)(re - rs - 1), 1.0f);
    edges[rs] = make_uint2((u32)n, __float_as_uint(m));
}

// ---------------------------------------------------------------------------
// shared FMA-GEMM epilogue (layer 0): pack xh to bf16 + al dots via 8-lane reduce
// ---------------------------------------------------------------------------
static __device__ __forceinline__ void store_xh_al(
        float acc[8][4], int n0, int r0, int c0, int cg,
        u32* __restrict__ xh, const float* __restrict__ asl, const float* __restrict__ adl,
        float* __restrict__ al_s, float* __restrict__ al_d) {
    float4 as4 = *(const float4*)&asl[c0];
    float4 ad4 = *(const float4*)&adl[c0];
    int hh = cg >> 3;
    #pragma unroll
    for (int i = 0; i < 8; i++) {
        int row = n0 + r0 + i;
        if (row < NN) {
            u32 lo = pack2(acc[i][0], acc[i][1]);
            u32 hi = pack2(acc[i][2], acc[i][3]);
            *(uint2*)&xh[(size_t)row * HQ + (c0 >> 1)] = make_uint2(lo, hi);
        }
        float ps = acc[i][0] * as4.x + acc[i][1] * as4.y + acc[i][2] * as4.z + acc[i][3] * as4.w;
        float pd = acc[i][0] * ad4.x + acc[i][1] * ad4.y + acc[i][2] * ad4.z + acc[i][3] * ad4.w;
        ps += __shfl_xor(ps, 1, 64); pd += __shfl_xor(pd, 1, 64);
        ps += __shfl_xor(ps, 2, 64); pd += __shfl_xor(pd, 2, 64);
        ps += __shfl_xor(ps, 4, 64); pd += __shfl_xor(pd, 4, 64);
        if ((cg & 7) == 0 && row < NN) {
            al_s[row * 4 + hh] = ps;
            al_d[row * 4 + hh] = pd;
        }
    }
}

// ---------------------------------------------------------------------------
// Layer 0, algebraically fused: h = x@Win + b_in  AND  xh = x@Wf + bf.
// ---------------------------------------------------------------------------
__global__ __launch_bounds__(256) void in_gemm_kernel(
        const float* __restrict__ x, const float* __restrict__ Win,
        const float* __restrict__ b_in, const float* __restrict__ wf,
        u32* __restrict__ h, u32* __restrict__ xh,
        const float* __restrict__ a_src0, const float* __restrict__ a_dst0,
        float* __restrict__ al_s, float* __restrict__ al_d) {
    __shared__ float xs[64][36];
    __shared__ float ws[32][128];
    int n0 = blockIdx.x * 64;
    int t = threadIdx.x;
    int cg = t & 31, rg = t >> 5;
    int c0 = cg * 4, r0 = rg * 8;
    #pragma unroll
    for (int it = 0; it < 2; it++) {
        int idx = t + it * 256;
        int row = idx >> 3, kk = (idx & 7) * 4;
        float4 v = make_float4(0.f, 0.f, 0.f, 0.f);
        if (n0 + row < NN) v = *(const float4*)&x[(size_t)(n0 + row) * 32 + kk];
        *(float4*)&xs[row][kk] = v;
    }
    #pragma unroll
    for (int it = 0; it < 4; it++) {
        int idx = t + it * 256;
        int kr = idx >> 5, f4 = (idx & 31) * 4;
        *(float4*)&ws[kr][f4] = *(const float4*)&Win[kr * HID + f4];
    }
    __syncthreads();
    {
        float acc[8][4] = {};
        #pragma unroll 8
        for (int k = 0; k < 32; k++) {
            float4 b4 = *(const float4*)&ws[k][c0];
            #pragma unroll
            for (int i = 0; i < 8; i++) {
                float a = xs[r0 + i][k];
                acc[i][0] += a * b4.x; acc[i][1] += a * b4.y;
                acc[i][2] += a * b4.z; acc[i][3] += a * b4.w;
            }
        }
        float4 bi = *(const float4*)&b_in[c0];
        #pragma unroll
        for (int i = 0; i < 8; i++) {
            int row = n0 + r0 + i;
            if (row < NN) {
                u32 lo = pack2(acc[i][0] + bi.x, acc[i][1] + bi.y);
                u32 hi = pack2(acc[i][2] + bi.z, acc[i][3] + bi.w);
                *(uint2*)&h[(size_t)row * HQ + (c0 >> 1)] = make_uint2(lo, hi);
            }
        }
    }
    __syncthreads();
    #pragma unroll
    for (int it = 0; it < 4; it++) {
        int idx = t + it * 256;
        int kr = idx >> 5, f4 = (idx & 31) * 4;
        *(float4*)&ws[kr][f4] = *(const float4*)&wf[kr * HID + f4];
    }
    __syncthreads();
    float acc2[8][4] = {};
    #pragma unroll 8
    for (int k = 0; k < 32; k++) {
        float4 b4 = *(const float4*)&ws[k][c0];
        #pragma unroll
        for (int i = 0; i < 8; i++) {
            float a = xs[r0 + i][k];
            acc2[i][0] += a * b4.x; acc2[i][1] += a * b4.y;
            acc2[i][2] += a * b4.z; acc2[i][3] += a * b4.w;
        }
    }
    float4 bf4 = *(const float4*)&wf[32 * HID + c0];
    #pragma unroll
    for (int i = 0; i < 8; i++) {
        acc2[i][0] += bf4.x; acc2[i][1] += bf4.y; acc2[i][2] += bf4.z; acc2[i][3] += bf4.w;
    }
    store_xh_al(acc2, n0, r0, c0, cg, xh, a_src0, a_dst0, al_s, al_d);
}

// ---------------------------------------------------------------------------
// Layers 1..2 via MFMA; LN stats reduced inline from the previous layer's
// partials buffer (saves the single-block stats dispatch).
// ---------------------------------------------------------------------------
__global__ __launch_bounds__(256) void gemm_mfma_kernel(const u32* __restrict__ h,
        const u32* __restrict__ wb, u32* __restrict__ xh, const u32* __restrict__ g,
        const float* __restrict__ lnw, const float* __restrict__ lnb,
        const float* __restrict__ partials, u32* __restrict__ hout,
        float* __restrict__ al_s, float* __restrict__ al_d) {
    __shared__ u32 hsu[4096];                // 16KB, frag-ordered [rt][ks][lane][4]
    __shared__ float sred[8];
    int n0 = blockIdx.x * 64;
    int t = threadIdx.x;
    int wv = t >> 6, lane = t & 63;
    int q = lane >> 4, n16 = lane & 15;

    // inline LN-stats reduction: 2048 floats = 512 float4, 2 per thread
    {
        const float4* pp = (const float4*)partials;
        float4 v0 = pp[t * 2], v1 = pp[t * 2 + 1];
        float s = v0.x + v0.z + v1.x + v1.z;
        float qq = v0.y + v0.w + v1.y + v1.w;
        #pragma unroll
        for (int off = 1; off <= 32; off <<= 1) {
            s += __shfl_xor(s, off, 64);
            qq += __shfl_xor(qq, off, 64);
        }
        if (lane == 0) { sred[wv * 2] = s; sred[wv * 2 + 1] = qq; }
    }
    __syncthreads();
    float S = sred[0] + sred[2] + sred[4] + sred[6];
    float Q = sred[1] + sred[3] + sred[5] + sred[7];
    const float M = (float)NN * (float)HID;
    float mean = S / M;
    float rstd = rsqrtf(fmaxf(Q / M - mean * mean, 0.f) + LN_EPS);

    bf16x8 bfrag[2][4];
    #pragma unroll
    for (int ks = 0; ks < 4; ks++) {
        #pragma unroll
        for (int cc = 0; cc < 2; cc++) {
            int ct = wv * 2 + cc;
            uint4 r = *(const uint4*)&wb[(size_t)((ks * 9 + ct) * 64 + lane) * 4];
            bfrag[cc][ks] = __builtin_bit_cast(bf16x8, r);
        }
    }
    bf16x8 bal[4];
    #pragma unroll
    for (int ks = 0; ks < 4; ks++) {
        uint4 r = *(const uint4*)&wb[(size_t)((ks * 9 + 8) * 64 + lane) * 4];
        bal[ks] = __builtin_bit_cast(bf16x8, r);
    }

    {
        int row = t >> 2;
        int qq = t & 3;
        int gr = n0 + row;
        int rt = row >> 4, m = row & 15;
        #pragma unroll
        for (int ks = 0; ks < 4; ks++) {
            int kk = ks * 32 + qq * 8;
            uint4 op = make_uint4(0u, 0u, 0u, 0u);
            if (gr < NN) {
                size_t base = (size_t)gr * HQ + (kk >> 1);
                uint4 gp = *(const uint4*)&g[base];
                uint4 hp = *(const uint4*)&h[base];
                float4 wA = *(const float4*)&lnw[kk];
                float4 wB = *(const float4*)&lnw[kk + 4];
                float4 bA = *(const float4*)&lnb[kk];
                float4 bB = *(const float4*)&lnb[kk + 4];
                float v0 = fmaxf((bflo(gp.x) - mean) * rstd * wA.x + bA.x + bflo(hp.x), 0.f);
                float v1 = fmaxf((bfhi(gp.x) - mean) * rstd * wA.y + bA.y + bfhi(hp.x), 0.f);
                float v2 = fmaxf((bflo(gp.y) - mean) * rstd * wA.z + bA.z + bflo(hp.y), 0.f);
                float v3 = fmaxf((bfhi(gp.y) - mean) * rstd * wA.w + bA.w + bfhi(hp.y), 0.f);
                float v4 = fmaxf((bflo(gp.z) - mean) * rstd * wB.x + bB.x + bflo(hp.z), 0.f);
                float v5 = fmaxf((bfhi(gp.z) - mean) * rstd * wB.y + bB.y + bfhi(hp.z), 0.f);
                float v6 = fmaxf((bflo(gp.w) - mean) * rstd * wB.z + bB.z + bflo(hp.w), 0.f);
                float v7 = fmaxf((bfhi(gp.w) - mean) * rstd * wB.w + bB.w + bfhi(hp.w), 0.f);
                op.x = pack2(v0, v1); op.y = pack2(v2, v3);
                op.z = pack2(v4, v5); op.w = pack2(v6, v7);
                *(uint4*)&hout[base] = op;
            }
            *(uint4*)&hsu[((rt * 4 + ks) * 64 + qq * 16 + m) * 4] = op;
        }
    }
    __syncthreads();

    f32x4 acc[4][2];
    f32x4 accal[4];
    #pragma unroll
    for (int rt = 0; rt < 4; rt++) {
        acc[rt][0] = (f32x4){0.f, 0.f, 0.f, 0.f};
        acc[rt][1] = (f32x4){0.f, 0.f, 0.f, 0.f};
        accal[rt]  = (f32x4){0.f, 0.f, 0.f, 0.f};
    }
    #pragma unroll
    for (int rt = 0; rt < 4; rt++) {
        #pragma unroll
        for (int ks = 0; ks < 4; ks++) {
            uint4 araw = *(const uint4*)&hsu[((rt * 4 + ks) * 64 + lane) * 4];
            bf16x8 af = __builtin_bit_cast(bf16x8, araw);
            acc[rt][0] = __builtin_amdgcn_mfma_f32_16x16x32_bf16(af, bfrag[0][ks], acc[rt][0], 0, 0, 0);
            acc[rt][1] = __builtin_amdgcn_mfma_f32_16x16x32_bf16(af, bfrag[1][ks], acc[rt][1], 0, 0, 0);
            if (wv == 3)
                accal[rt] = __builtin_amdgcn_mfma_f32_16x16x32_bf16(af, bal[ks], accal[rt], 0, 0, 0);
        }
    }

    #pragma unroll
    for (int rt = 0; rt < 4; rt++) {
        #pragma unroll
        for (int reg = 0; reg < 4; reg++) {
            int row = n0 + rt * 16 + q * 4 + reg;
            #pragma unroll
            for (int cc = 0; cc < 2; cc++) {
                float v = acc[rt][cc][reg];
                float vp = __shfl_xor(v, 1, 64);
                if (!(n16 & 1) && row < NN) {
                    int colp = (wv * 2 + cc) * 8 + (n16 >> 1);
                    xh[(size_t)row * HQ + colp] = pack2(v, vp);
                }
            }
            if (wv == 3 && row < NN && n16 < 8) {
                float v = accal[rt][reg];
                if (n16 < 4) al_s[row * 4 + n16] = v;
                else         al_d[row * 4 + (n16 - 4)] = v;
            }
        }
    }
}

// ---------------------------------------------------------------------------
// GAT aggregation v4: one wave = 4 consecutive nodes; pass 2 unrolled 4x
// (4 uint4 gathers in flight per lane).
// ---------------------------------------------------------------------------
__global__ __launch_bounds__(256) void gat_agg_kernel(const int* __restrict__ rowptr,
        const uint2* __restrict__ edges, const u32* __restrict__ xh,
        const float* __restrict__ al_s, const float* __restrict__ al_d,
        const float* __restrict__ wedot, const float* __restrict__ bg,
        u32* __restrict__ g, float* __restrict__ partials) {
    __shared__ float lds_ex[4][GCAP * 4];
    __shared__ int lds_src[4][GCAP];
    int wv = threadIdx.x >> 6, lane = threadIdx.x & 63;
    int base = (blockIdx.x * 4 + wv) * 4;
    if (base >= NN) return;
    float* ex_w = lds_ex[wv];
    int* src_w = lds_src[wv];
    int b1 = base + 1 < NN ? base + 1 : NN;
    int b2 = base + 2 < NN ? base + 2 : NN;
    int b3 = base + 3 < NN ? base + 3 : NN;
    int b4 = base + 4 < NN ? base + 4 : NN;
    int r0 = rowptr[base], r1 = rowptr[b1], r2 = rowptr[b2], r3 = rowptr[b3], r4 = rowptr[b4];
    int span = r4 - r0;
    int ncached = span < GCAP ? span : GCAP;
    float wd0 = wedot[0], wd1 = wedot[1], wd2 = wedot[2], wd3 = wedot[3];

    // Pass 1: logits+exp for the whole 4-node span, lane-parallel
    for (int i = lane; i < ncached; i += 64) {
        int gi = r0 + i;
        uint2 e = edges[gi];
        int s = (int)e.x;
        float eav = __uint_as_float(e.y);
        int d = (gi >= r1) + (gi >= r2) + (gi >= r3);
        float4 aldv = *(const float4*)&al_d[(base + d) * 4];
        float4 als = *(const float4*)&al_s[s * 4];
        float e0 = __expf(lrelu(als.x + aldv.x + eav * wd0));
        float e1 = __expf(lrelu(als.y + aldv.y + eav * wd1));
        float e2 = __expf(lrelu(als.z + aldv.z + eav * wd2));
        float e3 = __expf(lrelu(als.w + aldv.w + eav * wd3));
        src_w[i] = s;
        *(float4*)&ex_w[i * 4] = make_float4(e0, e1, e2, e3);
    }
    // wave-private LDS rows; same-wave ops in order -> no barrier

    // Pass 2: 16 lanes per node, 8 channels each, 4x unrolled
    int nl = lane >> 4, cg = lane & 15;
    int n = base + nl;
    bool nvalid = n < NN;
    int ls = (nl == 0 ? r0 : nl == 1 ? r1 : nl == 2 ? r2 : r3) - r0;
    int le = (nl == 0 ? r1 : nl == 1 ? r2 : nl == 2 ? r3 : r4) - r0;
    int lec = le < ncached ? le : ncached;
    int head = cg >> 2;
    int c4 = cg * 4;                          // u32 offset of lane's 8 channels
    float a0 = 0.f, a1 = 0.f, a2 = 0.f, a3 = 0.f;
    float a4 = 0.f, a5 = 0.f, a6 = 0.f, a7 = 0.f, den = 0.f;
    int j = ls;
    for (; j + 3 < lec; j += 4) {             // 4 uint4 loads in flight
        int s0 = src_w[j], s1 = src_w[j + 1], s2 = src_w[j + 2], s3 = src_w[j + 3];
        float e0 = ex_w[j * 4 + head],       e1 = ex_w[(j + 1) * 4 + head];
        float e2 = ex_w[(j + 2) * 4 + head], e3 = ex_w[(j + 3) * 4 + head];
        uint4 x0 = *(const uint4*)&xh[(size_t)s0 * HQ + c4];
        uint4 x1 = *(const uint4*)&xh[(size_t)s1 * HQ + c4];
        uint4 x2 = *(const uint4*)&xh[(size_t)s2 * HQ + c4];
        uint4 x3 = *(const uint4*)&xh[(size_t)s3 * HQ + c4];
        den += e0 + e1 + e2 + e3;
        a0 += e0 * bflo(x0.x); a1 += e0 * bfhi(x0.x);
        a2 += e0 * bflo(x0.y); a3 += e0 * bfhi(x0.y);
        a4 += e0 * bflo(x0.z); a5 += e0 * bfhi(x0.z);
        a6 += e0 * bflo(x0.w); a7 += e0 * bfhi(x0.w);
        a0 += e1 * bflo(x1.x); a1 += e1 * bfhi(x1.x);
        a2 += e1 * bflo(x1.y); a3 += e1 * bfhi(x1.y);
        a4 += e1 * bflo(x1.z); a5 += e1 * bfhi(x1.z);
        a6 += e1 * bflo(x1.w); a7 += e1 * bfhi(x1.w);
        a0 += e2 * bflo(x2.x); a1 += e2 * bfhi(x2.x);
        a2 += e2 * bflo(x2.y); a3 += e2 * bfhi(x2.y);
        a4 += e2 * bflo(x2.z); a5 += e2 * bfhi(x2.z);
        a6 += e2 * bflo(x2.w); a7 += e2 * bfhi(x2.w);
        a0 += e3 * bflo(x3.x); a1 += e3 * bfhi(x3.x);
        a2 += e3 * bflo(x3.y); a3 += e3 * bfhi(x3.y);
        a4 += e3 * bflo(x3.z); a5 += e3 * bfhi(x3.z);
        a6 += e3 * bflo(x3.w); a7 += e3 * bfhi(x3.w);
    }
    for (; j < lec; j++) {
        int s0 = src_w[j];
        float e0 = ex_w[j * 4 + head];
        uint4 x0 = *(const uint4*)&xh[(size_t)s0 * HQ + c4];
        den += e0;
        a0 += e0 * bflo(x0.x); a1 += e0 * bfhi(x0.x);
        a2 += e0 * bflo(x0.y); a3 += e0 * bfhi(x0.y);
        a4 += e0 * bflo(x0.z); a5 += e0 * bfhi(x0.z);
        a6 += e0 * bflo(x0.w); a7 += e0 * bfhi(x0.w);
    }
    // tail beyond LDS cache (vanishingly rare): recompute logits for this head
    if (le > lec && nvalid) {
        float aldh = al_d[n * 4 + head];
        float wdh = wedot[head];
        for (int jt = (ls > lec ? ls : lec); jt < le; jt++) {
            uint2 e = edges[r0 + jt];
            int s = (int)e.x;
            float eav = __uint_as_float(e.y);
            float ex = __expf(lrelu(al_s[s * 4 + head] + aldh + eav * wdh));
            den += ex;
            uint4 x0 = *(const uint4*)&xh[(size_t)s * HQ + c4];
            a0 += ex * bflo(x0.x); a1 += ex * bfhi(x0.x);
            a2 += ex * bflo(x0.y); a3 += ex * bfhi(x0.y);
            a4 += ex * bflo(x0.z); a5 += ex * bfhi(x0.z);
            a6 += ex * bflo(x0.w); a7 += ex * bfhi(x0.w);
        }
    }

    float inv = 1.0f / (den + 1e-16f);
    int c0 = cg * 8;
    float4 bgA = *(const float4*)&bg[c0];
    float4 bgB = *(const float4*)&bg[c0 + 4];
    float o0 = a0 * inv + bgA.x, o1 = a1 * inv + bgA.y;
    float o2 = a2 * inv + bgA.z, o3 = a3 * inv + bgA.w;
    float o4 = a4 * inv + bgB.x, o5 = a5 * inv + bgB.y;
    float o6 = a6 * inv + bgB.z, o7 = a7 * inv + bgB.w;
    float ss = 0.f, sq = 0.f;
    if (nvalid) {
        uint4 op;
        op.x = pack2(o0, o1); op.y = pack2(o2, o3);
        op.z = pack2(o4, o5); op.w = pack2(o6, o7);
        *(uint4*)&g[(size_t)n * HQ + c4] = op;
        ss = o0 + o1 + o2 + o3 + o4 + o5 + o6 + o7;
        sq = o0 * o0 + o1 * o1 + o2 * o2 + o3 * o3
           + o4 * o4 + o5 * o5 + o6 * o6 + o7 * o7;
    }
    #pragma unroll
    for (int off = 1; off <= 32; off <<= 1) {
        ss += __shfl_xor(ss, off, 64);
        sq += __shfl_xor(sq, off, 64);
    }
    if (lane == 0) {
        int sl = ((blockIdx.x * 4 + wv) & 1023) * 2;
        atomicAdd(&partials[sl], ss);
        atomicAdd(&partials[sl + 1], sq);
    }
}

// reduce partials -> {mean, rstd} (final layer only; feeds ln_out)
__global__ void stats_kernel(const float* __restrict__ partials, float* __restrict__ stats) {
    __shared__ float ls[16], lq[16];
    int tid = threadIdx.x;
    float s = partials[tid * 2], q = partials[tid * 2 + 1];
    #pragma unroll
    for (int off = 32; off; off >>= 1) {
        s += __shfl_xor(s, off, 64);
        q += __shfl_xor(q, off, 64);
    }
    int lane = tid & 63, wid = tid >> 6;
    if (lane == 0) { ls[wid] = s; lq[wid] = q; }
    __syncthreads();
    if (tid == 0) {
        float S = 0.f, Q = 0.f;
        for (int w2 = 0; w2 < 16; w2++) { S += ls[w2]; Q += lq[w2]; }
        const float M = (float)NN * (float)HID;
        float mean = S / M;
        float var = Q / M - mean * mean;
        stats[0] = mean;
        stats[1] = rsqrtf(fmaxf(var, 0.f) + LN_EPS);
    }
}

// final: out = relu(LN(g)+h) @ Wout + bout.  16 lanes/node x 8ch, 4 nodes/wave.
__global__ __launch_bounds__(256) void ln_out_kernel(const u32* __restrict__ g,
        const u32* __restrict__ h, const float* __restrict__ lnw,
        const float* __restrict__ lnb, const float* __restrict__ stats,
        const float* __restrict__ Wout, const float* __restrict__ bout,
        float* __restrict__ out) {
    __shared__ float wsh[HID * NOUT];
    int t = threadIdx.x;
    for (int i = t; i < HID * NOUT; i += 256) wsh[i] = Wout[i];
    __syncthreads();
    int wv = t >> 6, lane = t & 63;
    int nl = lane >> 4, cg = lane & 15;
    int n = (blockIdx.x * 4 + wv) * 4 + nl;
    bool nvalid = n < NN;
    float mean = stats[0], rstd = stats[1];
    float p[NOUT] = {};
    if (nvalid) {
        int c0 = cg * 8;
        uint4 gv = *(const uint4*)&g[(size_t)n * HQ + cg * 4];
        uint4 hv = *(const uint4*)&h[(size_t)n * HQ + cg * 4];
        float4 wA = *(const float4*)&lnw[c0], wB = *(const float4*)&lnw[c0 + 4];
        float4 bA = *(const float4*)&lnb[c0], bB = *(const float4*)&lnb[c0 + 4];
        float o[8];
        o[0] = fmaxf((bflo(gv.x) - mean) * rstd * wA.x + bA.x + bflo(hv.x), 0.f);
        o[1] = fmaxf((bfhi(gv.x) - mean) * rstd * wA.y + bA.y + bfhi(hv.x), 0.f);
        o[2] = fmaxf((bflo(gv.y) - mean) * rstd * wA.z + bA.z + bflo(hv.y), 0.f);
        o[3] = fmaxf((bfhi(gv.y) - mean) * rstd * wA.w + bA.w + bfhi(hv.y), 0.f);
        o[4] = fmaxf((bflo(gv.z) - mean) * rstd * wB.x + bB.x + bflo(hv.z), 0.f);
        o[5] = fmaxf((bfhi(gv.z) - mean) * rstd * wB.y + bB.y + bfhi(hv.z), 0.f);
        o[6] = fmaxf((bflo(gv.w) - mean) * rstd * wB.z + bB.z + bflo(hv.w), 0.f);
        o[7] = fmaxf((bfhi(gv.w) - mean) * rstd * wB.w + bB.w + bfhi(hv.w), 0.f);
        #pragma unroll
        for (int jj = 0; jj < NOUT; jj++) {
            float acc = 0.f;
            #pragma unroll
            for (int k = 0; k < 8; k++) acc += o[k] * wsh[(c0 + k) * NOUT + jj];
            p[jj] = acc;
        }
    }
    #pragma unroll
    for (int off = 1; off <= 8; off <<= 1) {
        #pragma unroll
        for (int jj = 0; jj < NOUT; jj++) p[jj] += __shfl_xor(p[jj], off, 64);
    }
    if (cg == 0 && nvalid) {
        #pragma unroll
        for (int jj = 0; jj < NOUT; jj++)
            out[(size_t)n * NOUT + jj] = p[jj] + bout[jj];
    }
}

// ---------------------------------------------------------------------------
extern "C" void kernel_launch(void* const* d_in, const int* in_sizes, int n_in,
                              void* d_out, int out_size, void* d_ws, size_t ws_size,
                              hipStream_t stream) {
    const float* x      = (const float*)d_in[0];
    const int*   ei     = (const int*)d_in[1];
    const float* ea     = (const float*)d_in[2];
    const float* Win    = (const float*)d_in[3];
    const float* b_in   = (const float*)d_in[4];
    const float* Wg     = (const float*)d_in[5];
    const float* bg     = (const float*)d_in[6];
    const float* a_src  = (const float*)d_in[7];
    const float* a_dst  = (const float*)d_in[8];
    const float* We     = (const float*)d_in[9];
    const float* a_edge = (const float*)d_in[10];
    const float* ln_w   = (const float*)d_in[11];
    const float* ln_b   = (const float*)d_in[12];
    const float* Wout   = (const float*)d_in[13];
    const float* bout   = (const float*)d_in[14];
    float* out = (float*)d_out;

    char* w = (char*)d_ws;
    size_t off = 0;
    auto alloc = [&](size_t bytes) -> void* {
        void* p = w + off;
        off = (off + bytes + 255) & ~(size_t)255;
        return p;
    };
    u32*   slot    = (u32*)alloc((size_t)EE * sizeof(u32));
    int*   cnt     = (int*)alloc(NN * sizeof(int));
    int*   rowptr  = (int*)alloc((NN + 1) * sizeof(int));
    int*   bsum    = (int*)alloc(NB_SCAN * sizeof(int));
    uint2* edges   = (uint2*)alloc((size_t)(EE + NN) * sizeof(uint2));
    u32*   h       = (u32*)alloc((size_t)NN * HQ * sizeof(u32));
    u32*   g       = (u32*)alloc((size_t)NN * HQ * sizeof(u32));
    u32*   xh      = (u32*)alloc((size_t)NN * HQ * sizeof(u32));
    float* al_s    = (float*)alloc((size_t)NN * NH * sizeof(float));
    float* al_d    = (float*)alloc((size_t)NN * NH * sizeof(float));
    float* wedot   = (float*)alloc(16 * sizeof(float));
    float* wf      = (float*)alloc(33 * HID * sizeof(float));
    u32*   wb      = (u32*)alloc((size_t)2 * WB_LSZ * sizeof(u32));
    float* partials = (float*)alloc(3 * 2048 * sizeof(float));
    float* stats   = (float*)alloc(16 * sizeof(float));
    (void)ws_size; (void)n_in; (void)in_sizes; (void)out_size;

    // --- prep (init + wedot + wfuse + pack) + CSR build ---
    prep_kernel<<<NB_INIT + 18 + 18, 256, 0, stream>>>(cnt, partials, We, a_edge, wedot,
                                                       Win, b_in, Wg, wf, a_src, a_dst, wb);
    hist_kernel<<<(EE + 255) / 256, 256, 0, stream>>>(ei, cnt, slot);
    scan1_kernel<<<NB_SCAN, 1024, 0, stream>>>(cnt, rowptr, bsum);
    scan2_kernel<<<1, 128, 0, stream>>>(bsum);
    scan3_kernel<<<NB_SCAN, 1024, 0, stream>>>(rowptr, bsum);
    scatter_kernel<<<(EE + 255) / 256, 256, 0, stream>>>(ei, ea, rowptr, slot, edges);
    selfloop_kernel<<<(NN + 255) / 256, 256, 0, stream>>>(rowptr, edges);

    const int ngrid = (NN + 63) / 64;
    in_gemm_kernel<<<ngrid, 256, 0, stream>>>(x, Win, b_in, wf, h, xh,
                                              a_src, a_dst, al_s, al_d);
    for (int l = 0; l < NL; l++) {
        if (l > 0) {
            gemm_mfma_kernel<<<ngrid, 256, 0, stream>>>(
                h, wb + (size_t)(l - 1) * WB_LSZ, xh, g,
                ln_w + (size_t)(l - 1) * HID, ln_b + (size_t)(l - 1) * HID,
                partials + (size_t)(l - 1) * 2048, h, al_s, al_d);
        }
        gat_agg_kernel<<<(NN + 15) / 16, 256, 0, stream>>>(
            rowptr, edges, xh, al_s, al_d, wedot + l * 4,
            bg + (size_t)l * HID, g, partials + (size_t)l * 2048);
    }
    stats_kernel<<<1, 1024, 0, stream>>>(partials + 2 * 2048, stats);

    ln_out_kernel<<<(NN + 15) / 16, 256, 0, stream>>>(g, h, ln_w + (size_t)2 * HID,
                                                      ln_b + (size_t)2 * HID,
                                                      stats, Wout, bout, out);
}

// Round 11
// 400.897 us; speedup vs baseline: 2.6419x; 1.0043x over previous
//
#include <hip/hip_runtime.h>
#include <hip/hip_bf16.h>

#define NN 100000
#define EE 800000
#define HID 128
#define NH 4
#define CH 32
#define NL 3
#define NOUT 5
#define NEG_SLOPE 0.2f
#define LN_EPS 1e-5f
#define GCAP 64            // LDS-cached edges per 4-node wave group (real edges only)
#define NB_SCAN 98         // ceil((NN+1)/1024)
#define HQ (HID / 2)       // u32-packed bf16 pairs per row
#define WB_LSZ 9216        // u32 per layer of packed B-frags: 4ks*9ct*64lane*4
#define NB_INIT 391        // ceil(NN/256)

typedef unsigned int u32;
typedef __attribute__((ext_vector_type(8))) short bf16x8;
typedef __attribute__((ext_vector_type(4))) float f32x4;

static __device__ __forceinline__ float bflo(u32 r) { return __uint_as_float(r << 16); }
static __device__ __forceinline__ float bfhi(u32 r) { return __uint_as_float(r & 0xffff0000u); }
static __device__ __forceinline__ unsigned short f2bf(float x) {
    union U { __hip_bfloat16 b; unsigned short s; } u;
    u.b = __float2bfloat16(x);
    return u.s;
}
static __device__ __forceinline__ u32 pack2(float a, float b) {
    return (u32)f2bf(a) | ((u32)f2bf(b) << 16);
}
static __device__ __forceinline__ float lrelu(float x) {
    return x > 0.f ? x : NEG_SLOPE * x;
}

// ---------------------------------------------------------------------------
// prep: cnt/partials init + wedot + WgA0 + wfuse + pack (layers 1-2 B-frags).
// ---------------------------------------------------------------------------
__global__ void prep_kernel(int* __restrict__ cnt, float* __restrict__ partials,
                            const float* __restrict__ We, const float* __restrict__ a_e,
                            float* __restrict__ wedot,
                            const float* __restrict__ Win, const float* __restrict__ b_in,
                            const float* __restrict__ Wg, float* __restrict__ wf,
                            const float* __restrict__ a_src, const float* __restrict__ a_dst,
                            u32* __restrict__ wb, float* __restrict__ wga) {
    int b = blockIdx.x, t = threadIdx.x;
    if (b < NB_INIT) {
        int n = b * 256 + t;
        if (n < NN) cnt[n] = 0;              // self-loops are synthetic now
        if (n < 3 * 2048) partials[n] = 0.f;
        return;
    }
    if (b == NB_INIT) {
        if (t < NL * NH) {
            int l = t >> 2, hh = t & 3;
            float s = 0.f;
            #pragma unroll
            for (int c = 0; c < CH; c++)
                s += We[l * HID + hh * CH + c] * a_e[l * HID + hh * CH + c];
            wedot[t] = s;
        }
        // WgA0[m][j] = head-masked (Wg0 @ Aext): j<4 src head j, j>=4 dst head j-4
        for (int i = t; i < HID * 8; i += 256) {
            int m = i >> 3, j = i & 7;
            int hh = j & 3;
            const float* a = (j < 4) ? (a_src + hh * CH) : (a_dst + hh * CH);
            const float* wrow = Wg + (size_t)m * HID + hh * CH;
            float s = 0.f;
            #pragma unroll
            for (int c = 0; c < CH; c++) s += wrow[c] * a[c];
            wga[i] = s;
        }
        return;
    }
    if (b < NB_INIT + 18) {
        // wfuse: wf[r][c] = sum_k (r<32 ? Win[r][k] : b_in[k]) * Wg0[k][c]
        int idx = (b - NB_INIT - 1) * 256 + t;
        if (idx >= 33 * HID) return;
        int r = idx >> 7, c = idx & 127;
        float acc = 0.f;
        for (int k = 0; k < HID; k++) {
            float a = (r < 32) ? Win[r * HID + k] : b_in[k];
            acc += a * Wg[(size_t)k * HID + c];
        }
        wf[r * HID + c] = acc;
        return;
    }
    // pack Wg[1..2] (+ head-masked al columns as 9th col-tile) into B-frags
    {
        int idx = (b - NB_INIT - 18) * 256 + t;   // 0..4607
        if (idx >= 2 * 2304) return;
        int l = idx / 2304;                  // 0 -> layer1, 1 -> layer2
        int rem = idx % 2304;
        int ks = rem / 576;
        int ct = (rem % 576) / 64;
        int lane = rem % 64;
        int q = lane >> 4, n = lane & 15;
        const float* W = Wg + (size_t)(l + 1) * HID * HID;
        float v[8];
        if (ct < 8) {
            #pragma unroll
            for (int j = 0; j < 8; j++) {
                int k = ks * 32 + q * 8 + j;
                v[j] = W[(size_t)k * HID + ct * 16 + n];
            }
        } else {
            #pragma unroll
            for (int j = 0; j < 8; j++) v[j] = 0.f;
            if (n < 8) {
                const float* a = (n < 4) ? (a_src + (l + 1) * HID + (n & 3) * CH)
                                         : (a_dst + (l + 1) * HID + (n & 3) * CH);
                #pragma unroll
                for (int j = 0; j < 8; j++) {
                    int k = ks * 32 + q * 8 + j;
                    const float* wrow = W + (size_t)k * HID + (n & 3) * CH;
                    float s = 0.f;
                    for (int c = 0; c < CH; c++) s += wrow[c] * a[c];
                    v[j] = s;
                }
            }
        }
        u32* dst = wb + (size_t)l * WB_LSZ + (size_t)((ks * 9 + ct) * 64 + lane) * 4;
        dst[0] = pack2(v[0], v[1]); dst[1] = pack2(v[2], v[3]);
        dst[2] = pack2(v[4], v[5]); dst[3] = pack2(v[6], v[7]);
    }
}

// ---------------------------------------------------------------------------
// prep2: pack layer-0 B-frags (Win 8ct | Wf 8ct | al tile) + bfA (needs wf/wga).
// grid 18 x 64.
// ---------------------------------------------------------------------------
__global__ __launch_bounds__(64) void prep2_kernel(const float* __restrict__ Win,
        const float* __restrict__ b_in, const float* __restrict__ wga,
        float* __restrict__ wf, u32* __restrict__ wb2) {
    int b = blockIdx.x, lane = threadIdx.x;
    int q = lane >> 4, n = lane & 15;
    if (b == 17) {
        if (lane < 8) {
            float s = 0.f;
            for (int m = 0; m < HID; m++) s += b_in[m] * wga[m * 8 + lane];
            wf[33 * HID + lane] = s;         // bfA
        }
        return;
    }
    float v[8];
    if (b < 8) {
        #pragma unroll
        for (int j = 0; j < 8; j++) v[j] = Win[(q * 8 + j) * HID + b * 16 + n];
    } else if (b < 16) {
        int ct = b - 8;
        #pragma unroll
        for (int j = 0; j < 8; j++) v[j] = wf[(q * 8 + j) * HID + ct * 16 + n];
    } else {                                 // al tile: Win @ WgA0
        #pragma unroll
        for (int j = 0; j < 8; j++) v[j] = 0.f;
        if (n < 8) {
            #pragma unroll
            for (int j = 0; j < 8; j++) {
                const float* wrow = Win + (q * 8 + j) * HID;
                float s = 0.f;
                for (int m = 0; m < HID; m++) s += wrow[m] * wga[m * 8 + n];
                v[j] = s;
            }
        }
    }
    u32* dst = wb2 + (size_t)(b * 64 + lane) * 4;
    dst[0] = pack2(v[0], v[1]); dst[1] = pack2(v[2], v[3]);
    dst[2] = pack2(v[4], v[5]); dst[3] = pack2(v[6], v[7]);
}

// ---------------------------------------------------------------------------
// CSR build. slot packs (d<<8)|s: deg is Poisson(8), max << 256.
// ---------------------------------------------------------------------------
__global__ void hist_kernel(const int* __restrict__ ei, int* __restrict__ cnt,
                            u32* __restrict__ slot) {
    int e = blockIdx.x * blockDim.x + threadIdx.x;
    if (e >= EE) return;
    int d = ei[EE + e];
    int s = atomicAdd(&cnt[d], 1);
    slot[e] = ((u32)d << 8) | (u32)s;
}

__global__ __launch_bounds__(1024) void scan1_kernel(const int* __restrict__ cnt,
                                                     int* __restrict__ rowptr,
                                                     int* __restrict__ bsum) {
    __shared__ int ws[16];
    int gid = blockIdx.x * 1024 + threadIdx.x;
    int v = (gid < NN) ? cnt[gid] : 0;
    int lane = threadIdx.x & 63, wid = threadIdx.x >> 6;
    int s = v;
    #pragma unroll
    for (int off = 1; off < 64; off <<= 1) {
        int t = __shfl_up(s, off, 64);
        if (lane >= off) s += t;
    }
    if (lane == 63) ws[wid] = s;
    __syncthreads();
    int add = 0;
    for (int w2 = 0; w2 < wid; w2++) add += ws[w2];
    int incl = s + add;
    if (gid <= NN) rowptr[gid] = incl - v;   // exclusive
    if (threadIdx.x == 1023) bsum[blockIdx.x] = incl;
}

__global__ void scan2_kernel(int* __restrict__ bsum) {
    __shared__ int w0tot;
    int tid = threadIdx.x;                   // 128 threads
    int v = (tid < NB_SCAN) ? bsum[tid] : 0;
    int lane = tid & 63, wid = tid >> 6;
    int s = v;
    #pragma unroll
    for (int off = 1; off < 64; off <<= 1) {
        int t = __shfl_up(s, off, 64);
        if (lane >= off) s += t;
    }
    if (wid == 0 && lane == 63) w0tot = s;
    __syncthreads();
    int incl = s + (wid ? w0tot : 0);
    if (tid < NB_SCAN) bsum[tid] = incl - v; // exclusive
}

__global__ void scan3_kernel(int* __restrict__ rowptr, const int* __restrict__ bsum) {
    int gid = blockIdx.x * 1024 + threadIdx.x;
    if (gid <= NN) rowptr[gid] += bsum[blockIdx.x];
}

// packed edge record: {src, ea bits} -> ONE 8B random store per edge
__global__ void scatter_kernel(const int* __restrict__ ei, const float* __restrict__ ea,
                               const int* __restrict__ rowptr, const u32* __restrict__ slot,
                               uint2* __restrict__ edges) {
    int e = blockIdx.x * blockDim.x + threadIdx.x;
    if (e >= EE) return;
    u32 p = slot[e];
    int d = (int)(p >> 8);
    int pos = rowptr[d] + (int)(p & 255u);
    edges[pos] = make_uint2((u32)ei[e], __float_as_uint(ea[e]));
}

// ---------------------------------------------------------------------------
// Layer 0 via MFMA (K=32, one slab): h = x@Win + b_in, xh = x@Wf + bf,
// al via 9th tile (Win@WgA0) + bfA. x staged as bf16 A-frags (4KB LDS).
// ---------------------------------------------------------------------------
__global__ __launch_bounds__(256) void in_gemm_kernel(
        const float* __restrict__ x, const u32* __restrict__ wb2,
        const float* __restrict__ wf, const float* __restrict__ b_in,
        u32* __restrict__ h, u32* __restrict__ xh,
        float* __restrict__ al_s, float* __restrict__ al_d) {
    __shared__ u32 xsu[1024];                // 4 rt x 64 lane x 4 u32
    int t = threadIdx.x;
    int wv = t >> 6, lane = t & 63;
    int q = lane >> 4, n16 = lane & 15;
    int n0 = blockIdx.x * 64;
    // stage x -> bf16 A-frags
    {
        int row = t >> 2, qq = t & 3;
        int gr = n0 + row;
        int rt = row >> 4, m = row & 15;
        uint4 op = make_uint4(0u, 0u, 0u, 0u);
        if (gr < NN) {
            float4 vA = *(const float4*)&x[(size_t)gr * 32 + qq * 8];
            float4 vB = *(const float4*)&x[(size_t)gr * 32 + qq * 8 + 4];
            op.x = pack2(vA.x, vA.y); op.y = pack2(vA.z, vA.w);
            op.z = pack2(vB.x, vB.y); op.w = pack2(vB.z, vB.w);
        }
        *(uint4*)&xsu[(rt * 64 + qq * 16 + m) * 4] = op;
    }
    // B frags: wave w owns col-tiles 2w,2w+1 for both GEMMs; wave 3 also al
    bf16x8 bwin[2], bwf[2], bal;
    #pragma unroll
    for (int cc = 0; cc < 2; cc++) {
        uint4 r0 = *(const uint4*)&wb2[(size_t)(((wv * 2 + cc)) * 64 + lane) * 4];
        uint4 r1 = *(const uint4*)&wb2[(size_t)((8 + wv * 2 + cc) * 64 + lane) * 4];
        bwin[cc] = __builtin_bit_cast(bf16x8, r0);
        bwf[cc]  = __builtin_bit_cast(bf16x8, r1);
    }
    {
        uint4 r = *(const uint4*)&wb2[(size_t)(16 * 64 + lane) * 4];
        bal = __builtin_bit_cast(bf16x8, r);
    }
    __syncthreads();
    f32x4 acch[4][2], accx[4][2], accal[4];
    #pragma unroll
    for (int rt = 0; rt < 4; rt++) {
        acch[rt][0] = (f32x4){0.f, 0.f, 0.f, 0.f};
        acch[rt][1] = (f32x4){0.f, 0.f, 0.f, 0.f};
        accx[rt][0] = (f32x4){0.f, 0.f, 0.f, 0.f};
        accx[rt][1] = (f32x4){0.f, 0.f, 0.f, 0.f};
        accal[rt]   = (f32x4){0.f, 0.f, 0.f, 0.f};
    }
    #pragma unroll
    for (int rt = 0; rt < 4; rt++) {
        uint4 araw = *(const uint4*)&xsu[(rt * 64 + lane) * 4];
        bf16x8 af = __builtin_bit_cast(bf16x8, araw);
        acch[rt][0] = __builtin_amdgcn_mfma_f32_16x16x32_bf16(af, bwin[0], acch[rt][0], 0, 0, 0);
        acch[rt][1] = __builtin_amdgcn_mfma_f32_16x16x32_bf16(af, bwin[1], acch[rt][1], 0, 0, 0);
        accx[rt][0] = __builtin_amdgcn_mfma_f32_16x16x32_bf16(af, bwf[0], accx[rt][0], 0, 0, 0);
        accx[rt][1] = __builtin_amdgcn_mfma_f32_16x16x32_bf16(af, bwf[1], accx[rt][1], 0, 0, 0);
        if (wv == 3)
            accal[rt] = __builtin_amdgcn_mfma_f32_16x16x32_bf16(af, bal, accal[rt], 0, 0, 0);
    }
    // epilogue
    float bi[2], bfv[2];
    #pragma unroll
    for (int cc = 0; cc < 2; cc++) {
        int col = (wv * 2 + cc) * 16 + n16;
        bi[cc] = b_in[col];
        bfv[cc] = wf[32 * HID + col];
    }
    float bfa = (wv == 3 && n16 < 8) ? wf[33 * HID + n16] : 0.f;
    #pragma unroll
    for (int rt = 0; rt < 4; rt++) {
        #pragma unroll
        for (int reg = 0; reg < 4; reg++) {
            int row = n0 + rt * 16 + q * 4 + reg;
            #pragma unroll
            for (int cc = 0; cc < 2; cc++) {
                float v = acch[rt][cc][reg] + bi[cc];
                float vp = __shfl_xor(v, 1, 64);
                float u = accx[rt][cc][reg] + bfv[cc];
                float up = __shfl_xor(u, 1, 64);
                if (!(n16 & 1) && row < NN) {
                    int colp = (wv * 2 + cc) * 8 + (n16 >> 1);
                    h[(size_t)row * HQ + colp] = pack2(v, vp);
                    xh[(size_t)row * HQ + colp] = pack2(u, up);
                }
            }
            if (wv == 3 && row < NN && n16 < 8) {
                float v = accal[rt][reg] + bfa;
                if (n16 < 4) al_s[row * 4 + n16] = v;
                else         al_d[row * 4 + (n16 - 4)] = v;
            }
        }
    }
}

// ---------------------------------------------------------------------------
// Layers 1..2 via MFMA; LN stats reduced inline from the previous layer's
// partials buffer.
// ---------------------------------------------------------------------------
__global__ __launch_bounds__(256) void gemm_mfma_kernel(const u32* __restrict__ h,
        const u32* __restrict__ wb, u32* __restrict__ xh, const u32* __restrict__ g,
        const float* __restrict__ lnw, const float* __restrict__ lnb,
        const float* __restrict__ partials, u32* __restrict__ hout,
        float* __restrict__ al_s, float* __restrict__ al_d) {
    __shared__ u32 hsu[4096];                // 16KB, frag-ordered [rt][ks][lane][4]
    __shared__ float sred[8];
    int n0 = blockIdx.x * 64;
    int t = threadIdx.x;
    int wv = t >> 6, lane = t & 63;
    int q = lane >> 4, n16 = lane & 15;

    {
        const float4* pp = (const float4*)partials;
        float4 v0 = pp[t * 2], v1 = pp[t * 2 + 1];
        float s = v0.x + v0.z + v1.x + v1.z;
        float qq = v0.y + v0.w + v1.y + v1.w;
        #pragma unroll
        for (int off = 1; off <= 32; off <<= 1) {
            s += __shfl_xor(s, off, 64);
            qq += __shfl_xor(qq, off, 64);
        }
        if (lane == 0) { sred[wv * 2] = s; sred[wv * 2 + 1] = qq; }
    }
    __syncthreads();
    float S = sred[0] + sred[2] + sred[4] + sred[6];
    float Q = sred[1] + sred[3] + sred[5] + sred[7];
    const float M = (float)NN * (float)HID;
    float mean = S / M;
    float rstd = rsqrtf(fmaxf(Q / M - mean * mean, 0.f) + LN_EPS);

    bf16x8 bfrag[2][4];
    #pragma unroll
    for (int ks = 0; ks < 4; ks++) {
        #pragma unroll
        for (int cc = 0; cc < 2; cc++) {
            int ct = wv * 2 + cc;
            uint4 r = *(const uint4*)&wb[(size_t)((ks * 9 + ct) * 64 + lane) * 4];
            bfrag[cc][ks] = __builtin_bit_cast(bf16x8, r);
        }
    }
    bf16x8 bal[4];
    #pragma unroll
    for (int ks = 0; ks < 4; ks++) {
        uint4 r = *(const uint4*)&wb[(size_t)((ks * 9 + 8) * 64 + lane) * 4];
        bal[ks] = __builtin_bit_cast(bf16x8, r);
    }

    {
        int row = t >> 2;
        int qq = t & 3;
        int gr = n0 + row;
        int rt = row >> 4, m = row & 15;
        #pragma unroll
        for (int ks = 0; ks < 4; ks++) {
            int kk = ks * 32 + qq * 8;
            uint4 op = make_uint4(0u, 0u, 0u, 0u);
            if (gr < NN) {
                size_t base = (size_t)gr * HQ + (kk >> 1);
                uint4 gp = *(const uint4*)&g[base];
                uint4 hp = *(const uint4*)&h[base];
                float4 wA = *(const float4*)&lnw[kk];
                float4 wB = *(const float4*)&lnw[kk + 4];
                float4 bA = *(const float4*)&lnb[kk];
                float4 bB = *(const float4*)&lnb[kk + 4];
                float v0 = fmaxf((bflo(gp.x) - mean) * rstd * wA.x + bA.x + bflo(hp.x), 0.f);
                float v1 = fmaxf((bfhi(gp.x) - mean) * rstd * wA.y + bA.y + bfhi(hp.x), 0.f);
                float v2 = fmaxf((bflo(gp.y) - mean) * rstd * wA.z + bA.z + bflo(hp.y), 0.f);
                float v3 = fmaxf((bfhi(gp.y) - mean) * rstd * wA.w + bA.w + bfhi(hp.y), 0.f);
                float v4 = fmaxf((bflo(gp.z) - mean) * rstd * wB.x + bB.x + bflo(hp.z), 0.f);
                float v5 = fmaxf((bfhi(gp.z) - mean) * rstd * wB.y + bB.y + bfhi(hp.z), 0.f);
                float v6 = fmaxf((bflo(gp.w) - mean) * rstd * wB.z + bB.z + bflo(hp.w), 0.f);
                float v7 = fmaxf((bfhi(gp.w) - mean) * rstd * wB.w + bB.w + bfhi(hp.w), 0.f);
                op.x = pack2(v0, v1); op.y = pack2(v2, v3);
                op.z = pack2(v4, v5); op.w = pack2(v6, v7);
                *(uint4*)&hout[base] = op;
            }
            *(uint4*)&hsu[((rt * 4 + ks) * 64 + qq * 16 + m) * 4] = op;
        }
    }
    __syncthreads();

    f32x4 acc[4][2];
    f32x4 accal[4];
    #pragma unroll
    for (int rt = 0; rt < 4; rt++) {
        acc[rt][0] = (f32x4){0.f, 0.f, 0.f, 0.f};
        acc[rt][1] = (f32x4){0.f, 0.f, 0.f, 0.f};
        accal[rt]  = (f32x4){0.f, 0.f, 0.f, 0.f};
    }
    #pragma unroll
    for (int rt = 0; rt < 4; rt++) {
        #pragma unroll
        for (int ks = 0; ks < 4; ks++) {
            uint4 araw = *(const uint4*)&hsu[((rt * 4 + ks) * 64 + lane) * 4];
            bf16x8 af = __builtin_bit_cast(bf16x8, araw);
            acc[rt][0] = __builtin_amdgcn_mfma_f32_16x16x32_bf16(af, bfrag[0][ks], acc[rt][0], 0, 0, 0);
            acc[rt][1] = __builtin_amdgcn_mfma_f32_16x16x32_bf16(af, bfrag[1][ks], acc[rt][1], 0, 0, 0);
            if (wv == 3)
                accal[rt] = __builtin_amdgcn_mfma_f32_16x16x32_bf16(af, bal[ks], accal[rt], 0, 0, 0);
        }
    }

    #pragma unroll
    for (int rt = 0; rt < 4; rt++) {
        #pragma unroll
        for (int reg = 0; reg < 4; reg++) {
            int row = n0 + rt * 16 + q * 4 + reg;
            #pragma unroll
            for (int cc = 0; cc < 2; cc++) {
                float v = acc[rt][cc][reg];
                float vp = __shfl_xor(v, 1, 64);
                if (!(n16 & 1) && row < NN) {
                    int colp = (wv * 2 + cc) * 8 + (n16 >> 1);
                    xh[(size_t)row * HQ + colp] = pack2(v, vp);
                }
            }
            if (wv == 3 && row < NN && n16 < 8) {
                float v = accal[rt][reg];
                if (n16 < 4) al_s[row * 4 + n16] = v;
                else         al_d[row * 4 + (n16 - 4)] = v;
            }
        }
    }
}

// ---------------------------------------------------------------------------
// GAT aggregation v5: one wave = 4 consecutive nodes; self-loops synthetic
// (attr mean computed in-kernel; no selfloop pass, no self records in edges).
// ---------------------------------------------------------------------------
__global__ __launch_bounds__(256) void gat_agg_kernel(const int* __restrict__ rowptr,
        const uint2* __restrict__ edges, const u32* __restrict__ xh,
        const float* __restrict__ al_s, const float* __restrict__ al_d,
        const float* __restrict__ wedot, const float* __restrict__ bg,
        u32* __restrict__ g, float* __restrict__ partials) {
    __shared__ float lds_ex[4][GCAP * 4];
    __shared__ float lds_ea[4][GCAP];
    __shared__ int lds_src[4][GCAP];
    int wv = threadIdx.x >> 6, lane = threadIdx.x & 63;
    int base = (blockIdx.x * 4 + wv) * 4;
    if (base >= NN) return;
    float* ex_w = lds_ex[wv];
    float* ea_w = lds_ea[wv];
    int* src_w = lds_src[wv];
    int b1 = base + 1 < NN ? base + 1 : NN;
    int b2 = base + 2 < NN ? base + 2 : NN;
    int b3 = base + 3 < NN ? base + 3 : NN;
    int b4 = base + 4 < NN ? base + 4 : NN;
    int r0 = rowptr[base], r1 = rowptr[b1], r2 = rowptr[b2], r3 = rowptr[b3], r4 = rowptr[b4];
    int span = r4 - r0;
    int ncached = span < GCAP ? span : GCAP;
    float wd0 = wedot[0], wd1 = wedot[1], wd2 = wedot[2], wd3 = wedot[3];

    // Pass 1: logits+exp (+ea cache) for the whole 4-node span, lane-parallel
    for (int i = lane; i < ncached; i += 64) {
        int gi = r0 + i;
        uint2 e = edges[gi];
        int s = (int)e.x;
        float eav = __uint_as_float(e.y);
        int d = (gi >= r1) + (gi >= r2) + (gi >= r3);
        float4 aldv = *(const float4*)&al_d[(base + d) * 4];
        float4 als = *(const float4*)&al_s[s * 4];
        float e0 = __expf(lrelu(als.x + aldv.x + eav * wd0));
        float e1 = __expf(lrelu(als.y + aldv.y + eav * wd1));
        float e2 = __expf(lrelu(als.z + aldv.z + eav * wd2));
        float e3 = __expf(lrelu(als.w + aldv.w + eav * wd3));
        src_w[i] = s;
        ea_w[i] = eav;
        *(float4*)&ex_w[i * 4] = make_float4(e0, e1, e2, e3);
    }
    // wave-private LDS rows; same-wave ops in order -> no barrier

    // Pass 2: 16 lanes per node, 8 channels each, 4x unrolled
    int nl = lane >> 4, cg = lane & 15;
    int n = base + nl;
    bool nvalid = n < NN;
    int ls = (nl == 0 ? r0 : nl == 1 ? r1 : nl == 2 ? r2 : r3) - r0;
    int le = (nl == 0 ? r1 : nl == 1 ? r2 : nl == 2 ? r3 : r4) - r0;
    int lec = le < ncached ? le : ncached;
    int head = cg >> 2;
    int c4 = cg * 4;                          // u32 offset of lane's 8 channels
    float wdh = head == 0 ? wd0 : head == 1 ? wd1 : head == 2 ? wd2 : wd3;
    float a0 = 0.f, a1 = 0.f, a2 = 0.f, a3 = 0.f;
    float a4 = 0.f, a5 = 0.f, a6 = 0.f, a7 = 0.f, den = 0.f, easum = 0.f;
    int j = ls;
    for (; j + 3 < lec; j += 4) {             // 4 uint4 loads in flight
        int s0 = src_w[j], s1 = src_w[j + 1], s2 = src_w[j + 2], s3 = src_w[j + 3];
        float e0 = ex_w[j * 4 + head],       e1 = ex_w[(j + 1) * 4 + head];
        float e2 = ex_w[(j + 2) * 4 + head], e3 = ex_w[(j + 3) * 4 + head];
        uint4 x0 = *(const uint4*)&xh[(size_t)s0 * HQ + c4];
        uint4 x1 = *(const uint4*)&xh[(size_t)s1 * HQ + c4];
        uint4 x2 = *(const uint4*)&xh[(size_t)s2 * HQ + c4];
        uint4 x3 = *(const uint4*)&xh[(size_t)s3 * HQ + c4];
        den += e0 + e1 + e2 + e3;
        easum += ea_w[j] + ea_w[j + 1] + ea_w[j + 2] + ea_w[j + 3];
        a0 += e0 * bflo(x0.x); a1 += e0 * bfhi(x0.x);
        a2 += e0 * bflo(x0.y); a3 += e0 * bfhi(x0.y);
        a4 += e0 * bflo(x0.z); a5 += e0 * bfhi(x0.z);
        a6 += e0 * bflo(x0.w); a7 += e0 * bfhi(x0.w);
        a0 += e1 * bflo(x1.x); a1 += e1 * bfhi(x1.x);
        a2 += e1 * bflo(x1.y); a3 += e1 * bfhi(x1.y);
        a4 += e1 * bflo(x1.z); a5 += e1 * bfhi(x1.z);
        a6 += e1 * bflo(x1.w); a7 += e1 * bfhi(x1.w);
        a0 += e2 * bflo(x2.x); a1 += e2 * bfhi(x2.x);
        a2 += e2 * bflo(x2.y); a3 += e2 * bfhi(x2.y);
        a4 += e2 * bflo(x2.z); a5 += e2 * bfhi(x2.z);
        a6 += e2 * bflo(x2.w); a7 += e2 * bfhi(x2.w);
        a0 += e3 * bflo(x3.x); a1 += e3 * bfhi(x3.x);
        a2 += e3 * bflo(x3.y); a3 += e3 * bfhi(x3.y);
        a4 += e3 * bflo(x3.z); a5 += e3 * bfhi(x3.z);
        a6 += e3 * bflo(x3.w); a7 += e3 * bfhi(x3.w);
    }
    for (; j < lec; j++) {
        int s0 = src_w[j];
        float e0 = ex_w[j * 4 + head];
        uint4 x0 = *(const uint4*)&xh[(size_t)s0 * HQ + c4];
        den += e0;
        easum += ea_w[j];
        a0 += e0 * bflo(x0.x); a1 += e0 * bfhi(x0.x);
        a2 += e0 * bflo(x0.y); a3 += e0 * bfhi(x0.y);
        a4 += e0 * bflo(x0.z); a5 += e0 * bfhi(x0.z);
        a6 += e0 * bflo(x0.w); a7 += e0 * bfhi(x0.w);
    }
    // tail beyond LDS cache (vanishingly rare): recompute logits for this head
    if (le > lec && nvalid) {
        float aldh = al_d[n * 4 + head];
        for (int jt = (ls > lec ? ls : lec); jt < le; jt++) {
            uint2 e = edges[r0 + jt];
            int s = (int)e.x;
            float eav = __uint_as_float(e.y);
            float ex = __expf(lrelu(al_s[s * 4 + head] + aldh + eav * wdh));
            den += ex;
            easum += eav;
            uint4 x0 = *(const uint4*)&xh[(size_t)s * HQ + c4];
            a0 += ex * bflo(x0.x); a1 += ex * bfhi(x0.x);
            a2 += ex * bflo(x0.y); a3 += ex * bfhi(x0.y);
            a4 += ex * bflo(x0.z); a5 += ex * bfhi(x0.z);
            a6 += ex * bflo(x0.w); a7 += ex * bfhi(x0.w);
        }
    }
    // synthetic self-loop: attr = mean of real edge attrs (PyG fill='mean')
    if (nvalid) {
        float mea = easum / fmaxf((float)(le - ls), 1.0f);
        float alh = al_s[n * 4 + head] + al_d[n * 4 + head];
        float ex = __expf(lrelu(alh + mea * wdh));
        den += ex;
        uint4 x0 = *(const uint4*)&xh[(size_t)n * HQ + c4];
        a0 += ex * bflo(x0.x); a1 += ex * bfhi(x0.x);
        a2 += ex * bflo(x0.y); a3 += ex * bfhi(x0.y);
        a4 += ex * bflo(x0.z); a5 += ex * bfhi(x0.z);
        a6 += ex * bflo(x0.w); a7 += ex * bfhi(x0.w);
    }

    float inv = 1.0f / (den + 1e-16f);
    int c0 = cg * 8;
    float4 bgA = *(const float4*)&bg[c0];
    float4 bgB = *(const float4*)&bg[c0 + 4];
    float o0 = a0 * inv + bgA.x, o1 = a1 * inv + bgA.y;
    float o2 = a2 * inv + bgA.z, o3 = a3 * inv + bgA.w;
    float o4 = a4 * inv + bgB.x, o5 = a5 * inv + bgB.y;
    float o6 = a6 * inv + bgB.z, o7 = a7 * inv + bgB.w;
    float ss = 0.f, sq = 0.f;
    if (nvalid) {
        uint4 op;
        op.x = pack2(o0, o1); op.y = pack2(o2, o3);
        op.z = pack2(o4, o5); op.w = pack2(o6, o7);
        *(uint4*)&g[(size_t)n * HQ + c4] = op;
        ss = o0 + o1 + o2 + o3 + o4 + o5 + o6 + o7;
        sq = o0 * o0 + o1 * o1 + o2 * o2 + o3 * o3
           + o4 * o4 + o5 * o5 + o6 * o6 + o7 * o7;
    }
    #pragma unroll
    for (int off = 1; off <= 32; off <<= 1) {
        ss += __shfl_xor(ss, off, 64);
        sq += __shfl_xor(sq, off, 64);
    }
    if (lane == 0) {
        int sl = ((blockIdx.x * 4 + wv) & 1023) * 2;
        atomicAdd(&partials[sl], ss);
        atomicAdd(&partials[sl + 1], sq);
    }
}

// final: out = relu(LN(g)+h) @ Wout + bout.  LN stats reduced inline.
__global__ __launch_bounds__(256) void ln_out_kernel(const u32* __restrict__ g,
        const u32* __restrict__ h, const float* __restrict__ lnw,
        const float* __restrict__ lnb, const float* __restrict__ partials,
        const float* __restrict__ Wout, const float* __restrict__ bout,
        float* __restrict__ out) {
    __shared__ float wsh[HID * NOUT];
    __shared__ float sred[8];
    int t = threadIdx.x;
    int wv = t >> 6, lane = t & 63;
    {
        const float4* pp = (const float4*)partials;
        float4 v0 = pp[t * 2], v1 = pp[t * 2 + 1];
        float s = v0.x + v0.z + v1.x + v1.z;
        float qq = v0.y + v0.w + v1.y + v1.w;
        #pragma unroll
        for (int off = 1; off <= 32; off <<= 1) {
            s += __shfl_xor(s, off, 64);
            qq += __shfl_xor(qq, off, 64);
        }
        if (lane == 0) { sred[wv * 2] = s; sred[wv * 2 + 1] = qq; }
    }
    for (int i = t; i < HID * NOUT; i += 256) wsh[i] = Wout[i];
    __syncthreads();
    float S = sred[0] + sred[2] + sred[4] + sred[6];
    float Q = sred[1] + sred[3] + sred[5] + sred[7];
    const float M = (float)NN * (float)HID;
    float mean = S / M;
    float rstd = rsqrtf(fmaxf(Q / M - mean * mean, 0.f) + LN_EPS);

    int nl = lane >> 4, cg = lane & 15;
    int n = (blockIdx.x * 4 + wv) * 4 + nl;
    bool nvalid = n < NN;
    float p[NOUT] = {};
    if (nvalid) {
        int c0 = cg * 8;
        uint4 gv = *(const uint4*)&g[(size_t)n * HQ + cg * 4];
        uint4 hv = *(const uint4*)&h[(size_t)n * HQ + cg * 4];
        float4 wA = *(const float4*)&lnw[c0], wB = *(const float4*)&lnw[c0 + 4];
        float4 bA = *(const float4*)&lnb[c0], bB = *(const float4*)&lnb[c0 + 4];
        float o[8];
        o[0] = fmaxf((bflo(gv.x) - mean) * rstd * wA.x + bA.x + bflo(hv.x), 0.f);
        o[1] = fmaxf((bfhi(gv.x) - mean) * rstd * wA.y + bA.y + bfhi(hv.x), 0.f);
        o[2] = fmaxf((bflo(gv.y) - mean) * rstd * wA.z + bA.z + bflo(hv.y), 0.f);
        o[3] = fmaxf((bfhi(gv.y) - mean) * rstd * wA.w + bA.w + bfhi(hv.y), 0.f);
        o[4] = fmaxf((bflo(gv.z) - mean) * rstd * wB.x + bB.x + bflo(hv.z), 0.f);
        o[5] = fmaxf((bfhi(gv.z) - mean) * rstd * wB.y + bB.y + bfhi(hv.z), 0.f);
        o[6] = fmaxf((bflo(gv.w) - mean) * rstd * wB.z + bB.z + bflo(hv.w), 0.f);
        o[7] = fmaxf((bfhi(gv.w) - mean) * rstd * wB.w + bB.w + bfhi(hv.w), 0.f);
        #pragma unroll
        for (int jj = 0; jj < NOUT; jj++) {
            float acc = 0.f;
            #pragma unroll
            for (int k = 0; k < 8; k++) acc += o[k] * wsh[(c0 + k) * NOUT + jj];
            p[jj] = acc;
        }
    }
    #pragma unroll
    for (int off = 1; off <= 8; off <<= 1) {
        #pragma unroll
        for (int jj = 0; jj < NOUT; jj++) p[jj] += __shfl_xor(p[jj], off, 64);
    }
    if (cg == 0 && nvalid) {
        #pragma unroll
        for (int jj = 0; jj < NOUT; jj++)
            out[(size_t)n * NOUT + jj] = p[jj] + bout[jj];
    }
}

// ---------------------------------------------------------------------------
extern "C" void kernel_launch(void* const* d_in, const int* in_sizes, int n_in,
                              void* d_out, int out_size, void* d_ws, size_t ws_size,
                              hipStream_t stream) {
    const float* x      = (const float*)d_in[0];
    const int*   ei     = (const int*)d_in[1];
    const float* ea     = (const float*)d_in[2];
    const float* Win    = (const float*)d_in[3];
    const float* b_in   = (const float*)d_in[4];
    const float* Wg     = (const float*)d_in[5];
    const float* bg     = (const float*)d_in[6];
    const float* a_src  = (const float*)d_in[7];
    const float* a_dst  = (const float*)d_in[8];
    const float* We     = (const float*)d_in[9];
    const float* a_edge = (const float*)d_in[10];
    const float* ln_w   = (const float*)d_in[11];
    const float* ln_b   = (const float*)d_in[12];
    const float* Wout   = (const float*)d_in[13];
    const float* bout   = (const float*)d_in[14];
    float* out = (float*)d_out;

    char* w = (char*)d_ws;
    size_t off = 0;
    auto alloc = [&](size_t bytes) -> void* {
        void* p = w + off;
        off = (off + bytes + 255) & ~(size_t)255;
        return p;
    };
    u32*   slot    = (u32*)alloc((size_t)EE * sizeof(u32));
    int*   cnt     = (int*)alloc(NN * sizeof(int));
    int*   rowptr  = (int*)alloc((NN + 1) * sizeof(int));
    int*   bsum    = (int*)alloc(NB_SCAN * sizeof(int));
    uint2* edges   = (uint2*)alloc((size_t)EE * sizeof(uint2));
    u32*   h       = (u32*)alloc((size_t)NN * HQ * sizeof(u32));
    u32*   g       = (u32*)alloc((size_t)NN * HQ * sizeof(u32));
    u32*   xh      = (u32*)alloc((size_t)NN * HQ * sizeof(u32));
    float* al_s    = (float*)alloc((size_t)NN * NH * sizeof(float));
    float* al_d    = (float*)alloc((size_t)NN * NH * sizeof(float));
    float* wedot   = (float*)alloc(16 * sizeof(float));
    float* wf      = (float*)alloc(34 * HID * sizeof(float));
    float* wga     = (float*)alloc(HID * 8 * sizeof(float));
    u32*   wb      = (u32*)alloc((size_t)2 * WB_LSZ * sizeof(u32));
    u32*   wb2     = (u32*)alloc(17 * 64 * 4 * sizeof(u32));
    float* partials = (float*)alloc(3 * 2048 * sizeof(float));
    (void)ws_size; (void)n_in; (void)in_sizes; (void)out_size;

    // --- prep + CSR build ---
    prep_kernel<<<NB_INIT + 18 + 18, 256, 0, stream>>>(cnt, partials, We, a_edge, wedot,
                                                       Win, b_in, Wg, wf, a_src, a_dst,
                                                       wb, wga);
    prep2_kernel<<<18, 64, 0, stream>>>(Win, b_in, wga, wf, wb2);
    hist_kernel<<<(EE + 255) / 256, 256, 0, stream>>>(ei, cnt, slot);
    scan1_kernel<<<NB_SCAN, 1024, 0, stream>>>(cnt, rowptr, bsum);
    scan2_kernel<<<1, 128, 0, stream>>>(bsum);
    scan3_kernel<<<NB_SCAN, 1024, 0, stream>>>(rowptr, bsum);
    scatter_kernel<<<(EE + 255) / 256, 256, 0, stream>>>(ei, ea, rowptr, slot, edges);

    const int ngrid = (NN + 63) / 64;
    in_gemm_kernel<<<ngrid, 256, 0, stream>>>(x, wb2, wf, b_in, h, xh, al_s, al_d);
    for (int l = 0; l < NL; l++) {
        if (l > 0) {
            gemm_mfma_kernel<<<ngrid, 256, 0, stream>>>(
                h, wb + (size_t)(l - 1) * WB_LSZ, xh, g,
                ln_w + (size_t)(l - 1) * HID, ln_b + (size_t)(l - 1) * HID,
                partials + (size_t)(l - 1) * 2048, h, al_s, al_d);
        }
        gat_agg_kernel<<<(NN + 15) / 16, 256, 0, stream>>>(
            rowptr, edges, xh, al_s, al_d, wedot + l * 4,
            bg + (size_t)l * HID, g, partials + (size_t)l * 2048);
    }

    ln_out_kernel<<<(NN + 15) / 16, 256, 0, stream>>>(g, h, ln_w + (size_t)2 * HID,
                                                      ln_b + (size_t)2 * HID,
                                                      partials + 2 * 2048, Wout, bout, out);
}

// Round 12
// 394.500 us; speedup vs baseline: 2.6847x; 1.0162x over previous
//
#include <hip/hip_runtime.h>
#include <hip/hip_bf16.h>

#define NN 100000
#define EE 800000
#define HID 128
#define NH 4
#define CH 32
#define NL 3
#define NOUT 5
#define NEG_SLOPE 0.2f
#define LN_EPS 1e-5f
#define GCAP 64            // LDS-cached edges per 4-node wave group (real edges only)
#define NB_SCAN 98         // ceil((NN+1)/1024)
#define HQ (HID / 2)       // u32-packed bf16 pairs per row
#define WB_LSZ 9216        // u32 per layer of packed B-frags: 4ks*9ct*64lane*4
#define HB 3125            // hist blocks = EE/256
#define NG64 1563          // in_gemm blocks = ceil(NN/64)

typedef unsigned int u32;
typedef __attribute__((ext_vector_type(8))) short bf16x8;
typedef __attribute__((ext_vector_type(4))) float f32x4;

static __device__ __forceinline__ float bflo(u32 r) { return __uint_as_float(r << 16); }
static __device__ __forceinline__ float bfhi(u32 r) { return __uint_as_float(r & 0xffff0000u); }
static __device__ __forceinline__ unsigned short f2bf(float x) {
    union U { __hip_bfloat16 b; unsigned short s; } u;
    u.b = __float2bfloat16(x);
    return u.s;
}
static __device__ __forceinline__ u32 pack2(float a, float b) {
    return (u32)f2bf(a) | ((u32)f2bf(b) << 16);
}
static __device__ __forceinline__ float lrelu(float x) {
    return x > 0.f ? x : NEG_SLOPE * x;
}

// ---------------------------------------------------------------------------
// Fused dispatch A: hist (blocks 0..HB-1) || weight prep (36 blocks).
// hist: one atomic per edge; slot packs (d<<8)|s (deg << 256).
// ---------------------------------------------------------------------------
__global__ void hist_prep_kernel(const int* __restrict__ ei, int* __restrict__ cnt,
                                 u32* __restrict__ slot,
                                 const float* __restrict__ We, const float* __restrict__ a_e,
                                 float* __restrict__ wedot,
                                 const float* __restrict__ Win, const float* __restrict__ b_in,
                                 const float* __restrict__ Wg, float* __restrict__ wf,
                                 const float* __restrict__ a_src, const float* __restrict__ a_dst,
                                 u32* __restrict__ wb, float* __restrict__ wga) {
    int b = blockIdx.x, t = threadIdx.x;
    if (b < HB) {
        int e = b * 256 + t;
        if (e >= EE) return;
        int d = ei[EE + e];
        int s = atomicAdd(&cnt[d], 1);
        slot[e] = ((u32)d << 8) | (u32)s;
        return;
    }
    if (b == HB) {
        if (t < NL * NH) {
            int l = t >> 2, hh = t & 3;
            float s = 0.f;
            #pragma unroll
            for (int c = 0; c < CH; c++)
                s += We[l * HID + hh * CH + c] * a_e[l * HID + hh * CH + c];
            wedot[t] = s;
        }
        // WgA0[m][j] = head-masked (Wg0 @ Aext): j<4 src head j, j>=4 dst head j-4
        for (int i = t; i < HID * 8; i += 256) {
            int m = i >> 3, j = i & 7;
            int hh = j & 3;
            const float* a = (j < 4) ? (a_src + hh * CH) : (a_dst + hh * CH);
            const float* wrow = Wg + (size_t)m * HID + hh * CH;
            float s = 0.f;
            #pragma unroll
            for (int c = 0; c < CH; c++) s += wrow[c] * a[c];
            wga[i] = s;
        }
        return;
    }
    if (b < HB + 18) {
        // wfuse: wf[r][c] = sum_k (r<32 ? Win[r][k] : b_in[k]) * Wg0[k][c]
        int idx = (b - HB - 1) * 256 + t;
        if (idx >= 33 * HID) return;
        int r = idx >> 7, c = idx & 127;
        float acc = 0.f;
        for (int k = 0; k < HID; k++) {
            float a = (r < 32) ? Win[r * HID + k] : b_in[k];
            acc += a * Wg[(size_t)k * HID + c];
        }
        wf[r * HID + c] = acc;
        return;
    }
    // pack Wg[1..2] (+ head-masked al columns as 9th col-tile) into B-frags
    {
        int idx = (b - HB - 18) * 256 + t;   // 0..4607
        if (idx >= 2 * 2304) return;
        int l = idx / 2304;
        int rem = idx % 2304;
        int ks = rem / 576;
        int ct = (rem % 576) / 64;
        int lane = rem % 64;
        int q = lane >> 4, n = lane & 15;
        const float* W = Wg + (size_t)(l + 1) * HID * HID;
        float v[8];
        if (ct < 8) {
            #pragma unroll
            for (int j = 0; j < 8; j++) {
                int k = ks * 32 + q * 8 + j;
                v[j] = W[(size_t)k * HID + ct * 16 + n];
            }
        } else {
            #pragma unroll
            for (int j = 0; j < 8; j++) v[j] = 0.f;
            if (n < 8) {
                const float* a = (n < 4) ? (a_src + (l + 1) * HID + (n & 3) * CH)
                                         : (a_dst + (l + 1) * HID + (n & 3) * CH);
                #pragma unroll
                for (int j = 0; j < 8; j++) {
                    int k = ks * 32 + q * 8 + j;
                    const float* wrow = W + (size_t)k * HID + (n & 3) * CH;
                    float s = 0.f;
                    for (int c = 0; c < CH; c++) s += wrow[c] * a[c];
                    v[j] = s;
                }
            }
        }
        u32* dst = wb + (size_t)l * WB_LSZ + (size_t)((ks * 9 + ct) * 64 + lane) * 4;
        dst[0] = pack2(v[0], v[1]); dst[1] = pack2(v[2], v[3]);
        dst[2] = pack2(v[4], v[5]); dst[3] = pack2(v[6], v[7]);
    }
}

__global__ __launch_bounds__(1024) void scan1_kernel(const int* __restrict__ cnt,
                                                     int* __restrict__ rowptr,
                                                     int* __restrict__ bsum) {
    __shared__ int ws[16];
    int gid = blockIdx.x * 1024 + threadIdx.x;
    int v = (gid < NN) ? cnt[gid] : 0;
    int lane = threadIdx.x & 63, wid = threadIdx.x >> 6;
    int s = v;
    #pragma unroll
    for (int off = 1; off < 64; off <<= 1) {
        int t = __shfl_up(s, off, 64);
        if (lane >= off) s += t;
    }
    if (lane == 63) ws[wid] = s;
    __syncthreads();
    int add = 0;
    for (int w2 = 0; w2 < wid; w2++) add += ws[w2];
    int incl = s + add;
    if (gid <= NN) rowptr[gid] = incl - v;   // exclusive
    if (threadIdx.x == 1023) bsum[blockIdx.x] = incl;
}

// Fused dispatch C: block 0 = scan2 (128 threads); blocks 1..18 = prep2
// (layer-0 B-frags: Win 8ct | Wf 8ct | al tile | bfA).
__global__ void scan2_prep2_kernel(int* __restrict__ bsum,
                                   const float* __restrict__ Win,
                                   const float* __restrict__ b_in,
                                   const float* __restrict__ wga,
                                   float* __restrict__ wf, u32* __restrict__ wb2) {
    if (blockIdx.x == 0) {
        __shared__ int w0tot_s;
        int tid = threadIdx.x;               // 128 threads
        int v = (tid < NB_SCAN) ? bsum[tid] : 0;
        int lane = tid & 63, wid = tid >> 6;
        int s = v;
        #pragma unroll
        for (int off = 1; off < 64; off <<= 1) {
            int t = __shfl_up(s, off, 64);
            if (lane >= off) s += t;
        }
        if (wid == 0 && lane == 63) w0tot_s = s;
        __syncthreads();
        int incl = s + (wid ? w0tot_s : 0);
        if (tid < NB_SCAN) bsum[tid] = incl - v; // exclusive
        return;
    }
    int b = blockIdx.x - 1;                  // 0..17
    int lane = threadIdx.x;
    if (lane >= 64) return;
    int q = lane >> 4, n = lane & 15;
    if (b == 17) {
        if (lane < 8) {
            float s = 0.f;
            for (int m = 0; m < HID; m++) s += b_in[m] * wga[m * 8 + lane];
            wf[33 * HID + lane] = s;         // bfA
        }
        return;
    }
    float v[8];
    if (b < 8) {
        #pragma unroll
        for (int j = 0; j < 8; j++) v[j] = Win[(q * 8 + j) * HID + b * 16 + n];
    } else if (b < 16) {
        int ct = b - 8;
        #pragma unroll
        for (int j = 0; j < 8; j++) v[j] = wf[(q * 8 + j) * HID + ct * 16 + n];
    } else {                                 // al tile: Win @ WgA0
        #pragma unroll
        for (int j = 0; j < 8; j++) v[j] = 0.f;
        if (n < 8) {
            #pragma unroll
            for (int j = 0; j < 8; j++) {
                const float* wrow = Win + (q * 8 + j) * HID;
                float s = 0.f;
                for (int m = 0; m < HID; m++) s += wrow[m] * wga[m * 8 + n];
                v[j] = s;
            }
        }
    }
    u32* dst = wb2 + (size_t)(b * 64 + lane) * 4;
    dst[0] = pack2(v[0], v[1]); dst[1] = pack2(v[2], v[3]);
    dst[2] = pack2(v[4], v[5]); dst[3] = pack2(v[6], v[7]);
}

__global__ void scan3_kernel(int* __restrict__ rowptr, const int* __restrict__ bsum) {
    int gid = blockIdx.x * 1024 + threadIdx.x;
    if (gid <= NN) rowptr[gid] += bsum[blockIdx.x];
}

// ---------------------------------------------------------------------------
// Fused dispatch E: scatter (blocks 0..HB-1) || layer-0 MFMA GEMM (NG64 blocks).
// scatter: one 8B random store per edge. in_gemm: h = x@Win + b_in,
// xh = x@Wf + bf, al via 9th tile; x staged as bf16 A-frags.
// ---------------------------------------------------------------------------
__global__ __launch_bounds__(256) void scatter_ingemm_kernel(
        const int* __restrict__ ei, const float* __restrict__ ea,
        const int* __restrict__ rowptr, const u32* __restrict__ slot,
        uint2* __restrict__ edges,
        const float* __restrict__ x, const u32* __restrict__ wb2,
        const float* __restrict__ wf, const float* __restrict__ b_in,
        u32* __restrict__ h, u32* __restrict__ xh,
        float* __restrict__ al_s, float* __restrict__ al_d) {
    __shared__ u32 xsu[1024];                // used by the in_gemm branch only
    if (blockIdx.x < HB) {
        int e = blockIdx.x * 256 + threadIdx.x;
        if (e >= EE) return;
        u32 p = slot[e];
        int d = (int)(p >> 8);
        int pos = rowptr[d] + (int)(p & 255u);
        edges[pos] = make_uint2((u32)ei[e], __float_as_uint(ea[e]));
        return;
    }
    int t = threadIdx.x;
    int wv = t >> 6, lane = t & 63;
    int q = lane >> 4, n16 = lane & 15;
    int n0 = (blockIdx.x - HB) * 64;
    // stage x -> bf16 A-frags
    {
        int row = t >> 2, qq = t & 3;
        int gr = n0 + row;
        int rt = row >> 4, m = row & 15;
        uint4 op = make_uint4(0u, 0u, 0u, 0u);
        if (gr < NN) {
            float4 vA = *(const float4*)&x[(size_t)gr * 32 + qq * 8];
            float4 vB = *(const float4*)&x[(size_t)gr * 32 + qq * 8 + 4];
            op.x = pack2(vA.x, vA.y); op.y = pack2(vA.z, vA.w);
            op.z = pack2(vB.x, vB.y); op.w = pack2(vB.z, vB.w);
        }
        *(uint4*)&xsu[(rt * 64 + qq * 16 + m) * 4] = op;
    }
    bf16x8 bwin[2], bwf[2], bal;
    #pragma unroll
    for (int cc = 0; cc < 2; cc++) {
        uint4 r0 = *(const uint4*)&wb2[(size_t)(((wv * 2 + cc)) * 64 + lane) * 4];
        uint4 r1 = *(const uint4*)&wb2[(size_t)((8 + wv * 2 + cc) * 64 + lane) * 4];
        bwin[cc] = __builtin_bit_cast(bf16x8, r0);
        bwf[cc]  = __builtin_bit_cast(bf16x8, r1);
    }
    {
        uint4 r = *(const uint4*)&wb2[(size_t)(16 * 64 + lane) * 4];
        bal = __builtin_bit_cast(bf16x8, r);
    }
    __syncthreads();
    f32x4 acch[4][2], accx[4][2], accal[4];
    #pragma unroll
    for (int rt = 0; rt < 4; rt++) {
        acch[rt][0] = (f32x4){0.f, 0.f, 0.f, 0.f};
        acch[rt][1] = (f32x4){0.f, 0.f, 0.f, 0.f};
        accx[rt][0] = (f32x4){0.f, 0.f, 0.f, 0.f};
        accx[rt][1] = (f32x4){0.f, 0.f, 0.f, 0.f};
        accal[rt]   = (f32x4){0.f, 0.f, 0.f, 0.f};
    }
    #pragma unroll
    for (int rt = 0; rt < 4; rt++) {
        uint4 araw = *(const uint4*)&xsu[(rt * 64 + lane) * 4];
        bf16x8 af = __builtin_bit_cast(bf16x8, araw);
        acch[rt][0] = __builtin_amdgcn_mfma_f32_16x16x32_bf16(af, bwin[0], acch[rt][0], 0, 0, 0);
        acch[rt][1] = __builtin_amdgcn_mfma_f32_16x16x32_bf16(af, bwin[1], acch[rt][1], 0, 0, 0);
        accx[rt][0] = __builtin_amdgcn_mfma_f32_16x16x32_bf16(af, bwf[0], accx[rt][0], 0, 0, 0);
        accx[rt][1] = __builtin_amdgcn_mfma_f32_16x16x32_bf16(af, bwf[1], accx[rt][1], 0, 0, 0);
        if (wv == 3)
            accal[rt] = __builtin_amdgcn_mfma_f32_16x16x32_bf16(af, bal, accal[rt], 0, 0, 0);
    }
    float bi[2], bfv[2];
    #pragma unroll
    for (int cc = 0; cc < 2; cc++) {
        int col = (wv * 2 + cc) * 16 + n16;
        bi[cc] = b_in[col];
        bfv[cc] = wf[32 * HID + col];
    }
    float bfa = (wv == 3 && n16 < 8) ? wf[33 * HID + n16] : 0.f;
    #pragma unroll
    for (int rt = 0; rt < 4; rt++) {
        #pragma unroll
        for (int reg = 0; reg < 4; reg++) {
            int row = n0 + rt * 16 + q * 4 + reg;
            #pragma unroll
            for (int cc = 0; cc < 2; cc++) {
                float v = acch[rt][cc][reg] + bi[cc];
                float vp = __shfl_xor(v, 1, 64);
                float u = accx[rt][cc][reg] + bfv[cc];
                float up = __shfl_xor(u, 1, 64);
                if (!(n16 & 1) && row < NN) {
                    int colp = (wv * 2 + cc) * 8 + (n16 >> 1);
                    h[(size_t)row * HQ + colp] = pack2(v, vp);
                    xh[(size_t)row * HQ + colp] = pack2(u, up);
                }
            }
            if (wv == 3 && row < NN && n16 < 8) {
                float v = accal[rt][reg] + bfa;
                if (n16 < 4) al_s[row * 4 + n16] = v;
                else         al_d[row * 4 + (n16 - 4)] = v;
            }
        }
    }
}

// ---------------------------------------------------------------------------
// Layers 1..2 via MFMA; LN stats reduced inline from the previous layer's
// partials buffer.
// ---------------------------------------------------------------------------
__global__ __launch_bounds__(256) void gemm_mfma_kernel(const u32* __restrict__ h,
        const u32* __restrict__ wb, u32* __restrict__ xh, const u32* __restrict__ g,
        const float* __restrict__ lnw, const float* __restrict__ lnb,
        const float* __restrict__ partials, u32* __restrict__ hout,
        float* __restrict__ al_s, float* __restrict__ al_d) {
    __shared__ u32 hsu[4096];                // 16KB, frag-ordered [rt][ks][lane][4]
    __shared__ float sred[8];
    int n0 = blockIdx.x * 64;
    int t = threadIdx.x;
    int wv = t >> 6, lane = t & 63;
    int q = lane >> 4, n16 = lane & 15;

    {
        const float4* pp = (const float4*)partials;
        float4 v0 = pp[t * 2], v1 = pp[t * 2 + 1];
        float s = v0.x + v0.z + v1.x + v1.z;
        float qq = v0.y + v0.w + v1.y + v1.w;
        #pragma unroll
        for (int off = 1; off <= 32; off <<= 1) {
            s += __shfl_xor(s, off, 64);
            qq += __shfl_xor(qq, off, 64);
        }
        if (lane == 0) { sred[wv * 2] = s; sred[wv * 2 + 1] = qq; }
    }
    __syncthreads();
    float S = sred[0] + sred[2] + sred[4] + sred[6];
    float Q = sred[1] + sred[3] + sred[5] + sred[7];
    const float M = (float)NN * (float)HID;
    float mean = S / M;
    float rstd = rsqrtf(fmaxf(Q / M - mean * mean, 0.f) + LN_EPS);

    bf16x8 bfrag[2][4];
    #pragma unroll
    for (int ks = 0; ks < 4; ks++) {
        #pragma unroll
        for (int cc = 0; cc < 2; cc++) {
            int ct = wv * 2 + cc;
            uint4 r = *(const uint4*)&wb[(size_t)((ks * 9 + ct) * 64 + lane) * 4];
            bfrag[cc][ks] = __builtin_bit_cast(bf16x8, r);
        }
    }
    bf16x8 bal[4];
    #pragma unroll
    for (int ks = 0; ks < 4; ks++) {
        uint4 r = *(const uint4*)&wb[(size_t)((ks * 9 + 8) * 64 + lane) * 4];
        bal[ks] = __builtin_bit_cast(bf16x8, r);
    }

    {
        int row = t >> 2;
        int qq = t & 3;
        int gr = n0 + row;
        int rt = row >> 4, m = row & 15;
        #pragma unroll
        for (int ks = 0; ks < 4; ks++) {
            int kk = ks * 32 + qq * 8;
            uint4 op = make_uint4(0u, 0u, 0u, 0u);
            if (gr < NN) {
                size_t base = (size_t)gr * HQ + (kk >> 1);
                uint4 gp = *(const uint4*)&g[base];
                uint4 hp = *(const uint4*)&h[base];
                float4 wA = *(const float4*)&lnw[kk];
                float4 wB = *(const float4*)&lnw[kk + 4];
                float4 bA = *(const float4*)&lnb[kk];
                float4 bB = *(const float4*)&lnb[kk + 4];
                float v0 = fmaxf((bflo(gp.x) - mean) * rstd * wA.x + bA.x + bflo(hp.x), 0.f);
                float v1 = fmaxf((bfhi(gp.x) - mean) * rstd * wA.y + bA.y + bfhi(hp.x), 0.f);
                float v2 = fmaxf((bflo(gp.y) - mean) * rstd * wA.z + bA.z + bflo(hp.y), 0.f);
                float v3 = fmaxf((bfhi(gp.y) - mean) * rstd * wA.w + bA.w + bfhi(hp.y), 0.f);
                float v4 = fmaxf((bflo(gp.z) - mean) * rstd * wB.x + bB.x + bflo(hp.z), 0.f);
                float v5 = fmaxf((bfhi(gp.z) - mean) * rstd * wB.y + bB.y + bfhi(hp.z), 0.f);
                float v6 = fmaxf((bflo(gp.w) - mean) * rstd * wB.z + bB.z + bflo(hp.w), 0.f);
                float v7 = fmaxf((bfhi(gp.w) - mean) * rstd * wB.w + bB.w + bfhi(hp.w), 0.f);
                op.x = pack2(v0, v1); op.y = pack2(v2, v3);
                op.z = pack2(v4, v5); op.w = pack2(v6, v7);
                *(uint4*)&hout[base] = op;
            }
            *(uint4*)&hsu[((rt * 4 + ks) * 64 + qq * 16 + m) * 4] = op;
        }
    }
    __syncthreads();

    f32x4 acc[4][2];
    f32x4 accal[4];
    #pragma unroll
    for (int rt = 0; rt < 4; rt++) {
        acc[rt][0] = (f32x4){0.f, 0.f, 0.f, 0.f};
        acc[rt][1] = (f32x4){0.f, 0.f, 0.f, 0.f};
        accal[rt]  = (f32x4){0.f, 0.f, 0.f, 0.f};
    }
    #pragma unroll
    for (int rt = 0; rt < 4; rt++) {
        #pragma unroll
        for (int ks = 0; ks < 4; ks++) {
            uint4 araw = *(const uint4*)&hsu[((rt * 4 + ks) * 64 + lane) * 4];
            bf16x8 af = __builtin_bit_cast(bf16x8, araw);
            acc[rt][0] = __builtin_amdgcn_mfma_f32_16x16x32_bf16(af, bfrag[0][ks], acc[rt][0], 0, 0, 0);
            acc[rt][1] = __builtin_amdgcn_mfma_f32_16x16x32_bf16(af, bfrag[1][ks], acc[rt][1], 0, 0, 0);
            if (wv == 3)
                accal[rt] = __builtin_amdgcn_mfma_f32_16x16x32_bf16(af, bal[ks], accal[rt], 0, 0, 0);
        }
    }

    #pragma unroll
    for (int rt = 0; rt < 4; rt++) {
        #pragma unroll
        for (int reg = 0; reg < 4; reg++) {
            int row = n0 + rt * 16 + q * 4 + reg;
            #pragma unroll
            for (int cc = 0; cc < 2; cc++) {
                float v = acc[rt][cc][reg];
                float vp = __shfl_xor(v, 1, 64);
                if (!(n16 & 1) && row < NN) {
                    int colp = (wv * 2 + cc) * 8 + (n16 >> 1);
                    xh[(size_t)row * HQ + colp] = pack2(v, vp);
                }
            }
            if (wv == 3 && row < NN && n16 < 8) {
                float v = accal[rt][reg];
                if (n16 < 4) al_s[row * 4 + n16] = v;
                else         al_d[row * 4 + (n16 - 4)] = v;
            }
        }
    }
}

// ---------------------------------------------------------------------------
// GAT aggregation v5 (unchanged): one wave = 4 consecutive nodes; synthetic
// self-loops.
// ---------------------------------------------------------------------------
__global__ __launch_bounds__(256) void gat_agg_kernel(const int* __restrict__ rowptr,
        const uint2* __restrict__ edges, const u32* __restrict__ xh,
        const float* __restrict__ al_s, const float* __restrict__ al_d,
        const float* __restrict__ wedot, const float* __restrict__ bg,
        u32* __restrict__ g, float* __restrict__ partials) {
    __shared__ float lds_ex[4][GCAP * 4];
    __shared__ float lds_ea[4][GCAP];
    __shared__ int lds_src[4][GCAP];
    int wv = threadIdx.x >> 6, lane = threadIdx.x & 63;
    int base = (blockIdx.x * 4 + wv) * 4;
    if (base >= NN) return;
    float* ex_w = lds_ex[wv];
    float* ea_w = lds_ea[wv];
    int* src_w = lds_src[wv];
    int b1 = base + 1 < NN ? base + 1 : NN;
    int b2 = base + 2 < NN ? base + 2 : NN;
    int b3 = base + 3 < NN ? base + 3 : NN;
    int b4 = base + 4 < NN ? base + 4 : NN;
    int r0 = rowptr[base], r1 = rowptr[b1], r2 = rowptr[b2], r3 = rowptr[b3], r4 = rowptr[b4];
    int span = r4 - r0;
    int ncached = span < GCAP ? span : GCAP;
    float wd0 = wedot[0], wd1 = wedot[1], wd2 = wedot[2], wd3 = wedot[3];

    for (int i = lane; i < ncached; i += 64) {
        int gi = r0 + i;
        uint2 e = edges[gi];
        int s = (int)e.x;
        float eav = __uint_as_float(e.y);
        int d = (gi >= r1) + (gi >= r2) + (gi >= r3);
        float4 aldv = *(const float4*)&al_d[(base + d) * 4];
        float4 als = *(const float4*)&al_s[s * 4];
        float e0 = __expf(lrelu(als.x + aldv.x + eav * wd0));
        float e1 = __expf(lrelu(als.y + aldv.y + eav * wd1));
        float e2 = __expf(lrelu(als.z + aldv.z + eav * wd2));
        float e3 = __expf(lrelu(als.w + aldv.w + eav * wd3));
        src_w[i] = s;
        ea_w[i] = eav;
        *(float4*)&ex_w[i * 4] = make_float4(e0, e1, e2, e3);
    }

    int nl = lane >> 4, cg = lane & 15;
    int n = base + nl;
    bool nvalid = n < NN;
    int ls = (nl == 0 ? r0 : nl == 1 ? r1 : nl == 2 ? r2 : r3) - r0;
    int le = (nl == 0 ? r1 : nl == 1 ? r2 : nl == 2 ? r3 : r4) - r0;
    int lec = le < ncached ? le : ncached;
    int head = cg >> 2;
    int c4 = cg * 4;
    float wdh = head == 0 ? wd0 : head == 1 ? wd1 : head == 2 ? wd2 : wd3;
    float a0 = 0.f, a1 = 0.f, a2 = 0.f, a3 = 0.f;
    float a4 = 0.f, a5 = 0.f, a6 = 0.f, a7 = 0.f, den = 0.f, easum = 0.f;
    int j = ls;
    for (; j + 3 < lec; j += 4) {
        int s0 = src_w[j], s1 = src_w[j + 1], s2 = src_w[j + 2], s3 = src_w[j + 3];
        float e0 = ex_w[j * 4 + head],       e1 = ex_w[(j + 1) * 4 + head];
        float e2 = ex_w[(j + 2) * 4 + head], e3 = ex_w[(j + 3) * 4 + head];
        uint4 x0 = *(const uint4*)&xh[(size_t)s0 * HQ + c4];
        uint4 x1 = *(const uint4*)&xh[(size_t)s1 * HQ + c4];
        uint4 x2 = *(const uint4*)&xh[(size_t)s2 * HQ + c4];
        uint4 x3 = *(const uint4*)&xh[(size_t)s3 * HQ + c4];
        den += e0 + e1 + e2 + e3;
        easum += ea_w[j] + ea_w[j + 1] + ea_w[j + 2] + ea_w[j + 3];
        a0 += e0 * bflo(x0.x); a1 += e0 * bfhi(x0.x);
        a2 += e0 * bflo(x0.y); a3 += e0 * bfhi(x0.y);
        a4 += e0 * bflo(x0.z); a5 += e0 * bfhi(x0.z);
        a6 += e0 * bflo(x0.w); a7 += e0 * bfhi(x0.w);
        a0 += e1 * bflo(x1.x); a1 += e1 * bfhi(x1.x);
        a2 += e1 * bflo(x1.y); a3 += e1 * bfhi(x1.y);
        a4 += e1 * bflo(x1.z); a5 += e1 * bfhi(x1.z);
        a6 += e1 * bflo(x1.w); a7 += e1 * bfhi(x1.w);
        a0 += e2 * bflo(x2.x); a1 += e2 * bfhi(x2.x);
        a2 += e2 * bflo(x2.y); a3 += e2 * bfhi(x2.y);
        a4 += e2 * bflo(x2.z); a5 += e2 * bfhi(x2.z);
        a6 += e2 * bflo(x2.w); a7 += e2 * bfhi(x2.w);
        a0 += e3 * bflo(x3.x); a1 += e3 * bfhi(x3.x);
        a2 += e3 * bflo(x3.y); a3 += e3 * bfhi(x3.y);
        a4 += e3 * bflo(x3.z); a5 += e3 * bfhi(x3.z);
        a6 += e3 * bflo(x3.w); a7 += e3 * bfhi(x3.w);
    }
    for (; j < lec; j++) {
        int s0 = src_w[j];
        float e0 = ex_w[j * 4 + head];
        uint4 x0 = *(const uint4*)&xh[(size_t)s0 * HQ + c4];
        den += e0;
        easum += ea_w[j];
        a0 += e0 * bflo(x0.x); a1 += e0 * bfhi(x0.x);
        a2 += e0 * bflo(x0.y); a3 += e0 * bfhi(x0.y);
        a4 += e0 * bflo(x0.z); a5 += e0 * bfhi(x0.z);
        a6 += e0 * bflo(x0.w); a7 += e0 * bfhi(x0.w);
    }
    if (le > lec && nvalid) {
        float aldh = al_d[n * 4 + head];
        for (int jt = (ls > lec ? ls : lec); jt < le; jt++) {
            uint2 e = edges[r0 + jt];
            int s = (int)e.x;
            float eav = __uint_as_float(e.y);
            float ex = __expf(lrelu(al_s[s * 4 + head] + aldh + eav * wdh));
            den += ex;
            easum += eav;
            uint4 x0 = *(const uint4*)&xh[(size_t)s * HQ + c4];
            a0 += ex * bflo(x0.x); a1 += ex * bfhi(x0.x);
            a2 += ex * bflo(x0.y); a3 += ex * bfhi(x0.y);
            a4 += ex * bflo(x0.z); a5 += ex * bfhi(x0.z);
            a6 += ex * bflo(x0.w); a7 += ex * bfhi(x0.w);
        }
    }
    if (nvalid) {
        float mea = easum / fmaxf((float)(le - ls), 1.0f);
        float alh = al_s[n * 4 + head] + al_d[n * 4 + head];
        float ex = __expf(lrelu(alh + mea * wdh));
        den += ex;
        uint4 x0 = *(const uint4*)&xh[(size_t)n * HQ + c4];
        a0 += ex * bflo(x0.x); a1 += ex * bfhi(x0.x);
        a2 += ex * bflo(x0.y); a3 += ex * bfhi(x0.y);
        a4 += ex * bflo(x0.z); a5 += ex * bfhi(x0.z);
        a6 += ex * bflo(x0.w); a7 += ex * bfhi(x0.w);
    }

    float inv = 1.0f / (den + 1e-16f);
    int c0 = cg * 8;
    float4 bgA = *(const float4*)&bg[c0];
    float4 bgB = *(const float4*)&bg[c0 + 4];
    float o0 = a0 * inv + bgA.x, o1 = a1 * inv + bgA.y;
    float o2 = a2 * inv + bgA.z, o3 = a3 * inv + bgA.w;
    float o4 = a4 * inv + bgB.x, o5 = a5 * inv + bgB.y;
    float o6 = a6 * inv + bgB.z, o7 = a7 * inv + bgB.w;
    float ss = 0.f, sq = 0.f;
    if (nvalid) {
        uint4 op;
        op.x = pack2(o0, o1); op.y = pack2(o2, o3);
        op.z = pack2(o4, o5); op.w = pack2(o6, o7);
        *(uint4*)&g[(size_t)n * HQ + c4] = op;
        ss = o0 + o1 + o2 + o3 + o4 + o5 + o6 + o7;
        sq = o0 * o0 + o1 * o1 + o2 * o2 + o3 * o3
           + o4 * o4 + o5 * o5 + o6 * o6 + o7 * o7;
    }
    #pragma unroll
    for (int off = 1; off <= 32; off <<= 1) {
        ss += __shfl_xor(ss, off, 64);
        sq += __shfl_xor(sq, off, 64);
    }
    if (lane == 0) {
        int sl = ((blockIdx.x * 4 + wv) & 1023) * 2;
        atomicAdd(&partials[sl], ss);
        atomicAdd(&partials[sl + 1], sq);
    }
}

// final: out = relu(LN(g)+h) @ Wout + bout.  LN stats reduced inline.
__global__ __launch_bounds__(256) void ln_out_kernel(const u32* __restrict__ g,
        const u32* __restrict__ h, const float* __restrict__ lnw,
        const float* __restrict__ lnb, const float* __restrict__ partials,
        const float* __restrict__ Wout, const float* __restrict__ bout,
        float* __restrict__ out) {
    __shared__ float wsh[HID * NOUT];
    __shared__ float sred[8];
    int t = threadIdx.x;
    int wv = t >> 6, lane = t & 63;
    {
        const float4* pp = (const float4*)partials;
        float4 v0 = pp[t * 2], v1 = pp[t * 2 + 1];
        float s = v0.x + v0.z + v1.x + v1.z;
        float qq = v0.y + v0.w + v1.y + v1.w;
        #pragma unroll
        for (int off = 1; off <= 32; off <<= 1) {
            s += __shfl_xor(s, off, 64);
            qq += __shfl_xor(qq, off, 64);
        }
        if (lane == 0) { sred[wv * 2] = s; sred[wv * 2 + 1] = qq; }
    }
    for (int i = t; i < HID * NOUT; i += 256) wsh[i] = Wout[i];
    __syncthreads();
    float S = sred[0] + sred[2] + sred[4] + sred[6];
    float Q = sred[1] + sred[3] + sred[5] + sred[7];
    const float M = (float)NN * (float)HID;
    float mean = S / M;
    float rstd = rsqrtf(fmaxf(Q / M - mean * mean, 0.f) + LN_EPS);

    int nl = lane >> 4, cg = lane & 15;
    int n = (blockIdx.x * 4 + wv) * 4 + nl;
    bool nvalid = n < NN;
    float p[NOUT] = {};
    if (nvalid) {
        int c0 = cg * 8;
        uint4 gv = *(const uint4*)&g[(size_t)n * HQ + cg * 4];
        uint4 hv = *(const uint4*)&h[(size_t)n * HQ + cg * 4];
        float4 wA = *(const float4*)&lnw[c0], wB = *(const float4*)&lnw[c0 + 4];
        float4 bA = *(const float4*)&lnb[c0], bB = *(const float4*)&lnb[c0 + 4];
        float o[8];
        o[0] = fmaxf((bflo(gv.x) - mean) * rstd * wA.x + bA.x + bflo(hv.x), 0.f);
        o[1] = fmaxf((bfhi(gv.x) - mean) * rstd * wA.y + bA.y + bfhi(hv.x), 0.f);
        o[2] = fmaxf((bflo(gv.y) - mean) * rstd * wA.z + bA.z + bflo(hv.y), 0.f);
        o[3] = fmaxf((bfhi(gv.y) - mean) * rstd * wA.w + bA.w + bfhi(hv.y), 0.f);
        o[4] = fmaxf((bflo(gv.z) - mean) * rstd * wB.x + bB.x + bflo(hv.z), 0.f);
        o[5] = fmaxf((bfhi(gv.z) - mean) * rstd * wB.y + bB.y + bfhi(hv.z), 0.f);
        o[6] = fmaxf((bflo(gv.w) - mean) * rstd * wB.z + bB.z + bflo(hv.w), 0.f);
        o[7] = fmaxf((bfhi(gv.w) - mean) * rstd * wB.w + bB.w + bfhi(hv.w), 0.f);
        #pragma unroll
        for (int jj = 0; jj < NOUT; jj++) {
            float acc = 0.f;
            #pragma unroll
            for (int k = 0; k < 8; k++) acc += o[k] * wsh[(c0 + k) * NOUT + jj];
            p[jj] = acc;
        }
    }
    #pragma unroll
    for (int off = 1; off <= 8; off <<= 1) {
        #pragma unroll
        for (int jj = 0; jj < NOUT; jj++) p[jj] += __shfl_xor(p[jj], off, 64);
    }
    if (cg == 0 && nvalid) {
        #pragma unroll
        for (int jj = 0; jj < NOUT; jj++)
            out[(size_t)n * NOUT + jj] = p[jj] + bout[jj];
    }
}

// ---------------------------------------------------------------------------
extern "C" void kernel_launch(void* const* d_in, const int* in_sizes, int n_in,
                              void* d_out, int out_size, void* d_ws, size_t ws_size,
                              hipStream_t stream) {
    const float* x      = (const float*)d_in[0];
    const int*   ei     = (const int*)d_in[1];
    const float* ea     = (const float*)d_in[2];
    const float* Win    = (const float*)d_in[3];
    const float* b_in   = (const float*)d_in[4];
    const float* Wg     = (const float*)d_in[5];
    const float* bg     = (const float*)d_in[6];
    const float* a_src  = (const float*)d_in[7];
    const float* a_dst  = (const float*)d_in[8];
    const float* We     = (const float*)d_in[9];
    const float* a_edge = (const float*)d_in[10];
    const float* ln_w   = (const float*)d_in[11];
    const float* ln_b   = (const float*)d_in[12];
    const float* Wout   = (const float*)d_in[13];
    const float* bout   = (const float*)d_in[14];
    float* out = (float*)d_out;

    char* w = (char*)d_ws;
    size_t off = 0;
    auto alloc = [&](size_t bytes) -> void* {
        void* p = w + off;
        off = (off + bytes + 255) & ~(size_t)255;
        return p;
    };
    // zeroed region first (one memset): cnt + partials
    int*   cnt     = (int*)alloc(NN * sizeof(int));
    float* partials = (float*)alloc(3 * 2048 * sizeof(float));
    size_t zero_span = off;
    u32*   slot    = (u32*)alloc((size_t)EE * sizeof(u32));
    int*   rowptr  = (int*)alloc((NN + 1) * sizeof(int));
    int*   bsum    = (int*)alloc(NB_SCAN * sizeof(int));
    uint2* edges   = (uint2*)alloc((size_t)EE * sizeof(uint2));
    u32*   h       = (u32*)alloc((size_t)NN * HQ * sizeof(u32));
    u32*   g       = (u32*)alloc((size_t)NN * HQ * sizeof(u32));
    u32*   xh      = (u32*)alloc((size_t)NN * HQ * sizeof(u32));
    float* al_s    = (float*)alloc((size_t)NN * NH * sizeof(float));
    float* al_d    = (float*)alloc((size_t)NN * NH * sizeof(float));
    float* wedot   = (float*)alloc(16 * sizeof(float));
    float* wf      = (float*)alloc(34 * HID * sizeof(float));
    float* wga     = (float*)alloc(HID * 8 * sizeof(float));
    u32*   wb      = (u32*)alloc((size_t)2 * WB_LSZ * sizeof(u32));
    u32*   wb2     = (u32*)alloc(17 * 64 * 4 * sizeof(u32));
    (void)ws_size; (void)n_in; (void)in_sizes; (void)out_size;

    hipMemsetAsync(d_ws, 0, zero_span, stream);
    // A: hist || weight prep
    hist_prep_kernel<<<HB + 36, 256, 0, stream>>>(ei, cnt, slot, We, a_edge, wedot,
                                                  Win, b_in, Wg, wf, a_src, a_dst,
                                                  wb, wga);
    scan1_kernel<<<NB_SCAN, 1024, 0, stream>>>(cnt, rowptr, bsum);
    // C: scan2 || prep2
    scan2_prep2_kernel<<<19, 128, 0, stream>>>(bsum, Win, b_in, wga, wf, wb2);
    scan3_kernel<<<NB_SCAN, 1024, 0, stream>>>(rowptr, bsum);
    // E: scatter || layer-0 MFMA GEMM
    scatter_ingemm_kernel<<<HB + NG64, 256, 0, stream>>>(ei, ea, rowptr, slot, edges,
                                                         x, wb2, wf, b_in, h, xh,
                                                         al_s, al_d);
    for (int l = 0; l < NL; l++) {
        if (l > 0) {
            gemm_mfma_kernel<<<NG64, 256, 0, stream>>>(
                h, wb + (size_t)(l - 1) * WB_LSZ, xh, g,
                ln_w + (size_t)(l - 1) * HID, ln_b + (size_t)(l - 1) * HID,
                partials + (size_t)(l - 1) * 2048, h, al_s, al_d);
        }
        gat_agg_kernel<<<(NN + 15) / 16, 256, 0, stream>>>(
            rowptr, edges, xh, al_s, al_d, wedot + l * 4,
            bg + (size_t)l * HID, g, partials + (size_t)l * 2048);
    }

    ln_out_kernel<<<(NN + 15) / 16, 256, 0, stream>>>(g, h, ln_w + (size_t)2 * HID,
                                                      ln_b + (size_t)2 * HID,
                                                      partials + 2 * 2048, Wout, bout, out);
}

// Round 13
// 390.044 us; speedup vs baseline: 2.7154x; 1.0114x over previous
//
#include <hip/hip_runtime.h>
#include <hip/hip_bf16.h>

#define NN 100000
#define EE 800000
#define HID 128
#define NH 4
#define CH 32
#define NL 3
#define NOUT 5
#define NEG_SLOPE 0.2f
#define LN_EPS 1e-5f
#define GCAP 64            // LDS-cached edges per 4-node wave group (real edges only)
#define NB_SCAN 98         // ceil((NN+1)/1024)
#define HQ (HID / 2)       // u32-packed bf16 pairs per row
#define WB_LSZ 9216        // u32 per layer of packed B-frags: 4ks*9ct*64lane*4
#define HB4 782            // hist blocks: ceil(EE/1024), 4 edges/thread
#define SB4 782            // scatter blocks, 4 edges/thread
#define NG64 1563          // in_gemm blocks = ceil(NN/64)

typedef unsigned int u32;
typedef __attribute__((ext_vector_type(8))) short bf16x8;
typedef __attribute__((ext_vector_type(4))) float f32x4;

static __device__ __forceinline__ float bflo(u32 r) { return __uint_as_float(r << 16); }
static __device__ __forceinline__ float bfhi(u32 r) { return __uint_as_float(r & 0xffff0000u); }
static __device__ __forceinline__ unsigned short f2bf(float x) {
    union U { __hip_bfloat16 b; unsigned short s; } u;
    u.b = __float2bfloat16(x);
    return u.s;
}
static __device__ __forceinline__ u32 pack2(float a, float b) {
    return (u32)f2bf(a) | ((u32)f2bf(b) << 16);
}
static __device__ __forceinline__ float lrelu(float x) {
    return x > 0.f ? x : NEG_SLOPE * x;
}

// ---------------------------------------------------------------------------
// Fused dispatch A: hist (blocks 0..HB4-1, 4 edges/thread) || weight prep.
// ---------------------------------------------------------------------------
__global__ void hist_prep_kernel(const int* __restrict__ ei, int* __restrict__ cnt,
                                 u32* __restrict__ slot,
                                 const float* __restrict__ We, const float* __restrict__ a_e,
                                 float* __restrict__ wedot,
                                 const float* __restrict__ Win, const float* __restrict__ b_in,
                                 const float* __restrict__ Wg, float* __restrict__ wf,
                                 const float* __restrict__ a_src, const float* __restrict__ a_dst,
                                 u32* __restrict__ wb, float* __restrict__ wga) {
    int b = blockIdx.x, t = threadIdx.x;
    if (b < HB4) {
        int e0 = b * 1024 + t;
        #pragma unroll
        for (int k = 0; k < 4; k++) {
            int e = e0 + k * 256;
            if (e < EE) {
                int d = ei[EE + e];
                int s = atomicAdd(&cnt[d], 1);
                slot[e] = ((u32)d << 8) | (u32)s;
            }
        }
        return;
    }
    if (b == HB4) {
        if (t < NL * NH) {
            int l = t >> 2, hh = t & 3;
            float s = 0.f;
            #pragma unroll
            for (int c = 0; c < CH; c++)
                s += We[l * HID + hh * CH + c] * a_e[l * HID + hh * CH + c];
            wedot[t] = s;
        }
        // WgA0[m][j] = head-masked (Wg0 @ Aext): j<4 src head j, j>=4 dst head j-4
        for (int i = t; i < HID * 8; i += 256) {
            int m = i >> 3, j = i & 7;
            int hh = j & 3;
            const float* a = (j < 4) ? (a_src + hh * CH) : (a_dst + hh * CH);
            const float* wrow = Wg + (size_t)m * HID + hh * CH;
            float s = 0.f;
            #pragma unroll
            for (int c = 0; c < CH; c++) s += wrow[c] * a[c];
            wga[i] = s;
        }
        return;
    }
    if (b < HB4 + 18) {
        // wfuse: wf[r][c] = sum_k (r<32 ? Win[r][k] : b_in[k]) * Wg0[k][c]
        int idx = (b - HB4 - 1) * 256 + t;
        if (idx >= 33 * HID) return;
        int r = idx >> 7, c = idx & 127;
        float acc = 0.f;
        for (int k = 0; k < HID; k++) {
            float a = (r < 32) ? Win[r * HID + k] : b_in[k];
            acc += a * Wg[(size_t)k * HID + c];
        }
        wf[r * HID + c] = acc;
        return;
    }
    // pack Wg[1..2] (+ head-masked al columns as 9th col-tile) into B-frags
    {
        int idx = (b - HB4 - 18) * 256 + t;   // 0..4607
        if (idx >= 2 * 2304) return;
        int l = idx / 2304;
        int rem = idx % 2304;
        int ks = rem / 576;
        int ct = (rem % 576) / 64;
        int lane = rem % 64;
        int q = lane >> 4, n = lane & 15;
        const float* W = Wg + (size_t)(l + 1) * HID * HID;
        float v[8];
        if (ct < 8) {
            #pragma unroll
            for (int j = 0; j < 8; j++) {
                int k = ks * 32 + q * 8 + j;
                v[j] = W[(size_t)k * HID + ct * 16 + n];
            }
        } else {
            #pragma unroll
            for (int j = 0; j < 8; j++) v[j] = 0.f;
            if (n < 8) {
                const float* a = (n < 4) ? (a_src + (l + 1) * HID + (n & 3) * CH)
                                         : (a_dst + (l + 1) * HID + (n & 3) * CH);
                #pragma unroll
                for (int j = 0; j < 8; j++) {
                    int k = ks * 32 + q * 8 + j;
                    const float* wrow = W + (size_t)k * HID + (n & 3) * CH;
                    float s = 0.f;
                    for (int c = 0; c < CH; c++) s += wrow[c] * a[c];
                    v[j] = s;
                }
            }
        }
        u32* dst = wb + (size_t)l * WB_LSZ + (size_t)((ks * 9 + ct) * 64 + lane) * 4;
        dst[0] = pack2(v[0], v[1]); dst[1] = pack2(v[2], v[3]);
        dst[2] = pack2(v[4], v[5]); dst[3] = pack2(v[6], v[7]);
    }
}

// ---------------------------------------------------------------------------
// Fused dispatch B: single-pass scan (decoupled lookback, blocks 0..NB_SCAN-1)
// || prep2 (layer-0 B-frags, blocks NB_SCAN..NB_SCAN+17).
// sums/prefixes/flags are zeroed by the memset each launch.
// ---------------------------------------------------------------------------
__global__ __launch_bounds__(1024) void scan_prep2_kernel(const int* __restrict__ cnt,
        int* __restrict__ rowptr, int* __restrict__ sums, int* __restrict__ prefixes,
        int* __restrict__ flags,
        const float* __restrict__ Win, const float* __restrict__ b_in,
        const float* __restrict__ wga, float* __restrict__ wf, u32* __restrict__ wb2) {
    if (blockIdx.x >= NB_SCAN) {
        int b = blockIdx.x - NB_SCAN;        // 0..17
        int lane = threadIdx.x;
        if (lane >= 64) return;
        int q = lane >> 4, n = lane & 15;
        if (b == 17) {
            if (lane < 8) {
                float s = 0.f;
                for (int m = 0; m < HID; m++) s += b_in[m] * wga[m * 8 + lane];
                wf[33 * HID + lane] = s;     // bfA
            }
            return;
        }
        float v[8];
        if (b < 8) {
            #pragma unroll
            for (int j = 0; j < 8; j++) v[j] = Win[(q * 8 + j) * HID + b * 16 + n];
        } else if (b < 16) {
            int ct = b - 8;
            #pragma unroll
            for (int j = 0; j < 8; j++) v[j] = wf[(q * 8 + j) * HID + ct * 16 + n];
        } else {                             // al tile: Win @ WgA0
            #pragma unroll
            for (int j = 0; j < 8; j++) v[j] = 0.f;
            if (n < 8) {
                #pragma unroll
                for (int j = 0; j < 8; j++) {
                    const float* wrow = Win + (q * 8 + j) * HID;
                    float s = 0.f;
                    for (int m = 0; m < HID; m++) s += wrow[m] * wga[m * 8 + n];
                    v[j] = s;
                }
            }
        }
        u32* dst = wb2 + (size_t)(b * 64 + lane) * 4;
        dst[0] = pack2(v[0], v[1]); dst[1] = pack2(v[2], v[3]);
        dst[2] = pack2(v[4], v[5]); dst[3] = pack2(v[6], v[7]);
        return;
    }
    // --- scan block ---
    __shared__ int ws[16];
    __shared__ int bprefix;
    int b = blockIdx.x;
    int gid = b * 1024 + threadIdx.x;
    int v = (gid < NN) ? cnt[gid] : 0;
    int lane = threadIdx.x & 63, wid = threadIdx.x >> 6;
    int s = v;
    #pragma unroll
    for (int off = 1; off < 64; off <<= 1) {
        int t2 = __shfl_up(s, off, 64);
        if (lane >= off) s += t2;
    }
    if (lane == 63) ws[wid] = s;
    __syncthreads();
    int add = 0;
    for (int w2 = 0; w2 < wid; w2++) add += ws[w2];
    int incl = s + add;                      // block-local inclusive
    if (threadIdx.x == 0) {
        int total = 0;
        for (int w2 = 0; w2 < 16; w2++) total += ws[w2];
        atomicExch(&sums[b], total);
        __threadfence();
        atomicExch(&flags[b], 1);
        int pfx = 0;
        for (int i = b - 1; i >= 0; i--) {
            int f;
            do { f = atomicAdd(&flags[i], 0); } while (f == 0);
            if (f == 2) { pfx += atomicAdd(&prefixes[i], 0); break; }
            pfx += atomicAdd(&sums[i], 0);
        }
        atomicExch(&prefixes[b], pfx + total);
        __threadfence();
        atomicExch(&flags[b], 2);
        bprefix = pfx;
    }
    __syncthreads();
    int pfx = bprefix;
    if (gid <= NN) rowptr[gid] = pfx + incl - v;   // exclusive
}

// ---------------------------------------------------------------------------
// Fused dispatch C: scatter (blocks 0..SB4-1, 4 edges/thread) || layer-0 MFMA
// GEMM. scatter: one 8B random store per edge.
// ---------------------------------------------------------------------------
__global__ __launch_bounds__(256) void scatter_ingemm_kernel(
        const int* __restrict__ ei, const float* __restrict__ ea,
        const int* __restrict__ rowptr, const u32* __restrict__ slot,
        uint2* __restrict__ edges,
        const float* __restrict__ x, const u32* __restrict__ wb2,
        const float* __restrict__ wf, const float* __restrict__ b_in,
        u32* __restrict__ h, u32* __restrict__ xh,
        float* __restrict__ al_s, float* __restrict__ al_d) {
    __shared__ u32 xsu[1024];                // used by the in_gemm branch only
    if (blockIdx.x < SB4) {
        int e0 = blockIdx.x * 1024 + threadIdx.x;
        #pragma unroll
        for (int k = 0; k < 4; k++) {
            int e = e0 + k * 256;
            if (e < EE) {
                u32 p = slot[e];
                int d = (int)(p >> 8);
                int pos = rowptr[d] + (int)(p & 255u);
                edges[pos] = make_uint2((u32)ei[e], __float_as_uint(ea[e]));
            }
        }
        return;
    }
    int t = threadIdx.x;
    int wv = t >> 6, lane = t & 63;
    int q = lane >> 4, n16 = lane & 15;
    int n0 = (blockIdx.x - SB4) * 64;
    // stage x -> bf16 A-frags
    {
        int row = t >> 2, qq = t & 3;
        int gr = n0 + row;
        int rt = row >> 4, m = row & 15;
        uint4 op = make_uint4(0u, 0u, 0u, 0u);
        if (gr < NN) {
            float4 vA = *(const float4*)&x[(size_t)gr * 32 + qq * 8];
            float4 vB = *(const float4*)&x[(size_t)gr * 32 + qq * 8 + 4];
            op.x = pack2(vA.x, vA.y); op.y = pack2(vA.z, vA.w);
            op.z = pack2(vB.x, vB.y); op.w = pack2(vB.z, vB.w);
        }
        *(uint4*)&xsu[(rt * 64 + qq * 16 + m) * 4] = op;
    }
    bf16x8 bwin[2], bwf[2], bal;
    #pragma unroll
    for (int cc = 0; cc < 2; cc++) {
        uint4 r0 = *(const uint4*)&wb2[(size_t)(((wv * 2 + cc)) * 64 + lane) * 4];
        uint4 r1 = *(const uint4*)&wb2[(size_t)((8 + wv * 2 + cc) * 64 + lane) * 4];
        bwin[cc] = __builtin_bit_cast(bf16x8, r0);
        bwf[cc]  = __builtin_bit_cast(bf16x8, r1);
    }
    {
        uint4 r = *(const uint4*)&wb2[(size_t)(16 * 64 + lane) * 4];
        bal = __builtin_bit_cast(bf16x8, r);
    }
    __syncthreads();
    f32x4 acch[4][2], accx[4][2], accal[4];
    #pragma unroll
    for (int rt = 0; rt < 4; rt++) {
        acch[rt][0] = (f32x4){0.f, 0.f, 0.f, 0.f};
        acch[rt][1] = (f32x4){0.f, 0.f, 0.f, 0.f};
        accx[rt][0] = (f32x4){0.f, 0.f, 0.f, 0.f};
        accx[rt][1] = (f32x4){0.f, 0.f, 0.f, 0.f};
        accal[rt]   = (f32x4){0.f, 0.f, 0.f, 0.f};
    }
    #pragma unroll
    for (int rt = 0; rt < 4; rt++) {
        uint4 araw = *(const uint4*)&xsu[(rt * 64 + lane) * 4];
        bf16x8 af = __builtin_bit_cast(bf16x8, araw);
        acch[rt][0] = __builtin_amdgcn_mfma_f32_16x16x32_bf16(af, bwin[0], acch[rt][0], 0, 0, 0);
        acch[rt][1] = __builtin_amdgcn_mfma_f32_16x16x32_bf16(af, bwin[1], acch[rt][1], 0, 0, 0);
        accx[rt][0] = __builtin_amdgcn_mfma_f32_16x16x32_bf16(af, bwf[0], accx[rt][0], 0, 0, 0);
        accx[rt][1] = __builtin_amdgcn_mfma_f32_16x16x32_bf16(af, bwf[1], accx[rt][1], 0, 0, 0);
        if (wv == 3)
            accal[rt] = __builtin_amdgcn_mfma_f32_16x16x32_bf16(af, bal, accal[rt], 0, 0, 0);
    }
    float bi[2], bfv[2];
    #pragma unroll
    for (int cc = 0; cc < 2; cc++) {
        int col = (wv * 2 + cc) * 16 + n16;
        bi[cc] = b_in[col];
        bfv[cc] = wf[32 * HID + col];
    }
    float bfa = (wv == 3 && n16 < 8) ? wf[33 * HID + n16] : 0.f;
    #pragma unroll
    for (int rt = 0; rt < 4; rt++) {
        #pragma unroll
        for (int reg = 0; reg < 4; reg++) {
            int row = n0 + rt * 16 + q * 4 + reg;
            #pragma unroll
            for (int cc = 0; cc < 2; cc++) {
                float v = acch[rt][cc][reg] + bi[cc];
                float vp = __shfl_xor(v, 1, 64);
                float u = accx[rt][cc][reg] + bfv[cc];
                float up = __shfl_xor(u, 1, 64);
                if (!(n16 & 1) && row < NN) {
                    int colp = (wv * 2 + cc) * 8 + (n16 >> 1);
                    h[(size_t)row * HQ + colp] = pack2(v, vp);
                    xh[(size_t)row * HQ + colp] = pack2(u, up);
                }
            }
            if (wv == 3 && row < NN && n16 < 8) {
                float v = accal[rt][reg] + bfa;
                if (n16 < 4) al_s[row * 4 + n16] = v;
                else         al_d[row * 4 + (n16 - 4)] = v;
            }
        }
    }
}

// ---------------------------------------------------------------------------
// Layers 1..2 via MFMA; LN stats reduced inline from the previous layer's
// partials buffer.
// ---------------------------------------------------------------------------
__global__ __launch_bounds__(256) void gemm_mfma_kernel(const u32* __restrict__ h,
        const u32* __restrict__ wb, u32* __restrict__ xh, const u32* __restrict__ g,
        const float* __restrict__ lnw, const float* __restrict__ lnb,
        const float* __restrict__ partials, u32* __restrict__ hout,
        float* __restrict__ al_s, float* __restrict__ al_d) {
    __shared__ u32 hsu[4096];                // 16KB, frag-ordered [rt][ks][lane][4]
    __shared__ float sred[8];
    int n0 = blockIdx.x * 64;
    int t = threadIdx.x;
    int wv = t >> 6, lane = t & 63;
    int q = lane >> 4, n16 = lane & 15;

    {
        const float4* pp = (const float4*)partials;
        float4 v0 = pp[t * 2], v1 = pp[t * 2 + 1];
        float s = v0.x + v0.z + v1.x + v1.z;
        float qq = v0.y + v0.w + v1.y + v1.w;
        #pragma unroll
        for (int off = 1; off <= 32; off <<= 1) {
            s += __shfl_xor(s, off, 64);
            qq += __shfl_xor(qq, off, 64);
        }
        if (lane == 0) { sred[wv * 2] = s; sred[wv * 2 + 1] = qq; }
    }
    __syncthreads();
    float S = sred[0] + sred[2] + sred[4] + sred[6];
    float Q = sred[1] + sred[3] + sred[5] + sred[7];
    const float M = (float)NN * (float)HID;
    float mean = S / M;
    float rstd = rsqrtf(fmaxf(Q / M - mean * mean, 0.f) + LN_EPS);

    bf16x8 bfrag[2][4];
    #pragma unroll
    for (int ks = 0; ks < 4; ks++) {
        #pragma unroll
        for (int cc = 0; cc < 2; cc++) {
            int ct = wv * 2 + cc;
            uint4 r = *(const uint4*)&wb[(size_t)((ks * 9 + ct) * 64 + lane) * 4];
            bfrag[cc][ks] = __builtin_bit_cast(bf16x8, r);
        }
    }
    bf16x8 bal[4];
    #pragma unroll
    for (int ks = 0; ks < 4; ks++) {
        uint4 r = *(const uint4*)&wb[(size_t)((ks * 9 + 8) * 64 + lane) * 4];
        bal[ks] = __builtin_bit_cast(bf16x8, r);
    }

    {
        int row = t >> 2;
        int qq = t & 3;
        int gr = n0 + row;
        int rt = row >> 4, m = row & 15;
        #pragma unroll
        for (int ks = 0; ks < 4; ks++) {
            int kk = ks * 32 + qq * 8;
            uint4 op = make_uint4(0u, 0u, 0u, 0u);
            if (gr < NN) {
                size_t base = (size_t)gr * HQ + (kk >> 1);
                uint4 gp = *(const uint4*)&g[base];
                uint4 hp = *(const uint4*)&h[base];
                float4 wA = *(const float4*)&lnw[kk];
                float4 wB = *(const float4*)&lnw[kk + 4];
                float4 bA = *(const float4*)&lnb[kk];
                float4 bB = *(const float4*)&lnb[kk + 4];
                float v0 = fmaxf((bflo(gp.x) - mean) * rstd * wA.x + bA.x + bflo(hp.x), 0.f);
                float v1 = fmaxf((bfhi(gp.x) - mean) * rstd * wA.y + bA.y + bfhi(hp.x), 0.f);
                float v2 = fmaxf((bflo(gp.y) - mean) * rstd * wA.z + bA.z + bflo(hp.y), 0.f);
                float v3 = fmaxf((bfhi(gp.y) - mean) * rstd * wA.w + bA.w + bfhi(hp.y), 0.f);
                float v4 = fmaxf((bflo(gp.z) - mean) * rstd * wB.x + bB.x + bflo(hp.z), 0.f);
                float v5 = fmaxf((bfhi(gp.z) - mean) * rstd * wB.y + bB.y + bfhi(hp.z), 0.f);
                float v6 = fmaxf((bflo(gp.w) - mean) * rstd * wB.z + bB.z + bflo(hp.w), 0.f);
                float v7 = fmaxf((bfhi(gp.w) - mean) * rstd * wB.w + bB.w + bfhi(hp.w), 0.f);
                op.x = pack2(v0, v1); op.y = pack2(v2, v3);
                op.z = pack2(v4, v5); op.w = pack2(v6, v7);
                *(uint4*)&hout[base] = op;
            }
            *(uint4*)&hsu[((rt * 4 + ks) * 64 + qq * 16 + m) * 4] = op;
        }
    }
    __syncthreads();

    f32x4 acc[4][2];
    f32x4 accal[4];
    #pragma unroll
    for (int rt = 0; rt < 4; rt++) {
        acc[rt][0] = (f32x4){0.f, 0.f, 0.f, 0.f};
        acc[rt][1] = (f32x4){0.f, 0.f, 0.f, 0.f};
        accal[rt]  = (f32x4){0.f, 0.f, 0.f, 0.f};
    }
    #pragma unroll
    for (int rt = 0; rt < 4; rt++) {
        #pragma unroll
        for (int ks = 0; ks < 4; ks++) {
            uint4 araw = *(const uint4*)&hsu[((rt * 4 + ks) * 64 + lane) * 4];
            bf16x8 af = __builtin_bit_cast(bf16x8, araw);
            acc[rt][0] = __builtin_amdgcn_mfma_f32_16x16x32_bf16(af, bfrag[0][ks], acc[rt][0], 0, 0, 0);
            acc[rt][1] = __builtin_amdgcn_mfma_f32_16x16x32_bf16(af, bfrag[1][ks], acc[rt][1], 0, 0, 0);
            if (wv == 3)
                accal[rt] = __builtin_amdgcn_mfma_f32_16x16x32_bf16(af, bal[ks], accal[rt], 0, 0, 0);
        }
    }

    #pragma unroll
    for (int rt = 0; rt < 4; rt++) {
        #pragma unroll
        for (int reg = 0; reg < 4; reg++) {
            int row = n0 + rt * 16 + q * 4 + reg;
            #pragma unroll
            for (int cc = 0; cc < 2; cc++) {
                float v = acc[rt][cc][reg];
                float vp = __shfl_xor(v, 1, 64);
                if (!(n16 & 1) && row < NN) {
                    int colp = (wv * 2 + cc) * 8 + (n16 >> 1);
                    xh[(size_t)row * HQ + colp] = pack2(v, vp);
                }
            }
            if (wv == 3 && row < NN && n16 < 8) {
                float v = accal[rt][reg];
                if (n16 < 4) al_s[row * 4 + n16] = v;
                else         al_d[row * 4 + (n16 - 4)] = v;
            }
        }
    }
}

// ---------------------------------------------------------------------------
// GAT aggregation v5 (unchanged): one wave = 4 consecutive nodes; synthetic
// self-loops.
// ---------------------------------------------------------------------------
__global__ __launch_bounds__(256) void gat_agg_kernel(const int* __restrict__ rowptr,
        const uint2* __restrict__ edges, const u32* __restrict__ xh,
        const float* __restrict__ al_s, const float* __restrict__ al_d,
        const float* __restrict__ wedot, const float* __restrict__ bg,
        u32* __restrict__ g, float* __restrict__ partials) {
    __shared__ float lds_ex[4][GCAP * 4];
    __shared__ float lds_ea[4][GCAP];
    __shared__ int lds_src[4][GCAP];
    int wv = threadIdx.x >> 6, lane = threadIdx.x & 63;
    int base = (blockIdx.x * 4 + wv) * 4;
    if (base >= NN) return;
    float* ex_w = lds_ex[wv];
    float* ea_w = lds_ea[wv];
    int* src_w = lds_src[wv];
    int b1 = base + 1 < NN ? base + 1 : NN;
    int b2 = base + 2 < NN ? base + 2 : NN;
    int b3 = base + 3 < NN ? base + 3 : NN;
    int b4 = base + 4 < NN ? base + 4 : NN;
    int r0 = rowptr[base], r1 = rowptr[b1], r2 = rowptr[b2], r3 = rowptr[b3], r4 = rowptr[b4];
    int span = r4 - r0;
    int ncached = span < GCAP ? span : GCAP;
    float wd0 = wedot[0], wd1 = wedot[1], wd2 = wedot[2], wd3 = wedot[3];

    for (int i = lane; i < ncached; i += 64) {
        int gi = r0 + i;
        uint2 e = edges[gi];
        int s = (int)e.x;
        float eav = __uint_as_float(e.y);
        int d = (gi >= r1) + (gi >= r2) + (gi >= r3);
        float4 aldv = *(const float4*)&al_d[(base + d) * 4];
        float4 als = *(const float4*)&al_s[s * 4];
        float e0 = __expf(lrelu(als.x + aldv.x + eav * wd0));
        float e1 = __expf(lrelu(als.y + aldv.y + eav * wd1));
        float e2 = __expf(lrelu(als.z + aldv.z + eav * wd2));
        float e3 = __expf(lrelu(als.w + aldv.w + eav * wd3));
        src_w[i] = s;
        ea_w[i] = eav;
        *(float4*)&ex_w[i * 4] = make_float4(e0, e1, e2, e3);
    }

    int nl = lane >> 4, cg = lane & 15;
    int n = base + nl;
    bool nvalid = n < NN;
    int ls = (nl == 0 ? r0 : nl == 1 ? r1 : nl == 2 ? r2 : r3) - r0;
    int le = (nl == 0 ? r1 : nl == 1 ? r2 : nl == 2 ? r3 : r4) - r0;
    int lec = le < ncached ? le : ncached;
    int head = cg >> 2;
    int c4 = cg * 4;
    float wdh = head == 0 ? wd0 : head == 1 ? wd1 : head == 2 ? wd2 : wd3;
    float a0 = 0.f, a1 = 0.f, a2 = 0.f, a3 = 0.f;
    float a4 = 0.f, a5 = 0.f, a6 = 0.f, a7 = 0.f, den = 0.f, easum = 0.f;
    int j = ls;
    for (; j + 3 < lec; j += 4) {
        int s0 = src_w[j], s1 = src_w[j + 1], s2 = src_w[j + 2], s3 = src_w[j + 3];
        float e0 = ex_w[j * 4 + head],       e1 = ex_w[(j + 1) * 4 + head];
        float e2 = ex_w[(j + 2) * 4 + head], e3 = ex_w[(j + 3) * 4 + head];
        uint4 x0 = *(const uint4*)&xh[(size_t)s0 * HQ + c4];
        uint4 x1 = *(const uint4*)&xh[(size_t)s1 * HQ + c4];
        uint4 x2 = *(const uint4*)&xh[(size_t)s2 * HQ + c4];
        uint4 x3 = *(const uint4*)&xh[(size_t)s3 * HQ + c4];
        den += e0 + e1 + e2 + e3;
        easum += ea_w[j] + ea_w[j + 1] + ea_w[j + 2] + ea_w[j + 3];
        a0 += e0 * bflo(x0.x); a1 += e0 * bfhi(x0.x);
        a2 += e0 * bflo(x0.y); a3 += e0 * bfhi(x0.y);
        a4 += e0 * bflo(x0.z); a5 += e0 * bfhi(x0.z);
        a6 += e0 * bflo(x0.w); a7 += e0 * bfhi(x0.w);
        a0 += e1 * bflo(x1.x); a1 += e1 * bfhi(x1.x);
        a2 += e1 * bflo(x1.y); a3 += e1 * bfhi(x1.y);
        a4 += e1 * bflo(x1.z); a5 += e1 * bfhi(x1.z);
        a6 += e1 * bflo(x1.w); a7 += e1 * bfhi(x1.w);
        a0 += e2 * bflo(x2.x); a1 += e2 * bfhi(x2.x);
        a2 += e2 * bflo(x2.y); a3 += e2 * bfhi(x2.y);
        a4 += e2 * bflo(x2.z); a5 += e2 * bfhi(x2.z);
        a6 += e2 * bflo(x2.w); a7 += e2 * bfhi(x2.w);
        a0 += e3 * bflo(x3.x); a1 += e3 * bfhi(x3.x);
        a2 += e3 * bflo(x3.y); a3 += e3 * bfhi(x3.y);
        a4 += e3 * bflo(x3.z); a5 += e3 * bfhi(x3.z);
        a6 += e3 * bflo(x3.w); a7 += e3 * bfhi(x3.w);
    }
    for (; j < lec; j++) {
        int s0 = src_w[j];
        float e0 = ex_w[j * 4 + head];
        uint4 x0 = *(const uint4*)&xh[(size_t)s0 * HQ + c4];
        den += e0;
        easum += ea_w[j];
        a0 += e0 * bflo(x0.x); a1 += e0 * bfhi(x0.x);
        a2 += e0 * bflo(x0.y); a3 += e0 * bfhi(x0.y);
        a4 += e0 * bflo(x0.z); a5 += e0 * bfhi(x0.z);
        a6 += e0 * bflo(x0.w); a7 += e0 * bfhi(x0.w);
    }
    if (le > lec && nvalid) {
        float aldh = al_d[n * 4 + head];
        for (int jt = (ls > lec ? ls : lec); jt < le; jt++) {
            uint2 e = edges[r0 + jt];
            int s = (int)e.x;
            float eav = __uint_as_float(e.y);
            float ex = __expf(lrelu(al_s[s * 4 + head] + aldh + eav * wdh));
            den += ex;
            easum += eav;
            uint4 x0 = *(const uint4*)&xh[(size_t)s * HQ + c4];
            a0 += ex * bflo(x0.x); a1 += ex * bfhi(x0.x);
            a2 += ex * bflo(x0.y); a3 += ex * bfhi(x0.y);
            a4 += ex * bflo(x0.z); a5 += ex * bfhi(x0.z);
            a6 += ex * bflo(x0.w); a7 += ex * bfhi(x0.w);
        }
    }
    if (nvalid) {
        float mea = easum / fmaxf((float)(le - ls), 1.0f);
        float alh = al_s[n * 4 + head] + al_d[n * 4 + head];
        float ex = __expf(lrelu(alh + mea * wdh));
        den += ex;
        uint4 x0 = *(const uint4*)&xh[(size_t)n * HQ + c4];
        a0 += ex * bflo(x0.x); a1 += ex * bfhi(x0.x);
        a2 += ex * bflo(x0.y); a3 += ex * bfhi(x0.y);
        a4 += ex * bflo(x0.z); a5 += ex * bfhi(x0.z);
        a6 += ex * bflo(x0.w); a7 += ex * bfhi(x0.w);
    }

    float inv = 1.0f / (den + 1e-16f);
    int c0 = cg * 8;
    float4 bgA = *(const float4*)&bg[c0];
    float4 bgB = *(const float4*)&bg[c0 + 4];
    float o0 = a0 * inv + bgA.x, o1 = a1 * inv + bgA.y;
    float o2 = a2 * inv + bgA.z, o3 = a3 * inv + bgA.w;
    float o4 = a4 * inv + bgB.x, o5 = a5 * inv + bgB.y;
    float o6 = a6 * inv + bgB.z, o7 = a7 * inv + bgB.w;
    float ss = 0.f, sq = 0.f;
    if (nvalid) {
        uint4 op;
        op.x = pack2(o0, o1); op.y = pack2(o2, o3);
        op.z = pack2(o4, o5); op.w = pack2(o6, o7);
        *(uint4*)&g[(size_t)n * HQ + c4] = op;
        ss = o0 + o1 + o2 + o3 + o4 + o5 + o6 + o7;
        sq = o0 * o0 + o1 * o1 + o2 * o2 + o3 * o3
           + o4 * o4 + o5 * o5 + o6 * o6 + o7 * o7;
    }
    #pragma unroll
    for (int off = 1; off <= 32; off <<= 1) {
        ss += __shfl_xor(ss, off, 64);
        sq += __shfl_xor(sq, off, 64);
    }
    if (lane == 0) {
        int sl = ((blockIdx.x * 4 + wv) & 1023) * 2;
        atomicAdd(&partials[sl], ss);
        atomicAdd(&partials[sl + 1], sq);
    }
}

// final: out = relu(LN(g)+h) @ Wout + bout.  LN stats reduced inline.
__global__ __launch_bounds__(256) void ln_out_kernel(const u32* __restrict__ g,
        const u32* __restrict__ h, const float* __restrict__ lnw,
        const float* __restrict__ lnb, const float* __restrict__ partials,
        const float* __restrict__ Wout, const float* __restrict__ bout,
        float* __restrict__ out) {
    __shared__ float wsh[HID * NOUT];
    __shared__ float sred[8];
    int t = threadIdx.x;
    int wv = t >> 6, lane = t & 63;
    {
        const float4* pp = (const float4*)partials;
        float4 v0 = pp[t * 2], v1 = pp[t * 2 + 1];
        float s = v0.x + v0.z + v1.x + v1.z;
        float qq = v0.y + v0.w + v1.y + v1.w;
        #pragma unroll
        for (int off = 1; off <= 32; off <<= 1) {
            s += __shfl_xor(s, off, 64);
            qq += __shfl_xor(qq, off, 64);
        }
        if (lane == 0) { sred[wv * 2] = s; sred[wv * 2 + 1] = qq; }
    }
    for (int i = t; i < HID * NOUT; i += 256) wsh[i] = Wout[i];
    __syncthreads();
    float S = sred[0] + sred[2] + sred[4] + sred[6];
    float Q = sred[1] + sred[3] + sred[5] + sred[7];
    const float M = (float)NN * (float)HID;
    float mean = S / M;
    float rstd = rsqrtf(fmaxf(Q / M - mean * mean, 0.f) + LN_EPS);

    int nl = lane >> 4, cg = lane & 15;
    int n = (blockIdx.x * 4 + wv) * 4 + nl;
    bool nvalid = n < NN;
    float p[NOUT] = {};
    if (nvalid) {
        int c0 = cg * 8;
        uint4 gv = *(const uint4*)&g[(size_t)n * HQ + cg * 4];
        uint4 hv = *(const uint4*)&h[(size_t)n * HQ + cg * 4];
        float4 wA = *(const float4*)&lnw[c0], wB = *(const float4*)&lnw[c0 + 4];
        float4 bA = *(const float4*)&lnb[c0], bB = *(const float4*)&lnb[c0 + 4];
        float o[8];
        o[0] = fmaxf((bflo(gv.x) - mean) * rstd * wA.x + bA.x + bflo(hv.x), 0.f);
        o[1] = fmaxf((bfhi(gv.x) - mean) * rstd * wA.y + bA.y + bfhi(hv.x), 0.f);
        o[2] = fmaxf((bflo(gv.y) - mean) * rstd * wA.z + bA.z + bflo(hv.y), 0.f);
        o[3] = fmaxf((bfhi(gv.y) - mean) * rstd * wA.w + bA.w + bfhi(hv.y), 0.f);
        o[4] = fmaxf((bflo(gv.z) - mean) * rstd * wB.x + bB.x + bflo(hv.z), 0.f);
        o[5] = fmaxf((bfhi(gv.z) - mean) * rstd * wB.y + bB.y + bfhi(hv.z), 0.f);
        o[6] = fmaxf((bflo(gv.w) - mean) * rstd * wB.z + bB.z + bflo(hv.w), 0.f);
        o[7] = fmaxf((bfhi(gv.w) - mean) * rstd * wB.w + bB.w + bfhi(hv.w), 0.f);
        #pragma unroll
        for (int jj = 0; jj < NOUT; jj++) {
            float acc = 0.f;
            #pragma unroll
            for (int k = 0; k < 8; k++) acc += o[k] * wsh[(c0 + k) * NOUT + jj];
            p[jj] = acc;
        }
    }
    #pragma unroll
    for (int off = 1; off <= 8; off <<= 1) {
        #pragma unroll
        for (int jj = 0; jj < NOUT; jj++) p[jj] += __shfl_xor(p[jj], off, 64);
    }
    if (cg == 0 && nvalid) {
        #pragma unroll
        for (int jj = 0; jj < NOUT; jj++)
            out[(size_t)n * NOUT + jj] = p[jj] + bout[jj];
    }
}

// ---------------------------------------------------------------------------
extern "C" void kernel_launch(void* const* d_in, const int* in_sizes, int n_in,
                              void* d_out, int out_size, void* d_ws, size_t ws_size,
                              hipStream_t stream) {
    const float* x      = (const float*)d_in[0];
    const int*   ei     = (const int*)d_in[1];
    const float* ea     = (const float*)d_in[2];
    const float* Win    = (const float*)d_in[3];
    const float* b_in   = (const float*)d_in[4];
    const float* Wg     = (const float*)d_in[5];
    const float* bg     = (const float*)d_in[6];
    const float* a_src  = (const float*)d_in[7];
    const float* a_dst  = (const float*)d_in[8];
    const float* We     = (const float*)d_in[9];
    const float* a_edge = (const float*)d_in[10];
    const float* ln_w   = (const float*)d_in[11];
    const float* ln_b   = (const float*)d_in[12];
    const float* Wout   = (const float*)d_in[13];
    const float* bout   = (const float*)d_in[14];
    float* out = (float*)d_out;

    char* w = (char*)d_ws;
    size_t off = 0;
    auto alloc = [&](size_t bytes) -> void* {
        void* p = w + off;
        off = (off + bytes + 255) & ~(size_t)255;
        return p;
    };
    // zeroed region first (one memset): cnt + partials + scan state
    int*   cnt      = (int*)alloc(NN * sizeof(int));
    float* partials = (float*)alloc(3 * 2048 * sizeof(float));
    int*   sums     = (int*)alloc(NB_SCAN * sizeof(int));
    int*   prefixes = (int*)alloc(NB_SCAN * sizeof(int));
    int*   flags    = (int*)alloc(NB_SCAN * sizeof(int));
    size_t zero_span = off;
    u32*   slot    = (u32*)alloc((size_t)EE * sizeof(u32));
    int*   rowptr  = (int*)alloc((NN + 1) * sizeof(int));
    uint2* edges   = (uint2*)alloc((size_t)EE * sizeof(uint2));
    u32*   h       = (u32*)alloc((size_t)NN * HQ * sizeof(u32));
    u32*   g       = (u32*)alloc((size_t)NN * HQ * sizeof(u32));
    u32*   xh      = (u32*)alloc((size_t)NN * HQ * sizeof(u32));
    float* al_s    = (float*)alloc((size_t)NN * NH * sizeof(float));
    float* al_d    = (float*)alloc((size_t)NN * NH * sizeof(float));
    float* wedot   = (float*)alloc(16 * sizeof(float));
    float* wf      = (float*)alloc(34 * HID * sizeof(float));
    float* wga     = (float*)alloc(HID * 8 * sizeof(float));
    u32*   wb      = (u32*)alloc((size_t)2 * WB_LSZ * sizeof(u32));
    u32*   wb2     = (u32*)alloc(17 * 64 * 4 * sizeof(u32));
    (void)ws_size; (void)n_in; (void)in_sizes; (void)out_size;

    hipMemsetAsync(d_ws, 0, zero_span, stream);
    // A: hist (4 edges/thread) || weight prep
    hist_prep_kernel<<<HB4 + 36, 256, 0, stream>>>(ei, cnt, slot, We, a_edge, wedot,
                                                   Win, b_in, Wg, wf, a_src, a_dst,
                                                   wb, wga);
    // B: single-pass scan (decoupled lookback) || prep2
    scan_prep2_kernel<<<NB_SCAN + 18, 1024, 0, stream>>>(cnt, rowptr, sums, prefixes,
                                                         flags, Win, b_in, wga, wf, wb2);
    // C: scatter (4 edges/thread) || layer-0 MFMA GEMM
    scatter_ingemm_kernel<<<SB4 + NG64, 256, 0, stream>>>(ei, ea, rowptr, slot, edges,
                                                          x, wb2, wf, b_in, h, xh,
                                                          al_s, al_d);
    for (int l = 0; l < NL; l++) {
        if (l > 0) {
            gemm_mfma_kernel<<<NG64, 256, 0, stream>>>(
                h, wb + (size_t)(l - 1) * WB_LSZ, xh, g,
                ln_w + (size_t)(l - 1) * HID, ln_b + (size_t)(l - 1) * HID,
                partials + (size_t)(l - 1) * 2048, h, al_s, al_d);
        }
        gat_agg_kernel<<<(NN + 15) / 16, 256, 0, stream>>>(
            rowptr, edges, xh, al_s, al_d, wedot + l * 4,
            bg + (size_t)l * HID, g, partials + (size_t)l * 2048);
    }

    ln_out_kernel<<<(NN + 15) / 16, 256, 0, stream>>>(g, h, ln_w + (size_t)2 * HID,
                                                      ln_b + (size_t)2 * HID,
                                                      partials + 2 * 2048, Wout, bout, out);
}

// Round 14
// 382.898 us; speedup vs baseline: 2.7661x; 1.0187x over previous
//
#include <hip/hip_runtime.h>
#include <hip/hip_bf16.h>

#define NN 100000
#define EE 800000
#define HID 128
#define NH 4
#define CH 32
#define NL 3
#define NOUT 5
#define NEG_SLOPE 0.2f
#define LN_EPS 1e-5f
#define GCAP 128           // LDS-cached edges per 8-node wave group (real edges only)
#define NB_SCAN 98         // ceil((NN+1)/1024)
#define HQ (HID / 2)       // u32-packed bf16 pairs per row
#define WB_LSZ 9216        // u32 per layer of packed B-frags: 4ks*9ct*64lane*4
#define HB8 391            // hist blocks: ceil(EE/2048), 8 edges/thread
#define SB8 391            // scatter blocks, 8 edges/thread
#define NG64 1563          // in_gemm blocks = ceil(NN/64)

typedef unsigned int u32;
typedef __attribute__((ext_vector_type(8))) short bf16x8;
typedef __attribute__((ext_vector_type(4))) float f32x4;

static __device__ __forceinline__ float bflo(u32 r) { return __uint_as_float(r << 16); }
static __device__ __forceinline__ float bfhi(u32 r) { return __uint_as_float(r & 0xffff0000u); }
static __device__ __forceinline__ unsigned short f2bf(float x) {
    union U { __hip_bfloat16 b; unsigned short s; } u;
    u.b = __float2bfloat16(x);
    return u.s;
}
static __device__ __forceinline__ u32 pack2(float a, float b) {
    return (u32)f2bf(a) | ((u32)f2bf(b) << 16);
}
static __device__ __forceinline__ float lrelu(float x) {
    return x > 0.f ? x : NEG_SLOPE * x;
}

// ---------------------------------------------------------------------------
// Fused dispatch A: hist (blocks 0..HB8-1, 8 edges/thread) || weight prep.
// ---------------------------------------------------------------------------
__global__ void hist_prep_kernel(const int* __restrict__ ei, int* __restrict__ cnt,
                                 u32* __restrict__ slot,
                                 const float* __restrict__ We, const float* __restrict__ a_e,
                                 float* __restrict__ wedot,
                                 const float* __restrict__ Win, const float* __restrict__ b_in,
                                 const float* __restrict__ Wg, float* __restrict__ wf,
                                 const float* __restrict__ a_src, const float* __restrict__ a_dst,
                                 u32* __restrict__ wb, float* __restrict__ wga) {
    int b = blockIdx.x, t = threadIdx.x;
    if (b < HB8) {
        int e0 = b * 2048 + t;
        #pragma unroll
        for (int k = 0; k < 8; k++) {
            int e = e0 + k * 256;
            if (e < EE) {
                int d = ei[EE + e];
                int s = atomicAdd(&cnt[d], 1);
                slot[e] = ((u32)d << 8) | (u32)s;
            }
        }
        return;
    }
    if (b == HB8) {
        if (t < NL * NH) {
            int l = t >> 2, hh = t & 3;
            float s = 0.f;
            #pragma unroll
            for (int c = 0; c < CH; c++)
                s += We[l * HID + hh * CH + c] * a_e[l * HID + hh * CH + c];
            wedot[t] = s;
        }
        // WgA0[m][j] = head-masked (Wg0 @ Aext): j<4 src head j, j>=4 dst head j-4
        for (int i = t; i < HID * 8; i += 256) {
            int m = i >> 3, j = i & 7;
            int hh = j & 3;
            const float* a = (j < 4) ? (a_src + hh * CH) : (a_dst + hh * CH);
            const float* wrow = Wg + (size_t)m * HID + hh * CH;
            float s = 0.f;
            #pragma unroll
            for (int c = 0; c < CH; c++) s += wrow[c] * a[c];
            wga[i] = s;
        }
        return;
    }
    if (b < HB8 + 18) {
        // wfuse: wf[r][c] = sum_k (r<32 ? Win[r][k] : b_in[k]) * Wg0[k][c]
        int idx = (b - HB8 - 1) * 256 + t;
        if (idx >= 33 * HID) return;
        int r = idx >> 7, c = idx & 127;
        float acc = 0.f;
        for (int k = 0; k < HID; k++) {
            float a = (r < 32) ? Win[r * HID + k] : b_in[k];
            acc += a * Wg[(size_t)k * HID + c];
        }
        wf[r * HID + c] = acc;
        return;
    }
    // pack Wg[1..2] (+ head-masked al columns as 9th col-tile) into B-frags
    {
        int idx = (b - HB8 - 18) * 256 + t;   // 0..4607
        if (idx >= 2 * 2304) return;
        int l = idx / 2304;
        int rem = idx % 2304;
        int ks = rem / 576;
        int ct = (rem % 576) / 64;
        int lane = rem % 64;
        int q = lane >> 4, n = lane & 15;
        const float* W = Wg + (size_t)(l + 1) * HID * HID;
        float v[8];
        if (ct < 8) {
            #pragma unroll
            for (int j = 0; j < 8; j++) {
                int k = ks * 32 + q * 8 + j;
                v[j] = W[(size_t)k * HID + ct * 16 + n];
            }
        } else {
            #pragma unroll
            for (int j = 0; j < 8; j++) v[j] = 0.f;
            if (n < 8) {
                const float* a = (n < 4) ? (a_src + (l + 1) * HID + (n & 3) * CH)
                                         : (a_dst + (l + 1) * HID + (n & 3) * CH);
                #pragma unroll
                for (int j = 0; j < 8; j++) {
                    int k = ks * 32 + q * 8 + j;
                    const float* wrow = W + (size_t)k * HID + (n & 3) * CH;
                    float s = 0.f;
                    for (int c = 0; c < CH; c++) s += wrow[c] * a[c];
                    v[j] = s;
                }
            }
        }
        u32* dst = wb + (size_t)l * WB_LSZ + (size_t)((ks * 9 + ct) * 64 + lane) * 4;
        dst[0] = pack2(v[0], v[1]); dst[1] = pack2(v[2], v[3]);
        dst[2] = pack2(v[4], v[5]); dst[3] = pack2(v[6], v[7]);
    }
}

// ---------------------------------------------------------------------------
// Fused dispatch B: single-pass scan (decoupled lookback) || prep2.
// ---------------------------------------------------------------------------
__global__ __launch_bounds__(1024) void scan_prep2_kernel(const int* __restrict__ cnt,
        int* __restrict__ rowptr, int* __restrict__ sums, int* __restrict__ prefixes,
        int* __restrict__ flags,
        const float* __restrict__ Win, const float* __restrict__ b_in,
        const float* __restrict__ wga, float* __restrict__ wf, u32* __restrict__ wb2) {
    if (blockIdx.x >= NB_SCAN) {
        int b = blockIdx.x - NB_SCAN;        // 0..17
        int lane = threadIdx.x;
        if (lane >= 64) return;
        int q = lane >> 4, n = lane & 15;
        if (b == 17) {
            if (lane < 8) {
                float s = 0.f;
                for (int m = 0; m < HID; m++) s += b_in[m] * wga[m * 8 + lane];
                wf[33 * HID + lane] = s;     // bfA
            }
            return;
        }
        float v[8];
        if (b < 8) {
            #pragma unroll
            for (int j = 0; j < 8; j++) v[j] = Win[(q * 8 + j) * HID + b * 16 + n];
        } else if (b < 16) {
            int ct = b - 8;
            #pragma unroll
            for (int j = 0; j < 8; j++) v[j] = wf[(q * 8 + j) * HID + ct * 16 + n];
        } else {                             // al tile: Win @ WgA0
            #pragma unroll
            for (int j = 0; j < 8; j++) v[j] = 0.f;
            if (n < 8) {
                #pragma unroll
                for (int j = 0; j < 8; j++) {
                    const float* wrow = Win + (q * 8 + j) * HID;
                    float s = 0.f;
                    for (int m = 0; m < HID; m++) s += wrow[m] * wga[m * 8 + n];
                    v[j] = s;
                }
            }
        }
        u32* dst = wb2 + (size_t)(b * 64 + lane) * 4;
        dst[0] = pack2(v[0], v[1]); dst[1] = pack2(v[2], v[3]);
        dst[2] = pack2(v[4], v[5]); dst[3] = pack2(v[6], v[7]);
        return;
    }
    // --- scan block ---
    __shared__ int ws[16];
    __shared__ int bprefix;
    int b = blockIdx.x;
    int gid = b * 1024 + threadIdx.x;
    int v = (gid < NN) ? cnt[gid] : 0;
    int lane = threadIdx.x & 63, wid = threadIdx.x >> 6;
    int s = v;
    #pragma unroll
    for (int off = 1; off < 64; off <<= 1) {
        int t2 = __shfl_up(s, off, 64);
        if (lane >= off) s += t2;
    }
    if (lane == 63) ws[wid] = s;
    __syncthreads();
    int add = 0;
    for (int w2 = 0; w2 < wid; w2++) add += ws[w2];
    int incl = s + add;                      // block-local inclusive
    if (threadIdx.x == 0) {
        int total = 0;
        for (int w2 = 0; w2 < 16; w2++) total += ws[w2];
        atomicExch(&sums[b], total);
        __threadfence();
        atomicExch(&flags[b], 1);
        int pfx = 0;
        for (int i = b - 1; i >= 0; i--) {
            int f;
            do { f = atomicAdd(&flags[i], 0); } while (f == 0);
            if (f == 2) { pfx += atomicAdd(&prefixes[i], 0); break; }
            pfx += atomicAdd(&sums[i], 0);
        }
        atomicExch(&prefixes[b], pfx + total);
        __threadfence();
        atomicExch(&flags[b], 2);
        bprefix = pfx;
    }
    __syncthreads();
    int pfx = bprefix;
    if (gid <= NN) rowptr[gid] = pfx + incl - v;   // exclusive
}

// ---------------------------------------------------------------------------
// Fused dispatch C: scatter (blocks 0..SB8-1, 8 edges/thread) || layer-0 MFMA
// GEMM.
// ---------------------------------------------------------------------------
__global__ __launch_bounds__(256) void scatter_ingemm_kernel(
        const int* __restrict__ ei, const float* __restrict__ ea,
        const int* __restrict__ rowptr, const u32* __restrict__ slot,
        uint2* __restrict__ edges,
        const float* __restrict__ x, const u32* __restrict__ wb2,
        const float* __restrict__ wf, const float* __restrict__ b_in,
        u32* __restrict__ h, u32* __restrict__ xh,
        float* __restrict__ al_s, float* __restrict__ al_d) {
    __shared__ u32 xsu[1024];                // used by the in_gemm branch only
    if (blockIdx.x < SB8) {
        int e0 = blockIdx.x * 2048 + threadIdx.x;
        #pragma unroll
        for (int k = 0; k < 8; k++) {
            int e = e0 + k * 256;
            if (e < EE) {
                u32 p = slot[e];
                int d = (int)(p >> 8);
                int pos = rowptr[d] + (int)(p & 255u);
                edges[pos] = make_uint2((u32)ei[e], __float_as_uint(ea[e]));
            }
        }
        return;
    }
    int t = threadIdx.x;
    int wv = t >> 6, lane = t & 63;
    int q = lane >> 4, n16 = lane & 15;
    int n0 = (blockIdx.x - SB8) * 64;
    // stage x -> bf16 A-frags
    {
        int row = t >> 2, qq = t & 3;
        int gr = n0 + row;
        int rt = row >> 4, m = row & 15;
        uint4 op = make_uint4(0u, 0u, 0u, 0u);
        if (gr < NN) {
            float4 vA = *(const float4*)&x[(size_t)gr * 32 + qq * 8];
            float4 vB = *(const float4*)&x[(size_t)gr * 32 + qq * 8 + 4];
            op.x = pack2(vA.x, vA.y); op.y = pack2(vA.z, vA.w);
            op.z = pack2(vB.x, vB.y); op.w = pack2(vB.z, vB.w);
        }
        *(uint4*)&xsu[(rt * 64 + qq * 16 + m) * 4] = op;
    }
    bf16x8 bwin[2], bwf[2], bal;
    #pragma unroll
    for (int cc = 0; cc < 2; cc++) {
        uint4 r0 = *(const uint4*)&wb2[(size_t)(((wv * 2 + cc)) * 64 + lane) * 4];
        uint4 r1 = *(const uint4*)&wb2[(size_t)((8 + wv * 2 + cc) * 64 + lane) * 4];
        bwin[cc] = __builtin_bit_cast(bf16x8, r0);
        bwf[cc]  = __builtin_bit_cast(bf16x8, r1);
    }
    {
        uint4 r = *(const uint4*)&wb2[(size_t)(16 * 64 + lane) * 4];
        bal = __builtin_bit_cast(bf16x8, r);
    }
    __syncthreads();
    f32x4 acch[4][2], accx[4][2], accal[4];
    #pragma unroll
    for (int rt = 0; rt < 4; rt++) {
        acch[rt][0] = (f32x4){0.f, 0.f, 0.f, 0.f};
        acch[rt][1] = (f32x4){0.f, 0.f, 0.f, 0.f};
        accx[rt][0] = (f32x4){0.f, 0.f, 0.f, 0.f};
        accx[rt][1] = (f32x4){0.f, 0.f, 0.f, 0.f};
        accal[rt]   = (f32x4){0.f, 0.f, 0.f, 0.f};
    }
    #pragma unroll
    for (int rt = 0; rt < 4; rt++) {
        uint4 araw = *(const uint4*)&xsu[(rt * 64 + lane) * 4];
        bf16x8 af = __builtin_bit_cast(bf16x8, araw);
        acch[rt][0] = __builtin_amdgcn_mfma_f32_16x16x32_bf16(af, bwin[0], acch[rt][0], 0, 0, 0);
        acch[rt][1] = __builtin_amdgcn_mfma_f32_16x16x32_bf16(af, bwin[1], acch[rt][1], 0, 0, 0);
        accx[rt][0] = __builtin_amdgcn_mfma_f32_16x16x32_bf16(af, bwf[0], accx[rt][0], 0, 0, 0);
        accx[rt][1] = __builtin_amdgcn_mfma_f32_16x16x32_bf16(af, bwf[1], accx[rt][1], 0, 0, 0);
        if (wv == 3)
            accal[rt] = __builtin_amdgcn_mfma_f32_16x16x32_bf16(af, bal, accal[rt], 0, 0, 0);
    }
    float bi[2], bfv[2];
    #pragma unroll
    for (int cc = 0; cc < 2; cc++) {
        int col = (wv * 2 + cc) * 16 + n16;
        bi[cc] = b_in[col];
        bfv[cc] = wf[32 * HID + col];
    }
    float bfa = (wv == 3 && n16 < 8) ? wf[33 * HID + n16] : 0.f;
    #pragma unroll
    for (int rt = 0; rt < 4; rt++) {
        #pragma unroll
        for (int reg = 0; reg < 4; reg++) {
            int row = n0 + rt * 16 + q * 4 + reg;
            #pragma unroll
            for (int cc = 0; cc < 2; cc++) {
                float v = acch[rt][cc][reg] + bi[cc];
                float vp = __shfl_xor(v, 1, 64);
                float u = accx[rt][cc][reg] + bfv[cc];
                float up = __shfl_xor(u, 1, 64);
                if (!(n16 & 1) && row < NN) {
                    int colp = (wv * 2 + cc) * 8 + (n16 >> 1);
                    h[(size_t)row * HQ + colp] = pack2(v, vp);
                    xh[(size_t)row * HQ + colp] = pack2(u, up);
                }
            }
            if (wv == 3 && row < NN && n16 < 8) {
                float v = accal[rt][reg] + bfa;
                if (n16 < 4) al_s[row * 4 + n16] = v;
                else         al_d[row * 4 + (n16 - 4)] = v;
            }
        }
    }
}

// ---------------------------------------------------------------------------
// Layers 1..2 via MFMA; LN stats reduced inline from the previous layer's
// partials buffer.
// ---------------------------------------------------------------------------
__global__ __launch_bounds__(256) void gemm_mfma_kernel(const u32* __restrict__ h,
        const u32* __restrict__ wb, u32* __restrict__ xh, const u32* __restrict__ g,
        const float* __restrict__ lnw, const float* __restrict__ lnb,
        const float* __restrict__ partials, u32* __restrict__ hout,
        float* __restrict__ al_s, float* __restrict__ al_d) {
    __shared__ u32 hsu[4096];                // 16KB, frag-ordered [rt][ks][lane][4]
    __shared__ float sred[8];
    int n0 = blockIdx.x * 64;
    int t = threadIdx.x;
    int wv = t >> 6, lane = t & 63;
    int q = lane >> 4, n16 = lane & 15;

    {
        const float4* pp = (const float4*)partials;
        float4 v0 = pp[t * 2], v1 = pp[t * 2 + 1];
        float s = v0.x + v0.z + v1.x + v1.z;
        float qq = v0.y + v0.w + v1.y + v1.w;
        #pragma unroll
        for (int off = 1; off <= 32; off <<= 1) {
            s += __shfl_xor(s, off, 64);
            qq += __shfl_xor(qq, off, 64);
        }
        if (lane == 0) { sred[wv * 2] = s; sred[wv * 2 + 1] = qq; }
    }
    __syncthreads();
    float S = sred[0] + sred[2] + sred[4] + sred[6];
    float Q = sred[1] + sred[3] + sred[5] + sred[7];
    const float M = (float)NN * (float)HID;
    float mean = S / M;
    float rstd = rsqrtf(fmaxf(Q / M - mean * mean, 0.f) + LN_EPS);

    bf16x8 bfrag[2][4];
    #pragma unroll
    for (int ks = 0; ks < 4; ks++) {
        #pragma unroll
        for (int cc = 0; cc < 2; cc++) {
            int ct = wv * 2 + cc;
            uint4 r = *(const uint4*)&wb[(size_t)((ks * 9 + ct) * 64 + lane) * 4];
            bfrag[cc][ks] = __builtin_bit_cast(bf16x8, r);
        }
    }
    bf16x8 bal[4];
    #pragma unroll
    for (int ks = 0; ks < 4; ks++) {
        uint4 r = *(const uint4*)&wb[(size_t)((ks * 9 + 8) * 64 + lane) * 4];
        bal[ks] = __builtin_bit_cast(bf16x8, r);
    }

    {
        int row = t >> 2;
        int qq = t & 3;
        int gr = n0 + row;
        int rt = row >> 4, m = row & 15;
        #pragma unroll
        for (int ks = 0; ks < 4; ks++) {
            int kk = ks * 32 + qq * 8;
            uint4 op = make_uint4(0u, 0u, 0u, 0u);
            if (gr < NN) {
                size_t base = (size_t)gr * HQ + (kk >> 1);
                uint4 gp = *(const uint4*)&g[base];
                uint4 hp = *(const uint4*)&h[base];
                float4 wA = *(const float4*)&lnw[kk];
                float4 wB = *(const float4*)&lnw[kk + 4];
                float4 bA = *(const float4*)&lnb[kk];
                float4 bB = *(const float4*)&lnb[kk + 4];
                float v0 = fmaxf((bflo(gp.x) - mean) * rstd * wA.x + bA.x + bflo(hp.x), 0.f);
                float v1 = fmaxf((bfhi(gp.x) - mean) * rstd * wA.y + bA.y + bfhi(hp.x), 0.f);
                float v2 = fmaxf((bflo(gp.y) - mean) * rstd * wA.z + bA.z + bflo(hp.y), 0.f);
                float v3 = fmaxf((bfhi(gp.y) - mean) * rstd * wA.w + bA.w + bfhi(hp.y), 0.f);
                float v4 = fmaxf((bflo(gp.z) - mean) * rstd * wB.x + bB.x + bflo(hp.z), 0.f);
                float v5 = fmaxf((bfhi(gp.z) - mean) * rstd * wB.y + bB.y + bfhi(hp.z), 0.f);
                float v6 = fmaxf((bflo(gp.w) - mean) * rstd * wB.z + bB.z + bflo(hp.w), 0.f);
                float v7 = fmaxf((bfhi(gp.w) - mean) * rstd * wB.w + bB.w + bfhi(hp.w), 0.f);
                op.x = pack2(v0, v1); op.y = pack2(v2, v3);
                op.z = pack2(v4, v5); op.w = pack2(v6, v7);
                *(uint4*)&hout[base] = op;
            }
            *(uint4*)&hsu[((rt * 4 + ks) * 64 + qq * 16 + m) * 4] = op;
        }
    }
    __syncthreads();

    f32x4 acc[4][2];
    f32x4 accal[4];
    #pragma unroll
    for (int rt = 0; rt < 4; rt++) {
        acc[rt][0] = (f32x4){0.f, 0.f, 0.f, 0.f};
        acc[rt][1] = (f32x4){0.f, 0.f, 0.f, 0.f};
        accal[rt]  = (f32x4){0.f, 0.f, 0.f, 0.f};
    }
    #pragma unroll
    for (int rt = 0; rt < 4; rt++) {
        #pragma unroll
        for (int ks = 0; ks < 4; ks++) {
            uint4 araw = *(const uint4*)&hsu[((rt * 4 + ks) * 64 + lane) * 4];
            bf16x8 af = __builtin_bit_cast(bf16x8, araw);
            acc[rt][0] = __builtin_amdgcn_mfma_f32_16x16x32_bf16(af, bfrag[0][ks], acc[rt][0], 0, 0, 0);
            acc[rt][1] = __builtin_amdgcn_mfma_f32_16x16x32_bf16(af, bfrag[1][ks], acc[rt][1], 0, 0, 0);
            if (wv == 3)
                accal[rt] = __builtin_amdgcn_mfma_f32_16x16x32_bf16(af, bal[ks], accal[rt], 0, 0, 0);
        }
    }

    #pragma unroll
    for (int rt = 0; rt < 4; rt++) {
        #pragma unroll
        for (int reg = 0; reg < 4; reg++) {
            int row = n0 + rt * 16 + q * 4 + reg;
            #pragma unroll
            for (int cc = 0; cc < 2; cc++) {
                float v = acc[rt][cc][reg];
                float vp = __shfl_xor(v, 1, 64);
                if (!(n16 & 1) && row < NN) {
                    int colp = (wv * 2 + cc) * 8 + (n16 >> 1);
                    xh[(size_t)row * HQ + colp] = pack2(v, vp);
                }
            }
            if (wv == 3 && row < NN && n16 < 8) {
                float v = accal[rt][reg];
                if (n16 < 4) al_s[row * 4 + n16] = v;
                else         al_d[row * 4 + (n16 - 4)] = v;
            }
        }
    }
}

// ---------------------------------------------------------------------------
// GAT aggregation v6: one wave = 8 consecutive nodes (full pass-1 lane
// utilization). Pass 2: 8 lanes/node x 16 channels (2 uint4 per edge),
// 2x unrolled -> 4 loads in flight. den redundant per node; synthetic
// self-loops; rowptr broadcast via shfl.
// ---------------------------------------------------------------------------
__global__ __launch_bounds__(256) void gat_agg_kernel(const int* __restrict__ rowptr,
        const uint2* __restrict__ edges, const u32* __restrict__ xh,
        const float* __restrict__ al_s, const float* __restrict__ al_d,
        const float* __restrict__ wedot, const float* __restrict__ bg,
        u32* __restrict__ g, float* __restrict__ partials) {
    __shared__ float lds_ex[4][GCAP * 4];
    __shared__ float lds_ea[4][GCAP];
    __shared__ int lds_src[4][GCAP];
    int wv = threadIdx.x >> 6, lane = threadIdx.x & 63;
    int base = (blockIdx.x * 4 + wv) * 8;
    if (base >= NN) return;
    float* ex_w = lds_ex[wv];
    float* ea_w = lds_ea[wv];
    int* src_w = lds_src[wv];
    // rowptr[base..base+8] via 9-lane load + shfl broadcast
    int rv = 0;
    if (lane < 9) {
        int idx = base + lane;
        rv = rowptr[idx < NN ? idx : NN];
    }
    int r0 = __shfl(rv, 0, 64), r1 = __shfl(rv, 1, 64), r2 = __shfl(rv, 2, 64);
    int r3 = __shfl(rv, 3, 64), r4 = __shfl(rv, 4, 64), r5 = __shfl(rv, 5, 64);
    int r6 = __shfl(rv, 6, 64), r7 = __shfl(rv, 7, 64), r8 = __shfl(rv, 8, 64);
    int span = r8 - r0;
    int ncached = span < GCAP ? span : GCAP;
    float wd0 = wedot[0], wd1 = wedot[1], wd2 = wedot[2], wd3 = wedot[3];

    // Pass 1: logits+exp (+ea cache) for the whole 8-node span, lane-parallel
    for (int i = lane; i < ncached; i += 64) {
        int gi = r0 + i;
        uint2 e = edges[gi];
        int s = (int)e.x;
        float eav = __uint_as_float(e.y);
        int d = (gi >= r1) + (gi >= r2) + (gi >= r3) + (gi >= r4)
              + (gi >= r5) + (gi >= r6) + (gi >= r7);
        float4 aldv = *(const float4*)&al_d[(base + d) * 4];
        float4 als = *(const float4*)&al_s[s * 4];
        float e0 = __expf(lrelu(als.x + aldv.x + eav * wd0));
        float e1 = __expf(lrelu(als.y + aldv.y + eav * wd1));
        float e2 = __expf(lrelu(als.z + aldv.z + eav * wd2));
        float e3 = __expf(lrelu(als.w + aldv.w + eav * wd3));
        src_w[i] = s;
        ea_w[i] = eav;
        *(float4*)&ex_w[i * 4] = make_float4(e0, e1, e2, e3);
    }
    // wave-private LDS rows; same-wave ops in order -> no barrier

    // Pass 2: 8 lanes per node, 16 channels each (2 uint4 per edge), 2x unroll
    int nl = lane >> 3, cg = lane & 7;
    int n = base + nl;
    bool nvalid = n < NN;
    int lsv, lev;
    {
        // ls = r[nl]-r0, le = r[nl+1]-r0 via selects
        int ra = nl == 0 ? r0 : nl == 1 ? r1 : nl == 2 ? r2 : nl == 3 ? r3
               : nl == 4 ? r4 : nl == 5 ? r5 : nl == 6 ? r6 : r7;
        int rb = nl == 0 ? r1 : nl == 1 ? r2 : nl == 2 ? r3 : nl == 3 ? r4
               : nl == 4 ? r5 : nl == 5 ? r6 : nl == 6 ? r7 : r8;
        lsv = ra - r0; lev = rb - r0;
    }
    int lec = lev < ncached ? lev : ncached;
    int head = cg >> 1;
    int c8 = cg * 8;                          // u32 offset of lane's 16 channels
    float wdh = head == 0 ? wd0 : head == 1 ? wd1 : head == 2 ? wd2 : wd3;
    float a0 = 0.f, a1 = 0.f, a2 = 0.f, a3 = 0.f;
    float a4 = 0.f, a5 = 0.f, a6 = 0.f, a7 = 0.f;
    float a8 = 0.f, a9 = 0.f, aA = 0.f, aB = 0.f;
    float aC = 0.f, aD = 0.f, aE = 0.f, aF = 0.f;
    float den = 0.f, easum = 0.f;
    int j = lsv;
    for (; j + 1 < lec; j += 2) {             // 4 uint4 loads in flight
        int s0 = src_w[j], s1 = src_w[j + 1];
        float e0 = ex_w[j * 4 + head], e1 = ex_w[(j + 1) * 4 + head];
        const u32* p0 = &xh[(size_t)s0 * HQ + c8];
        const u32* p1 = &xh[(size_t)s1 * HQ + c8];
        uint4 x0a = *(const uint4*)p0, x0b = *(const uint4*)(p0 + 4);
        uint4 x1a = *(const uint4*)p1, x1b = *(const uint4*)(p1 + 4);
        den += e0 + e1;
        easum += ea_w[j] + ea_w[j + 1];
        a0 += e0 * bflo(x0a.x); a1 += e0 * bfhi(x0a.x);
        a2 += e0 * bflo(x0a.y); a3 += e0 * bfhi(x0a.y);
        a4 += e0 * bflo(x0a.z); a5 += e0 * bfhi(x0a.z);
        a6 += e0 * bflo(x0a.w); a7 += e0 * bfhi(x0a.w);
        a8 += e0 * bflo(x0b.x); a9 += e0 * bfhi(x0b.x);
        aA += e0 * bflo(x0b.y); aB += e0 * bfhi(x0b.y);
        aC += e0 * bflo(x0b.z); aD += e0 * bfhi(x0b.z);
        aE += e0 * bflo(x0b.w); aF += e0 * bfhi(x0b.w);
        a0 += e1 * bflo(x1a.x); a1 += e1 * bfhi(x1a.x);
        a2 += e1 * bflo(x1a.y); a3 += e1 * bfhi(x1a.y);
        a4 += e1 * bflo(x1a.z); a5 += e1 * bfhi(x1a.z);
        a6 += e1 * bflo(x1a.w); a7 += e1 * bfhi(x1a.w);
        a8 += e1 * bflo(x1b.x); a9 += e1 * bfhi(x1b.x);
        aA += e1 * bflo(x1b.y); aB += e1 * bfhi(x1b.y);
        aC += e1 * bflo(x1b.z); aD += e1 * bfhi(x1b.z);
        aE += e1 * bflo(x1b.w); aF += e1 * bfhi(x1b.w);
    }
    if (j < lec) {
        int s0 = src_w[j];
        float e0 = ex_w[j * 4 + head];
        const u32* p0 = &xh[(size_t)s0 * HQ + c8];
        uint4 x0a = *(const uint4*)p0, x0b = *(const uint4*)(p0 + 4);
        den += e0;
        easum += ea_w[j];
        a0 += e0 * bflo(x0a.x); a1 += e0 * bfhi(x0a.x);
        a2 += e0 * bflo(x0a.y); a3 += e0 * bfhi(x0a.y);
        a4 += e0 * bflo(x0a.z); a5 += e0 * bfhi(x0a.z);
        a6 += e0 * bflo(x0a.w); a7 += e0 * bfhi(x0a.w);
        a8 += e0 * bflo(x0b.x); a9 += e0 * bfhi(x0b.x);
        aA += e0 * bflo(x0b.y); aB += e0 * bfhi(x0b.y);
        aC += e0 * bflo(x0b.z); aD += e0 * bfhi(x0b.z);
        aE += e0 * bflo(x0b.w); aF += e0 * bfhi(x0b.w);
        j++;
    }
    // tail beyond LDS cache (rare): recompute logits for this head
    if (lev > lec && nvalid) {
        float aldh = al_d[n * 4 + head];
        for (int jt = (lsv > lec ? lsv : lec); jt < lev; jt++) {
            uint2 e = edges[r0 + jt];
            int s = (int)e.x;
            float eav = __uint_as_float(e.y);
            float ex = __expf(lrelu(al_s[s * 4 + head] + aldh + eav * wdh));
            den += ex;
            easum += eav;
            const u32* p0 = &xh[(size_t)s * HQ + c8];
            uint4 x0a = *(const uint4*)p0, x0b = *(const uint4*)(p0 + 4);
            a0 += ex * bflo(x0a.x); a1 += ex * bfhi(x0a.x);
            a2 += ex * bflo(x0a.y); a3 += ex * bfhi(x0a.y);
            a4 += ex * bflo(x0a.z); a5 += ex * bfhi(x0a.z);
            a6 += ex * bflo(x0a.w); a7 += ex * bfhi(x0a.w);
            a8 += ex * bflo(x0b.x); a9 += ex * bfhi(x0b.x);
            aA += ex * bflo(x0b.y); aB += ex * bfhi(x0b.y);
            aC += ex * bflo(x0b.z); aD += ex * bfhi(x0b.z);
            aE += ex * bflo(x0b.w); aF += ex * bfhi(x0b.w);
        }
    }
    // synthetic self-loop: attr = mean of real edge attrs (PyG fill='mean')
    if (nvalid) {
        float mea = easum / fmaxf((float)(lev - lsv), 1.0f);
        float alh = al_s[n * 4 + head] + al_d[n * 4 + head];
        float ex = __expf(lrelu(alh + mea * wdh));
        den += ex;
        const u32* p0 = &xh[(size_t)n * HQ + c8];
        uint4 x0a = *(const uint4*)p0, x0b = *(const uint4*)(p0 + 4);
        a0 += ex * bflo(x0a.x); a1 += ex * bfhi(x0a.x);
        a2 += ex * bflo(x0a.y); a3 += ex * bfhi(x0a.y);
        a4 += ex * bflo(x0a.z); a5 += ex * bfhi(x0a.z);
        a6 += ex * bflo(x0a.w); a7 += ex * bfhi(x0a.w);
        a8 += ex * bflo(x0b.x); a9 += ex * bfhi(x0b.x);
        aA += ex * bflo(x0b.y); aB += ex * bfhi(x0b.y);
        aC += ex * bflo(x0b.z); aD += ex * bfhi(x0b.z);
        aE += ex * bflo(x0b.w); aF += ex * bfhi(x0b.w);
    }

    float inv = 1.0f / (den + 1e-16f);
    int c0 = cg * 16;
    float4 bg0 = *(const float4*)&bg[c0];
    float4 bg1 = *(const float4*)&bg[c0 + 4];
    float4 bg2 = *(const float4*)&bg[c0 + 8];
    float4 bg3 = *(const float4*)&bg[c0 + 12];
    float o0 = a0 * inv + bg0.x, o1 = a1 * inv + bg0.y;
    float o2 = a2 * inv + bg0.z, o3 = a3 * inv + bg0.w;
    float o4 = a4 * inv + bg1.x, o5 = a5 * inv + bg1.y;
    float o6 = a6 * inv + bg1.z, o7 = a7 * inv + bg1.w;
    float o8 = a8 * inv + bg2.x, o9 = a9 * inv + bg2.y;
    float oA = aA * inv + bg2.z, oB = aB * inv + bg2.w;
    float oC = aC * inv + bg3.x, oD = aD * inv + bg3.y;
    float oE = aE * inv + bg3.z, oF = aF * inv + bg3.w;
    float ss = 0.f, sq = 0.f;
    if (nvalid) {
        uint4 opA, opB;
        opA.x = pack2(o0, o1); opA.y = pack2(o2, o3);
        opA.z = pack2(o4, o5); opA.w = pack2(o6, o7);
        opB.x = pack2(o8, o9); opB.y = pack2(oA, oB);
        opB.z = pack2(oC, oD); opB.w = pack2(oE, oF);
        *(uint4*)&g[(size_t)n * HQ + c8] = opA;
        *(uint4*)&g[(size_t)n * HQ + c8 + 4] = opB;
        ss = o0 + o1 + o2 + o3 + o4 + o5 + o6 + o7
           + o8 + o9 + oA + oB + oC + oD + oE + oF;
        sq = o0 * o0 + o1 * o1 + o2 * o2 + o3 * o3
           + o4 * o4 + o5 * o5 + o6 * o6 + o7 * o7
           + o8 * o8 + o9 * o9 + oA * oA + oB * oB
           + oC * oC + oD * oD + oE * oE + oF * oF;
    }
    #pragma unroll
    for (int off = 1; off <= 32; off <<= 1) {
        ss += __shfl_xor(ss, off, 64);
        sq += __shfl_xor(sq, off, 64);
    }
    if (lane == 0) {
        int sl = ((blockIdx.x * 4 + wv) & 1023) * 2;
        atomicAdd(&partials[sl], ss);
        atomicAdd(&partials[sl + 1], sq);
    }
}

// final: out = relu(LN(g)+h) @ Wout + bout.  LN stats reduced inline.
__global__ __launch_bounds__(256) void ln_out_kernel(const u32* __restrict__ g,
        const u32* __restrict__ h, const float* __restrict__ lnw,
        const float* __restrict__ lnb, const float* __restrict__ partials,
        const float* __restrict__ Wout, const float* __restrict__ bout,
        float* __restrict__ out) {
    __shared__ float wsh[HID * NOUT];
    __shared__ float sred[8];
    int t = threadIdx.x;
    int wv = t >> 6, lane = t & 63;
    {
        const float4* pp = (const float4*)partials;
        float4 v0 = pp[t * 2], v1 = pp[t * 2 + 1];
        float s = v0.x + v0.z + v1.x + v1.z;
        float qq = v0.y + v0.w + v1.y + v1.w;
        #pragma unroll
        for (int off = 1; off <= 32; off <<= 1) {
            s += __shfl_xor(s, off, 64);
            qq += __shfl_xor(qq, off, 64);
        }
        if (lane == 0) { sred[wv * 2] = s; sred[wv * 2 + 1] = qq; }
    }
    for (int i = t; i < HID * NOUT; i += 256) wsh[i] = Wout[i];
    __syncthreads();
    float S = sred[0] + sred[2] + sred[4] + sred[6];
    float Q = sred[1] + sred[3] + sred[5] + sred[7];
    const float M = (float)NN * (float)HID;
    float mean = S / M;
    float rstd = rsqrtf(fmaxf(Q / M - mean * mean, 0.f) + LN_EPS);

    int nl = lane >> 4, cg = lane & 15;
    int n = (blockIdx.x * 4 + wv) * 4 + nl;
    bool nvalid = n < NN;
    float p[NOUT] = {};
    if (nvalid) {
        int c0 = cg * 8;
        uint4 gv = *(const uint4*)&g[(size_t)n * HQ + cg * 4];
        uint4 hv = *(const uint4*)&h[(size_t)n * HQ + cg * 4];
        float4 wA = *(const float4*)&lnw[c0], wB = *(const float4*)&lnw[c0 + 4];
        float4 bA = *(const float4*)&lnb[c0], bB = *(const float4*)&lnb[c0 + 4];
        float o[8];
        o[0] = fmaxf((bflo(gv.x) - mean) * rstd * wA.x + bA.x + bflo(hv.x), 0.f);
        o[1] = fmaxf((bfhi(gv.x) - mean) * rstd * wA.y + bA.y + bfhi(hv.x), 0.f);
        o[2] = fmaxf((bflo(gv.y) - mean) * rstd * wA.z + bA.z + bflo(hv.y), 0.f);
        o[3] = fmaxf((bfhi(gv.y) - mean) * rstd * wA.w + bA.w + bfhi(hv.y), 0.f);
        o[4] = fmaxf((bflo(gv.z) - mean) * rstd * wB.x + bB.x + bflo(hv.z), 0.f);
        o[5] = fmaxf((bfhi(gv.z) - mean) * rstd * wB.y + bB.y + bfhi(hv.z), 0.f);
        o[6] = fmaxf((bflo(gv.w) - mean) * rstd * wB.z + bB.z + bflo(hv.w), 0.f);
        o[7] = fmaxf((bfhi(gv.w) - mean) * rstd * wB.w + bB.w + bfhi(hv.w), 0.f);
        #pragma unroll
        for (int jj = 0; jj < NOUT; jj++) {
            float acc = 0.f;
            #pragma unroll
            for (int k = 0; k < 8; k++) acc += o[k] * wsh[(c0 + k) * NOUT + jj];
            p[jj] = acc;
        }
    }
    #pragma unroll
    for (int off = 1; off <= 8; off <<= 1) {
        #pragma unroll
        for (int jj = 0; jj < NOUT; jj++) p[jj] += __shfl_xor(p[jj], off, 64);
    }
    if (cg == 0 && nvalid) {
        #pragma unroll
        for (int jj = 0; jj < NOUT; jj++)
            out[(size_t)n * NOUT + jj] = p[jj] + bout[jj];
    }
}

// ---------------------------------------------------------------------------
extern "C" void kernel_launch(void* const* d_in, const int* in_sizes, int n_in,
                              void* d_out, int out_size, void* d_ws, size_t ws_size,
                              hipStream_t stream) {
    const float* x      = (const float*)d_in[0];
    const int*   ei     = (const int*)d_in[1];
    const float* ea     = (const float*)d_in[2];
    const float* Win    = (const float*)d_in[3];
    const float* b_in   = (const float*)d_in[4];
    const float* Wg     = (const float*)d_in[5];
    const float* bg     = (const float*)d_in[6];
    const float* a_src  = (const float*)d_in[7];
    const float* a_dst  = (const float*)d_in[8];
    const float* We     = (const float*)d_in[9];
    const float* a_edge = (const float*)d_in[10];
    const float* ln_w   = (const float*)d_in[11];
    const float* ln_b   = (const float*)d_in[12];
    const float* Wout   = (const float*)d_in[13];
    const float* bout   = (const float*)d_in[14];
    float* out = (float*)d_out;

    char* w = (char*)d_ws;
    size_t off = 0;
    auto alloc = [&](size_t bytes) -> void* {
        void* p = w + off;
        off = (off + bytes + 255) & ~(size_t)255;
        return p;
    };
    // zeroed region first (one memset): cnt + partials + scan state
    int*   cnt      = (int*)alloc(NN * sizeof(int));
    float* partials = (float*)alloc(3 * 2048 * sizeof(float));
    int*   sums     = (int*)alloc(NB_SCAN * sizeof(int));
    int*   prefixes = (int*)alloc(NB_SCAN * sizeof(int));
    int*   flags    = (int*)alloc(NB_SCAN * sizeof(int));
    size_t zero_span = off;
    u32*   slot    = (u32*)alloc((size_t)EE * sizeof(u32));
    int*   rowptr  = (int*)alloc((NN + 1) * sizeof(int));
    uint2* edges   = (uint2*)alloc((size_t)EE * sizeof(uint2));
    u32*   h       = (u32*)alloc((size_t)NN * HQ * sizeof(u32));
    u32*   g       = (u32*)alloc((size_t)NN * HQ * sizeof(u32));
    u32*   xh      = (u32*)alloc((size_t)NN * HQ * sizeof(u32));
    float* al_s    = (float*)alloc((size_t)NN * NH * sizeof(float));
    float* al_d    = (float*)alloc((size_t)NN * NH * sizeof(float));
    float* wedot   = (float*)alloc(16 * sizeof(float));
    float* wf      = (float*)alloc(34 * HID * sizeof(float));
    float* wga     = (float*)alloc(HID * 8 * sizeof(float));
    u32*   wb      = (u32*)alloc((size_t)2 * WB_LSZ * sizeof(u32));
    u32*   wb2     = (u32*)alloc(17 * 64 * 4 * sizeof(u32));
    (void)ws_size; (void)n_in; (void)in_sizes; (void)out_size;

    hipMemsetAsync(d_ws, 0, zero_span, stream);
    // A: hist (8 edges/thread) || weight prep
    hist_prep_kernel<<<HB8 + 36, 256, 0, stream>>>(ei, cnt, slot, We, a_edge, wedot,
                                                   Win, b_in, Wg, wf, a_src, a_dst,
                                                   wb, wga);
    // B: single-pass scan (decoupled lookback) || prep2
    scan_prep2_kernel<<<NB_SCAN + 18, 1024, 0, stream>>>(cnt, rowptr, sums, prefixes,
                                                         flags, Win, b_in, wga, wf, wb2);
    // C: scatter (8 edges/thread) || layer-0 MFMA GEMM
    scatter_ingemm_kernel<<<SB8 + NG64, 256, 0, stream>>>(ei, ea, rowptr, slot, edges,
                                                          x, wb2, wf, b_in, h, xh,
                                                          al_s, al_d);
    for (int l = 0; l < NL; l++) {
        if (l > 0) {
            gemm_mfma_kernel<<<NG64, 256, 0, stream>>>(
                h, wb + (size_t)(l - 1) * WB_LSZ, xh, g,
                ln_w + (size_t)(l - 1) * HID, ln_b + (size_t)(l - 1) * HID,
                partials + (size_t)(l - 1) * 2048, h, al_s, al_d);
        }
        gat_agg_kernel<<<(NN + 31) / 32, 256, 0, stream>>>(
            rowptr, edges, xh, al_s, al_d, wedot + l * 4,
            bg + (size_t)l * HID, g, partials + (size_t)l * 2048);
    }

    ln_out_kernel<<<(NN + 15) / 16, 256, 0, stream>>>(g, h, ln_w + (size_t)2 * HID,
                                                      ln_b + (size_t)2 * HID,
                                                      partials + 2 * 2048, Wout, bout, out);
}